// Round 9
// baseline (354.011 us; speedup 1.0000x reference)
//
#include <hip/hip_runtime.h>
#include <hip/hip_bf16.h>

// Problem constants
#define DMODEL 1024
#define DIN    2048
#define NH     32
#define HD     64
#define DS     64
#define LSEQ   1024
#define BB     2
#define DTOT   5312           // 2*DIN + 2*64 + 32 + 1024 + 32
#define ROWS   (BB*LSEQ)      // 2048
// column offsets inside zxbcdt
#define OFF_Z   0
#define OFF_X   2048
#define OFF_BR  4096
#define OFF_CR  4160
#define OFF_DT  4224
#define OFF_TH  4256
#define OFF_LAM 5280
#define NZX     4096          // z+x columns done in single-pass bf16 MFMA
#define NREM    (DTOT - NZX)  // 1216 cols done in 3-pass split-bf16 MFMA

typedef short  s16x8 __attribute__((ext_vector_type(8)));
typedef float  f32x4 __attribute__((ext_vector_type(4)));

__device__ __forceinline__ unsigned int f2bf(float f) {   // RNE f32->bf16 (finite inputs)
    unsigned int u = __float_as_uint(f);
    u += 0x7fffu + ((u >> 16) & 1u);
    return u >> 16;
}
// pack two floats to bf16x2
__device__ __forceinline__ unsigned int pk(float x, float y) {
    return f2bf(x) | (f2bf(y) << 16);
}
// split two floats into bf16x2 hi + bf16x2 lo (residual)
__device__ __forceinline__ void split2(float x, float y, unsigned int& h, unsigned int& l) {
    const unsigned int hx = f2bf(x), hy = f2bf(y);
    h = hx | (hy << 16);
    l = pk(x - __uint_as_float(hx << 16), y - __uint_as_float(hy << 16));
}

// ---------------------------------------------------------------------------
// bf16 MFMA GEMM, z/x block: zx[:, 0:4096] = u @ W[0:4096,:]^T
// 128x128 tile, BK=32, 4 waves (2x2), wave = 64x64 out.
// ---------------------------------------------------------------------------
#define LDB 40
__global__ __launch_bounds__(256) void mfma_gemm_zx(const float* __restrict__ u,
                                                    const float* __restrict__ W,
                                                    float* __restrict__ zx) {
    __shared__ unsigned short Al[128][LDB];
    __shared__ unsigned short Bl[128][LDB];
    const int tid = threadIdx.x;
    const int m0 = blockIdx.y * 128, n0 = blockIdx.x * 128;
    const int lane = tid & 63, wave = tid >> 6;
    const int wr = wave >> 1, wc = wave & 1;
    const int lr = lane >> 4, lc = lane & 15;
    const int r  = tid >> 2;
    const int cb = (tid & 3) * 8;

    f32x4 acc[4][4] = {};

    const float* uA = u + (size_t)(m0 + r) * DMODEL + cb;
    const float* uB = W + (size_t)(n0 + r) * DMODEL + cb;

    for (int k0 = 0; k0 < DMODEL; k0 += 32) {
        const float4 a0 = *(const float4*)(uA + k0);
        const float4 a1 = *(const float4*)(uA + k0 + 4);
        const float4 a2 = *(const float4*)(uA + k0 + (size_t)64 * DMODEL);
        const float4 a3 = *(const float4*)(uA + k0 + (size_t)64 * DMODEL + 4);
        const float4 b0 = *(const float4*)(uB + k0);
        const float4 b1 = *(const float4*)(uB + k0 + 4);
        const float4 b2 = *(const float4*)(uB + k0 + (size_t)64 * DMODEL);
        const float4 b3 = *(const float4*)(uB + k0 + (size_t)64 * DMODEL + 4);
        __syncthreads();
        uint4 q;
        q.x = pk(a0.x, a0.y); q.y = pk(a0.z, a0.w); q.z = pk(a1.x, a1.y); q.w = pk(a1.z, a1.w);
        *(uint4*)&Al[r][cb] = q;
        q.x = pk(a2.x, a2.y); q.y = pk(a2.z, a2.w); q.z = pk(a3.x, a3.y); q.w = pk(a3.z, a3.w);
        *(uint4*)&Al[r + 64][cb] = q;
        q.x = pk(b0.x, b0.y); q.y = pk(b0.z, b0.w); q.z = pk(b1.x, b1.y); q.w = pk(b1.z, b1.w);
        *(uint4*)&Bl[r][cb] = q;
        q.x = pk(b2.x, b2.y); q.y = pk(b2.z, b2.w); q.z = pk(b3.x, b3.y); q.w = pk(b3.z, b3.w);
        *(uint4*)&Bl[r + 64][cb] = q;
        __syncthreads();
        s16x8 af[4], bf[4];
        #pragma unroll
        for (int f = 0; f < 4; ++f) {
            af[f] = *(const s16x8*)&Al[wr * 64 + f * 16 + lc][lr * 8];
            bf[f] = *(const s16x8*)&Bl[wc * 64 + f * 16 + lc][lr * 8];
        }
        #pragma unroll
        for (int fm = 0; fm < 4; ++fm)
            #pragma unroll
            for (int fn = 0; fn < 4; ++fn)
                acc[fm][fn] = __builtin_amdgcn_mfma_f32_16x16x32_bf16(
                    af[fm], bf[fn], acc[fm][fn], 0, 0, 0);
    }

    #pragma unroll
    for (int fm = 0; fm < 4; ++fm)
        #pragma unroll
        for (int fn = 0; fn < 4; ++fn) {
            const size_t col = n0 + wc * 64 + fn * 16 + lc;
            #pragma unroll
            for (int j = 0; j < 4; ++j) {
                const size_t row = m0 + wr * 64 + fm * 16 + lr * 4 + j;
                zx[row * DTOT + col] = acc[fm][fn][j];
            }
        }
}

// ---------------------------------------------------------------------------
// bf16 MFMA GEMM, generic 128x64 tile single-pass: C = A[M][K] @ B[N][K]^T
// 4 waves (2x2), wave = 64x32 out. Used for out_proj (N=1024, K=2048).
// ---------------------------------------------------------------------------
__global__ __launch_bounds__(256) void mfma_gemm_out(const float* __restrict__ A,
                                                     const float* __restrict__ B,
                                                     float* __restrict__ C,
                                                     int K, int ldc) {
    __shared__ unsigned short Als[128][LDB];
    __shared__ unsigned short Bls[64][LDB];
    const int tid = threadIdx.x;
    const int m0 = blockIdx.y * 128, n0 = blockIdx.x * 64;
    const int lane = tid & 63, wave = tid >> 6;
    const int wr = wave >> 1, wc = wave & 1;
    const int lr = lane >> 4, lc = lane & 15;
    const int r  = tid >> 2;
    const int cb = (tid & 3) * 8;

    f32x4 acc[4][2] = {};

    const float* pA = A + (size_t)(m0 + r) * K + cb;
    const float* pB = B + (size_t)(n0 + r) * K + cb;

    for (int k0 = 0; k0 < K; k0 += 32) {
        const float4 a0 = *(const float4*)(pA + k0);
        const float4 a1 = *(const float4*)(pA + k0 + 4);
        const float4 a2 = *(const float4*)(pA + k0 + (size_t)64 * K);
        const float4 a3 = *(const float4*)(pA + k0 + (size_t)64 * K + 4);
        const float4 b0 = *(const float4*)(pB + k0);
        const float4 b1 = *(const float4*)(pB + k0 + 4);
        __syncthreads();
        uint4 q;
        q.x = pk(a0.x, a0.y); q.y = pk(a0.z, a0.w); q.z = pk(a1.x, a1.y); q.w = pk(a1.z, a1.w);
        *(uint4*)&Als[r][cb] = q;
        q.x = pk(a2.x, a2.y); q.y = pk(a2.z, a2.w); q.z = pk(a3.x, a3.y); q.w = pk(a3.z, a3.w);
        *(uint4*)&Als[r + 64][cb] = q;
        q.x = pk(b0.x, b0.y); q.y = pk(b0.z, b0.w); q.z = pk(b1.x, b1.y); q.w = pk(b1.z, b1.w);
        *(uint4*)&Bls[r][cb] = q;
        __syncthreads();
        s16x8 af[4], bf[2];
        #pragma unroll
        for (int f = 0; f < 4; ++f)
            af[f] = *(const s16x8*)&Als[wr * 64 + f * 16 + lc][lr * 8];
        #pragma unroll
        for (int f = 0; f < 2; ++f)
            bf[f] = *(const s16x8*)&Bls[wc * 32 + f * 16 + lc][lr * 8];
        #pragma unroll
        for (int fm = 0; fm < 4; ++fm)
            #pragma unroll
            for (int fn = 0; fn < 2; ++fn)
                acc[fm][fn] = __builtin_amdgcn_mfma_f32_16x16x32_bf16(
                    af[fm], bf[fn], acc[fm][fn], 0, 0, 0);
    }

    #pragma unroll
    for (int fm = 0; fm < 4; ++fm)
        #pragma unroll
        for (int fn = 0; fn < 2; ++fn) {
            const size_t col = n0 + wc * 32 + fn * 16 + lc;
            #pragma unroll
            for (int j = 0; j < 4; ++j) {
                const size_t row = m0 + wr * 64 + fm * 16 + lr * 4 + j;
                C[row * (size_t)ldc + col] = acc[fm][fn][j];
            }
        }
}

// ---------------------------------------------------------------------------
// split-bf16 3-pass MFMA GEMM for the sensitive columns (theta cumsum!):
// u=uh+ul, W=wh+wl; acc += uh*wh + uh*wl + ul*wh  (~fp32 accuracy, MFMA speed)
// 128x64 tile, N=1216=19*64 exact. ldc=DTOT, out offset +NZX by caller.
// ---------------------------------------------------------------------------
__global__ __launch_bounds__(256) void mfma_gemm_rem3(const float* __restrict__ u,
                                                      const float* __restrict__ W,
                                                      float* __restrict__ zxr) {
    __shared__ unsigned short Ah[128][LDB], Alo[128][LDB];
    __shared__ unsigned short Bh[64][LDB],  Blo[64][LDB];
    const int tid = threadIdx.x;
    const int m0 = blockIdx.y * 128, n0 = blockIdx.x * 64;
    const int lane = tid & 63, wave = tid >> 6;
    const int wr = wave >> 1, wc = wave & 1;
    const int lr = lane >> 4, lc = lane & 15;
    const int r  = tid >> 2;
    const int cb = (tid & 3) * 8;

    f32x4 acc[4][2] = {};

    const float* pA = u + (size_t)(m0 + r) * DMODEL + cb;
    const float* pB = W + (size_t)(n0 + r) * DMODEL + cb;   // n0+r <= 1215 < NREM

    for (int k0 = 0; k0 < DMODEL; k0 += 32) {
        const float4 a0 = *(const float4*)(pA + k0);
        const float4 a1 = *(const float4*)(pA + k0 + 4);
        const float4 a2 = *(const float4*)(pA + k0 + (size_t)64 * DMODEL);
        const float4 a3 = *(const float4*)(pA + k0 + (size_t)64 * DMODEL + 4);
        const float4 b0 = *(const float4*)(pB + k0);
        const float4 b1 = *(const float4*)(pB + k0 + 4);
        __syncthreads();
        uint4 qh, ql;
        split2(a0.x, a0.y, qh.x, ql.x); split2(a0.z, a0.w, qh.y, ql.y);
        split2(a1.x, a1.y, qh.z, ql.z); split2(a1.z, a1.w, qh.w, ql.w);
        *(uint4*)&Ah[r][cb] = qh; *(uint4*)&Alo[r][cb] = ql;
        split2(a2.x, a2.y, qh.x, ql.x); split2(a2.z, a2.w, qh.y, ql.y);
        split2(a3.x, a3.y, qh.z, ql.z); split2(a3.z, a3.w, qh.w, ql.w);
        *(uint4*)&Ah[r + 64][cb] = qh; *(uint4*)&Alo[r + 64][cb] = ql;
        split2(b0.x, b0.y, qh.x, ql.x); split2(b0.z, b0.w, qh.y, ql.y);
        split2(b1.x, b1.y, qh.z, ql.z); split2(b1.z, b1.w, qh.w, ql.w);
        *(uint4*)&Bh[r][cb] = qh; *(uint4*)&Blo[r][cb] = ql;
        __syncthreads();
        s16x8 ahf[4], alf[4], bhf[2], blf[2];
        #pragma unroll
        for (int f = 0; f < 4; ++f) {
            ahf[f] = *(const s16x8*)&Ah[wr * 64 + f * 16 + lc][lr * 8];
            alf[f] = *(const s16x8*)&Alo[wr * 64 + f * 16 + lc][lr * 8];
        }
        #pragma unroll
        for (int f = 0; f < 2; ++f) {
            bhf[f] = *(const s16x8*)&Bh[wc * 32 + f * 16 + lc][lr * 8];
            blf[f] = *(const s16x8*)&Blo[wc * 32 + f * 16 + lc][lr * 8];
        }
        #pragma unroll
        for (int fm = 0; fm < 4; ++fm)
            #pragma unroll
            for (int fn = 0; fn < 2; ++fn) {
                acc[fm][fn] = __builtin_amdgcn_mfma_f32_16x16x32_bf16(
                    ahf[fm], bhf[fn], acc[fm][fn], 0, 0, 0);
                acc[fm][fn] = __builtin_amdgcn_mfma_f32_16x16x32_bf16(
                    ahf[fm], blf[fn], acc[fm][fn], 0, 0, 0);
                acc[fm][fn] = __builtin_amdgcn_mfma_f32_16x16x32_bf16(
                    alf[fm], bhf[fn], acc[fm][fn], 0, 0, 0);
            }
    }

    #pragma unroll
    for (int fm = 0; fm < 4; ++fm)
        #pragma unroll
        for (int fn = 0; fn < 2; ++fn) {
            const size_t col = n0 + wc * 32 + fn * 16 + lc;
            #pragma unroll
            for (int j = 0; j < 4; ++j) {
                const size_t row = m0 + wr * 64 + fm * 16 + lr * 4 + j;
                zxr[row * DTOT + col] = acc[fm][fn][j];
            }
        }
}

// ---------------------------------------------------------------------------
// prep: RMS-norm Br/Cr; alpha/beta/gamma packed as float4 in (b,h,l) layout.
// ---------------------------------------------------------------------------
__global__ __launch_bounds__(64) void prep_kernel(const float* __restrict__ zx,
        const float* __restrict__ dt_bias, const float* __restrict__ A_log,
        const float* __restrict__ B_norm_w, const float* __restrict__ C_norm_w,
        float* __restrict__ Bg, float* __restrict__ Cg,
        float4* __restrict__ abg4) {
    const int bl = blockIdx.x;
    const int b = bl >> 10, l = bl & (LSEQ - 1);
    const int t  = threadIdx.x;
    const float* row = zx + (size_t)bl * DTOT;
    const float br = row[OFF_BR + t];
    const float cr = row[OFF_CR + t];
    float ssb = br * br, ssc = cr * cr;
    #pragma unroll
    for (int k = 1; k < 64; k <<= 1) { ssb += __shfl_xor(ssb, k); ssc += __shfl_xor(ssc, k); }
    const float scB = rsqrtf(ssb * (1.f / 64.f) + 1e-5f);
    const float scC = rsqrtf(ssc * (1.f / 64.f) + 1e-5f);
    Bg[(size_t)bl * 64 + t] = br * scB * B_norm_w[t];
    Cg[(size_t)bl * 64 + t] = cr * scC * C_norm_w[t];
    if (t < NH) {
        const float dtr = row[OFF_DT + t] + dt_bias[t];
        const float dt  = (dtr > 20.f) ? dtr : log1pf(expf(dtr));
        const float lamr = row[OFF_LAM + t];
        const float lam  = 1.f / (1.f + expf(-lamr));
        const float Ah   = -expf(A_log[t]);
        const float al   = expf(dt * Ah);
        const size_t o = ((size_t)b * NH + t) * LSEQ + l;
        abg4[o] = make_float4(al, (1.f - lam) * dt * al, lam * dt, 0.f);
    }
}

// ---------------------------------------------------------------------------
// cumsum of thr over L, per (b,h): 32 dims.
// ---------------------------------------------------------------------------
__global__ __launch_bounds__(256) void cumsum_kernel(const float* __restrict__ zx,
                                                     float* __restrict__ th_cs) {
    const int bh = blockIdx.x;
    const int b = bh >> 5, h = bh & 31;
    const int d = threadIdx.x & 31, seg = threadIdx.x >> 5;
    const float* base = zx + (size_t)b * LSEQ * DTOT + OFF_TH + h * 32 + d;
    float* out = th_cs + (size_t)b * LSEQ * 1024 + h * 32 + d;
    __shared__ float sums[8][33];
    const int l0 = seg * 128;
    float s = 0.f;
    #pragma unroll 4
    for (int i = 0; i < 128; ++i) s += base[(size_t)(l0 + i) * DTOT];
    sums[seg][d] = s;
    __syncthreads();
    float acc = 0.f;
    for (int s2 = 0; s2 < seg; ++s2) acc += sums[s2][d];
    #pragma unroll 4
    for (int i = 0; i < 128; ++i) {
        acc += base[(size_t)(l0 + i) * DTOT];
        out[(size_t)(l0 + i) * 1024] = acc;
    }
}

// ---------------------------------------------------------------------------
// rot: Bh/Ch = rot(broadcast(Bg/Cg)+bias). Brot/Crot layout (B,NH,L,DS).
// ---------------------------------------------------------------------------
__global__ __launch_bounds__(256) void rot_kernel(const float* __restrict__ th_cs,
        const float* __restrict__ Bg, const float* __restrict__ Cg,
        const float* __restrict__ B_bias, const float* __restrict__ C_bias,
        float* __restrict__ Brot, float* __restrict__ Crot) {
    const size_t idx = (size_t)blockIdx.x * 256 + threadIdx.x;
    const int j = (int)(idx & 31);
    const int h = (int)((idx >> 5) & 31);
    const size_t bl = idx >> 10;
    const int l = (int)(bl & (LSEQ - 1));
    const int b = (int)(bl >> 10);
    const float th = th_cs[idx];
    float s, c;
    sincosf(th, &s, &c);
    float v1 = Bg[bl * 64 + j]      + B_bias[h * 64 + j];
    float v2 = Bg[bl * 64 + 32 + j] + B_bias[h * 64 + 32 + j];
    const size_t ob = ((size_t)(b * NH + h) * LSEQ + l) * DS + j;
    Brot[ob]      = v1 * c - v2 * s;
    Brot[ob + 32] = v1 * s + v2 * c;
    v1 = Cg[bl * 64 + j]      + C_bias[h * 64 + j];
    v2 = Cg[bl * 64 + 32 + j] + C_bias[h * 64 + 32 + j];
    Crot[ob]      = v1 * c - v2 * s;
    Crot[ob + 32] = v1 * s + v2 * c;
}

// ---------------------------------------------------------------------------
// DPP 16-lane row sum (VALU pipe). Lane 15 of each 16-lane row holds the sum.
// ---------------------------------------------------------------------------
__device__ __forceinline__ float row_sum16(float x) {
    int t;
    t = __builtin_amdgcn_update_dpp(0, __float_as_int(x), 0x111, 0xf, 0xf, true);
    x += __int_as_float(t);
    t = __builtin_amdgcn_update_dpp(0, __float_as_int(x), 0x112, 0xf, 0xf, true);
    x += __int_as_float(t);
    t = __builtin_amdgcn_update_dpp(0, __float_as_int(x), 0x114, 0xf, 0xf, true);
    x += __int_as_float(t);
    t = __builtin_amdgcn_update_dpp(0, __float_as_int(x), 0x118, 0xf, 0xf, true);
    x += __int_as_float(t);
    return x;
}

// ---------------------------------------------------------------------------
// scan v3b: DEPTH-8 rotating register pipeline from global, NO LDS.
// __launch_bounds__(256, 1): the grid pins occupancy at 1 wave/SIMD anyway,
// so allow the full VGPR budget — round-8's (256) default capped at 80 VGPR
// and the compiler sank the loads, collapsing effective depth to ~2
// (168 us, 390 cy/step ~= 900 cy HBM latency / depth 2).
// ---------------------------------------------------------------------------
#define DEPTH 8

__global__ __launch_bounds__(256, 1) void scan_kernel(const float* __restrict__ zx,
        const float* __restrict__ Brot, const float* __restrict__ Crot,
        const float4* __restrict__ abg4, const float* __restrict__ Dp,
        float* __restrict__ yb) {
    const int blk = blockIdx.x;
    const int ptile = blk & 3, h = (blk >> 2) & 31, b = blk >> 7;
    const int tid = threadIdx.x;
    const int pl = tid >> 4, ng = tid & 15;
    const int p = ptile * 16 + pl;
    const int n0 = ng * 4;

    const size_t bh = (size_t)b * NH + h;
    const float* Bbase = Brot + bh * LSEQ * DS + n0;
    const float* Cbase = Crot + bh * LSEQ * DS + n0;
    const float4* abase = abg4 + bh * LSEQ;
    const float* xbase = zx + (size_t)b * LSEQ * DTOT + OFF_X + h * HD + p;
    const float Dh = Dp[h];
    float* ybase = yb + (size_t)b * LSEQ * DIN + h * HD + p;

    float4 Bb[DEPTH], Cb[DEPTH], ab[DEPTH];
    float  xb[DEPTH];

    #pragma unroll
    for (int d = 0; d < DEPTH; ++d) {
        Bb[d] = *(const float4*)(Bbase + (size_t)d * DS);
        Cb[d] = *(const float4*)(Cbase + (size_t)d * DS);
        ab[d] = ((const float4*)abase)[d];
        xb[d] = xbase[(size_t)d * DTOT];
    }

    float hs0 = 0.f, hs1 = 0.f, hs2 = 0.f, hs3 = 0.f;
    float Bp0 = 0.f, Bp1 = 0.f, Bp2 = 0.f, Bp3 = 0.f;
    float xprev = 0.f;

    for (int t0 = 0; t0 < LSEQ; t0 += DEPTH) {
        #pragma unroll
        for (int d = 0; d < DEPTH; ++d) {
            const float4 Bv = Bb[d];
            const float4 Cv = Cb[d];
            const float4 av = ab[d];
            const float  xv = xb[d];
            // issue loads for step t0+d+DEPTH (clamped at tail; redundant loads harmless)
            int tn = t0 + d + DEPTH; if (tn > LSEQ - 1) tn = LSEQ - 1;
            Bb[d] = *(const float4*)(Bbase + (size_t)tn * DS);
            Cb[d] = *(const float4*)(Cbase + (size_t)tn * DS);
            ab[d] = ((const float4*)abase)[tn];
            xb[d] = xbase[(size_t)tn * DTOT];
            // compute step t0+d
            const float cp = av.y * xprev;
            const float cc = av.z * xv;
            float ys;
            hs0 = fmaf(av.x, hs0, fmaf(cp, Bp0, cc * Bv.x)); ys  = Cv.x * hs0;
            hs1 = fmaf(av.x, hs1, fmaf(cp, Bp1, cc * Bv.y)); ys += Cv.y * hs1;
            hs2 = fmaf(av.x, hs2, fmaf(cp, Bp2, cc * Bv.z)); ys += Cv.z * hs2;
            hs3 = fmaf(av.x, hs3, fmaf(cp, Bp3, cc * Bv.w)); ys += Cv.w * hs3;
            ys = row_sum16(ys);
            if (ng == 15) ybase[(size_t)(t0 + d) * DIN] = fmaf(Dh, xv, ys);
            Bp0 = Bv.x; Bp1 = Bv.y; Bp2 = Bv.z; Bp3 = Bv.w;
            xprev = xv;
        }
    }
}

// ---------------------------------------------------------------------------
// gate + final RMS norm
// ---------------------------------------------------------------------------
__global__ __launch_bounds__(256) void gate_norm_kernel(const float* __restrict__ yb,
        const float* __restrict__ zx, const float* __restrict__ norm_w,
        float* __restrict__ gn) {
    const int bl = blockIdx.x;
    const int tid = threadIdx.x;
    const float* yrow = yb + (size_t)bl * DIN;
    const float* zrow = zx + (size_t)bl * DTOT + OFF_Z;
    float g[8];
    float ss = 0.f;
    #pragma unroll
    for (int i = 0; i < 8; ++i) {
        const int c = tid + i * 256;
        const float yv = yrow[c];
        const float zv = zrow[c];
        const float sg = 1.f / (1.f + expf(-zv));
        const float gv = yv * zv * sg;
        g[i] = gv;
        ss += gv * gv;
    }
    #pragma unroll
    for (int k = 1; k < 64; k <<= 1) ss += __shfl_xor(ss, k);
    __shared__ float wsum[4];
    if ((tid & 63) == 0) wsum[tid >> 6] = ss;
    __syncthreads();
    ss = wsum[0] + wsum[1] + wsum[2] + wsum[3];
    const float sc = rsqrtf(ss * (1.f / 2048.f) + 1e-5f);
    #pragma unroll
    for (int i = 0; i < 8; ++i) {
        const int c = tid + i * 256;
        gn[(size_t)bl * DIN + c] = g[i] * sc * norm_w[c];
    }
}

// ---------------------------------------------------------------------------
extern "C" void kernel_launch(void* const* d_in, const int* in_sizes, int n_in,
                              void* d_out, int out_size, void* d_ws, size_t ws_size,
                              hipStream_t stream) {
    const float* u          = (const float*)d_in[0];
    const float* in_proj_w  = (const float*)d_in[1];
    const float* dt_bias    = (const float*)d_in[2];
    const float* A_log      = (const float*)d_in[3];
    const float* Dp         = (const float*)d_in[4];
    const float* B_norm_w   = (const float*)d_in[5];
    const float* C_norm_w   = (const float*)d_in[6];
    const float* B_bias     = (const float*)d_in[7];
    const float* C_bias     = (const float*)d_in[8];
    const float* norm_w     = (const float*)d_in[9];
    const float* out_proj_w = (const float*)d_in[10];
    float* out = (float*)d_out;

    float* p = (float*)d_ws;
    float* zx    = p; p += (size_t)ROWS * DTOT;
    float* th_cs = p; p += (size_t)ROWS * 1024;
    float* Brot  = p; p += (size_t)ROWS * 2048;
    float* Crot  = p; p += (size_t)ROWS * 2048;
    float* Bg    = p; p += (size_t)ROWS * 64;
    float* Cg    = p; p += (size_t)ROWS * 64;
    float4* abg4 = (float4*)p; p += (size_t)ROWS * NH * 4;
    float* yb    = p; p += (size_t)ROWS * 2048;
    float* gn    = Brot;   // reuse: Brot dead after scan

    // 1a. z/x block via bf16 MFMA: zx[:, 0:4096]
    mfma_gemm_zx<<<dim3(NZX / 128, ROWS / 128), 256, 0, stream>>>(u, in_proj_w, zx);
    // 1b. sensitive columns via split-bf16 3-pass MFMA: zx[:, 4096:5312]
    mfma_gemm_rem3<<<dim3(NREM / 64, ROWS / 128), 256, 0, stream>>>(
        u, in_proj_w + (size_t)NZX * DMODEL, zx + NZX);
    // 2. per-row prep
    prep_kernel<<<ROWS, 64, 0, stream>>>(zx, dt_bias, A_log, B_norm_w, C_norm_w,
                                         Bg, Cg, abg4);
    // 3. cumsum of theta over L
    cumsum_kernel<<<BB * NH, 256, 0, stream>>>(zx, th_cs);
    // 4. rotary on B/C
    rot_kernel<<<(ROWS * 1024) / 256, 256, 0, stream>>>(th_cs, Bg, Cg, B_bias, C_bias,
                                                        Brot, Crot);
    // 5. sequential scan over L (register-pipelined, full VGPR budget)
    scan_kernel<<<BB * NH * 4, 256, 0, stream>>>(zx, Brot, Crot, abg4, Dp, yb);
    // 6. gate + RMS norm
    gate_norm_kernel<<<ROWS, 256, 0, stream>>>(yb, zx, norm_w, gn);
    // 7. out = gn @ out_proj_w^T  via bf16 MFMA (128x64 tile, 256 blocks)
    mfma_gemm_out<<<dim3(DMODEL / 64, ROWS / 128), 256, 0, stream>>>(
        gn, out_proj_w, out, DIN, DMODEL);
}

// Round 10
// 317.553 us; speedup vs baseline: 1.1148x; 1.1148x over previous
//
#include <hip/hip_runtime.h>
#include <hip/hip_bf16.h>

// Problem constants
#define DMODEL 1024
#define DIN    2048
#define NH     32
#define HD     64
#define DS     64
#define LSEQ   1024
#define BB     2
#define DTOT   5312           // 2*DIN + 2*64 + 32 + 1024 + 32
#define ROWS   (BB*LSEQ)      // 2048
// column offsets inside zxbcdt
#define OFF_Z   0
#define OFF_X   2048
#define OFF_BR  4096
#define OFF_CR  4160
#define OFF_DT  4224
#define OFF_TH  4256
#define OFF_LAM 5280
#define NZX     4096          // z+x columns done in single-pass bf16 MFMA
#define NREM    (DTOT - NZX)  // 1216 cols done in 3-pass split-bf16 MFMA
// segmented scan
#define NSEG 8
#define SEG  (LSEQ / NSEG)    // 128

typedef short  s16x8 __attribute__((ext_vector_type(8)));
typedef float  f32x4 __attribute__((ext_vector_type(4)));

__device__ __forceinline__ unsigned int f2bf(float f) {   // RNE f32->bf16 (finite inputs)
    unsigned int u = __float_as_uint(f);
    u += 0x7fffu + ((u >> 16) & 1u);
    return u >> 16;
}
__device__ __forceinline__ unsigned int pk(float x, float y) {
    return f2bf(x) | (f2bf(y) << 16);
}
__device__ __forceinline__ void split2(float x, float y, unsigned int& h, unsigned int& l) {
    const unsigned int hx = f2bf(x), hy = f2bf(y);
    h = hx | (hy << 16);
    l = pk(x - __uint_as_float(hx << 16), y - __uint_as_float(hy << 16));
}

// ---------------------------------------------------------------------------
// bf16 MFMA GEMM, z/x block: zx[:, 0:4096] = u @ W[0:4096,:]^T
// ---------------------------------------------------------------------------
#define LDB 40
__global__ __launch_bounds__(256) void mfma_gemm_zx(const float* __restrict__ u,
                                                    const float* __restrict__ W,
                                                    float* __restrict__ zx) {
    __shared__ unsigned short Al[128][LDB];
    __shared__ unsigned short Bl[128][LDB];
    const int tid = threadIdx.x;
    const int m0 = blockIdx.y * 128, n0 = blockIdx.x * 128;
    const int lane = tid & 63, wave = tid >> 6;
    const int wr = wave >> 1, wc = wave & 1;
    const int lr = lane >> 4, lc = lane & 15;
    const int r  = tid >> 2;
    const int cb = (tid & 3) * 8;

    f32x4 acc[4][4] = {};

    const float* uA = u + (size_t)(m0 + r) * DMODEL + cb;
    const float* uB = W + (size_t)(n0 + r) * DMODEL + cb;

    for (int k0 = 0; k0 < DMODEL; k0 += 32) {
        const float4 a0 = *(const float4*)(uA + k0);
        const float4 a1 = *(const float4*)(uA + k0 + 4);
        const float4 a2 = *(const float4*)(uA + k0 + (size_t)64 * DMODEL);
        const float4 a3 = *(const float4*)(uA + k0 + (size_t)64 * DMODEL + 4);
        const float4 b0 = *(const float4*)(uB + k0);
        const float4 b1 = *(const float4*)(uB + k0 + 4);
        const float4 b2 = *(const float4*)(uB + k0 + (size_t)64 * DMODEL);
        const float4 b3 = *(const float4*)(uB + k0 + (size_t)64 * DMODEL + 4);
        __syncthreads();
        uint4 q;
        q.x = pk(a0.x, a0.y); q.y = pk(a0.z, a0.w); q.z = pk(a1.x, a1.y); q.w = pk(a1.z, a1.w);
        *(uint4*)&Al[r][cb] = q;
        q.x = pk(a2.x, a2.y); q.y = pk(a2.z, a2.w); q.z = pk(a3.x, a3.y); q.w = pk(a3.z, a3.w);
        *(uint4*)&Al[r + 64][cb] = q;
        q.x = pk(b0.x, b0.y); q.y = pk(b0.z, b0.w); q.z = pk(b1.x, b1.y); q.w = pk(b1.z, b1.w);
        *(uint4*)&Bl[r][cb] = q;
        q.x = pk(b2.x, b2.y); q.y = pk(b2.z, b2.w); q.z = pk(b3.x, b3.y); q.w = pk(b3.z, b3.w);
        *(uint4*)&Bl[r + 64][cb] = q;
        __syncthreads();
        s16x8 af[4], bf[4];
        #pragma unroll
        for (int f = 0; f < 4; ++f) {
            af[f] = *(const s16x8*)&Al[wr * 64 + f * 16 + lc][lr * 8];
            bf[f] = *(const s16x8*)&Bl[wc * 64 + f * 16 + lc][lr * 8];
        }
        #pragma unroll
        for (int fm = 0; fm < 4; ++fm)
            #pragma unroll
            for (int fn = 0; fn < 4; ++fn)
                acc[fm][fn] = __builtin_amdgcn_mfma_f32_16x16x32_bf16(
                    af[fm], bf[fn], acc[fm][fn], 0, 0, 0);
    }

    #pragma unroll
    for (int fm = 0; fm < 4; ++fm)
        #pragma unroll
        for (int fn = 0; fn < 4; ++fn) {
            const size_t col = n0 + wc * 64 + fn * 16 + lc;
            #pragma unroll
            for (int j = 0; j < 4; ++j) {
                const size_t row = m0 + wr * 64 + fm * 16 + lr * 4 + j;
                zx[row * DTOT + col] = acc[fm][fn][j];
            }
        }
}

// ---------------------------------------------------------------------------
// bf16 MFMA GEMM, 128x64 tile: out_proj (N=1024, K=2048).
// ---------------------------------------------------------------------------
__global__ __launch_bounds__(256) void mfma_gemm_out(const float* __restrict__ A,
                                                     const float* __restrict__ B,
                                                     float* __restrict__ C,
                                                     int K, int ldc) {
    __shared__ unsigned short Als[128][LDB];
    __shared__ unsigned short Bls[64][LDB];
    const int tid = threadIdx.x;
    const int m0 = blockIdx.y * 128, n0 = blockIdx.x * 64;
    const int lane = tid & 63, wave = tid >> 6;
    const int wr = wave >> 1, wc = wave & 1;
    const int lr = lane >> 4, lc = lane & 15;
    const int r  = tid >> 2;
    const int cb = (tid & 3) * 8;

    f32x4 acc[4][2] = {};

    const float* pA = A + (size_t)(m0 + r) * K + cb;
    const float* pB = B + (size_t)(n0 + r) * K + cb;

    for (int k0 = 0; k0 < K; k0 += 32) {
        const float4 a0 = *(const float4*)(pA + k0);
        const float4 a1 = *(const float4*)(pA + k0 + 4);
        const float4 a2 = *(const float4*)(pA + k0 + (size_t)64 * K);
        const float4 a3 = *(const float4*)(pA + k0 + (size_t)64 * K + 4);
        const float4 b0 = *(const float4*)(pB + k0);
        const float4 b1 = *(const float4*)(pB + k0 + 4);
        __syncthreads();
        uint4 q;
        q.x = pk(a0.x, a0.y); q.y = pk(a0.z, a0.w); q.z = pk(a1.x, a1.y); q.w = pk(a1.z, a1.w);
        *(uint4*)&Als[r][cb] = q;
        q.x = pk(a2.x, a2.y); q.y = pk(a2.z, a2.w); q.z = pk(a3.x, a3.y); q.w = pk(a3.z, a3.w);
        *(uint4*)&Als[r + 64][cb] = q;
        q.x = pk(b0.x, b0.y); q.y = pk(b0.z, b0.w); q.z = pk(b1.x, b1.y); q.w = pk(b1.z, b1.w);
        *(uint4*)&Bls[r][cb] = q;
        __syncthreads();
        s16x8 af[4], bf[2];
        #pragma unroll
        for (int f = 0; f < 4; ++f)
            af[f] = *(const s16x8*)&Als[wr * 64 + f * 16 + lc][lr * 8];
        #pragma unroll
        for (int f = 0; f < 2; ++f)
            bf[f] = *(const s16x8*)&Bls[wc * 32 + f * 16 + lc][lr * 8];
        #pragma unroll
        for (int fm = 0; fm < 4; ++fm)
            #pragma unroll
            for (int fn = 0; fn < 2; ++fn)
                acc[fm][fn] = __builtin_amdgcn_mfma_f32_16x16x32_bf16(
                    af[fm], bf[fn], acc[fm][fn], 0, 0, 0);
    }

    #pragma unroll
    for (int fm = 0; fm < 4; ++fm)
        #pragma unroll
        for (int fn = 0; fn < 2; ++fn) {
            const size_t col = n0 + wc * 32 + fn * 16 + lc;
            #pragma unroll
            for (int j = 0; j < 4; ++j) {
                const size_t row = m0 + wr * 64 + fm * 16 + lr * 4 + j;
                C[row * (size_t)ldc + col] = acc[fm][fn][j];
            }
        }
}

// ---------------------------------------------------------------------------
// split-bf16 3-pass MFMA GEMM for the sensitive columns (theta cumsum!)
// ---------------------------------------------------------------------------
__global__ __launch_bounds__(256) void mfma_gemm_rem3(const float* __restrict__ u,
                                                      const float* __restrict__ W,
                                                      float* __restrict__ zxr) {
    __shared__ unsigned short Ah[128][LDB], Alo[128][LDB];
    __shared__ unsigned short Bh[64][LDB],  Blo[64][LDB];
    const int tid = threadIdx.x;
    const int m0 = blockIdx.y * 128, n0 = blockIdx.x * 64;
    const int lane = tid & 63, wave = tid >> 6;
    const int wr = wave >> 1, wc = wave & 1;
    const int lr = lane >> 4, lc = lane & 15;
    const int r  = tid >> 2;
    const int cb = (tid & 3) * 8;

    f32x4 acc[4][2] = {};

    const float* pA = u + (size_t)(m0 + r) * DMODEL + cb;
    const float* pB = W + (size_t)(n0 + r) * DMODEL + cb;

    for (int k0 = 0; k0 < DMODEL; k0 += 32) {
        const float4 a0 = *(const float4*)(pA + k0);
        const float4 a1 = *(const float4*)(pA + k0 + 4);
        const float4 a2 = *(const float4*)(pA + k0 + (size_t)64 * DMODEL);
        const float4 a3 = *(const float4*)(pA + k0 + (size_t)64 * DMODEL + 4);
        const float4 b0 = *(const float4*)(pB + k0);
        const float4 b1 = *(const float4*)(pB + k0 + 4);
        __syncthreads();
        uint4 qh, ql;
        split2(a0.x, a0.y, qh.x, ql.x); split2(a0.z, a0.w, qh.y, ql.y);
        split2(a1.x, a1.y, qh.z, ql.z); split2(a1.z, a1.w, qh.w, ql.w);
        *(uint4*)&Ah[r][cb] = qh; *(uint4*)&Alo[r][cb] = ql;
        split2(a2.x, a2.y, qh.x, ql.x); split2(a2.z, a2.w, qh.y, ql.y);
        split2(a3.x, a3.y, qh.z, ql.z); split2(a3.z, a3.w, qh.w, ql.w);
        *(uint4*)&Ah[r + 64][cb] = qh; *(uint4*)&Alo[r + 64][cb] = ql;
        split2(b0.x, b0.y, qh.x, ql.x); split2(b0.z, b0.w, qh.y, ql.y);
        split2(b1.x, b1.y, qh.z, ql.z); split2(b1.z, b1.w, qh.w, ql.w);
        *(uint4*)&Bh[r][cb] = qh; *(uint4*)&Blo[r][cb] = ql;
        __syncthreads();
        s16x8 ahf[4], alf[4], bhf[2], blf[2];
        #pragma unroll
        for (int f = 0; f < 4; ++f) {
            ahf[f] = *(const s16x8*)&Ah[wr * 64 + f * 16 + lc][lr * 8];
            alf[f] = *(const s16x8*)&Alo[wr * 64 + f * 16 + lc][lr * 8];
        }
        #pragma unroll
        for (int f = 0; f < 2; ++f) {
            bhf[f] = *(const s16x8*)&Bh[wc * 32 + f * 16 + lc][lr * 8];
            blf[f] = *(const s16x8*)&Blo[wc * 32 + f * 16 + lc][lr * 8];
        }
        #pragma unroll
        for (int fm = 0; fm < 4; ++fm)
            #pragma unroll
            for (int fn = 0; fn < 2; ++fn) {
                acc[fm][fn] = __builtin_amdgcn_mfma_f32_16x16x32_bf16(
                    ahf[fm], bhf[fn], acc[fm][fn], 0, 0, 0);
                acc[fm][fn] = __builtin_amdgcn_mfma_f32_16x16x32_bf16(
                    ahf[fm], blf[fn], acc[fm][fn], 0, 0, 0);
                acc[fm][fn] = __builtin_amdgcn_mfma_f32_16x16x32_bf16(
                    alf[fm], bhf[fn], acc[fm][fn], 0, 0, 0);
            }
    }

    #pragma unroll
    for (int fm = 0; fm < 4; ++fm)
        #pragma unroll
        for (int fn = 0; fn < 2; ++fn) {
            const size_t col = n0 + wc * 32 + fn * 16 + lc;
            #pragma unroll
            for (int j = 0; j < 4; ++j) {
                const size_t row = m0 + wr * 64 + fm * 16 + lr * 4 + j;
                zxr[row * DTOT + col] = acc[fm][fn][j];
            }
        }
}

// ---------------------------------------------------------------------------
// prep: RMS-norm Br/Cr; alpha/beta/gamma packed as float4 in (b,h,l) layout.
// ---------------------------------------------------------------------------
__global__ __launch_bounds__(64) void prep_kernel(const float* __restrict__ zx,
        const float* __restrict__ dt_bias, const float* __restrict__ A_log,
        const float* __restrict__ B_norm_w, const float* __restrict__ C_norm_w,
        float* __restrict__ Bg, float* __restrict__ Cg,
        float4* __restrict__ abg4) {
    const int bl = blockIdx.x;
    const int b = bl >> 10, l = bl & (LSEQ - 1);
    const int t  = threadIdx.x;
    const float* row = zx + (size_t)bl * DTOT;
    const float br = row[OFF_BR + t];
    const float cr = row[OFF_CR + t];
    float ssb = br * br, ssc = cr * cr;
    #pragma unroll
    for (int k = 1; k < 64; k <<= 1) { ssb += __shfl_xor(ssb, k); ssc += __shfl_xor(ssc, k); }
    const float scB = rsqrtf(ssb * (1.f / 64.f) + 1e-5f);
    const float scC = rsqrtf(ssc * (1.f / 64.f) + 1e-5f);
    Bg[(size_t)bl * 64 + t] = br * scB * B_norm_w[t];
    Cg[(size_t)bl * 64 + t] = cr * scC * C_norm_w[t];
    if (t < NH) {
        const float dtr = row[OFF_DT + t] + dt_bias[t];
        const float dt  = (dtr > 20.f) ? dtr : log1pf(expf(dtr));
        const float lamr = row[OFF_LAM + t];
        const float lam  = 1.f / (1.f + expf(-lamr));
        const float Ah   = -expf(A_log[t]);
        const float al   = expf(dt * Ah);
        const size_t o = ((size_t)b * NH + t) * LSEQ + l;
        abg4[o] = make_float4(al, (1.f - lam) * dt * al, lam * dt, 0.f);
    }
}

// ---------------------------------------------------------------------------
// cumsum of thr over L, per (b,h): 32 dims.
// ---------------------------------------------------------------------------
__global__ __launch_bounds__(256) void cumsum_kernel(const float* __restrict__ zx,
                                                     float* __restrict__ th_cs) {
    const int bh = blockIdx.x;
    const int b = bh >> 5, h = bh & 31;
    const int d = threadIdx.x & 31, seg = threadIdx.x >> 5;
    const float* base = zx + (size_t)b * LSEQ * DTOT + OFF_TH + h * 32 + d;
    float* out = th_cs + (size_t)b * LSEQ * 1024 + h * 32 + d;
    __shared__ float sums[8][33];
    const int l0 = seg * 128;
    float s = 0.f;
    #pragma unroll 4
    for (int i = 0; i < 128; ++i) s += base[(size_t)(l0 + i) * DTOT];
    sums[seg][d] = s;
    __syncthreads();
    float acc = 0.f;
    for (int s2 = 0; s2 < seg; ++s2) acc += sums[s2][d];
    #pragma unroll 4
    for (int i = 0; i < 128; ++i) {
        acc += base[(size_t)(l0 + i) * DTOT];
        out[(size_t)(l0 + i) * 1024] = acc;
    }
}

// ---------------------------------------------------------------------------
// rot: Bh/Ch = rot(broadcast(Bg/Cg)+bias). Brot/Crot layout (B,NH,L,DS).
// ---------------------------------------------------------------------------
__global__ __launch_bounds__(256) void rot_kernel(const float* __restrict__ th_cs,
        const float* __restrict__ Bg, const float* __restrict__ Cg,
        const float* __restrict__ B_bias, const float* __restrict__ C_bias,
        float* __restrict__ Brot, float* __restrict__ Crot) {
    const size_t idx = (size_t)blockIdx.x * 256 + threadIdx.x;
    const int j = (int)(idx & 31);
    const int h = (int)((idx >> 5) & 31);
    const size_t bl = idx >> 10;
    const int l = (int)(bl & (LSEQ - 1));
    const int b = (int)(bl >> 10);
    const float th = th_cs[idx];
    float s, c;
    sincosf(th, &s, &c);
    float v1 = Bg[bl * 64 + j]      + B_bias[h * 64 + j];
    float v2 = Bg[bl * 64 + 32 + j] + B_bias[h * 64 + 32 + j];
    const size_t ob = ((size_t)(b * NH + h) * LSEQ + l) * DS + j;
    Brot[ob]      = v1 * c - v2 * s;
    Brot[ob + 32] = v1 * s + v2 * c;
    v1 = Cg[bl * 64 + j]      + C_bias[h * 64 + j];
    v2 = Cg[bl * 64 + 32 + j] + C_bias[h * 64 + 32 + j];
    Crot[ob]      = v1 * c - v2 * s;
    Crot[ob + 32] = v1 * s + v2 * c;
}

// ---------------------------------------------------------------------------
// DPP 16-lane row sum (VALU pipe). Lane 15 of each 16-lane row holds the sum.
// ---------------------------------------------------------------------------
__device__ __forceinline__ float row_sum16(float x) {
    int t;
    t = __builtin_amdgcn_update_dpp(0, __float_as_int(x), 0x111, 0xf, 0xf, true);
    x += __int_as_float(t);
    t = __builtin_amdgcn_update_dpp(0, __float_as_int(x), 0x112, 0xf, 0xf, true);
    x += __int_as_float(t);
    t = __builtin_amdgcn_update_dpp(0, __float_as_int(x), 0x114, 0xf, 0xf, true);
    x += __int_as_float(t);
    t = __builtin_amdgcn_update_dpp(0, __float_as_int(x), 0x118, 0xf, 0xf, true);
    x += __int_as_float(t);
    return x;
}

// ---------------------------------------------------------------------------
// Segmented scan. Linear recurrence with per-head SCALAR decay a_t:
//   h_end(seg) = h_local_end(seg) + (prod a)*h_start(seg)  — exact.
// The bx_prev input term is DATA (B[t-1],x[t-1]), loadable at any segment
// start. 8 segments -> 2048 blocks -> 8 waves/SIMD of TLP (vs 1 before);
// __launch_bounds__(256,8) caps VGPR at 64 to guarantee that occupancy.
// ---------------------------------------------------------------------------
// pass 1: per-segment local scan from h=0; store h_local_end + prod(alpha).
__global__ __launch_bounds__(256, 8) void scan_p1(const float* __restrict__ zx,
        const float* __restrict__ Brot, const float4* __restrict__ abg4,
        float* __restrict__ hseg, float* __restrict__ aprod) {
    const int blk = blockIdx.x;
    const int s = blk & (NSEG - 1), ptile = (blk >> 3) & 3, h = (blk >> 5) & 31, b = blk >> 10;
    const int tid = threadIdx.x;
    const int pl = tid >> 4, ng = tid & 15;
    const int p = ptile * 16 + pl;
    const int n0 = ng * 4;
    const int t0 = s * SEG;

    const size_t bh = (size_t)b * NH + h;
    const float* Bbase = Brot + bh * LSEQ * DS + n0;
    const float4* abase = abg4 + bh * LSEQ;
    const float* xbase = zx + (size_t)b * LSEQ * DTOT + OFF_X + h * HD + p;

    float hs0 = 0.f, hs1 = 0.f, hs2 = 0.f, hs3 = 0.f;
    float Bp0 = 0.f, Bp1 = 0.f, Bp2 = 0.f, Bp3 = 0.f;
    float xprev = 0.f, aP = 1.f;
    if (s > 0) {
        const float4 Bm = *(const float4*)(Bbase + (size_t)(t0 - 1) * DS);
        Bp0 = Bm.x; Bp1 = Bm.y; Bp2 = Bm.z; Bp3 = Bm.w;
        xprev = xbase[(size_t)(t0 - 1) * DTOT];
    }

    #pragma unroll 4
    for (int t = t0; t < t0 + SEG; ++t) {
        const float4 Bv = *(const float4*)(Bbase + (size_t)t * DS);
        const float4 av = abase[t];
        const float  xv = xbase[(size_t)t * DTOT];
        const float cp = av.y * xprev;
        const float cc = av.z * xv;
        hs0 = fmaf(av.x, hs0, fmaf(cp, Bp0, cc * Bv.x));
        hs1 = fmaf(av.x, hs1, fmaf(cp, Bp1, cc * Bv.y));
        hs2 = fmaf(av.x, hs2, fmaf(cp, Bp2, cc * Bv.z));
        hs3 = fmaf(av.x, hs3, fmaf(cp, Bp3, cc * Bv.w));
        aP *= av.x;
        Bp0 = Bv.x; Bp1 = Bv.y; Bp2 = Bv.z; Bp3 = Bv.w;
        xprev = xv;
    }

    float* hp = hseg + (((bh * NSEG + s) * HD + p) * DS + n0);
    *(float4*)hp = make_float4(hs0, hs1, hs2, hs3);
    if (tid == 0) aprod[bh * NSEG + s] = aP;
}

// fixup: sequential over the 8 segments (in place: hseg becomes h_start).
__global__ __launch_bounds__(256) void scan_fix(float* __restrict__ hseg,
                                                const float* __restrict__ aprod) {
    const int blk = blockIdx.x;          // (b,h,ptile): 256
    const int ptile = blk & 3, h = (blk >> 2) & 31, b = blk >> 7;
    const int tid = threadIdx.x;
    const int pl = tid >> 4, ng = tid & 15;
    const int p = ptile * 16 + pl;
    const int n0 = ng * 4;
    const size_t bh = (size_t)b * NH + h;

    float4 cur = make_float4(0.f, 0.f, 0.f, 0.f);
    #pragma unroll
    for (int s = 0; s < NSEG; ++s) {
        float* hp = hseg + (((bh * NSEG + s) * HD + p) * DS + n0);
        const float4 tmp = *(const float4*)hp;   // h_local_end[s]
        *(float4*)hp = cur;                      // h_start[s]
        const float a = aprod[bh * NSEG + s];
        cur.x = fmaf(a, cur.x, tmp.x);
        cur.y = fmaf(a, cur.y, tmp.y);
        cur.z = fmaf(a, cur.z, tmp.z);
        cur.w = fmaf(a, cur.w, tmp.w);
    }
}

// pass 2: full scan per segment from the corrected h_start; emits y.
__global__ __launch_bounds__(256, 8) void scan_p2(const float* __restrict__ zx,
        const float* __restrict__ Brot, const float* __restrict__ Crot,
        const float4* __restrict__ abg4, const float* __restrict__ hseg,
        const float* __restrict__ Dp, float* __restrict__ yb) {
    const int blk = blockIdx.x;
    const int s = blk & (NSEG - 1), ptile = (blk >> 3) & 3, h = (blk >> 5) & 31, b = blk >> 10;
    const int tid = threadIdx.x;
    const int pl = tid >> 4, ng = tid & 15;
    const int p = ptile * 16 + pl;
    const int n0 = ng * 4;
    const int t0 = s * SEG;

    const size_t bh = (size_t)b * NH + h;
    const float* Bbase = Brot + bh * LSEQ * DS + n0;
    const float* Cbase = Crot + bh * LSEQ * DS + n0;
    const float4* abase = abg4 + bh * LSEQ;
    const float* xbase = zx + (size_t)b * LSEQ * DTOT + OFF_X + h * HD + p;
    const float Dh = Dp[h];
    float* ybase = yb + (size_t)b * LSEQ * DIN + h * HD + p;

    const float4 h0v = *(const float4*)(hseg + (((bh * NSEG + s) * HD + p) * DS + n0));
    float hs0 = h0v.x, hs1 = h0v.y, hs2 = h0v.z, hs3 = h0v.w;
    float Bp0 = 0.f, Bp1 = 0.f, Bp2 = 0.f, Bp3 = 0.f;
    float xprev = 0.f;
    if (s > 0) {
        const float4 Bm = *(const float4*)(Bbase + (size_t)(t0 - 1) * DS);
        Bp0 = Bm.x; Bp1 = Bm.y; Bp2 = Bm.z; Bp3 = Bm.w;
        xprev = xbase[(size_t)(t0 - 1) * DTOT];
    }

    #pragma unroll 2
    for (int t = t0; t < t0 + SEG; ++t) {
        const float4 Bv = *(const float4*)(Bbase + (size_t)t * DS);
        const float4 Cv = *(const float4*)(Cbase + (size_t)t * DS);
        const float4 av = abase[t];
        const float  xv = xbase[(size_t)t * DTOT];
        const float cp = av.y * xprev;
        const float cc = av.z * xv;
        float ys;
        hs0 = fmaf(av.x, hs0, fmaf(cp, Bp0, cc * Bv.x)); ys  = Cv.x * hs0;
        hs1 = fmaf(av.x, hs1, fmaf(cp, Bp1, cc * Bv.y)); ys += Cv.y * hs1;
        hs2 = fmaf(av.x, hs2, fmaf(cp, Bp2, cc * Bv.z)); ys += Cv.z * hs2;
        hs3 = fmaf(av.x, hs3, fmaf(cp, Bp3, cc * Bv.w)); ys += Cv.w * hs3;
        ys = row_sum16(ys);
        if (ng == 15) ybase[(size_t)t * DIN] = fmaf(Dh, xv, ys);
        Bp0 = Bv.x; Bp1 = Bv.y; Bp2 = Bv.z; Bp3 = Bv.w;
        xprev = xv;
    }
}

// ---------------------------------------------------------------------------
// gate + final RMS norm
// ---------------------------------------------------------------------------
__global__ __launch_bounds__(256) void gate_norm_kernel(const float* __restrict__ yb,
        const float* __restrict__ zx, const float* __restrict__ norm_w,
        float* __restrict__ gn) {
    const int bl = blockIdx.x;
    const int tid = threadIdx.x;
    const float* yrow = yb + (size_t)bl * DIN;
    const float* zrow = zx + (size_t)bl * DTOT + OFF_Z;
    float g[8];
    float ss = 0.f;
    #pragma unroll
    for (int i = 0; i < 8; ++i) {
        const int c = tid + i * 256;
        const float yv = yrow[c];
        const float zv = zrow[c];
        const float sg = 1.f / (1.f + expf(-zv));
        const float gv = yv * zv * sg;
        g[i] = gv;
        ss += gv * gv;
    }
    #pragma unroll
    for (int k = 1; k < 64; k <<= 1) ss += __shfl_xor(ss, k);
    __shared__ float wsum[4];
    if ((tid & 63) == 0) wsum[tid >> 6] = ss;
    __syncthreads();
    ss = wsum[0] + wsum[1] + wsum[2] + wsum[3];
    const float sc = rsqrtf(ss * (1.f / 2048.f) + 1e-5f);
    #pragma unroll
    for (int i = 0; i < 8; ++i) {
        const int c = tid + i * 256;
        gn[(size_t)bl * DIN + c] = g[i] * sc * norm_w[c];
    }
}

// ---------------------------------------------------------------------------
extern "C" void kernel_launch(void* const* d_in, const int* in_sizes, int n_in,
                              void* d_out, int out_size, void* d_ws, size_t ws_size,
                              hipStream_t stream) {
    const float* u          = (const float*)d_in[0];
    const float* in_proj_w  = (const float*)d_in[1];
    const float* dt_bias    = (const float*)d_in[2];
    const float* A_log      = (const float*)d_in[3];
    const float* Dp         = (const float*)d_in[4];
    const float* B_norm_w   = (const float*)d_in[5];
    const float* C_norm_w   = (const float*)d_in[6];
    const float* B_bias     = (const float*)d_in[7];
    const float* C_bias     = (const float*)d_in[8];
    const float* norm_w     = (const float*)d_in[9];
    const float* out_proj_w = (const float*)d_in[10];
    float* out = (float*)d_out;

    float* p = (float*)d_ws;
    float* zx    = p; p += (size_t)ROWS * DTOT;
    float* th_cs = p; p += (size_t)ROWS * 1024;   // dead after rot -> reused as hseg
    float* Brot  = p; p += (size_t)ROWS * 2048;
    float* Crot  = p; p += (size_t)ROWS * 2048;
    float* Bg    = p; p += (size_t)ROWS * 64;     // dead after rot -> reused as aprod
    float* Cg    = p; p += (size_t)ROWS * 64;
    float4* abg4 = (float4*)p; p += (size_t)ROWS * NH * 4;
    float* yb    = p; p += (size_t)ROWS * 2048;
    float* gn    = Brot;    // Brot dead after scan_p2
    float* hseg  = th_cs;   // needs 64*8*64*64 = 2,097,152 floats = exactly th_cs size
    float* aprod = Bg;      // needs 512 floats

    // 1a. z/x block via bf16 MFMA: zx[:, 0:4096]
    mfma_gemm_zx<<<dim3(NZX / 128, ROWS / 128), 256, 0, stream>>>(u, in_proj_w, zx);
    // 1b. sensitive columns via split-bf16 3-pass MFMA: zx[:, 4096:5312]
    mfma_gemm_rem3<<<dim3(NREM / 64, ROWS / 128), 256, 0, stream>>>(
        u, in_proj_w + (size_t)NZX * DMODEL, zx + NZX);
    // 2. per-row prep
    prep_kernel<<<ROWS, 64, 0, stream>>>(zx, dt_bias, A_log, B_norm_w, C_norm_w,
                                         Bg, Cg, abg4);
    // 3. cumsum of theta over L
    cumsum_kernel<<<BB * NH, 256, 0, stream>>>(zx, th_cs);
    // 4. rotary on B/C
    rot_kernel<<<(ROWS * 1024) / 256, 256, 0, stream>>>(th_cs, Bg, Cg, B_bias, C_bias,
                                                        Brot, Crot);
    // 5. segmented scan: local pass -> fixup -> final pass
    scan_p1<<<BB * NH * 4 * NSEG, 256, 0, stream>>>(zx, Brot, abg4, hseg, aprod);
    scan_fix<<<BB * NH * 4, 256, 0, stream>>>(hseg, aprod);
    scan_p2<<<BB * NH * 4 * NSEG, 256, 0, stream>>>(zx, Brot, Crot, abg4, hseg, Dp, yb);
    // 6. gate + RMS norm
    gate_norm_kernel<<<ROWS, 256, 0, stream>>>(yb, zx, norm_w, gn);
    // 7. out = gn @ out_proj_w^T  via bf16 MFMA
    mfma_gemm_out<<<dim3(DMODEL / 64, ROWS / 128), 256, 0, stream>>>(
        gn, out_proj_w, out, DIN, DMODEL);
}

// Round 11
// 293.238 us; speedup vs baseline: 1.2072x; 1.0829x over previous
//
#include <hip/hip_runtime.h>
#include <hip/hip_bf16.h>

// Problem constants
#define DMODEL 1024
#define DIN    2048
#define NH     32
#define HD     64
#define DS     64
#define LSEQ   1024
#define BB     2
#define DTOT   5312           // 2*DIN + 2*64 + 32 + 1024 + 32
#define ROWS   (BB*LSEQ)      // 2048
// column offsets inside zxbcdt
#define OFF_Z   0
#define OFF_X   2048
#define OFF_BR  4096
#define OFF_CR  4160
#define OFF_DT  4224
#define OFF_TH  4256
#define OFF_LAM 5280
#define NZX     4096          // z+x columns: single-pass bf16 MFMA
#define NREM    (DTOT - NZX)  // 1216 cols: 3-pass split-bf16 MFMA
// segmented scan
#define NSEG 8
#define SEG  (LSEQ / NSEG)    // 128

typedef short  s16x8 __attribute__((ext_vector_type(8)));
typedef float  f32x4 __attribute__((ext_vector_type(4)));
typedef unsigned short u16;

__device__ __forceinline__ unsigned int f2bf(float f) {   // RNE f32->bf16 (finite inputs)
    unsigned int u = __float_as_uint(f);
    u += 0x7fffu + ((u >> 16) & 1u);
    return u >> 16;
}
__device__ __forceinline__ unsigned int pk(float x, float y) {
    return f2bf(x) | (f2bf(y) << 16);
}

// ---------------------------------------------------------------------------
// conversion kernels: fp32 -> bf16 (hi) and residual (lo). Values are
// bit-identical to the previous inline f2bf/split2 — absmax must not move.
// ---------------------------------------------------------------------------
__global__ __launch_bounds__(256) void conv_u(const float* __restrict__ src,
        u16* __restrict__ hi, u16* __restrict__ lo) {
    const size_t i4 = ((size_t)blockIdx.x * 256 + threadIdx.x) * 4;
    const float4 v = *(const float4*)(src + i4);
    const unsigned int h0 = f2bf(v.x), h1 = f2bf(v.y), h2 = f2bf(v.z), h3 = f2bf(v.w);
    uint2 hw, lw;
    hw.x = h0 | (h1 << 16); hw.y = h2 | (h3 << 16);
    lw.x = pk(v.x - __uint_as_float(h0 << 16), v.y - __uint_as_float(h1 << 16));
    lw.y = pk(v.z - __uint_as_float(h2 << 16), v.w - __uint_as_float(h3 << 16));
    *(uint2*)(hi + i4) = hw;
    *(uint2*)(lo + i4) = lw;
}

__global__ __launch_bounds__(256) void conv_w(const float* __restrict__ src,
        u16* __restrict__ hi, u16* __restrict__ lo) {
    const size_t i4 = ((size_t)blockIdx.x * 256 + threadIdx.x) * 4;
    const float4 v = *(const float4*)(src + i4);
    const unsigned int h0 = f2bf(v.x), h1 = f2bf(v.y), h2 = f2bf(v.z), h3 = f2bf(v.w);
    uint2 hw, lw;
    hw.x = h0 | (h1 << 16); hw.y = h2 | (h3 << 16);
    lw.x = pk(v.x - __uint_as_float(h0 << 16), v.y - __uint_as_float(h1 << 16));
    lw.y = pk(v.z - __uint_as_float(h2 << 16), v.w - __uint_as_float(h3 << 16));
    *(uint2*)(hi + i4) = hw;
    if ((i4 >> 10) >= NZX)                       // rows >= 4096: keep residual
        *(uint2*)(lo + (i4 - (size_t)NZX * DMODEL)) = lw;
}

__global__ __launch_bounds__(256) void conv_wo(const float* __restrict__ src,
        u16* __restrict__ hi) {
    const size_t i4 = ((size_t)blockIdx.x * 256 + threadIdx.x) * 4;
    const float4 v = *(const float4*)(src + i4);
    uint2 hw;
    hw.x = pk(v.x, v.y); hw.y = pk(v.z, v.w);
    *(uint2*)(hi + i4) = hw;
}

// ---------------------------------------------------------------------------
// bf16 MFMA GEMM, z/x block: zx[:, 0:4096] = u_bf @ w_bf[0:4096,:]^T
// 128x128 tile, BK=32, 4 waves (2x2). Operands pre-converted to bf16.
// ---------------------------------------------------------------------------
#define LDB 40
__global__ __launch_bounds__(256) void mfma_gemm_zx(const u16* __restrict__ uA_,
                                                    const u16* __restrict__ uW,
                                                    float* __restrict__ zx) {
    __shared__ u16 Al[128][LDB];
    __shared__ u16 Bl[128][LDB];
    const int tid = threadIdx.x;
    const int m0 = blockIdx.y * 128, n0 = blockIdx.x * 128;
    const int lane = tid & 63, wave = tid >> 6;
    const int wr = wave >> 1, wc = wave & 1;
    const int lr = lane >> 4, lc = lane & 15;
    const int r  = tid >> 2;
    const int cb = (tid & 3) * 8;

    f32x4 acc[4][4] = {};

    const u16* pA = uA_ + (size_t)(m0 + r) * DMODEL + cb;
    const u16* pB = uW  + (size_t)(n0 + r) * DMODEL + cb;

    for (int k0 = 0; k0 < DMODEL; k0 += 32) {
        const s16x8 a0 = *(const s16x8*)(pA + k0);
        const s16x8 a1 = *(const s16x8*)(pA + k0 + (size_t)64 * DMODEL);
        const s16x8 b0 = *(const s16x8*)(pB + k0);
        const s16x8 b1 = *(const s16x8*)(pB + k0 + (size_t)64 * DMODEL);
        __syncthreads();
        *(s16x8*)&Al[r][cb]      = a0;
        *(s16x8*)&Al[r + 64][cb] = a1;
        *(s16x8*)&Bl[r][cb]      = b0;
        *(s16x8*)&Bl[r + 64][cb] = b1;
        __syncthreads();
        s16x8 af[4], bf[4];
        #pragma unroll
        for (int f = 0; f < 4; ++f) {
            af[f] = *(const s16x8*)&Al[wr * 64 + f * 16 + lc][lr * 8];
            bf[f] = *(const s16x8*)&Bl[wc * 64 + f * 16 + lc][lr * 8];
        }
        #pragma unroll
        for (int fm = 0; fm < 4; ++fm)
            #pragma unroll
            for (int fn = 0; fn < 4; ++fn)
                acc[fm][fn] = __builtin_amdgcn_mfma_f32_16x16x32_bf16(
                    af[fm], bf[fn], acc[fm][fn], 0, 0, 0);
    }

    #pragma unroll
    for (int fm = 0; fm < 4; ++fm)
        #pragma unroll
        for (int fn = 0; fn < 4; ++fn) {
            const size_t col = n0 + wc * 64 + fn * 16 + lc;
            #pragma unroll
            for (int j = 0; j < 4; ++j) {
                const size_t row = m0 + wr * 64 + fm * 16 + lr * 4 + j;
                zx[row * DTOT + col] = acc[fm][fn][j];
            }
        }
}

// ---------------------------------------------------------------------------
// bf16 MFMA GEMM, 128x64 tile: out = gn_bf @ wo_bf^T (N=1024, K=2048)
// ---------------------------------------------------------------------------
__global__ __launch_bounds__(256) void mfma_gemm_out(const u16* __restrict__ A,
                                                     const u16* __restrict__ B,
                                                     float* __restrict__ C,
                                                     int K, int ldc) {
    __shared__ u16 Als[128][LDB];
    __shared__ u16 Bls[64][LDB];
    const int tid = threadIdx.x;
    const int m0 = blockIdx.y * 128, n0 = blockIdx.x * 64;
    const int lane = tid & 63, wave = tid >> 6;
    const int wr = wave >> 1, wc = wave & 1;
    const int lr = lane >> 4, lc = lane & 15;
    const int r  = tid >> 2;
    const int cb = (tid & 3) * 8;

    f32x4 acc[4][2] = {};

    const u16* pA = A + (size_t)(m0 + r) * K + cb;
    const u16* pB = B + (size_t)(n0 + r) * K + cb;

    for (int k0 = 0; k0 < K; k0 += 32) {
        const s16x8 a0 = *(const s16x8*)(pA + k0);
        const s16x8 a1 = *(const s16x8*)(pA + k0 + (size_t)64 * K);
        const s16x8 b0 = *(const s16x8*)(pB + k0);
        __syncthreads();
        *(s16x8*)&Als[r][cb]      = a0;
        *(s16x8*)&Als[r + 64][cb] = a1;
        *(s16x8*)&Bls[r][cb]      = b0;
        __syncthreads();
        s16x8 af[4], bf[2];
        #pragma unroll
        for (int f = 0; f < 4; ++f)
            af[f] = *(const s16x8*)&Als[wr * 64 + f * 16 + lc][lr * 8];
        #pragma unroll
        for (int f = 0; f < 2; ++f)
            bf[f] = *(const s16x8*)&Bls[wc * 32 + f * 16 + lc][lr * 8];
        #pragma unroll
        for (int fm = 0; fm < 4; ++fm)
            #pragma unroll
            for (int fn = 0; fn < 2; ++fn)
                acc[fm][fn] = __builtin_amdgcn_mfma_f32_16x16x32_bf16(
                    af[fm], bf[fn], acc[fm][fn], 0, 0, 0);
    }

    #pragma unroll
    for (int fm = 0; fm < 4; ++fm)
        #pragma unroll
        for (int fn = 0; fn < 2; ++fn) {
            const size_t col = n0 + wc * 32 + fn * 16 + lc;
            #pragma unroll
            for (int j = 0; j < 4; ++j) {
                const size_t row = m0 + wr * 64 + fm * 16 + lr * 4 + j;
                C[row * (size_t)ldc + col] = acc[fm][fn][j];
            }
        }
}

// ---------------------------------------------------------------------------
// split-bf16 3-pass MFMA GEMM, sensitive columns (theta cumsum):
// acc += uh*wh + uh*wl + ul*wh. Operands pre-split to bf16 hi/lo.
// ---------------------------------------------------------------------------
__global__ __launch_bounds__(256) void mfma_gemm_rem3(const u16* __restrict__ uh,
        const u16* __restrict__ ul, const u16* __restrict__ wh,
        const u16* __restrict__ wl, float* __restrict__ zxr) {
    __shared__ u16 Ah[128][LDB], Alo[128][LDB];
    __shared__ u16 Bh[64][LDB],  Blo[64][LDB];
    const int tid = threadIdx.x;
    const int m0 = blockIdx.y * 128, n0 = blockIdx.x * 64;
    const int lane = tid & 63, wave = tid >> 6;
    const int wr = wave >> 1, wc = wave & 1;
    const int lr = lane >> 4, lc = lane & 15;
    const int r  = tid >> 2;
    const int cb = (tid & 3) * 8;

    f32x4 acc[4][2] = {};

    const u16* pAh = uh + (size_t)(m0 + r) * DMODEL + cb;
    const u16* pAl = ul + (size_t)(m0 + r) * DMODEL + cb;
    const u16* pBh = wh + (size_t)(n0 + r) * DMODEL + cb;   // n0+r <= 1215
    const u16* pBl = wl + (size_t)(n0 + r) * DMODEL + cb;

    for (int k0 = 0; k0 < DMODEL; k0 += 32) {
        const s16x8 ah0 = *(const s16x8*)(pAh + k0);
        const s16x8 ah1 = *(const s16x8*)(pAh + k0 + (size_t)64 * DMODEL);
        const s16x8 al0 = *(const s16x8*)(pAl + k0);
        const s16x8 al1 = *(const s16x8*)(pAl + k0 + (size_t)64 * DMODEL);
        const s16x8 bh0 = *(const s16x8*)(pBh + k0);
        const s16x8 bl0 = *(const s16x8*)(pBl + k0);
        __syncthreads();
        *(s16x8*)&Ah[r][cb]       = ah0;
        *(s16x8*)&Ah[r + 64][cb]  = ah1;
        *(s16x8*)&Alo[r][cb]      = al0;
        *(s16x8*)&Alo[r + 64][cb] = al1;
        *(s16x8*)&Bh[r][cb]       = bh0;
        *(s16x8*)&Blo[r][cb]      = bl0;
        __syncthreads();
        s16x8 ahf[4], alf[4], bhf[2], blf[2];
        #pragma unroll
        for (int f = 0; f < 4; ++f) {
            ahf[f] = *(const s16x8*)&Ah[wr * 64 + f * 16 + lc][lr * 8];
            alf[f] = *(const s16x8*)&Alo[wr * 64 + f * 16 + lc][lr * 8];
        }
        #pragma unroll
        for (int f = 0; f < 2; ++f) {
            bhf[f] = *(const s16x8*)&Bh[wc * 32 + f * 16 + lc][lr * 8];
            blf[f] = *(const s16x8*)&Blo[wc * 32 + f * 16 + lc][lr * 8];
        }
        #pragma unroll
        for (int fm = 0; fm < 4; ++fm)
            #pragma unroll
            for (int fn = 0; fn < 2; ++fn) {
                acc[fm][fn] = __builtin_amdgcn_mfma_f32_16x16x32_bf16(
                    ahf[fm], bhf[fn], acc[fm][fn], 0, 0, 0);
                acc[fm][fn] = __builtin_amdgcn_mfma_f32_16x16x32_bf16(
                    ahf[fm], blf[fn], acc[fm][fn], 0, 0, 0);
                acc[fm][fn] = __builtin_amdgcn_mfma_f32_16x16x32_bf16(
                    alf[fm], bhf[fn], acc[fm][fn], 0, 0, 0);
            }
    }

    #pragma unroll
    for (int fm = 0; fm < 4; ++fm)
        #pragma unroll
        for (int fn = 0; fn < 2; ++fn) {
            const size_t col = n0 + wc * 32 + fn * 16 + lc;
            #pragma unroll
            for (int j = 0; j < 4; ++j) {
                const size_t row = m0 + wr * 64 + fm * 16 + lr * 4 + j;
                zxr[row * DTOT + col] = acc[fm][fn][j];
            }
        }
}

// ---------------------------------------------------------------------------
// prep: RMS-norm Br/Cr; alpha/beta/gamma packed as float4 in (b,h,l) layout.
// ---------------------------------------------------------------------------
__global__ __launch_bounds__(64) void prep_kernel(const float* __restrict__ zx,
        const float* __restrict__ dt_bias, const float* __restrict__ A_log,
        const float* __restrict__ B_norm_w, const float* __restrict__ C_norm_w,
        float* __restrict__ Bg, float* __restrict__ Cg,
        float4* __restrict__ abg4) {
    const int bl = blockIdx.x;
    const int b = bl >> 10, l = bl & (LSEQ - 1);
    const int t  = threadIdx.x;
    const float* row = zx + (size_t)bl * DTOT;
    const float br = row[OFF_BR + t];
    const float cr = row[OFF_CR + t];
    float ssb = br * br, ssc = cr * cr;
    #pragma unroll
    for (int k = 1; k < 64; k <<= 1) { ssb += __shfl_xor(ssb, k); ssc += __shfl_xor(ssc, k); }
    const float scB = rsqrtf(ssb * (1.f / 64.f) + 1e-5f);
    const float scC = rsqrtf(ssc * (1.f / 64.f) + 1e-5f);
    Bg[(size_t)bl * 64 + t] = br * scB * B_norm_w[t];
    Cg[(size_t)bl * 64 + t] = cr * scC * C_norm_w[t];
    if (t < NH) {
        const float dtr = row[OFF_DT + t] + dt_bias[t];
        const float dt  = (dtr > 20.f) ? dtr : log1pf(expf(dtr));
        const float lamr = row[OFF_LAM + t];
        const float lam  = 1.f / (1.f + expf(-lamr));
        const float Ah   = -expf(A_log[t]);
        const float al   = expf(dt * Ah);
        const size_t o = ((size_t)b * NH + t) * LSEQ + l;
        abg4[o] = make_float4(al, (1.f - lam) * dt * al, lam * dt, 0.f);
    }
}

// ---------------------------------------------------------------------------
// cumsum of thr over L, per (b,h): 32 dims.
// ---------------------------------------------------------------------------
__global__ __launch_bounds__(256) void cumsum_kernel(const float* __restrict__ zx,
                                                     float* __restrict__ th_cs) {
    const int bh = blockIdx.x;
    const int b = bh >> 5, h = bh & 31;
    const int d = threadIdx.x & 31, seg = threadIdx.x >> 5;
    const float* base = zx + (size_t)b * LSEQ * DTOT + OFF_TH + h * 32 + d;
    float* out = th_cs + (size_t)b * LSEQ * 1024 + h * 32 + d;
    __shared__ float sums[8][33];
    const int l0 = seg * 128;
    float s = 0.f;
    #pragma unroll 4
    for (int i = 0; i < 128; ++i) s += base[(size_t)(l0 + i) * DTOT];
    sums[seg][d] = s;
    __syncthreads();
    float acc = 0.f;
    for (int s2 = 0; s2 < seg; ++s2) acc += sums[s2][d];
    #pragma unroll 4
    for (int i = 0; i < 128; ++i) {
        acc += base[(size_t)(l0 + i) * DTOT];
        out[(size_t)(l0 + i) * 1024] = acc;
    }
}

// ---------------------------------------------------------------------------
// rot: Bh/Ch = rot(broadcast(Bg/Cg)+bias). Brot/Crot layout (B,NH,L,DS).
// ---------------------------------------------------------------------------
__global__ __launch_bounds__(256) void rot_kernel(const float* __restrict__ th_cs,
        const float* __restrict__ Bg, const float* __restrict__ Cg,
        const float* __restrict__ B_bias, const float* __restrict__ C_bias,
        float* __restrict__ Brot, float* __restrict__ Crot) {
    const size_t idx = (size_t)blockIdx.x * 256 + threadIdx.x;
    const int j = (int)(idx & 31);
    const int h = (int)((idx >> 5) & 31);
    const size_t bl = idx >> 10;
    const int l = (int)(bl & (LSEQ - 1));
    const int b = (int)(bl >> 10);
    const float th = th_cs[idx];
    float s, c;
    sincosf(th, &s, &c);
    float v1 = Bg[bl * 64 + j]      + B_bias[h * 64 + j];
    float v2 = Bg[bl * 64 + 32 + j] + B_bias[h * 64 + 32 + j];
    const size_t ob = ((size_t)(b * NH + h) * LSEQ + l) * DS + j;
    Brot[ob]      = v1 * c - v2 * s;
    Brot[ob + 32] = v1 * s + v2 * c;
    v1 = Cg[bl * 64 + j]      + C_bias[h * 64 + j];
    v2 = Cg[bl * 64 + 32 + j] + C_bias[h * 64 + 32 + j];
    Crot[ob]      = v1 * c - v2 * s;
    Crot[ob + 32] = v1 * s + v2 * c;
}

// ---------------------------------------------------------------------------
// DPP 16-lane row sum (VALU pipe). Lane 15 of each 16-lane row holds the sum.
// ---------------------------------------------------------------------------
__device__ __forceinline__ float row_sum16(float x) {
    int t;
    t = __builtin_amdgcn_update_dpp(0, __float_as_int(x), 0x111, 0xf, 0xf, true);
    x += __int_as_float(t);
    t = __builtin_amdgcn_update_dpp(0, __float_as_int(x), 0x112, 0xf, 0xf, true);
    x += __int_as_float(t);
    t = __builtin_amdgcn_update_dpp(0, __float_as_int(x), 0x114, 0xf, 0xf, true);
    x += __int_as_float(t);
    t = __builtin_amdgcn_update_dpp(0, __float_as_int(x), 0x118, 0xf, 0xf, true);
    x += __int_as_float(t);
    return x;
}

// ---------------------------------------------------------------------------
// Segmented scan (exact): h_end(seg) = h_local_end + (prod a)*h_start.
// 8 segments -> 2048 blocks -> 8 waves/SIMD TLP.
// ---------------------------------------------------------------------------
__global__ __launch_bounds__(256, 8) void scan_p1(const float* __restrict__ zx,
        const float* __restrict__ Brot, const float4* __restrict__ abg4,
        float* __restrict__ hseg, float* __restrict__ aprod) {
    const int blk = blockIdx.x;
    const int s = blk & (NSEG - 1), ptile = (blk >> 3) & 3, h = (blk >> 5) & 31, b = blk >> 10;
    const int tid = threadIdx.x;
    const int pl = tid >> 4, ng = tid & 15;
    const int p = ptile * 16 + pl;
    const int n0 = ng * 4;
    const int t0 = s * SEG;

    const size_t bh = (size_t)b * NH + h;
    const float* Bbase = Brot + bh * LSEQ * DS + n0;
    const float4* abase = abg4 + bh * LSEQ;
    const float* xbase = zx + (size_t)b * LSEQ * DTOT + OFF_X + h * HD + p;

    float hs0 = 0.f, hs1 = 0.f, hs2 = 0.f, hs3 = 0.f;
    float Bp0 = 0.f, Bp1 = 0.f, Bp2 = 0.f, Bp3 = 0.f;
    float xprev = 0.f, aP = 1.f;
    if (s > 0) {
        const float4 Bm = *(const float4*)(Bbase + (size_t)(t0 - 1) * DS);
        Bp0 = Bm.x; Bp1 = Bm.y; Bp2 = Bm.z; Bp3 = Bm.w;
        xprev = xbase[(size_t)(t0 - 1) * DTOT];
    }

    #pragma unroll 4
    for (int t = t0; t < t0 + SEG; ++t) {
        const float4 Bv = *(const float4*)(Bbase + (size_t)t * DS);
        const float4 av = abase[t];
        const float  xv = xbase[(size_t)t * DTOT];
        const float cp = av.y * xprev;
        const float cc = av.z * xv;
        hs0 = fmaf(av.x, hs0, fmaf(cp, Bp0, cc * Bv.x));
        hs1 = fmaf(av.x, hs1, fmaf(cp, Bp1, cc * Bv.y));
        hs2 = fmaf(av.x, hs2, fmaf(cp, Bp2, cc * Bv.z));
        hs3 = fmaf(av.x, hs3, fmaf(cp, Bp3, cc * Bv.w));
        aP *= av.x;
        Bp0 = Bv.x; Bp1 = Bv.y; Bp2 = Bv.z; Bp3 = Bv.w;
        xprev = xv;
    }

    float* hp = hseg + (((bh * NSEG + s) * HD + p) * DS + n0);
    *(float4*)hp = make_float4(hs0, hs1, hs2, hs3);
    if (tid == 0) aprod[bh * NSEG + s] = aP;
}

__global__ __launch_bounds__(256) void scan_fix(float* __restrict__ hseg,
                                                const float* __restrict__ aprod) {
    const int blk = blockIdx.x;          // (b,h,ptile): 256
    const int ptile = blk & 3, h = (blk >> 2) & 31, b = blk >> 7;
    const int tid = threadIdx.x;
    const int pl = tid >> 4, ng = tid & 15;
    const int p = ptile * 16 + pl;
    const int n0 = ng * 4;
    const size_t bh = (size_t)b * NH + h;

    float4 cur = make_float4(0.f, 0.f, 0.f, 0.f);
    #pragma unroll
    for (int s = 0; s < NSEG; ++s) {
        float* hp = hseg + (((bh * NSEG + s) * HD + p) * DS + n0);
        const float4 tmp = *(const float4*)hp;   // h_local_end[s]
        *(float4*)hp = cur;                      // h_start[s]
        const float a = aprod[bh * NSEG + s];
        cur.x = fmaf(a, cur.x, tmp.x);
        cur.y = fmaf(a, cur.y, tmp.y);
        cur.z = fmaf(a, cur.z, tmp.z);
        cur.w = fmaf(a, cur.w, tmp.w);
    }
}

__global__ __launch_bounds__(256, 8) void scan_p2(const float* __restrict__ zx,
        const float* __restrict__ Brot, const float* __restrict__ Crot,
        const float4* __restrict__ abg4, const float* __restrict__ hseg,
        const float* __restrict__ Dp, float* __restrict__ yb) {
    const int blk = blockIdx.x;
    const int s = blk & (NSEG - 1), ptile = (blk >> 3) & 3, h = (blk >> 5) & 31, b = blk >> 10;
    const int tid = threadIdx.x;
    const int pl = tid >> 4, ng = tid & 15;
    const int p = ptile * 16 + pl;
    const int n0 = ng * 4;
    const int t0 = s * SEG;

    const size_t bh = (size_t)b * NH + h;
    const float* Bbase = Brot + bh * LSEQ * DS + n0;
    const float* Cbase = Crot + bh * LSEQ * DS + n0;
    const float4* abase = abg4 + bh * LSEQ;
    const float* xbase = zx + (size_t)b * LSEQ * DTOT + OFF_X + h * HD + p;
    const float Dh = Dp[h];
    float* ybase = yb + (size_t)b * LSEQ * DIN + h * HD + p;

    const float4 h0v = *(const float4*)(hseg + (((bh * NSEG + s) * HD + p) * DS + n0));
    float hs0 = h0v.x, hs1 = h0v.y, hs2 = h0v.z, hs3 = h0v.w;
    float Bp0 = 0.f, Bp1 = 0.f, Bp2 = 0.f, Bp3 = 0.f;
    float xprev = 0.f;
    if (s > 0) {
        const float4 Bm = *(const float4*)(Bbase + (size_t)(t0 - 1) * DS);
        Bp0 = Bm.x; Bp1 = Bm.y; Bp2 = Bm.z; Bp3 = Bm.w;
        xprev = xbase[(size_t)(t0 - 1) * DTOT];
    }

    #pragma unroll 2
    for (int t = t0; t < t0 + SEG; ++t) {
        const float4 Bv = *(const float4*)(Bbase + (size_t)t * DS);
        const float4 Cv = *(const float4*)(Cbase + (size_t)t * DS);
        const float4 av = abase[t];
        const float  xv = xbase[(size_t)t * DTOT];
        const float cp = av.y * xprev;
        const float cc = av.z * xv;
        float ys;
        hs0 = fmaf(av.x, hs0, fmaf(cp, Bp0, cc * Bv.x)); ys  = Cv.x * hs0;
        hs1 = fmaf(av.x, hs1, fmaf(cp, Bp1, cc * Bv.y)); ys += Cv.y * hs1;
        hs2 = fmaf(av.x, hs2, fmaf(cp, Bp2, cc * Bv.z)); ys += Cv.z * hs2;
        hs3 = fmaf(av.x, hs3, fmaf(cp, Bp3, cc * Bv.w)); ys += Cv.w * hs3;
        ys = row_sum16(ys);
        if (ng == 15) ybase[(size_t)t * DIN] = fmaf(Dh, xv, ys);
        Bp0 = Bv.x; Bp1 = Bv.y; Bp2 = Bv.z; Bp3 = Bv.w;
        xprev = xv;
    }
}

// ---------------------------------------------------------------------------
// gate + final RMS norm; emits bf16 directly for the out_proj GEMM.
// ---------------------------------------------------------------------------
__global__ __launch_bounds__(256) void gate_norm_kernel(const float* __restrict__ yb,
        const float* __restrict__ zx, const float* __restrict__ norm_w,
        u16* __restrict__ gnb) {
    const int bl = blockIdx.x;
    const int tid = threadIdx.x;
    const float* yrow = yb + (size_t)bl * DIN;
    const float* zrow = zx + (size_t)bl * DTOT + OFF_Z;
    float g[8];
    float ss = 0.f;
    #pragma unroll
    for (int i = 0; i < 8; ++i) {
        const int c = tid + i * 256;
        const float yv = yrow[c];
        const float zv = zrow[c];
        const float sg = 1.f / (1.f + expf(-zv));
        const float gv = yv * zv * sg;
        g[i] = gv;
        ss += gv * gv;
    }
    #pragma unroll
    for (int k = 1; k < 64; k <<= 1) ss += __shfl_xor(ss, k);
    __shared__ float wsum[4];
    if ((tid & 63) == 0) wsum[tid >> 6] = ss;
    __syncthreads();
    ss = wsum[0] + wsum[1] + wsum[2] + wsum[3];
    const float sc = rsqrtf(ss * (1.f / 2048.f) + 1e-5f);
    #pragma unroll
    for (int i = 0; i < 8; ++i) {
        const int c = tid + i * 256;
        gnb[(size_t)bl * DIN + c] = (u16)f2bf(g[i] * sc * norm_w[c]);
    }
}

// ---------------------------------------------------------------------------
extern "C" void kernel_launch(void* const* d_in, const int* in_sizes, int n_in,
                              void* d_out, int out_size, void* d_ws, size_t ws_size,
                              hipStream_t stream) {
    const float* u          = (const float*)d_in[0];
    const float* in_proj_w  = (const float*)d_in[1];
    const float* dt_bias    = (const float*)d_in[2];
    const float* A_log      = (const float*)d_in[3];
    const float* Dp         = (const float*)d_in[4];
    const float* B_norm_w   = (const float*)d_in[5];
    const float* C_norm_w   = (const float*)d_in[6];
    const float* B_bias     = (const float*)d_in[7];
    const float* C_bias     = (const float*)d_in[8];
    const float* norm_w     = (const float*)d_in[9];
    const float* out_proj_w = (const float*)d_in[10];
    float* out = (float*)d_out;

    float* p = (float*)d_ws;
    float* zx    = p; p += (size_t)ROWS * DTOT;
    float* th_cs = p; p += (size_t)ROWS * 1024;   // dead after rot -> hseg
    float* Brot  = p; p += (size_t)ROWS * 2048;   // Brot+Crot double as bf16 scratch
    float* Crot  = p; p += (size_t)ROWS * 2048;
    float* Bg    = p; p += (size_t)ROWS * 64;     // dead after rot -> aprod
    float* Cg    = p; p += (size_t)ROWS * 64;
    float4* abg4 = (float4*)p; p += (size_t)ROWS * NH * 4;
    float* yb    = p; p += (size_t)ROWS * 2048;
    float* hseg  = th_cs;
    float* aprod = Bg;

    // Phase-A bf16 scratch inside Brot+Crot (8,388,608 floats; used 5,439,488):
    // consumed by the GEMMs BEFORE rot writes Brot/Crot (stream-ordered).
    u16* u_bf = (u16*)Brot;                           // 2,097,152
    u16* u_lo = u_bf + (size_t)ROWS * DMODEL;         // 2,097,152
    u16* w_bf = u_lo + (size_t)ROWS * DMODEL;         // 5,439,488
    u16* w_lo = w_bf + (size_t)DTOT * DMODEL;         // 1,245,184
    // Phase-B (after scan, Brot/Crot dead again):
    u16* gn_bf = (u16*)Brot;                          // 4,194,304
    u16* wo_bf = gn_bf + (size_t)ROWS * DIN;          // 2,097,152

    // 0. one-time fp32 -> bf16 (+residual) conversions
    conv_u<<<(ROWS * DMODEL / 4) / 256, 256, 0, stream>>>(u, u_bf, u_lo);
    conv_w<<<((size_t)DTOT * DMODEL / 4) / 256, 256, 0, stream>>>(in_proj_w, w_bf, w_lo);
    // 1a. z/x block via bf16 MFMA: zx[:, 0:4096]
    mfma_gemm_zx<<<dim3(NZX / 128, ROWS / 128), 256, 0, stream>>>(u_bf, w_bf, zx);
    // 1b. sensitive columns via split-bf16 3-pass MFMA: zx[:, 4096:5312]
    mfma_gemm_rem3<<<dim3(NREM / 64, ROWS / 128), 256, 0, stream>>>(
        u_bf, u_lo, w_bf + (size_t)NZX * DMODEL, w_lo, zx + NZX);
    // 2. per-row prep
    prep_kernel<<<ROWS, 64, 0, stream>>>(zx, dt_bias, A_log, B_norm_w, C_norm_w,
                                         Bg, Cg, abg4);
    // 3. cumsum of theta over L
    cumsum_kernel<<<BB * NH, 256, 0, stream>>>(zx, th_cs);
    // 4. rotary on B/C (overwrites bf16 scratch — GEMMs already done)
    rot_kernel<<<(ROWS * 1024) / 256, 256, 0, stream>>>(th_cs, Bg, Cg, B_bias, C_bias,
                                                        Brot, Crot);
    // 5. segmented scan: local pass -> fixup -> final pass
    scan_p1<<<BB * NH * 4 * NSEG, 256, 0, stream>>>(zx, Brot, abg4, hseg, aprod);
    scan_fix<<<BB * NH * 4, 256, 0, stream>>>(hseg, aprod);
    scan_p2<<<BB * NH * 4 * NSEG, 256, 0, stream>>>(zx, Brot, Crot, abg4, hseg, Dp, yb);
    // 6. out_proj_w -> bf16 (Crot region dead after scan_p2)
    conv_wo<<<(DMODEL * DIN / 4) / 256, 256, 0, stream>>>(out_proj_w, wo_bf);
    // 7. gate + RMS norm -> bf16
    gate_norm_kernel<<<ROWS, 256, 0, stream>>>(yb, zx, norm_w, gn_bf);
    // 8. out = gn @ out_proj_w^T via bf16 MFMA
    mfma_gemm_out<<<dim3(DMODEL / 64, ROWS / 128), 256, 0, stream>>>(
        gn_bf, wo_bf, out, DIN, DMODEL);
}

// Round 12
// 284.883 us; speedup vs baseline: 1.2427x; 1.0293x over previous
//
#include <hip/hip_runtime.h>
#include <hip/hip_bf16.h>

// Problem constants
#define DMODEL 1024
#define DIN    2048
#define NH     32
#define HD     64
#define DS     64
#define LSEQ   1024
#define BB     2
#define DTOT   5312           // 2*DIN + 2*64 + 32 + 1024 + 32
#define ROWS   (BB*LSEQ)      // 2048
// column offsets inside zxbcdt
#define OFF_Z   0
#define OFF_X   2048
#define OFF_BR  4096
#define OFF_CR  4160
#define OFF_DT  4224
#define OFF_TH  4256
#define OFF_LAM 5280
#define NZX     4096          // z+x columns: single-pass bf16 MFMA
#define NREM    (DTOT - NZX)  // 1216 cols: 3-pass split-bf16 MFMA
// segmented scan
#define NSEG 8
#define SEG  (LSEQ / NSEG)    // 128

typedef short  s16x8 __attribute__((ext_vector_type(8)));
typedef float  f32x4 __attribute__((ext_vector_type(4)));
typedef unsigned short u16;

__device__ __forceinline__ unsigned int f2bf(float f) {   // RNE f32->bf16 (finite inputs)
    unsigned int u = __float_as_uint(f);
    u += 0x7fffu + ((u >> 16) & 1u);
    return u >> 16;
}
__device__ __forceinline__ unsigned int pk(float x, float y) {
    return f2bf(x) | (f2bf(y) << 16);
}

// HBM -> LDS direct 16B copy (global_load_lds_dwordx4). Dest must be
// wave-uniform base + lane*16 (m104): we use dest = ldsBase + tid*16B.
typedef const __attribute__((address_space(1))) unsigned int glb_u32;
typedef __attribute__((address_space(3))) unsigned int lds_u32;
__device__ __forceinline__ void gload16(const void* g, void* l) {
    __builtin_amdgcn_global_load_lds((glb_u32*)g, (lds_u32*)l, 16, 0, 0);
}

// ---------------------------------------------------------------------------
// conversion kernels: fp32 -> bf16 (hi) and residual (lo). Bit-identical
// to inline f2bf/split — absmax must not move.
// ---------------------------------------------------------------------------
__global__ __launch_bounds__(256) void conv_u(const float* __restrict__ src,
        u16* __restrict__ hi, u16* __restrict__ lo) {
    const size_t i4 = ((size_t)blockIdx.x * 256 + threadIdx.x) * 4;
    const float4 v = *(const float4*)(src + i4);
    const unsigned int h0 = f2bf(v.x), h1 = f2bf(v.y), h2 = f2bf(v.z), h3 = f2bf(v.w);
    uint2 hw, lw;
    hw.x = h0 | (h1 << 16); hw.y = h2 | (h3 << 16);
    lw.x = pk(v.x - __uint_as_float(h0 << 16), v.y - __uint_as_float(h1 << 16));
    lw.y = pk(v.z - __uint_as_float(h2 << 16), v.w - __uint_as_float(h3 << 16));
    *(uint2*)(hi + i4) = hw;
    *(uint2*)(lo + i4) = lw;
}

__global__ __launch_bounds__(256) void conv_w(const float* __restrict__ src,
        u16* __restrict__ hi, u16* __restrict__ lo) {
    const size_t i4 = ((size_t)blockIdx.x * 256 + threadIdx.x) * 4;
    const float4 v = *(const float4*)(src + i4);
    const unsigned int h0 = f2bf(v.x), h1 = f2bf(v.y), h2 = f2bf(v.z), h3 = f2bf(v.w);
    uint2 hw, lw;
    hw.x = h0 | (h1 << 16); hw.y = h2 | (h3 << 16);
    lw.x = pk(v.x - __uint_as_float(h0 << 16), v.y - __uint_as_float(h1 << 16));
    lw.y = pk(v.z - __uint_as_float(h2 << 16), v.w - __uint_as_float(h3 << 16));
    *(uint2*)(hi + i4) = hw;
    if ((i4 >> 10) >= NZX)                       // rows >= 4096: keep residual
        *(uint2*)(lo + (i4 - (size_t)NZX * DMODEL)) = lw;
}

__global__ __launch_bounds__(256) void conv_wo(const float* __restrict__ src,
        u16* __restrict__ hi) {
    const size_t i4 = ((size_t)blockIdx.x * 256 + threadIdx.x) * 4;
    const float4 v = *(const float4*)(src + i4);
    uint2 hw;
    hw.x = pk(v.x, v.y); hw.y = pk(v.z, v.w);
    *(uint2*)(hi + i4) = hw;
}

// ---------------------------------------------------------------------------
// bf16 MFMA GEMM, z/x block: zx[:, 0:4096] = u_bf @ w_bf[0:4096,:]^T
// 128x128 tile, BK=32, 4 waves. global_load_lds staging, linear LDS [128][32].
// ---------------------------------------------------------------------------
__global__ __launch_bounds__(256) void mfma_gemm_zx(const u16* __restrict__ uA_,
                                                    const u16* __restrict__ uW,
                                                    float* __restrict__ zx) {
    __shared__ u16 Al[128 * 32];
    __shared__ u16 Bl[128 * 32];
    const int tid = threadIdx.x;
    const int m0 = blockIdx.y * 128, n0 = blockIdx.x * 128;
    const int lane = tid & 63, wave = tid >> 6;
    const int wr = wave >> 1, wc = wave & 1;
    const int lr = lane >> 4, lc = lane & 15;
    const int sr = tid >> 2;            // staging row 0..63
    const int sc = (tid & 3) * 8;       // staging col (u16)

    f32x4 acc[4][4] = {};

    const u16* pA = uA_ + (size_t)(m0 + sr) * DMODEL + sc;
    const u16* pB = uW  + (size_t)(n0 + sr) * DMODEL + sc;
    u16* ldA = Al + tid * 8;            // dest = base + tid*16B (lane-linear)
    u16* ldB = Bl + tid * 8;

    for (int k0 = 0; k0 < DMODEL; k0 += 32) {
        __syncthreads();                 // prev iteration's frag reads done
        gload16(pA + k0, ldA);
        gload16(pA + k0 + (size_t)64 * DMODEL, ldA + 2048);
        gload16(pB + k0, ldB);
        gload16(pB + k0 + (size_t)64 * DMODEL, ldB + 2048);
        __syncthreads();                 // vmcnt(0) drained -> tile visible
        s16x8 af[4], bf[4];
        #pragma unroll
        for (int f = 0; f < 4; ++f) {
            af[f] = *(const s16x8*)&Al[(wr * 64 + f * 16 + lc) * 32 + lr * 8];
            bf[f] = *(const s16x8*)&Bl[(wc * 64 + f * 16 + lc) * 32 + lr * 8];
        }
        #pragma unroll
        for (int fm = 0; fm < 4; ++fm)
            #pragma unroll
            for (int fn = 0; fn < 4; ++fn)
                acc[fm][fn] = __builtin_amdgcn_mfma_f32_16x16x32_bf16(
                    af[fm], bf[fn], acc[fm][fn], 0, 0, 0);
    }

    #pragma unroll
    for (int fm = 0; fm < 4; ++fm)
        #pragma unroll
        for (int fn = 0; fn < 4; ++fn) {
            const size_t col = n0 + wc * 64 + fn * 16 + lc;
            #pragma unroll
            for (int j = 0; j < 4; ++j) {
                const size_t row = m0 + wr * 64 + fm * 16 + lr * 4 + j;
                zx[row * DTOT + col] = acc[fm][fn][j];
            }
        }
}

// ---------------------------------------------------------------------------
// bf16 MFMA GEMM, 128x64 tile: out = gn_bf @ wo_bf^T (N=1024, K=2048)
// ---------------------------------------------------------------------------
__global__ __launch_bounds__(256) void mfma_gemm_out(const u16* __restrict__ A,
                                                     const u16* __restrict__ B,
                                                     float* __restrict__ C,
                                                     int K, int ldc) {
    __shared__ u16 Als[128 * 32];
    __shared__ u16 Bls[64 * 32];
    const int tid = threadIdx.x;
    const int m0 = blockIdx.y * 128, n0 = blockIdx.x * 64;
    const int lane = tid & 63, wave = tid >> 6;
    const int wr = wave >> 1, wc = wave & 1;
    const int lr = lane >> 4, lc = lane & 15;
    const int sr = tid >> 2;
    const int sc = (tid & 3) * 8;

    f32x4 acc[4][2] = {};

    const u16* pA = A + (size_t)(m0 + sr) * K + sc;
    const u16* pB = B + (size_t)(n0 + sr) * K + sc;
    u16* ldA = Als + tid * 8;
    u16* ldB = Bls + tid * 8;

    for (int k0 = 0; k0 < K; k0 += 32) {
        __syncthreads();
        gload16(pA + k0, ldA);
        gload16(pA + k0 + (size_t)64 * K, ldA + 2048);
        gload16(pB + k0, ldB);
        __syncthreads();
        s16x8 af[4], bf[2];
        #pragma unroll
        for (int f = 0; f < 4; ++f)
            af[f] = *(const s16x8*)&Als[(wr * 64 + f * 16 + lc) * 32 + lr * 8];
        #pragma unroll
        for (int f = 0; f < 2; ++f)
            bf[f] = *(const s16x8*)&Bls[(wc * 32 + f * 16 + lc) * 32 + lr * 8];
        #pragma unroll
        for (int fm = 0; fm < 4; ++fm)
            #pragma unroll
            for (int fn = 0; fn < 2; ++fn)
                acc[fm][fn] = __builtin_amdgcn_mfma_f32_16x16x32_bf16(
                    af[fm], bf[fn], acc[fm][fn], 0, 0, 0);
    }

    #pragma unroll
    for (int fm = 0; fm < 4; ++fm)
        #pragma unroll
        for (int fn = 0; fn < 2; ++fn) {
            const size_t col = n0 + wc * 32 + fn * 16 + lc;
            #pragma unroll
            for (int j = 0; j < 4; ++j) {
                const size_t row = m0 + wr * 64 + fm * 16 + lr * 4 + j;
                C[row * (size_t)ldc + col] = acc[fm][fn][j];
            }
        }
}

// ---------------------------------------------------------------------------
// split-bf16 3-pass MFMA GEMM, sensitive columns (theta cumsum):
// acc += uh*wh + uh*wl + ul*wh. global_load_lds staging (6 issues/K-step).
// ---------------------------------------------------------------------------
__global__ __launch_bounds__(256) void mfma_gemm_rem3(const u16* __restrict__ uh,
        const u16* __restrict__ ul, const u16* __restrict__ wh,
        const u16* __restrict__ wl, float* __restrict__ zxr) {
    __shared__ u16 Ah[128 * 32], Alo[128 * 32];
    __shared__ u16 Bh[64 * 32],  Blo[64 * 32];
    const int tid = threadIdx.x;
    const int m0 = blockIdx.y * 128, n0 = blockIdx.x * 64;
    const int lane = tid & 63, wave = tid >> 6;
    const int wr = wave >> 1, wc = wave & 1;
    const int lr = lane >> 4, lc = lane & 15;
    const int sr = tid >> 2;
    const int sc = (tid & 3) * 8;

    f32x4 acc[4][2] = {};

    const u16* pAh = uh + (size_t)(m0 + sr) * DMODEL + sc;
    const u16* pAl = ul + (size_t)(m0 + sr) * DMODEL + sc;
    const u16* pBh = wh + (size_t)(n0 + sr) * DMODEL + sc;   // n0+sr <= 1215
    const u16* pBl = wl + (size_t)(n0 + sr) * DMODEL + sc;
    u16* ldAh = Ah  + tid * 8;
    u16* ldAl = Alo + tid * 8;
    u16* ldBh = Bh  + tid * 8;
    u16* ldBl = Blo + tid * 8;

    for (int k0 = 0; k0 < DMODEL; k0 += 32) {
        __syncthreads();
        gload16(pAh + k0, ldAh);
        gload16(pAh + k0 + (size_t)64 * DMODEL, ldAh + 2048);
        gload16(pAl + k0, ldAl);
        gload16(pAl + k0 + (size_t)64 * DMODEL, ldAl + 2048);
        gload16(pBh + k0, ldBh);
        gload16(pBl + k0, ldBl);
        __syncthreads();
        s16x8 ahf[4], alf[4], bhf[2], blf[2];
        #pragma unroll
        for (int f = 0; f < 4; ++f) {
            ahf[f] = *(const s16x8*)&Ah[(wr * 64 + f * 16 + lc) * 32 + lr * 8];
            alf[f] = *(const s16x8*)&Alo[(wr * 64 + f * 16 + lc) * 32 + lr * 8];
        }
        #pragma unroll
        for (int f = 0; f < 2; ++f) {
            bhf[f] = *(const s16x8*)&Bh[(wc * 32 + f * 16 + lc) * 32 + lr * 8];
            blf[f] = *(const s16x8*)&Blo[(wc * 32 + f * 16 + lc) * 32 + lr * 8];
        }
        #pragma unroll
        for (int fm = 0; fm < 4; ++fm)
            #pragma unroll
            for (int fn = 0; fn < 2; ++fn) {
                acc[fm][fn] = __builtin_amdgcn_mfma_f32_16x16x32_bf16(
                    ahf[fm], bhf[fn], acc[fm][fn], 0, 0, 0);
                acc[fm][fn] = __builtin_amdgcn_mfma_f32_16x16x32_bf16(
                    ahf[fm], blf[fn], acc[fm][fn], 0, 0, 0);
                acc[fm][fn] = __builtin_amdgcn_mfma_f32_16x16x32_bf16(
                    alf[fm], bhf[fn], acc[fm][fn], 0, 0, 0);
            }
    }

    #pragma unroll
    for (int fm = 0; fm < 4; ++fm)
        #pragma unroll
        for (int fn = 0; fn < 2; ++fn) {
            const size_t col = n0 + wc * 32 + fn * 16 + lc;
            #pragma unroll
            for (int j = 0; j < 4; ++j) {
                const size_t row = m0 + wr * 64 + fm * 16 + lr * 4 + j;
                zxr[row * DTOT + col] = acc[fm][fn][j];
            }
        }
}

// ---------------------------------------------------------------------------
// prep: RMS-norm Br/Cr; alpha/beta/gamma packed as float4 in (b,h,l) layout.
// ---------------------------------------------------------------------------
__global__ __launch_bounds__(64) void prep_kernel(const float* __restrict__ zx,
        const float* __restrict__ dt_bias, const float* __restrict__ A_log,
        const float* __restrict__ B_norm_w, const float* __restrict__ C_norm_w,
        float* __restrict__ Bg, float* __restrict__ Cg,
        float4* __restrict__ abg4) {
    const int bl = blockIdx.x;
    const int b = bl >> 10, l = bl & (LSEQ - 1);
    const int t  = threadIdx.x;
    const float* row = zx + (size_t)bl * DTOT;
    const float br = row[OFF_BR + t];
    const float cr = row[OFF_CR + t];
    float ssb = br * br, ssc = cr * cr;
    #pragma unroll
    for (int k = 1; k < 64; k <<= 1) { ssb += __shfl_xor(ssb, k); ssc += __shfl_xor(ssc, k); }
    const float scB = rsqrtf(ssb * (1.f / 64.f) + 1e-5f);
    const float scC = rsqrtf(ssc * (1.f / 64.f) + 1e-5f);
    Bg[(size_t)bl * 64 + t] = br * scB * B_norm_w[t];
    Cg[(size_t)bl * 64 + t] = cr * scC * C_norm_w[t];
    if (t < NH) {
        const float dtr = row[OFF_DT + t] + dt_bias[t];
        const float dt  = (dtr > 20.f) ? dtr : log1pf(expf(dtr));
        const float lamr = row[OFF_LAM + t];
        const float lam  = 1.f / (1.f + expf(-lamr));
        const float Ah   = -expf(A_log[t]);
        const float al   = expf(dt * Ah);
        const size_t o = ((size_t)b * NH + t) * LSEQ + l;
        abg4[o] = make_float4(al, (1.f - lam) * dt * al, lam * dt, 0.f);
    }
}

// ---------------------------------------------------------------------------
// cumsum of thr over L, per (b,h): 32 dims.
// ---------------------------------------------------------------------------
__global__ __launch_bounds__(256) void cumsum_kernel(const float* __restrict__ zx,
                                                     float* __restrict__ th_cs) {
    const int bh = blockIdx.x;
    const int b = bh >> 5, h = bh & 31;
    const int d = threadIdx.x & 31, seg = threadIdx.x >> 5;
    const float* base = zx + (size_t)b * LSEQ * DTOT + OFF_TH + h * 32 + d;
    float* out = th_cs + (size_t)b * LSEQ * 1024 + h * 32 + d;
    __shared__ float sums[8][33];
    const int l0 = seg * 128;
    float s = 0.f;
    #pragma unroll 4
    for (int i = 0; i < 128; ++i) s += base[(size_t)(l0 + i) * DTOT];
    sums[seg][d] = s;
    __syncthreads();
    float acc = 0.f;
    for (int s2 = 0; s2 < seg; ++s2) acc += sums[s2][d];
    #pragma unroll 4
    for (int i = 0; i < 128; ++i) {
        acc += base[(size_t)(l0 + i) * DTOT];
        out[(size_t)(l0 + i) * 1024] = acc;
    }
}

// ---------------------------------------------------------------------------
// rot: Bh/Ch = rot(broadcast(Bg/Cg)+bias). Brot/Crot layout (B,NH,L,DS).
// ---------------------------------------------------------------------------
__global__ __launch_bounds__(256) void rot_kernel(const float* __restrict__ th_cs,
        const float* __restrict__ Bg, const float* __restrict__ Cg,
        const float* __restrict__ B_bias, const float* __restrict__ C_bias,
        float* __restrict__ Brot, float* __restrict__ Crot) {
    const size_t idx = (size_t)blockIdx.x * 256 + threadIdx.x;
    const int j = (int)(idx & 31);
    const int h = (int)((idx >> 5) & 31);
    const size_t bl = idx >> 10;
    const int l = (int)(bl & (LSEQ - 1));
    const int b = (int)(bl >> 10);
    const float th = th_cs[idx];
    float s, c;
    sincosf(th, &s, &c);
    float v1 = Bg[bl * 64 + j]      + B_bias[h * 64 + j];
    float v2 = Bg[bl * 64 + 32 + j] + B_bias[h * 64 + 32 + j];
    const size_t ob = ((size_t)(b * NH + h) * LSEQ + l) * DS + j;
    Brot[ob]      = v1 * c - v2 * s;
    Brot[ob + 32] = v1 * s + v2 * c;
    v1 = Cg[bl * 64 + j]      + C_bias[h * 64 + j];
    v2 = Cg[bl * 64 + 32 + j] + C_bias[h * 64 + 32 + j];
    Crot[ob]      = v1 * c - v2 * s;
    Crot[ob + 32] = v1 * s + v2 * c;
}

// ---------------------------------------------------------------------------
// DPP 16-lane row sum (VALU pipe). Lane 15 of each 16-lane row holds the sum.
// ---------------------------------------------------------------------------
__device__ __forceinline__ float row_sum16(float x) {
    int t;
    t = __builtin_amdgcn_update_dpp(0, __float_as_int(x), 0x111, 0xf, 0xf, true);
    x += __int_as_float(t);
    t = __builtin_amdgcn_update_dpp(0, __float_as_int(x), 0x112, 0xf, 0xf, true);
    x += __int_as_float(t);
    t = __builtin_amdgcn_update_dpp(0, __float_as_int(x), 0x114, 0xf, 0xf, true);
    x += __int_as_float(t);
    t = __builtin_amdgcn_update_dpp(0, __float_as_int(x), 0x118, 0xf, 0xf, true);
    x += __int_as_float(t);
    return x;
}

// ---------------------------------------------------------------------------
// Segmented scan (exact): h_end(seg) = h_local_end + (prod a)*h_start.
// 8 segments -> 2048 blocks -> 8 waves/SIMD TLP.
// ---------------------------------------------------------------------------
__global__ __launch_bounds__(256, 8) void scan_p1(const float* __restrict__ zx,
        const float* __restrict__ Brot, const float4* __restrict__ abg4,
        float* __restrict__ hseg, float* __restrict__ aprod) {
    const int blk = blockIdx.x;
    const int s = blk & (NSEG - 1), ptile = (blk >> 3) & 3, h = (blk >> 5) & 31, b = blk >> 10;
    const int tid = threadIdx.x;
    const int pl = tid >> 4, ng = tid & 15;
    const int p = ptile * 16 + pl;
    const int n0 = ng * 4;
    const int t0 = s * SEG;

    const size_t bh = (size_t)b * NH + h;
    const float* Bbase = Brot + bh * LSEQ * DS + n0;
    const float4* abase = abg4 + bh * LSEQ;
    const float* xbase = zx + (size_t)b * LSEQ * DTOT + OFF_X + h * HD + p;

    float hs0 = 0.f, hs1 = 0.f, hs2 = 0.f, hs3 = 0.f;
    float Bp0 = 0.f, Bp1 = 0.f, Bp2 = 0.f, Bp3 = 0.f;
    float xprev = 0.f, aP = 1.f;
    if (s > 0) {
        const float4 Bm = *(const float4*)(Bbase + (size_t)(t0 - 1) * DS);
        Bp0 = Bm.x; Bp1 = Bm.y; Bp2 = Bm.z; Bp3 = Bm.w;
        xprev = xbase[(size_t)(t0 - 1) * DTOT];
    }

    #pragma unroll 4
    for (int t = t0; t < t0 + SEG; ++t) {
        const float4 Bv = *(const float4*)(Bbase + (size_t)t * DS);
        const float4 av = abase[t];
        const float  xv = xbase[(size_t)t * DTOT];
        const float cp = av.y * xprev;
        const float cc = av.z * xv;
        hs0 = fmaf(av.x, hs0, fmaf(cp, Bp0, cc * Bv.x));
        hs1 = fmaf(av.x, hs1, fmaf(cp, Bp1, cc * Bv.y));
        hs2 = fmaf(av.x, hs2, fmaf(cp, Bp2, cc * Bv.z));
        hs3 = fmaf(av.x, hs3, fmaf(cp, Bp3, cc * Bv.w));
        aP *= av.x;
        Bp0 = Bv.x; Bp1 = Bv.y; Bp2 = Bv.z; Bp3 = Bv.w;
        xprev = xv;
    }

    float* hp = hseg + (((bh * NSEG + s) * HD + p) * DS + n0);
    *(float4*)hp = make_float4(hs0, hs1, hs2, hs3);
    if (tid == 0) aprod[bh * NSEG + s] = aP;
}

__global__ __launch_bounds__(256) void scan_fix(float* __restrict__ hseg,
                                                const float* __restrict__ aprod) {
    const int blk = blockIdx.x;          // (b,h,ptile): 256
    const int ptile = blk & 3, h = (blk >> 2) & 31, b = blk >> 7;
    const int tid = threadIdx.x;
    const int pl = tid >> 4, ng = tid & 15;
    const int p = ptile * 16 + pl;
    const int n0 = ng * 4;
    const size_t bh = (size_t)b * NH + h;

    float4 cur = make_float4(0.f, 0.f, 0.f, 0.f);
    #pragma unroll
    for (int s = 0; s < NSEG; ++s) {
        float* hp = hseg + (((bh * NSEG + s) * HD + p) * DS + n0);
        const float4 tmp = *(const float4*)hp;   // h_local_end[s]
        *(float4*)hp = cur;                      // h_start[s]
        const float a = aprod[bh * NSEG + s];
        cur.x = fmaf(a, cur.x, tmp.x);
        cur.y = fmaf(a, cur.y, tmp.y);
        cur.z = fmaf(a, cur.z, tmp.z);
        cur.w = fmaf(a, cur.w, tmp.w);
    }
}

__global__ __launch_bounds__(256, 8) void scan_p2(const float* __restrict__ zx,
        const float* __restrict__ Brot, const float* __restrict__ Crot,
        const float4* __restrict__ abg4, const float* __restrict__ hseg,
        const float* __restrict__ Dp, float* __restrict__ yb) {
    const int blk = blockIdx.x;
    const int s = blk & (NSEG - 1), ptile = (blk >> 3) & 3, h = (blk >> 5) & 31, b = blk >> 10;
    const int tid = threadIdx.x;
    const int pl = tid >> 4, ng = tid & 15;
    const int p = ptile * 16 + pl;
    const int n0 = ng * 4;
    const int t0 = s * SEG;

    const size_t bh = (size_t)b * NH + h;
    const float* Bbase = Brot + bh * LSEQ * DS + n0;
    const float* Cbase = Crot + bh * LSEQ * DS + n0;
    const float4* abase = abg4 + bh * LSEQ;
    const float* xbase = zx + (size_t)b * LSEQ * DTOT + OFF_X + h * HD + p;
    const float Dh = Dp[h];
    float* ybase = yb + (size_t)b * LSEQ * DIN + h * HD + p;

    const float4 h0v = *(const float4*)(hseg + (((bh * NSEG + s) * HD + p) * DS + n0));
    float hs0 = h0v.x, hs1 = h0v.y, hs2 = h0v.z, hs3 = h0v.w;
    float Bp0 = 0.f, Bp1 = 0.f, Bp2 = 0.f, Bp3 = 0.f;
    float xprev = 0.f;
    if (s > 0) {
        const float4 Bm = *(const float4*)(Bbase + (size_t)(t0 - 1) * DS);
        Bp0 = Bm.x; Bp1 = Bm.y; Bp2 = Bm.z; Bp3 = Bm.w;
        xprev = xbase[(size_t)(t0 - 1) * DTOT];
    }

    #pragma unroll 4
    for (int t = t0; t < t0 + SEG; ++t) {
        const float4 Bv = *(const float4*)(Bbase + (size_t)t * DS);
        const float4 Cv = *(const float4*)(Cbase + (size_t)t * DS);
        const float4 av = abase[t];
        const float  xv = xbase[(size_t)t * DTOT];
        const float cp = av.y * xprev;
        const float cc = av.z * xv;
        float ys;
        hs0 = fmaf(av.x, hs0, fmaf(cp, Bp0, cc * Bv.x)); ys  = Cv.x * hs0;
        hs1 = fmaf(av.x, hs1, fmaf(cp, Bp1, cc * Bv.y)); ys += Cv.y * hs1;
        hs2 = fmaf(av.x, hs2, fmaf(cp, Bp2, cc * Bv.z)); ys += Cv.z * hs2;
        hs3 = fmaf(av.x, hs3, fmaf(cp, Bp3, cc * Bv.w)); ys += Cv.w * hs3;
        ys = row_sum16(ys);
        if (ng == 15) ybase[(size_t)t * DIN] = fmaf(Dh, xv, ys);
        Bp0 = Bv.x; Bp1 = Bv.y; Bp2 = Bv.z; Bp3 = Bv.w;
        xprev = xv;
    }
}

// ---------------------------------------------------------------------------
// gate + final RMS norm; emits bf16 directly for the out_proj GEMM.
// ---------------------------------------------------------------------------
__global__ __launch_bounds__(256) void gate_norm_kernel(const float* __restrict__ yb,
        const float* __restrict__ zx, const float* __restrict__ norm_w,
        u16* __restrict__ gnb) {
    const int bl = blockIdx.x;
    const int tid = threadIdx.x;
    const float* yrow = yb + (size_t)bl * DIN;
    const float* zrow = zx + (size_t)bl * DTOT + OFF_Z;
    float g[8];
    float ss = 0.f;
    #pragma unroll
    for (int i = 0; i < 8; ++i) {
        const int c = tid + i * 256;
        const float yv = yrow[c];
        const float zv = zrow[c];
        const float sg = 1.f / (1.f + expf(-zv));
        const float gv = yv * zv * sg;
        g[i] = gv;
        ss += gv * gv;
    }
    #pragma unroll
    for (int k = 1; k < 64; k <<= 1) ss += __shfl_xor(ss, k);
    __shared__ float wsum[4];
    if ((tid & 63) == 0) wsum[tid >> 6] = ss;
    __syncthreads();
    ss = wsum[0] + wsum[1] + wsum[2] + wsum[3];
    const float sc = rsqrtf(ss * (1.f / 2048.f) + 1e-5f);
    #pragma unroll
    for (int i = 0; i < 8; ++i) {
        const int c = tid + i * 256;
        gnb[(size_t)bl * DIN + c] = (u16)f2bf(g[i] * sc * norm_w[c]);
    }
}

// ---------------------------------------------------------------------------
extern "C" void kernel_launch(void* const* d_in, const int* in_sizes, int n_in,
                              void* d_out, int out_size, void* d_ws, size_t ws_size,
                              hipStream_t stream) {
    const float* u          = (const float*)d_in[0];
    const float* in_proj_w  = (const float*)d_in[1];
    const float* dt_bias    = (const float*)d_in[2];
    const float* A_log      = (const float*)d_in[3];
    const float* Dp         = (const float*)d_in[4];
    const float* B_norm_w   = (const float*)d_in[5];
    const float* C_norm_w   = (const float*)d_in[6];
    const float* B_bias     = (const float*)d_in[7];
    const float* C_bias     = (const float*)d_in[8];
    const float* norm_w     = (const float*)d_in[9];
    const float* out_proj_w = (const float*)d_in[10];
    float* out = (float*)d_out;

    float* p = (float*)d_ws;
    float* zx    = p; p += (size_t)ROWS * DTOT;
    float* th_cs = p; p += (size_t)ROWS * 1024;   // dead after rot -> hseg
    float* Brot  = p; p += (size_t)ROWS * 2048;   // Brot+Crot double as bf16 scratch
    float* Crot  = p; p += (size_t)ROWS * 2048;
    float* Bg    = p; p += (size_t)ROWS * 64;     // dead after rot -> aprod
    float* Cg    = p; p += (size_t)ROWS * 64;
    float4* abg4 = (float4*)p; p += (size_t)ROWS * NH * 4;
    float* yb    = p; p += (size_t)ROWS * 2048;
    float* hseg  = th_cs;
    float* aprod = Bg;

    // Phase-A bf16 scratch inside Brot+Crot (consumed before rot writes them):
    u16* u_bf = (u16*)Brot;                           // 2,097,152
    u16* u_lo = u_bf + (size_t)ROWS * DMODEL;         // 2,097,152
    u16* w_bf = u_lo + (size_t)ROWS * DMODEL;         // 5,439,488
    u16* w_lo = w_bf + (size_t)DTOT * DMODEL;         // 1,245,184
    // Phase-B (after scan, Brot/Crot dead again):
    u16* gn_bf = (u16*)Brot;                          // 4,194,304
    u16* wo_bf = gn_bf + (size_t)ROWS * DIN;          // 2,097,152

    // 0. one-time fp32 -> bf16 (+residual) conversions
    conv_u<<<(ROWS * DMODEL / 4) / 256, 256, 0, stream>>>(u, u_bf, u_lo);
    conv_w<<<((size_t)DTOT * DMODEL / 4) / 256, 256, 0, stream>>>(in_proj_w, w_bf, w_lo);
    // 1a. z/x block via bf16 MFMA (global_load_lds staging)
    mfma_gemm_zx<<<dim3(NZX / 128, ROWS / 128), 256, 0, stream>>>(u_bf, w_bf, zx);
    // 1b. sensitive columns via split-bf16 3-pass MFMA
    mfma_gemm_rem3<<<dim3(NREM / 64, ROWS / 128), 256, 0, stream>>>(
        u_bf, u_lo, w_bf + (size_t)NZX * DMODEL, w_lo, zx + NZX);
    // 2. per-row prep
    prep_kernel<<<ROWS, 64, 0, stream>>>(zx, dt_bias, A_log, B_norm_w, C_norm_w,
                                         Bg, Cg, abg4);
    // 3. cumsum of theta over L
    cumsum_kernel<<<BB * NH, 256, 0, stream>>>(zx, th_cs);
    // 4. rotary on B/C (overwrites bf16 scratch — GEMMs already done)
    rot_kernel<<<(ROWS * 1024) / 256, 256, 0, stream>>>(th_cs, Bg, Cg, B_bias, C_bias,
                                                        Brot, Crot);
    // 5. segmented scan: local pass -> fixup -> final pass
    scan_p1<<<BB * NH * 4 * NSEG, 256, 0, stream>>>(zx, Brot, abg4, hseg, aprod);
    scan_fix<<<BB * NH * 4, 256, 0, stream>>>(hseg, aprod);
    scan_p2<<<BB * NH * 4 * NSEG, 256, 0, stream>>>(zx, Brot, Crot, abg4, hseg, Dp, yb);
    // 6. out_proj_w -> bf16 (Crot region dead after scan_p2)
    conv_wo<<<(DMODEL * DIN / 4) / 256, 256, 0, stream>>>(out_proj_w, wo_bf);
    // 7. gate + RMS norm -> bf16
    gate_norm_kernel<<<ROWS, 256, 0, stream>>>(yb, zx, norm_w, gn_bf);
    // 8. out = gn @ out_proj_w^T via bf16 MFMA (global_load_lds staging)
    mfma_gemm_out<<<dim3(DMODEL / 64, ROWS / 128), 256, 0, stream>>>(
        gn_bf, wo_bf, out, DIN, DMODEL);
}

// Round 13
// 279.397 us; speedup vs baseline: 1.2671x; 1.0196x over previous
//
#include <hip/hip_runtime.h>
#include <hip/hip_bf16.h>

// Problem constants
#define DMODEL 1024
#define DIN    2048
#define NH     32
#define HD     64
#define DS     64
#define LSEQ   1024
#define BB     2
#define DTOT   5312           // 2*DIN + 2*64 + 32 + 1024 + 32
#define ROWS   (BB*LSEQ)      // 2048
// column offsets inside zxbcdt
#define OFF_Z   0
#define OFF_X   2048
#define OFF_BR  4096
#define OFF_CR  4160
#define OFF_DT  4224
#define OFF_TH  4256
#define OFF_LAM 5280
#define NZX     4096          // z+x columns: single-pass bf16 MFMA
#define NREM    (DTOT - NZX)  // 1216 cols: 3-pass split-bf16 MFMA
// segmented scan
#define NSEG 8
#define SEG  (LSEQ / NSEG)    // 128

typedef short  s16x8 __attribute__((ext_vector_type(8)));
typedef float  f32x4 __attribute__((ext_vector_type(4)));
typedef unsigned short u16;

__device__ __forceinline__ unsigned int f2bf(float f) {   // RNE f32->bf16 (finite inputs)
    unsigned int u = __float_as_uint(f);
    u += 0x7fffu + ((u >> 16) & 1u);
    return u >> 16;
}
__device__ __forceinline__ unsigned int pk(float x, float y) {
    return f2bf(x) | (f2bf(y) << 16);
}

// HBM -> LDS direct 16B copy (global_load_lds_dwordx4). Dest must be
// wave-uniform base + lane*16 (m104): dest = ldsBase + tid*16B.
typedef const __attribute__((address_space(1))) unsigned int glb_u32;
typedef __attribute__((address_space(3))) unsigned int lds_u32;
__device__ __forceinline__ void gload16(const void* g, void* l) {
    __builtin_amdgcn_global_load_lds((glb_u32*)g, (lds_u32*)l, 16, 0, 0);
}

// ---------------------------------------------------------------------------
// conversion kernels: fp32 -> bf16 (hi) and residual (lo). Bit-identical
// to inline f2bf/split — absmax must not move.
// ---------------------------------------------------------------------------
__global__ __launch_bounds__(256) void conv_u(const float* __restrict__ src,
        u16* __restrict__ hi, u16* __restrict__ lo) {
    const size_t i4 = ((size_t)blockIdx.x * 256 + threadIdx.x) * 4;
    const float4 v = *(const float4*)(src + i4);
    const unsigned int h0 = f2bf(v.x), h1 = f2bf(v.y), h2 = f2bf(v.z), h3 = f2bf(v.w);
    uint2 hw, lw;
    hw.x = h0 | (h1 << 16); hw.y = h2 | (h3 << 16);
    lw.x = pk(v.x - __uint_as_float(h0 << 16), v.y - __uint_as_float(h1 << 16));
    lw.y = pk(v.z - __uint_as_float(h2 << 16), v.w - __uint_as_float(h3 << 16));
    *(uint2*)(hi + i4) = hw;
    *(uint2*)(lo + i4) = lw;
}

__global__ __launch_bounds__(256) void conv_w(const float* __restrict__ src,
        u16* __restrict__ hi, u16* __restrict__ lo) {
    const size_t i4 = ((size_t)blockIdx.x * 256 + threadIdx.x) * 4;
    const float4 v = *(const float4*)(src + i4);
    const unsigned int h0 = f2bf(v.x), h1 = f2bf(v.y), h2 = f2bf(v.z), h3 = f2bf(v.w);
    uint2 hw, lw;
    hw.x = h0 | (h1 << 16); hw.y = h2 | (h3 << 16);
    lw.x = pk(v.x - __uint_as_float(h0 << 16), v.y - __uint_as_float(h1 << 16));
    lw.y = pk(v.z - __uint_as_float(h2 << 16), v.w - __uint_as_float(h3 << 16));
    *(uint2*)(hi + i4) = hw;
    if ((i4 >> 10) >= NZX)                       // rows >= 4096: keep residual
        *(uint2*)(lo + (i4 - (size_t)NZX * DMODEL)) = lw;
}

__global__ __launch_bounds__(256) void conv_wo(const float* __restrict__ src,
        u16* __restrict__ hi) {
    const size_t i4 = ((size_t)blockIdx.x * 256 + threadIdx.x) * 4;
    const float4 v = *(const float4*)(src + i4);
    uint2 hw;
    hw.x = pk(v.x, v.y); hw.y = pk(v.z, v.w);
    *(uint2*)(hi + i4) = hw;
}

// ---------------------------------------------------------------------------
// bf16 MFMA GEMM, z/x block: zx[:, 0:4096] = u_bf @ w_bf[0:4096,:]^T
// 128x128 tile, BK=32, 4 waves. 2-phase double-buffered global_load_lds:
// issue STAGE(k+1) BEFORE computing tile k; single barrier per K-step
// (the compiler's pre-barrier vmcnt(0) then waits for loads that had the
// whole MFMA phase in flight — T3-minimum recipe).
// ---------------------------------------------------------------------------
__global__ __launch_bounds__(256) void mfma_gemm_zx(const u16* __restrict__ uA_,
                                                    const u16* __restrict__ uW,
                                                    float* __restrict__ zx) {
    __shared__ u16 Al[2][128 * 32];
    __shared__ u16 Bl[2][128 * 32];
    const int tid = threadIdx.x;
    const int m0 = blockIdx.y * 128, n0 = blockIdx.x * 128;
    const int lane = tid & 63, wave = tid >> 6;
    const int wr = wave >> 1, wc = wave & 1;
    const int lr = lane >> 4, lc = lane & 15;
    const int sr = tid >> 2;            // staging row 0..63
    const int sc = (tid & 3) * 8;       // staging col (u16)

    f32x4 acc[4][4] = {};

    const u16* pA = uA_ + (size_t)(m0 + sr) * DMODEL + sc;
    const u16* pB = uW  + (size_t)(n0 + sr) * DMODEL + sc;

#define STAGE_ZX(buf, k0) {                                              \
        gload16(pA + (k0), &Al[buf][tid * 8]);                           \
        gload16(pA + (k0) + (size_t)64 * DMODEL, &Al[buf][tid * 8 + 2048]); \
        gload16(pB + (k0), &Bl[buf][tid * 8]);                           \
        gload16(pB + (k0) + (size_t)64 * DMODEL, &Bl[buf][tid * 8 + 2048]); }

    STAGE_ZX(0, 0);
    __syncthreads();                    // drain prologue stage
    int cur = 0;
    for (int k0 = 0; k0 < DMODEL; k0 += 32) {
        if (k0 + 32 < DMODEL) STAGE_ZX(cur ^ 1, k0 + 32);   // in flight over MFMA
        s16x8 af[4], bf[4];
        #pragma unroll
        for (int f = 0; f < 4; ++f) {
            af[f] = *(const s16x8*)&Al[cur][(wr * 64 + f * 16 + lc) * 32 + lr * 8];
            bf[f] = *(const s16x8*)&Bl[cur][(wc * 64 + f * 16 + lc) * 32 + lr * 8];
        }
        #pragma unroll
        for (int fm = 0; fm < 4; ++fm)
            #pragma unroll
            for (int fn = 0; fn < 4; ++fn)
                acc[fm][fn] = __builtin_amdgcn_mfma_f32_16x16x32_bf16(
                    af[fm], bf[fn], acc[fm][fn], 0, 0, 0);
        __syncthreads();                // drains next stage + syncs reads
        cur ^= 1;
    }
#undef STAGE_ZX

    #pragma unroll
    for (int fm = 0; fm < 4; ++fm)
        #pragma unroll
        for (int fn = 0; fn < 4; ++fn) {
            const size_t col = n0 + wc * 64 + fn * 16 + lc;
            #pragma unroll
            for (int j = 0; j < 4; ++j) {
                const size_t row = m0 + wr * 64 + fm * 16 + lr * 4 + j;
                zx[row * DTOT + col] = acc[fm][fn][j];
            }
        }
}

// ---------------------------------------------------------------------------
// bf16 MFMA GEMM, 128x64 tile, 2-phase dbuf: out = gn_bf @ wo_bf^T
// ---------------------------------------------------------------------------
__global__ __launch_bounds__(256) void mfma_gemm_out(const u16* __restrict__ A,
                                                     const u16* __restrict__ B,
                                                     float* __restrict__ C,
                                                     int K, int ldc) {
    __shared__ u16 Als[2][128 * 32];
    __shared__ u16 Bls[2][64 * 32];
    const int tid = threadIdx.x;
    const int m0 = blockIdx.y * 128, n0 = blockIdx.x * 64;
    const int lane = tid & 63, wave = tid >> 6;
    const int wr = wave >> 1, wc = wave & 1;
    const int lr = lane >> 4, lc = lane & 15;
    const int sr = tid >> 2;
    const int sc = (tid & 3) * 8;

    f32x4 acc[4][2] = {};

    const u16* pA = A + (size_t)(m0 + sr) * K + sc;
    const u16* pB = B + (size_t)(n0 + sr) * K + sc;

#define STAGE_OUT(buf, k0) {                                             \
        gload16(pA + (k0), &Als[buf][tid * 8]);                          \
        gload16(pA + (k0) + (size_t)64 * K, &Als[buf][tid * 8 + 2048]);  \
        gload16(pB + (k0), &Bls[buf][tid * 8]); }

    STAGE_OUT(0, 0);
    __syncthreads();
    int cur = 0;
    for (int k0 = 0; k0 < K; k0 += 32) {
        if (k0 + 32 < K) STAGE_OUT(cur ^ 1, k0 + 32);
        s16x8 af[4], bf[2];
        #pragma unroll
        for (int f = 0; f < 4; ++f)
            af[f] = *(const s16x8*)&Als[cur][(wr * 64 + f * 16 + lc) * 32 + lr * 8];
        #pragma unroll
        for (int f = 0; f < 2; ++f)
            bf[f] = *(const s16x8*)&Bls[cur][(wc * 32 + f * 16 + lc) * 32 + lr * 8];
        #pragma unroll
        for (int fm = 0; fm < 4; ++fm)
            #pragma unroll
            for (int fn = 0; fn < 2; ++fn)
                acc[fm][fn] = __builtin_amdgcn_mfma_f32_16x16x32_bf16(
                    af[fm], bf[fn], acc[fm][fn], 0, 0, 0);
        __syncthreads();
        cur ^= 1;
    }
#undef STAGE_OUT

    #pragma unroll
    for (int fm = 0; fm < 4; ++fm)
        #pragma unroll
        for (int fn = 0; fn < 2; ++fn) {
            const size_t col = n0 + wc * 32 + fn * 16 + lc;
            #pragma unroll
            for (int j = 0; j < 4; ++j) {
                const size_t row = m0 + wr * 64 + fm * 16 + lr * 4 + j;
                C[row * (size_t)ldc + col] = acc[fm][fn][j];
            }
        }
}

// ---------------------------------------------------------------------------
// split-bf16 3-pass MFMA GEMM, sensitive columns (theta cumsum):
// acc += uh*wh + uh*wl + ul*wh. 2-phase dbuf, 6 gload16/stage.
// ---------------------------------------------------------------------------
__global__ __launch_bounds__(256) void mfma_gemm_rem3(const u16* __restrict__ uh,
        const u16* __restrict__ ul, const u16* __restrict__ wh,
        const u16* __restrict__ wl, float* __restrict__ zxr) {
    __shared__ u16 Ah[2][128 * 32], Alo[2][128 * 32];
    __shared__ u16 Bh[2][64 * 32],  Blo[2][64 * 32];
    const int tid = threadIdx.x;
    const int m0 = blockIdx.y * 128, n0 = blockIdx.x * 64;
    const int lane = tid & 63, wave = tid >> 6;
    const int wr = wave >> 1, wc = wave & 1;
    const int lr = lane >> 4, lc = lane & 15;
    const int sr = tid >> 2;
    const int sc = (tid & 3) * 8;

    f32x4 acc[4][2] = {};

    const u16* pAh = uh + (size_t)(m0 + sr) * DMODEL + sc;
    const u16* pAl = ul + (size_t)(m0 + sr) * DMODEL + sc;
    const u16* pBh = wh + (size_t)(n0 + sr) * DMODEL + sc;   // n0+sr <= 1215
    const u16* pBl = wl + (size_t)(n0 + sr) * DMODEL + sc;

#define STAGE_R3(buf, k0) {                                                  \
        gload16(pAh + (k0), &Ah[buf][tid * 8]);                              \
        gload16(pAh + (k0) + (size_t)64 * DMODEL, &Ah[buf][tid * 8 + 2048]); \
        gload16(pAl + (k0), &Alo[buf][tid * 8]);                             \
        gload16(pAl + (k0) + (size_t)64 * DMODEL, &Alo[buf][tid * 8 + 2048]);\
        gload16(pBh + (k0), &Bh[buf][tid * 8]);                              \
        gload16(pBl + (k0), &Blo[buf][tid * 8]); }

    STAGE_R3(0, 0);
    __syncthreads();
    int cur = 0;
    for (int k0 = 0; k0 < DMODEL; k0 += 32) {
        if (k0 + 32 < DMODEL) STAGE_R3(cur ^ 1, k0 + 32);
        s16x8 ahf[4], alf[4], bhf[2], blf[2];
        #pragma unroll
        for (int f = 0; f < 4; ++f) {
            ahf[f] = *(const s16x8*)&Ah[cur][(wr * 64 + f * 16 + lc) * 32 + lr * 8];
            alf[f] = *(const s16x8*)&Alo[cur][(wr * 64 + f * 16 + lc) * 32 + lr * 8];
        }
        #pragma unroll
        for (int f = 0; f < 2; ++f) {
            bhf[f] = *(const s16x8*)&Bh[cur][(wc * 32 + f * 16 + lc) * 32 + lr * 8];
            blf[f] = *(const s16x8*)&Blo[cur][(wc * 32 + f * 16 + lc) * 32 + lr * 8];
        }
        #pragma unroll
        for (int fm = 0; fm < 4; ++fm)
            #pragma unroll
            for (int fn = 0; fn < 2; ++fn) {
                acc[fm][fn] = __builtin_amdgcn_mfma_f32_16x16x32_bf16(
                    ahf[fm], bhf[fn], acc[fm][fn], 0, 0, 0);
                acc[fm][fn] = __builtin_amdgcn_mfma_f32_16x16x32_bf16(
                    ahf[fm], blf[fn], acc[fm][fn], 0, 0, 0);
                acc[fm][fn] = __builtin_amdgcn_mfma_f32_16x16x32_bf16(
                    alf[fm], bhf[fn], acc[fm][fn], 0, 0, 0);
            }
        __syncthreads();
        cur ^= 1;
    }
#undef STAGE_R3

    #pragma unroll
    for (int fm = 0; fm < 4; ++fm)
        #pragma unroll
        for (int fn = 0; fn < 2; ++fn) {
            const size_t col = n0 + wc * 32 + fn * 16 + lc;
            #pragma unroll
            for (int j = 0; j < 4; ++j) {
                const size_t row = m0 + wr * 64 + fm * 16 + lr * 4 + j;
                zxr[row * DTOT + col] = acc[fm][fn][j];
            }
        }
}

// ---------------------------------------------------------------------------
// prep: RMS-norm Br/Cr; alpha/beta/gamma packed as float4 in (b,h,l) layout.
// ---------------------------------------------------------------------------
__global__ __launch_bounds__(64) void prep_kernel(const float* __restrict__ zx,
        const float* __restrict__ dt_bias, const float* __restrict__ A_log,
        const float* __restrict__ B_norm_w, const float* __restrict__ C_norm_w,
        float* __restrict__ Bg, float* __restrict__ Cg,
        float4* __restrict__ abg4) {
    const int bl = blockIdx.x;
    const int b = bl >> 10, l = bl & (LSEQ - 1);
    const int t  = threadIdx.x;
    const float* row = zx + (size_t)bl * DTOT;
    const float br = row[OFF_BR + t];
    const float cr = row[OFF_CR + t];
    float ssb = br * br, ssc = cr * cr;
    #pragma unroll
    for (int k = 1; k < 64; k <<= 1) { ssb += __shfl_xor(ssb, k); ssc += __shfl_xor(ssc, k); }
    const float scB = rsqrtf(ssb * (1.f / 64.f) + 1e-5f);
    const float scC = rsqrtf(ssc * (1.f / 64.f) + 1e-5f);
    Bg[(size_t)bl * 64 + t] = br * scB * B_norm_w[t];
    Cg[(size_t)bl * 64 + t] = cr * scC * C_norm_w[t];
    if (t < NH) {
        const float dtr = row[OFF_DT + t] + dt_bias[t];
        const float dt  = (dtr > 20.f) ? dtr : log1pf(expf(dtr));
        const float lamr = row[OFF_LAM + t];
        const float lam  = 1.f / (1.f + expf(-lamr));
        const float Ah   = -expf(A_log[t]);
        const float al   = expf(dt * Ah);
        const size_t o = ((size_t)b * NH + t) * LSEQ + l;
        abg4[o] = make_float4(al, (1.f - lam) * dt * al, lam * dt, 0.f);
    }
}

// ---------------------------------------------------------------------------
// cumsum of thr over L, per (b,h): 32 dims.
// ---------------------------------------------------------------------------
__global__ __launch_bounds__(256) void cumsum_kernel(const float* __restrict__ zx,
                                                     float* __restrict__ th_cs) {
    const int bh = blockIdx.x;
    const int b = bh >> 5, h = bh & 31;
    const int d = threadIdx.x & 31, seg = threadIdx.x >> 5;
    const float* base = zx + (size_t)b * LSEQ * DTOT + OFF_TH + h * 32 + d;
    float* out = th_cs + (size_t)b * LSEQ * 1024 + h * 32 + d;
    __shared__ float sums[8][33];
    const int l0 = seg * 128;
    float s = 0.f;
    #pragma unroll 4
    for (int i = 0; i < 128; ++i) s += base[(size_t)(l0 + i) * DTOT];
    sums[seg][d] = s;
    __syncthreads();
    float acc = 0.f;
    for (int s2 = 0; s2 < seg; ++s2) acc += sums[s2][d];
    #pragma unroll 4
    for (int i = 0; i < 128; ++i) {
        acc += base[(size_t)(l0 + i) * DTOT];
        out[(size_t)(l0 + i) * 1024] = acc;
    }
}

// ---------------------------------------------------------------------------
// rot: Bh/Ch = rot(broadcast(Bg/Cg)+bias). Brot/Crot layout (B,NH,L,DS).
// ---------------------------------------------------------------------------
__global__ __launch_bounds__(256) void rot_kernel(const float* __restrict__ th_cs,
        const float* __restrict__ Bg, const float* __restrict__ Cg,
        const float* __restrict__ B_bias, const float* __restrict__ C_bias,
        float* __restrict__ Brot, float* __restrict__ Crot) {
    const size_t idx = (size_t)blockIdx.x * 256 + threadIdx.x;
    const int j = (int)(idx & 31);
    const int h = (int)((idx >> 5) & 31);
    const size_t bl = idx >> 10;
    const int l = (int)(bl & (LSEQ - 1));
    const int b = (int)(bl >> 10);
    const float th = th_cs[idx];
    float s, c;
    sincosf(th, &s, &c);
    float v1 = Bg[bl * 64 + j]      + B_bias[h * 64 + j];
    float v2 = Bg[bl * 64 + 32 + j] + B_bias[h * 64 + 32 + j];
    const size_t ob = ((size_t)(b * NH + h) * LSEQ + l) * DS + j;
    Brot[ob]      = v1 * c - v2 * s;
    Brot[ob + 32] = v1 * s + v2 * c;
    v1 = Cg[bl * 64 + j]      + C_bias[h * 64 + j];
    v2 = Cg[bl * 64 + 32 + j] + C_bias[h * 64 + 32 + j];
    Crot[ob]      = v1 * c - v2 * s;
    Crot[ob + 32] = v1 * s + v2 * c;
}

// ---------------------------------------------------------------------------
// DPP 16-lane row sum (VALU pipe). Lane 15 of each 16-lane row holds the sum.
// ---------------------------------------------------------------------------
__device__ __forceinline__ float row_sum16(float x) {
    int t;
    t = __builtin_amdgcn_update_dpp(0, __float_as_int(x), 0x111, 0xf, 0xf, true);
    x += __int_as_float(t);
    t = __builtin_amdgcn_update_dpp(0, __float_as_int(x), 0x112, 0xf, 0xf, true);
    x += __int_as_float(t);
    t = __builtin_amdgcn_update_dpp(0, __float_as_int(x), 0x114, 0xf, 0xf, true);
    x += __int_as_float(t);
    t = __builtin_amdgcn_update_dpp(0, __float_as_int(x), 0x118, 0xf, 0xf, true);
    x += __int_as_float(t);
    return x;
}

// ---------------------------------------------------------------------------
// Segmented scan (exact): h_end(seg) = h_local_end + (prod a)*h_start.
// 8 segments -> 2048 blocks -> 8 waves/SIMD TLP.
// ---------------------------------------------------------------------------
__global__ __launch_bounds__(256, 8) void scan_p1(const float* __restrict__ zx,
        const float* __restrict__ Brot, const float4* __restrict__ abg4,
        float* __restrict__ hseg, float* __restrict__ aprod) {
    const int blk = blockIdx.x;
    const int s = blk & (NSEG - 1), ptile = (blk >> 3) & 3, h = (blk >> 5) & 31, b = blk >> 10;
    const int tid = threadIdx.x;
    const int pl = tid >> 4, ng = tid & 15;
    const int p = ptile * 16 + pl;
    const int n0 = ng * 4;
    const int t0 = s * SEG;

    const size_t bh = (size_t)b * NH + h;
    const float* Bbase = Brot + bh * LSEQ * DS + n0;
    const float4* abase = abg4 + bh * LSEQ;
    const float* xbase = zx + (size_t)b * LSEQ * DTOT + OFF_X + h * HD + p;

    float hs0 = 0.f, hs1 = 0.f, hs2 = 0.f, hs3 = 0.f;
    float Bp0 = 0.f, Bp1 = 0.f, Bp2 = 0.f, Bp3 = 0.f;
    float xprev = 0.f, aP = 1.f;
    if (s > 0) {
        const float4 Bm = *(const float4*)(Bbase + (size_t)(t0 - 1) * DS);
        Bp0 = Bm.x; Bp1 = Bm.y; Bp2 = Bm.z; Bp3 = Bm.w;
        xprev = xbase[(size_t)(t0 - 1) * DTOT];
    }

    #pragma unroll 4
    for (int t = t0; t < t0 + SEG; ++t) {
        const float4 Bv = *(const float4*)(Bbase + (size_t)t * DS);
        const float4 av = abase[t];
        const float  xv = xbase[(size_t)t * DTOT];
        const float cp = av.y * xprev;
        const float cc = av.z * xv;
        hs0 = fmaf(av.x, hs0, fmaf(cp, Bp0, cc * Bv.x));
        hs1 = fmaf(av.x, hs1, fmaf(cp, Bp1, cc * Bv.y));
        hs2 = fmaf(av.x, hs2, fmaf(cp, Bp2, cc * Bv.z));
        hs3 = fmaf(av.x, hs3, fmaf(cp, Bp3, cc * Bv.w));
        aP *= av.x;
        Bp0 = Bv.x; Bp1 = Bv.y; Bp2 = Bv.z; Bp3 = Bv.w;
        xprev = xv;
    }

    float* hp = hseg + (((bh * NSEG + s) * HD + p) * DS + n0);
    *(float4*)hp = make_float4(hs0, hs1, hs2, hs3);
    if (tid == 0) aprod[bh * NSEG + s] = aP;
}

__global__ __launch_bounds__(256) void scan_fix(float* __restrict__ hseg,
                                                const float* __restrict__ aprod) {
    const int blk = blockIdx.x;          // (b,h,ptile): 256
    const int ptile = blk & 3, h = (blk >> 2) & 31, b = blk >> 7;
    const int tid = threadIdx.x;
    const int pl = tid >> 4, ng = tid & 15;
    const int p = ptile * 16 + pl;
    const int n0 = ng * 4;
    const size_t bh = (size_t)b * NH + h;

    float4 cur = make_float4(0.f, 0.f, 0.f, 0.f);
    #pragma unroll
    for (int s = 0; s < NSEG; ++s) {
        float* hp = hseg + (((bh * NSEG + s) * HD + p) * DS + n0);
        const float4 tmp = *(const float4*)hp;   // h_local_end[s]
        *(float4*)hp = cur;                      // h_start[s]
        const float a = aprod[bh * NSEG + s];
        cur.x = fmaf(a, cur.x, tmp.x);
        cur.y = fmaf(a, cur.y, tmp.y);
        cur.z = fmaf(a, cur.z, tmp.z);
        cur.w = fmaf(a, cur.w, tmp.w);
    }
}

__global__ __launch_bounds__(256, 8) void scan_p2(const float* __restrict__ zx,
        const float* __restrict__ Brot, const float* __restrict__ Crot,
        const float4* __restrict__ abg4, const float* __restrict__ hseg,
        const float* __restrict__ Dp, float* __restrict__ yb) {
    const int blk = blockIdx.x;
    const int s = blk & (NSEG - 1), ptile = (blk >> 3) & 3, h = (blk >> 5) & 31, b = blk >> 10;
    const int tid = threadIdx.x;
    const int pl = tid >> 4, ng = tid & 15;
    const int p = ptile * 16 + pl;
    const int n0 = ng * 4;
    const int t0 = s * SEG;

    const size_t bh = (size_t)b * NH + h;
    const float* Bbase = Brot + bh * LSEQ * DS + n0;
    const float* Cbase = Crot + bh * LSEQ * DS + n0;
    const float4* abase = abg4 + bh * LSEQ;
    const float* xbase = zx + (size_t)b * LSEQ * DTOT + OFF_X + h * HD + p;
    const float Dh = Dp[h];
    float* ybase = yb + (size_t)b * LSEQ * DIN + h * HD + p;

    const float4 h0v = *(const float4*)(hseg + (((bh * NSEG + s) * HD + p) * DS + n0));
    float hs0 = h0v.x, hs1 = h0v.y, hs2 = h0v.z, hs3 = h0v.w;
    float Bp0 = 0.f, Bp1 = 0.f, Bp2 = 0.f, Bp3 = 0.f;
    float xprev = 0.f;
    if (s > 0) {
        const float4 Bm = *(const float4*)(Bbase + (size_t)(t0 - 1) * DS);
        Bp0 = Bm.x; Bp1 = Bm.y; Bp2 = Bm.z; Bp3 = Bm.w;
        xprev = xbase[(size_t)(t0 - 1) * DTOT];
    }

    #pragma unroll 4
    for (int t = t0; t < t0 + SEG; ++t) {
        const float4 Bv = *(const float4*)(Bbase + (size_t)t * DS);
        const float4 Cv = *(const float4*)(Cbase + (size_t)t * DS);
        const float4 av = abase[t];
        const float  xv = xbase[(size_t)t * DTOT];
        const float cp = av.y * xprev;
        const float cc = av.z * xv;
        float ys;
        hs0 = fmaf(av.x, hs0, fmaf(cp, Bp0, cc * Bv.x)); ys  = Cv.x * hs0;
        hs1 = fmaf(av.x, hs1, fmaf(cp, Bp1, cc * Bv.y)); ys += Cv.y * hs1;
        hs2 = fmaf(av.x, hs2, fmaf(cp, Bp2, cc * Bv.z)); ys += Cv.z * hs2;
        hs3 = fmaf(av.x, hs3, fmaf(cp, Bp3, cc * Bv.w)); ys += Cv.w * hs3;
        ys = row_sum16(ys);
        if (ng == 15) ybase[(size_t)t * DIN] = fmaf(Dh, xv, ys);
        Bp0 = Bv.x; Bp1 = Bv.y; Bp2 = Bv.z; Bp3 = Bv.w;
        xprev = xv;
    }
}

// ---------------------------------------------------------------------------
// gate + final RMS norm; emits bf16 directly for the out_proj GEMM.
// ---------------------------------------------------------------------------
__global__ __launch_bounds__(256) void gate_norm_kernel(const float* __restrict__ yb,
        const float* __restrict__ zx, const float* __restrict__ norm_w,
        u16* __restrict__ gnb) {
    const int bl = blockIdx.x;
    const int tid = threadIdx.x;
    const float* yrow = yb + (size_t)bl * DIN;
    const float* zrow = zx + (size_t)bl * DTOT + OFF_Z;
    float g[8];
    float ss = 0.f;
    #pragma unroll
    for (int i = 0; i < 8; ++i) {
        const int c = tid + i * 256;
        const float yv = yrow[c];
        const float zv = zrow[c];
        const float sg = 1.f / (1.f + expf(-zv));
        const float gv = yv * zv * sg;
        g[i] = gv;
        ss += gv * gv;
    }
    #pragma unroll
    for (int k = 1; k < 64; k <<= 1) ss += __shfl_xor(ss, k);
    __shared__ float wsum[4];
    if ((tid & 63) == 0) wsum[tid >> 6] = ss;
    __syncthreads();
    ss = wsum[0] + wsum[1] + wsum[2] + wsum[3];
    const float sc = rsqrtf(ss * (1.f / 2048.f) + 1e-5f);
    #pragma unroll
    for (int i = 0; i < 8; ++i) {
        const int c = tid + i * 256;
        gnb[(size_t)bl * DIN + c] = (u16)f2bf(g[i] * sc * norm_w[c]);
    }
}

// ---------------------------------------------------------------------------
extern "C" void kernel_launch(void* const* d_in, const int* in_sizes, int n_in,
                              void* d_out, int out_size, void* d_ws, size_t ws_size,
                              hipStream_t stream) {
    const float* u          = (const float*)d_in[0];
    const float* in_proj_w  = (const float*)d_in[1];
    const float* dt_bias    = (const float*)d_in[2];
    const float* A_log      = (const float*)d_in[3];
    const float* Dp         = (const float*)d_in[4];
    const float* B_norm_w   = (const float*)d_in[5];
    const float* C_norm_w   = (const float*)d_in[6];
    const float* B_bias     = (const float*)d_in[7];
    const float* C_bias     = (const float*)d_in[8];
    const float* norm_w     = (const float*)d_in[9];
    const float* out_proj_w = (const float*)d_in[10];
    float* out = (float*)d_out;

    float* p = (float*)d_ws;
    float* zx    = p; p += (size_t)ROWS * DTOT;
    float* th_cs = p; p += (size_t)ROWS * 1024;   // dead after rot -> hseg
    float* Brot  = p; p += (size_t)ROWS * 2048;   // Brot+Crot double as bf16 scratch
    float* Crot  = p; p += (size_t)ROWS * 2048;
    float* Bg    = p; p += (size_t)ROWS * 64;     // dead after rot -> aprod
    float* Cg    = p; p += (size_t)ROWS * 64;
    float4* abg4 = (float4*)p; p += (size_t)ROWS * NH * 4;
    float* yb    = p; p += (size_t)ROWS * 2048;
    float* hseg  = th_cs;
    float* aprod = Bg;

    // Phase-A bf16 scratch inside Brot+Crot (consumed before rot writes them):
    u16* u_bf = (u16*)Brot;                           // 2,097,152
    u16* u_lo = u_bf + (size_t)ROWS * DMODEL;         // 2,097,152
    u16* w_bf = u_lo + (size_t)ROWS * DMODEL;         // 5,439,488
    u16* w_lo = w_bf + (size_t)DTOT * DMODEL;         // 1,245,184
    // Phase-B (after scan, Brot/Crot dead again):
    u16* gn_bf = (u16*)Brot;                          // 4,194,304
    u16* wo_bf = gn_bf + (size_t)ROWS * DIN;          // 2,097,152

    // 0. one-time fp32 -> bf16 (+residual) conversions
    conv_u<<<(ROWS * DMODEL / 4) / 256, 256, 0, stream>>>(u, u_bf, u_lo);
    conv_w<<<((size_t)DTOT * DMODEL / 4) / 256, 256, 0, stream>>>(in_proj_w, w_bf, w_lo);
    // 1a. z/x block via bf16 MFMA (2-phase dbuf global_load_lds)
    mfma_gemm_zx<<<dim3(NZX / 128, ROWS / 128), 256, 0, stream>>>(u_bf, w_bf, zx);
    // 1b. sensitive columns via split-bf16 3-pass MFMA (2-phase dbuf)
    mfma_gemm_rem3<<<dim3(NREM / 64, ROWS / 128), 256, 0, stream>>>(
        u_bf, u_lo, w_bf + (size_t)NZX * DMODEL, w_lo, zx + NZX);
    // 2. per-row prep
    prep_kernel<<<ROWS, 64, 0, stream>>>(zx, dt_bias, A_log, B_norm_w, C_norm_w,
                                         Bg, Cg, abg4);
    // 3. cumsum of theta over L
    cumsum_kernel<<<BB * NH, 256, 0, stream>>>(zx, th_cs);
    // 4. rotary on B/C (overwrites bf16 scratch — GEMMs already done)
    rot_kernel<<<(ROWS * 1024) / 256, 256, 0, stream>>>(th_cs, Bg, Cg, B_bias, C_bias,
                                                        Brot, Crot);
    // 5. segmented scan: local pass -> fixup -> final pass
    scan_p1<<<BB * NH * 4 * NSEG, 256, 0, stream>>>(zx, Brot, abg4, hseg, aprod);
    scan_fix<<<BB * NH * 4, 256, 0, stream>>>(hseg, aprod);
    scan_p2<<<BB * NH * 4 * NSEG, 256, 0, stream>>>(zx, Brot, Crot, abg4, hseg, Dp, yb);
    // 6. out_proj_w -> bf16 (Crot region dead after scan_p2)
    conv_wo<<<(DMODEL * DIN / 4) / 256, 256, 0, stream>>>(out_proj_w, wo_bf);
    // 7. gate + RMS norm -> bf16
    gate_norm_kernel<<<ROWS, 256, 0, stream>>>(yb, zx, norm_w, gn_bf);
    // 8. out = gn @ out_proj_w^T via bf16 MFMA (2-phase dbuf)
    mfma_gemm_out<<<dim3(DMODEL / 64, ROWS / 128), 256, 0, stream>>>(
        gn_bf, wo_bf, out, DIN, DMODEL);
}

// Round 15
// 251.699 us; speedup vs baseline: 1.4065x; 1.1100x over previous
//
#include <hip/hip_runtime.h>
#include <hip/hip_bf16.h>

// Problem constants
#define DMODEL 1024
#define DIN    2048
#define NH     32
#define HD     64
#define DS     64
#define LSEQ   1024
#define BB     2
#define DTOT   5312           // 2*DIN + 2*64 + 32 + 1024 + 32
#define ROWS   (BB*LSEQ)      // 2048
// column offsets inside zxbcdt
#define OFF_Z   0
#define OFF_X   2048
#define OFF_BR  4096
#define OFF_CR  4160
#define OFF_DT  4224
#define OFF_TH  4256
#define OFF_LAM 5280
#define NZX     4096          // z+x columns: single-pass bf16 MFMA
#define NREM    (DTOT - NZX)  // 1216 cols: 3-pass split-bf16 MFMA
// segmented scan
#define NSEG 8
#define SEG  (LSEQ / NSEG)    // 128

typedef short  s16x8 __attribute__((ext_vector_type(8)));
typedef float  f32x4 __attribute__((ext_vector_type(4)));
typedef unsigned short u16;

__device__ __forceinline__ unsigned int f2bf(float f) {   // RNE f32->bf16 (finite inputs)
    unsigned int u = __float_as_uint(f);
    u += 0x7fffu + ((u >> 16) & 1u);
    return u >> 16;
}
__device__ __forceinline__ unsigned int pk(float x, float y) {
    return f2bf(x) | (f2bf(y) << 16);
}
__device__ __forceinline__ void split1(float v, u16& hi, u16& lo) {
    const unsigned int h = f2bf(v);
    hi = (u16)h;
    lo = (u16)f2bf(v - __uint_as_float(h << 16));
}

// HBM -> LDS direct 16B copy. Dest = wave-uniform base + lane*16 (m104).
typedef const __attribute__((address_space(1))) unsigned int glb_u32;
typedef __attribute__((address_space(3))) unsigned int lds_u32;
__device__ __forceinline__ void gload16(const void* g, void* l) {
    __builtin_amdgcn_global_load_lds((glb_u32*)g, (lds_u32*)l, 16, 0, 0);
}

// ---------------------------------------------------------------------------
// conversion kernels: fp32 -> bf16 (hi) and residual (lo).
// ---------------------------------------------------------------------------
__global__ __launch_bounds__(256) void conv_u(const float* __restrict__ src,
        u16* __restrict__ hi, u16* __restrict__ lo) {
    const size_t i4 = ((size_t)blockIdx.x * 256 + threadIdx.x) * 4;
    const float4 v = *(const float4*)(src + i4);
    const unsigned int h0 = f2bf(v.x), h1 = f2bf(v.y), h2 = f2bf(v.z), h3 = f2bf(v.w);
    uint2 hw, lw;
    hw.x = h0 | (h1 << 16); hw.y = h2 | (h3 << 16);
    lw.x = pk(v.x - __uint_as_float(h0 << 16), v.y - __uint_as_float(h1 << 16));
    lw.y = pk(v.z - __uint_as_float(h2 << 16), v.w - __uint_as_float(h3 << 16));
    *(uint2*)(hi + i4) = hw;
    *(uint2*)(lo + i4) = lw;
}

__global__ __launch_bounds__(256) void conv_w(const float* __restrict__ src,
        u16* __restrict__ hi, u16* __restrict__ lo) {
    const size_t i4 = ((size_t)blockIdx.x * 256 + threadIdx.x) * 4;
    const float4 v = *(const float4*)(src + i4);
    const unsigned int h0 = f2bf(v.x), h1 = f2bf(v.y), h2 = f2bf(v.z), h3 = f2bf(v.w);
    uint2 hw, lw;
    hw.x = h0 | (h1 << 16); hw.y = h2 | (h3 << 16);
    lw.x = pk(v.x - __uint_as_float(h0 << 16), v.y - __uint_as_float(h1 << 16));
    lw.y = pk(v.z - __uint_as_float(h2 << 16), v.w - __uint_as_float(h3 << 16));
    *(uint2*)(hi + i4) = hw;
    if ((i4 >> 10) >= NZX)
        *(uint2*)(lo + (i4 - (size_t)NZX * DMODEL)) = lw;
}

__global__ __launch_bounds__(256) void conv_wo(const float* __restrict__ src,
        u16* __restrict__ hi) {
    const size_t i4 = ((size_t)blockIdx.x * 256 + threadIdx.x) * 4;
    const float4 v = *(const float4*)(src + i4);
    uint2 hw;
    hw.x = pk(v.x, v.y); hw.y = pk(v.z, v.w);
    *(uint2*)(hi + i4) = hw;
}

// ---------------------------------------------------------------------------
// bf16 MFMA GEMM, z/x block (2-phase dbuf global_load_lds)
// ---------------------------------------------------------------------------
__global__ __launch_bounds__(256) void mfma_gemm_zx(const u16* __restrict__ uA_,
                                                    const u16* __restrict__ uW,
                                                    float* __restrict__ zx) {
    __shared__ u16 Al[2][128 * 32];
    __shared__ u16 Bl[2][128 * 32];
    const int tid = threadIdx.x;
    const int m0 = blockIdx.y * 128, n0 = blockIdx.x * 128;
    const int lane = tid & 63, wave = tid >> 6;
    const int wr = wave >> 1, wc = wave & 1;
    const int lr = lane >> 4, lc = lane & 15;
    const int sr = tid >> 2;
    const int sc = (tid & 3) * 8;

    f32x4 acc[4][4] = {};

    const u16* pA = uA_ + (size_t)(m0 + sr) * DMODEL + sc;
    const u16* pB = uW  + (size_t)(n0 + sr) * DMODEL + sc;

#define STAGE_ZX(buf, k0) {                                              \
        gload16(pA + (k0), &Al[buf][tid * 8]);                           \
        gload16(pA + (k0) + (size_t)64 * DMODEL, &Al[buf][tid * 8 + 2048]); \
        gload16(pB + (k0), &Bl[buf][tid * 8]);                           \
        gload16(pB + (k0) + (size_t)64 * DMODEL, &Bl[buf][tid * 8 + 2048]); }

    STAGE_ZX(0, 0);
    __syncthreads();
    int cur = 0;
    for (int k0 = 0; k0 < DMODEL; k0 += 32) {
        if (k0 + 32 < DMODEL) STAGE_ZX(cur ^ 1, k0 + 32);
        s16x8 af[4], bf[4];
        #pragma unroll
        for (int f = 0; f < 4; ++f) {
            af[f] = *(const s16x8*)&Al[cur][(wr * 64 + f * 16 + lc) * 32 + lr * 8];
            bf[f] = *(const s16x8*)&Bl[cur][(wc * 64 + f * 16 + lc) * 32 + lr * 8];
        }
        #pragma unroll
        for (int fm = 0; fm < 4; ++fm)
            #pragma unroll
            for (int fn = 0; fn < 4; ++fn)
                acc[fm][fn] = __builtin_amdgcn_mfma_f32_16x16x32_bf16(
                    af[fm], bf[fn], acc[fm][fn], 0, 0, 0);
        __syncthreads();
        cur ^= 1;
    }
#undef STAGE_ZX

    #pragma unroll
    for (int fm = 0; fm < 4; ++fm)
        #pragma unroll
        for (int fn = 0; fn < 4; ++fn) {
            const size_t col = n0 + wc * 64 + fn * 16 + lc;
            #pragma unroll
            for (int j = 0; j < 4; ++j) {
                const size_t row = m0 + wr * 64 + fm * 16 + lr * 4 + j;
                zx[row * DTOT + col] = acc[fm][fn][j];
            }
        }
}

// ---------------------------------------------------------------------------
// bf16 MFMA GEMM, 128x64 tile, 2-phase dbuf: out = gn_bf @ wo_bf^T
// ---------------------------------------------------------------------------
__global__ __launch_bounds__(256) void mfma_gemm_out(const u16* __restrict__ A,
                                                     const u16* __restrict__ B,
                                                     float* __restrict__ C,
                                                     int K, int ldc) {
    __shared__ u16 Als[2][128 * 32];
    __shared__ u16 Bls[2][64 * 32];
    const int tid = threadIdx.x;
    const int m0 = blockIdx.y * 128, n0 = blockIdx.x * 64;
    const int lane = tid & 63, wave = tid >> 6;
    const int wr = wave >> 1, wc = wave & 1;
    const int lr = lane >> 4, lc = lane & 15;
    const int sr = tid >> 2;
    const int sc = (tid & 3) * 8;

    f32x4 acc[4][2] = {};

    const u16* pA = A + (size_t)(m0 + sr) * K + sc;
    const u16* pB = B + (size_t)(n0 + sr) * K + sc;

#define STAGE_OUT(buf, k0) {                                             \
        gload16(pA + (k0), &Als[buf][tid * 8]);                          \
        gload16(pA + (k0) + (size_t)64 * K, &Als[buf][tid * 8 + 2048]);  \
        gload16(pB + (k0), &Bls[buf][tid * 8]); }

    STAGE_OUT(0, 0);
    __syncthreads();
    int cur = 0;
    for (int k0 = 0; k0 < K; k0 += 32) {
        if (k0 + 32 < K) STAGE_OUT(cur ^ 1, k0 + 32);
        s16x8 af[4], bf[2];
        #pragma unroll
        for (int f = 0; f < 4; ++f)
            af[f] = *(const s16x8*)&Als[cur][(wr * 64 + f * 16 + lc) * 32 + lr * 8];
        #pragma unroll
        for (int f = 0; f < 2; ++f)
            bf[f] = *(const s16x8*)&Bls[cur][(wc * 32 + f * 16 + lc) * 32 + lr * 8];
        #pragma unroll
        for (int fm = 0; fm < 4; ++fm)
            #pragma unroll
            for (int fn = 0; fn < 2; ++fn)
                acc[fm][fn] = __builtin_amdgcn_mfma_f32_16x16x32_bf16(
                    af[fm], bf[fn], acc[fm][fn], 0, 0, 0);
        __syncthreads();
        cur ^= 1;
    }
#undef STAGE_OUT

    #pragma unroll
    for (int fm = 0; fm < 4; ++fm)
        #pragma unroll
        for (int fn = 0; fn < 2; ++fn) {
            const size_t col = n0 + wc * 32 + fn * 16 + lc;
            #pragma unroll
            for (int j = 0; j < 4; ++j) {
                const size_t row = m0 + wr * 64 + fm * 16 + lr * 4 + j;
                C[row * (size_t)ldc + col] = acc[fm][fn][j];
            }
        }
}

// ---------------------------------------------------------------------------
// split-bf16 3-pass MFMA GEMM, sensitive columns (2-phase dbuf)
// ---------------------------------------------------------------------------
__global__ __launch_bounds__(256) void mfma_gemm_rem3(const u16* __restrict__ uh,
        const u16* __restrict__ ul, const u16* __restrict__ wh,
        const u16* __restrict__ wl, float* __restrict__ zxr) {
    __shared__ u16 Ah[2][128 * 32], Alo[2][128 * 32];
    __shared__ u16 Bh[2][64 * 32],  Blo[2][64 * 32];
    const int tid = threadIdx.x;
    const int m0 = blockIdx.y * 128, n0 = blockIdx.x * 64;
    const int lane = tid & 63, wave = tid >> 6;
    const int wr = wave >> 1, wc = wave & 1;
    const int lr = lane >> 4, lc = lane & 15;
    const int sr = tid >> 2;
    const int sc = (tid & 3) * 8;

    f32x4 acc[4][2] = {};

    const u16* pAh = uh + (size_t)(m0 + sr) * DMODEL + sc;
    const u16* pAl = ul + (size_t)(m0 + sr) * DMODEL + sc;
    const u16* pBh = wh + (size_t)(n0 + sr) * DMODEL + sc;
    const u16* pBl = wl + (size_t)(n0 + sr) * DMODEL + sc;

#define STAGE_R3(buf, k0) {                                                  \
        gload16(pAh + (k0), &Ah[buf][tid * 8]);                              \
        gload16(pAh + (k0) + (size_t)64 * DMODEL, &Ah[buf][tid * 8 + 2048]); \
        gload16(pAl + (k0), &Alo[buf][tid * 8]);                             \
        gload16(pAl + (k0) + (size_t)64 * DMODEL, &Alo[buf][tid * 8 + 2048]);\
        gload16(pBh + (k0), &Bh[buf][tid * 8]);                              \
        gload16(pBl + (k0), &Blo[buf][tid * 8]); }

    STAGE_R3(0, 0);
    __syncthreads();
    int cur = 0;
    for (int k0 = 0; k0 < DMODEL; k0 += 32) {
        if (k0 + 32 < DMODEL) STAGE_R3(cur ^ 1, k0 + 32);
        s16x8 ahf[4], alf[4], bhf[2], blf[2];
        #pragma unroll
        for (int f = 0; f < 4; ++f) {
            ahf[f] = *(const s16x8*)&Ah[cur][(wr * 64 + f * 16 + lc) * 32 + lr * 8];
            alf[f] = *(const s16x8*)&Alo[cur][(wr * 64 + f * 16 + lc) * 32 + lr * 8];
        }
        #pragma unroll
        for (int f = 0; f < 2; ++f) {
            bhf[f] = *(const s16x8*)&Bh[cur][(wc * 32 + f * 16 + lc) * 32 + lr * 8];
            blf[f] = *(const s16x8*)&Blo[cur][(wc * 32 + f * 16 + lc) * 32 + lr * 8];
        }
        #pragma unroll
        for (int fm = 0; fm < 4; ++fm)
            #pragma unroll
            for (int fn = 0; fn < 2; ++fn) {
                acc[fm][fn] = __builtin_amdgcn_mfma_f32_16x16x32_bf16(
                    ahf[fm], bhf[fn], acc[fm][fn], 0, 0, 0);
                acc[fm][fn] = __builtin_amdgcn_mfma_f32_16x16x32_bf16(
                    ahf[fm], blf[fn], acc[fm][fn], 0, 0, 0);
                acc[fm][fn] = __builtin_amdgcn_mfma_f32_16x16x32_bf16(
                    alf[fm], bhf[fn], acc[fm][fn], 0, 0, 0);
            }
        __syncthreads();
        cur ^= 1;
    }
#undef STAGE_R3

    #pragma unroll
    for (int fm = 0; fm < 4; ++fm)
        #pragma unroll
        for (int fn = 0; fn < 2; ++fn) {
            const size_t col = n0 + wc * 32 + fn * 16 + lc;
            #pragma unroll
            for (int j = 0; j < 4; ++j) {
                const size_t row = m0 + wr * 64 + fm * 16 + lr * 4 + j;
                zxr[row * DTOT + col] = acc[fm][fn][j];
            }
        }
}

// ---------------------------------------------------------------------------
// prep: RMS-norm Br/Cr; abg4 = (alpha, beta, gamma, beta'=(1-lam)*dt) in (b,h,l).
// ---------------------------------------------------------------------------
__global__ __launch_bounds__(64) void prep_kernel(const float* __restrict__ zx,
        const float* __restrict__ dt_bias, const float* __restrict__ A_log,
        const float* __restrict__ B_norm_w, const float* __restrict__ C_norm_w,
        float* __restrict__ Bg, float* __restrict__ Cg,
        float4* __restrict__ abg4) {
    const int bl = blockIdx.x;
    const int b = bl >> 10, l = bl & (LSEQ - 1);
    const int t  = threadIdx.x;
    const float* row = zx + (size_t)bl * DTOT;
    const float br = row[OFF_BR + t];
    const float cr = row[OFF_CR + t];
    float ssb = br * br, ssc = cr * cr;
    #pragma unroll
    for (int k = 1; k < 64; k <<= 1) { ssb += __shfl_xor(ssb, k); ssc += __shfl_xor(ssc, k); }
    const float scB = rsqrtf(ssb * (1.f / 64.f) + 1e-5f);
    const float scC = rsqrtf(ssc * (1.f / 64.f) + 1e-5f);
    Bg[(size_t)bl * 64 + t] = br * scB * B_norm_w[t];
    Cg[(size_t)bl * 64 + t] = cr * scC * C_norm_w[t];
    if (t < NH) {
        const float dtr = row[OFF_DT + t] + dt_bias[t];
        const float dt  = (dtr > 20.f) ? dtr : log1pf(expf(dtr));
        const float lamr = row[OFF_LAM + t];
        const float lam  = 1.f / (1.f + expf(-lamr));
        const float Ah   = -expf(A_log[t]);
        const float al   = expf(dt * Ah);
        const float bp   = (1.f - lam) * dt;            // beta' = b/a
        const size_t o = ((size_t)b * NH + t) * LSEQ + l;
        abg4[o] = make_float4(al, bp * al, lam * dt, bp);
    }
}

// ---------------------------------------------------------------------------
// cumsum of thr over L, per (b,h): 32 dims.
// ---------------------------------------------------------------------------
__global__ __launch_bounds__(256) void cumsum_kernel(const float* __restrict__ zx,
                                                     float* __restrict__ th_cs) {
    const int bh = blockIdx.x;
    const int b = bh >> 5, h = bh & 31;
    const int d = threadIdx.x & 31, seg = threadIdx.x >> 5;
    const float* base = zx + (size_t)b * LSEQ * DTOT + OFF_TH + h * 32 + d;
    float* out = th_cs + (size_t)b * LSEQ * 1024 + h * 32 + d;
    __shared__ float sums[8][33];
    const int l0 = seg * 128;
    float s = 0.f;
    #pragma unroll 4
    for (int i = 0; i < 128; ++i) s += base[(size_t)(l0 + i) * DTOT];
    sums[seg][d] = s;
    __syncthreads();
    float acc = 0.f;
    for (int s2 = 0; s2 < seg; ++s2) acc += sums[s2][d];
    #pragma unroll 4
    for (int i = 0; i < 128; ++i) {
        acc += base[(size_t)(l0 + i) * DTOT];
        out[(size_t)(l0 + i) * 1024] = acc;
    }
}

// ---------------------------------------------------------------------------
// rot: Bh/Ch = rot(broadcast(Bg/Cg)+bias). Brot/Crot layout (B,NH,L,DS).
// ---------------------------------------------------------------------------
__global__ __launch_bounds__(256) void rot_kernel(const float* __restrict__ th_cs,
        const float* __restrict__ Bg, const float* __restrict__ Cg,
        const float* __restrict__ B_bias, const float* __restrict__ C_bias,
        float* __restrict__ Brot, float* __restrict__ Crot) {
    const size_t idx = (size_t)blockIdx.x * 256 + threadIdx.x;
    const int j = (int)(idx & 31);
    const int h = (int)((idx >> 5) & 31);
    const size_t bl = idx >> 10;
    const int l = (int)(bl & (LSEQ - 1));
    const int b = (int)(bl >> 10);
    const float th = th_cs[idx];
    float s, c;
    sincosf(th, &s, &c);
    float v1 = Bg[bl * 64 + j]      + B_bias[h * 64 + j];
    float v2 = Bg[bl * 64 + 32 + j] + B_bias[h * 64 + 32 + j];
    const size_t ob = ((size_t)(b * NH + h) * LSEQ + l) * DS + j;
    Brot[ob]      = v1 * c - v2 * s;
    Brot[ob + 32] = v1 * s + v2 * c;
    v1 = Cg[bl * 64 + j]      + C_bias[h * 64 + j];
    v2 = Cg[bl * 64 + 32 + j] + C_bias[h * 64 + 32 + j];
    Crot[ob]      = v1 * c - v2 * s;
    Crot[ob + 32] = v1 * s + v2 * c;
}

// ---------------------------------------------------------------------------
// wcalc: per (b,h,seg): within-seg log-cumsum of alpha; emits
//   wbuf[bh,t] = exp(LE - L_t) * (gamma_t + beta'_{t+1})  (t<segend),  gamma_t at segend
//   aprod[bh,seg] = exp(LE);  bscale[bh,seg] = exp(LE)*beta'_{t0}  (0 for seg 0)
// 64 blocks x 64 threads; thread = (seg = lane>>3, sub = lane&7), 16 steps each.
// ---------------------------------------------------------------------------
__global__ __launch_bounds__(64) void wcalc_kernel(const float4* __restrict__ abg4,
        float* __restrict__ wbuf, float* __restrict__ aprod, float* __restrict__ bscale) {
    const int bh = blockIdx.x;
    const int lane = threadIdx.x;
    const int seg = lane >> 3, sub = lane & 7;
    const int t0 = seg * SEG;
    const int sbase = t0 + sub * 16;
    const float4* ab = abg4 + (size_t)bh * LSEQ;

    float part = 0.f;
    #pragma unroll
    for (int i = 0; i < 16; ++i) part += logf(ab[sbase + i].x);
    // inclusive scan over the 8 sub-lanes of this seg
    float incl = part;
    #pragma unroll
    for (int d = 1; d < 8; d <<= 1) {
        const float v = __shfl_up(incl, d, 8);
        if (sub >= d) incl += v;
    }
    const float LE = __shfl(incl, 7, 8);     // total over segment
    float Lrun = incl - part;                // exclusive prefix (= L_{sbase-1}, base L_{t0-1}=0)

    for (int i = 0; i < 16; ++i) {
        const int s = sbase + i;
        const float4 A = ab[s];
        Lrun += logf(A.x);
        float w;
        if ((s & (SEG - 1)) == (SEG - 1)) w = A.z;                // seg end: gamma only
        else w = __expf(LE - Lrun) * (A.z + ab[s + 1].w);
        wbuf[(size_t)bh * LSEQ + s] = w;
    }
    if (sub == 0) {
        aprod[bh * NSEG + seg] = __expf(LE);
        bscale[bh * NSEG + seg] = (seg > 0) ? __expf(LE) * ab[t0].w : 0.f;
    }
}

// ---------------------------------------------------------------------------
// hseg_gemm: per (b,h,seg): h_local_end[p,n] = sum_s wbuf_s * x_s[p] * B_s[n]
// as a split-bf16 3-pass MFMA GEMM (64x64 out, K=128). Output -> hseg[bh][seg][p][n].
// ---------------------------------------------------------------------------
#define WK 136   // u16 stride: multiple of 8 (16B-aligned b128 reads)
__global__ __launch_bounds__(256) void hseg_gemm(const float* __restrict__ zx,
        const float* __restrict__ Brot, const float* __restrict__ wbuf,
        float* __restrict__ hseg) {
    __shared__ u16 XH[64][WK], XL[64][WK], BHs[64][WK], BLs[64][WK];
    const int blk = blockIdx.x;
    const int seg = blk & (NSEG - 1), bh = blk >> 3;
    const int b = bh >> 5, h = bh & 31;
    const int tid = threadIdx.x;

    // stage: thread -> (s-row, 32-col half); fp32 loads, scale X by w, split to hi/lo
    {
        const int sIdx = tid >> 1, half = tid & 1;
        const int t = seg * SEG + sIdx;
        const float wv = wbuf[(size_t)bh * LSEQ + t];
        const float* xsrc = zx + ((size_t)b * LSEQ + t) * DTOT + OFF_X + h * 64 + half * 32;
        const float* bsrc = Brot + ((size_t)bh * LSEQ + t) * DS + half * 32;
        #pragma unroll
        for (int i = 0; i < 32; i += 4) {
            const float4 xv = *(const float4*)(xsrc + i);
            const float4 bv = *(const float4*)(bsrc + i);
            const int p0 = half * 32 + i;
            u16 hi, lo;
            split1(xv.x * wv, hi, lo); XH[p0 + 0][sIdx] = hi; XL[p0 + 0][sIdx] = lo;
            split1(xv.y * wv, hi, lo); XH[p0 + 1][sIdx] = hi; XL[p0 + 1][sIdx] = lo;
            split1(xv.z * wv, hi, lo); XH[p0 + 2][sIdx] = hi; XL[p0 + 2][sIdx] = lo;
            split1(xv.w * wv, hi, lo); XH[p0 + 3][sIdx] = hi; XL[p0 + 3][sIdx] = lo;
            split1(bv.x, hi, lo); BHs[p0 + 0][sIdx] = hi; BLs[p0 + 0][sIdx] = lo;
            split1(bv.y, hi, lo); BHs[p0 + 1][sIdx] = hi; BLs[p0 + 1][sIdx] = lo;
            split1(bv.z, hi, lo); BHs[p0 + 2][sIdx] = hi; BLs[p0 + 2][sIdx] = lo;
            split1(bv.w, hi, lo); BHs[p0 + 3][sIdx] = hi; BLs[p0 + 3][sIdx] = lo;
        }
    }
    __syncthreads();

    const int lane = tid & 63, wave = tid >> 6;
    const int wR = wave >> 1, wC = wave & 1;
    const int lr = lane >> 4, lc = lane & 15;

    f32x4 acc[2][2] = {};
    #pragma unroll
    for (int ks = 0; ks < 4; ++ks) {
        const int k0 = ks * 32;
        s16x8 xh[2], xl[2], bhf[2], blf[2];
        #pragma unroll
        for (int f = 0; f < 2; ++f) {
            const int pr = wR * 32 + f * 16 + lc;
            xh[f] = *(const s16x8*)&XH[pr][k0 + lr * 8];
            xl[f] = *(const s16x8*)&XL[pr][k0 + lr * 8];
            const int nr = wC * 32 + f * 16 + lc;
            bhf[f] = *(const s16x8*)&BHs[nr][k0 + lr * 8];
            blf[f] = *(const s16x8*)&BLs[nr][k0 + lr * 8];
        }
        #pragma unroll
        for (int fm = 0; fm < 2; ++fm)
            #pragma unroll
            for (int fn = 0; fn < 2; ++fn) {
                acc[fm][fn] = __builtin_amdgcn_mfma_f32_16x16x32_bf16(
                    xh[fm], bhf[fn], acc[fm][fn], 0, 0, 0);
                acc[fm][fn] = __builtin_amdgcn_mfma_f32_16x16x32_bf16(
                    xh[fm], blf[fn], acc[fm][fn], 0, 0, 0);
                acc[fm][fn] = __builtin_amdgcn_mfma_f32_16x16x32_bf16(
                    xl[fm], bhf[fn], acc[fm][fn], 0, 0, 0);
            }
    }

    float* hp = hseg + ((size_t)(bh * NSEG + seg) * HD) * DS;
    #pragma unroll
    for (int fm = 0; fm < 2; ++fm)
        #pragma unroll
        for (int fn = 0; fn < 2; ++fn) {
            const int n = wC * 32 + fn * 16 + lc;
            #pragma unroll
            for (int j = 0; j < 4; ++j) {
                const int p = wR * 32 + fm * 16 + lr * 4 + j;
                hp[p * DS + n] = acc[fm][fn][j];
            }
        }
}

// ---------------------------------------------------------------------------
// DPP 16-lane row sum (VALU pipe). Lane 15 of each 16-lane row holds the sum.
// ---------------------------------------------------------------------------
__device__ __forceinline__ float row_sum16(float x) {
    int t;
    t = __builtin_amdgcn_update_dpp(0, __float_as_int(x), 0x111, 0xf, 0xf, true);
    x += __int_as_float(t);
    t = __builtin_amdgcn_update_dpp(0, __float_as_int(x), 0x112, 0xf, 0xf, true);
    x += __int_as_float(t);
    t = __builtin_amdgcn_update_dpp(0, __float_as_int(x), 0x114, 0xf, 0xf, true);
    x += __int_as_float(t);
    t = __builtin_amdgcn_update_dpp(0, __float_as_int(x), 0x118, 0xf, 0xf, true);
    x += __int_as_float(t);
    return x;
}

// ---------------------------------------------------------------------------
// scan_fix: sequential over segments. h_local_end from hseg_gemm PLUS the
// cross-boundary rank-1 term bscale*B_{t0-1}[n]*x_{t0-1}[p]; in-place ->
// hseg becomes h_start per segment.
// ---------------------------------------------------------------------------
__global__ __launch_bounds__(256) void scan_fix(float* __restrict__ hseg,
        const float* __restrict__ aprod, const float* __restrict__ bscale,
        const float* __restrict__ zx, const float* __restrict__ Brot) {
    const int blk = blockIdx.x;          // (b,h,ptile): 256
    const int ptile = blk & 3, h = (blk >> 2) & 31, b = blk >> 7;
    const int tid = threadIdx.x;
    const int pl = tid >> 4, ng = tid & 15;
    const int p = ptile * 16 + pl;
    const int n0 = ng * 4;
    const size_t bh = (size_t)b * NH + h;

    float4 cur = make_float4(0.f, 0.f, 0.f, 0.f);
    #pragma unroll
    for (int s = 0; s < NSEG; ++s) {
        float* hp = hseg + (((bh * NSEG + s) * HD + p) * DS + n0);
        float4 tmp = *(const float4*)hp;     // local h_end (no boundary)
        if (s > 0) {
            const float bs = bscale[bh * NSEG + s];
            const int tm1 = s * SEG - 1;
            const float4 Bm = *(const float4*)(Brot + ((size_t)bh * LSEQ + tm1) * DS + n0);
            const float xm = zx[((size_t)b * LSEQ + tm1) * DTOT + OFF_X + h * HD + p];
            const float f = bs * xm;
            tmp.x = fmaf(f, Bm.x, tmp.x);
            tmp.y = fmaf(f, Bm.y, tmp.y);
            tmp.z = fmaf(f, Bm.z, tmp.z);
            tmp.w = fmaf(f, Bm.w, tmp.w);
        }
        *(float4*)hp = cur;                  // h_start[s]
        const float a = aprod[bh * NSEG + s];
        cur.x = fmaf(a, cur.x, tmp.x);
        cur.y = fmaf(a, cur.y, tmp.y);
        cur.z = fmaf(a, cur.z, tmp.z);
        cur.w = fmaf(a, cur.w, tmp.w);
    }
}

// ---------------------------------------------------------------------------
// scan_p2: full scan per segment from corrected h_start; emits y.
// ---------------------------------------------------------------------------
__global__ __launch_bounds__(256, 8) void scan_p2(const float* __restrict__ zx,
        const float* __restrict__ Brot, const float* __restrict__ Crot,
        const float4* __restrict__ abg4, const float* __restrict__ hseg,
        const float* __restrict__ Dp, float* __restrict__ yb) {
    const int blk = blockIdx.x;
    const int s = blk & (NSEG - 1), ptile = (blk >> 3) & 3, h = (blk >> 5) & 31, b = blk >> 10;
    const int tid = threadIdx.x;
    const int pl = tid >> 4, ng = tid & 15;
    const int p = ptile * 16 + pl;
    const int n0 = ng * 4;
    const int t0 = s * SEG;

    const size_t bh = (size_t)b * NH + h;
    const float* Bbase = Brot + bh * LSEQ * DS + n0;
    const float* Cbase = Crot + bh * LSEQ * DS + n0;
    const float4* abase = abg4 + bh * LSEQ;
    const float* xbase = zx + (size_t)b * LSEQ * DTOT + OFF_X + h * HD + p;
    const float Dh = Dp[h];
    float* ybase = yb + (size_t)b * LSEQ * DIN + h * HD + p;

    const float4 h0v = *(const float4*)(hseg + (((bh * NSEG + s) * HD + p) * DS + n0));
    float hs0 = h0v.x, hs1 = h0v.y, hs2 = h0v.z, hs3 = h0v.w;
    float Bp0 = 0.f, Bp1 = 0.f, Bp2 = 0.f, Bp3 = 0.f;
    float xprev = 0.f;
    if (s > 0) {
        const float4 Bm = *(const float4*)(Bbase + (size_t)(t0 - 1) * DS);
        Bp0 = Bm.x; Bp1 = Bm.y; Bp2 = Bm.z; Bp3 = Bm.w;
        xprev = xbase[(size_t)(t0 - 1) * DTOT];
    }

    #pragma unroll 4
    for (int t = t0; t < t0 + SEG; ++t) {
        const float4 Bv = *(const float4*)(Bbase + (size_t)t * DS);
        const float4 Cv = *(const float4*)(Cbase + (size_t)t * DS);
        const float4 av = abase[t];
        const float  xv = xbase[(size_t)t * DTOT];
        const float cp = av.y * xprev;
        const float cc = av.z * xv;
        float ys;
        hs0 = fmaf(av.x, hs0, fmaf(cp, Bp0, cc * Bv.x)); ys  = Cv.x * hs0;
        hs1 = fmaf(av.x, hs1, fmaf(cp, Bp1, cc * Bv.y)); ys += Cv.y * hs1;
        hs2 = fmaf(av.x, hs2, fmaf(cp, Bp2, cc * Bv.z)); ys += Cv.z * hs2;
        hs3 = fmaf(av.x, hs3, fmaf(cp, Bp3, cc * Bv.w)); ys += Cv.w * hs3;
        ys = row_sum16(ys);
        if (ng == 15) ybase[(size_t)t * DIN] = fmaf(Dh, xv, ys);
        Bp0 = Bv.x; Bp1 = Bv.y; Bp2 = Bv.z; Bp3 = Bv.w;
        xprev = xv;
    }
}

// ---------------------------------------------------------------------------
// gate + final RMS norm; emits bf16 directly for the out_proj GEMM.
// ---------------------------------------------------------------------------
__global__ __launch_bounds__(256) void gate_norm_kernel(const float* __restrict__ yb,
        const float* __restrict__ zx, const float* __restrict__ norm_w,
        u16* __restrict__ gnb) {
    const int bl = blockIdx.x;
    const int tid = threadIdx.x;
    const float* yrow = yb + (size_t)bl * DIN;
    const float* zrow = zx + (size_t)bl * DTOT + OFF_Z;
    float g[8];
    float ss = 0.f;
    #pragma unroll
    for (int i = 0; i < 8; ++i) {
        const int c = tid + i * 256;
        const float yv = yrow[c];
        const float zv = zrow[c];
        const float sg = 1.f / (1.f + expf(-zv));
        const float gv = yv * zv * sg;
        g[i] = gv;
        ss += gv * gv;
    }
    #pragma unroll
    for (int k = 1; k < 64; k <<= 1) ss += __shfl_xor(ss, k);
    __shared__ float wsum[4];
    if ((tid & 63) == 0) wsum[tid >> 6] = ss;
    __syncthreads();
    ss = wsum[0] + wsum[1] + wsum[2] + wsum[3];
    const float sc = rsqrtf(ss * (1.f / 2048.f) + 1e-5f);
    #pragma unroll
    for (int i = 0; i < 8; ++i) {
        const int c = tid + i * 256;
        gnb[(size_t)bl * DIN + c] = (u16)f2bf(g[i] * sc * norm_w[c]);
    }
}

// ---------------------------------------------------------------------------
extern "C" void kernel_launch(void* const* d_in, const int* in_sizes, int n_in,
                              void* d_out, int out_size, void* d_ws, size_t ws_size,
                              hipStream_t stream) {
    const float* u          = (const float*)d_in[0];
    const float* in_proj_w  = (const float*)d_in[1];
    const float* dt_bias    = (const float*)d_in[2];
    const float* A_log      = (const float*)d_in[3];
    const float* Dp         = (const float*)d_in[4];
    const float* B_norm_w   = (const float*)d_in[5];
    const float* C_norm_w   = (const float*)d_in[6];
    const float* B_bias     = (const float*)d_in[7];
    const float* C_bias     = (const float*)d_in[8];
    const float* norm_w     = (const float*)d_in[9];
    const float* out_proj_w = (const float*)d_in[10];
    float* out = (float*)d_out;

    float* p = (float*)d_ws;
    float* zx    = p; p += (size_t)ROWS * DTOT;
    float* th_cs = p; p += (size_t)ROWS * 1024;   // dead after rot -> hseg
    float* Brot  = p; p += (size_t)ROWS * 2048;   // doubles as bf16 scratch
    float* Crot  = p; p += (size_t)ROWS * 2048;
    float* Bg    = p; p += (size_t)ROWS * 64;     // dead after rot -> aprod/bscale
    float* Cg    = p; p += (size_t)ROWS * 64;     // dead after rot -> wbuf
    float4* abg4 = (float4*)p; p += (size_t)ROWS * NH * 4;
    float* yb    = p; p += (size_t)ROWS * 2048;
    float* hseg   = th_cs;                        // 64*8*64*64 = 2,097,152 floats
    float* aprod  = Bg;                           // 512 floats
    float* bscale = Bg + 512;                     // 512 floats
    float* wbuf   = Cg;                           // 64*1024 = 65,536 floats

    // Phase-A bf16 scratch inside Brot+Crot (consumed before rot writes them):
    u16* u_bf = (u16*)Brot;
    u16* u_lo = u_bf + (size_t)ROWS * DMODEL;
    u16* w_bf = u_lo + (size_t)ROWS * DMODEL;
    u16* w_lo = w_bf + (size_t)DTOT * DMODEL;
    // Phase-B (after scan, Brot/Crot dead again):
    u16* gn_bf = (u16*)Brot;
    u16* wo_bf = gn_bf + (size_t)ROWS * DIN;

    // 0. one-time fp32 -> bf16 (+residual) conversions
    conv_u<<<(ROWS * DMODEL / 4) / 256, 256, 0, stream>>>(u, u_bf, u_lo);
    conv_w<<<((size_t)DTOT * DMODEL / 4) / 256, 256, 0, stream>>>(in_proj_w, w_bf, w_lo);
    // 1a/1b. in_proj GEMMs
    mfma_gemm_zx<<<dim3(NZX / 128, ROWS / 128), 256, 0, stream>>>(u_bf, w_bf, zx);
    mfma_gemm_rem3<<<dim3(NREM / 64, ROWS / 128), 256, 0, stream>>>(
        u_bf, u_lo, w_bf + (size_t)NZX * DMODEL, w_lo, zx + NZX);
    // 2. per-row prep (abg4.w = beta')
    prep_kernel<<<ROWS, 64, 0, stream>>>(zx, dt_bias, A_log, B_norm_w, C_norm_w,
                                         Bg, Cg, abg4);
    // 3. cumsum of theta over L
    cumsum_kernel<<<BB * NH, 256, 0, stream>>>(zx, th_cs);
    // 4. rotary on B/C
    rot_kernel<<<(ROWS * 1024) / 256, 256, 0, stream>>>(th_cs, Bg, Cg, B_bias, C_bias,
                                                        Brot, Crot);
    // 5. segmented scan: weights -> h_end GEMM -> fixup -> final pass
    wcalc_kernel<<<BB * NH, 64, 0, stream>>>(abg4, wbuf, aprod, bscale);
    hseg_gemm<<<BB * NH * NSEG, 256, 0, stream>>>(zx, Brot, wbuf, hseg);
    scan_fix<<<BB * NH * 4, 256, 0, stream>>>(hseg, aprod, bscale, zx, Brot);
    scan_p2<<<BB * NH * 4 * NSEG, 256, 0, stream>>>(zx, Brot, Crot, abg4, hseg, Dp, yb);
    // 6-8. epilogue
    conv_wo<<<(DMODEL * DIN / 4) / 256, 256, 0, stream>>>(out_proj_w, wo_bf);
    gate_norm_kernel<<<ROWS, 256, 0, stream>>>(yb, zx, norm_w, gn_bf);
    mfma_gemm_out<<<dim3(DMODEL / 64, ROWS / 128), 256, 0, stream>>>(
        gn_bf, wo_bf, out, DIN, DMODEL);
}

// Round 16
// 209.416 us; speedup vs baseline: 1.6905x; 1.2019x over previous
//
#include <hip/hip_runtime.h>
#include <hip/hip_bf16.h>

// Problem constants
#define DMODEL 1024
#define DIN    2048
#define NH     32
#define HD     64
#define DS     64
#define LSEQ   1024
#define BB     2
#define DTOT   5312           // 2*DIN + 2*64 + 32 + 1024 + 32
#define ROWS   (BB*LSEQ)      // 2048
// column offsets inside zxbcdt
#define OFF_Z   0
#define OFF_X   2048
#define OFF_BR  4096
#define OFF_CR  4160
#define OFF_DT  4224
#define OFF_TH  4256
#define OFF_LAM 5280
#define NZX     4096          // z+x columns: single-pass bf16 MFMA
#define NREM    (DTOT - NZX)  // 1216 cols: 3-pass split-bf16 MFMA
// segmented scan
#define NSEG 8
#define SEG  (LSEQ / NSEG)    // 128

typedef short  s16x8 __attribute__((ext_vector_type(8)));
typedef float  f32x4 __attribute__((ext_vector_type(4)));
typedef unsigned short u16;

__device__ __forceinline__ unsigned int f2bf(float f) {   // RNE f32->bf16 (finite inputs)
    unsigned int u = __float_as_uint(f);
    u += 0x7fffu + ((u >> 16) & 1u);
    return u >> 16;
}
__device__ __forceinline__ unsigned int pk(float x, float y) {
    return f2bf(x) | (f2bf(y) << 16);
}
__device__ __forceinline__ void split1(float v, u16& hi, u16& lo) {
    const unsigned int h = f2bf(v);
    hi = (u16)h;
    lo = (u16)f2bf(v - __uint_as_float(h << 16));
}

// HBM -> LDS direct 16B copy. Dest = wave-uniform base + lane*16 (m104).
typedef const __attribute__((address_space(1))) unsigned int glb_u32;
typedef __attribute__((address_space(3))) unsigned int lds_u32;
__device__ __forceinline__ void gload16(const void* g, void* l) {
    __builtin_amdgcn_global_load_lds((glb_u32*)g, (lds_u32*)l, 16, 0, 0);
}

// ---------------------------------------------------------------------------
// conversion kernels: fp32 -> bf16 (hi) and residual (lo).
// ---------------------------------------------------------------------------
__global__ __launch_bounds__(256) void conv_u(const float* __restrict__ src,
        u16* __restrict__ hi, u16* __restrict__ lo) {
    const size_t i4 = ((size_t)blockIdx.x * 256 + threadIdx.x) * 4;
    const float4 v = *(const float4*)(src + i4);
    const unsigned int h0 = f2bf(v.x), h1 = f2bf(v.y), h2 = f2bf(v.z), h3 = f2bf(v.w);
    uint2 hw, lw;
    hw.x = h0 | (h1 << 16); hw.y = h2 | (h3 << 16);
    lw.x = pk(v.x - __uint_as_float(h0 << 16), v.y - __uint_as_float(h1 << 16));
    lw.y = pk(v.z - __uint_as_float(h2 << 16), v.w - __uint_as_float(h3 << 16));
    *(uint2*)(hi + i4) = hw;
    *(uint2*)(lo + i4) = lw;
}

__global__ __launch_bounds__(256) void conv_w(const float* __restrict__ src,
        u16* __restrict__ hi, u16* __restrict__ lo) {
    const size_t i4 = ((size_t)blockIdx.x * 256 + threadIdx.x) * 4;
    const float4 v = *(const float4*)(src + i4);
    const unsigned int h0 = f2bf(v.x), h1 = f2bf(v.y), h2 = f2bf(v.z), h3 = f2bf(v.w);
    uint2 hw, lw;
    hw.x = h0 | (h1 << 16); hw.y = h2 | (h3 << 16);
    lw.x = pk(v.x - __uint_as_float(h0 << 16), v.y - __uint_as_float(h1 << 16));
    lw.y = pk(v.z - __uint_as_float(h2 << 16), v.w - __uint_as_float(h3 << 16));
    *(uint2*)(hi + i4) = hw;
    if ((i4 >> 10) >= NZX)
        *(uint2*)(lo + (i4 - (size_t)NZX * DMODEL)) = lw;
}

__global__ __launch_bounds__(256) void conv_wo(const float* __restrict__ src,
        u16* __restrict__ hi) {
    const size_t i4 = ((size_t)blockIdx.x * 256 + threadIdx.x) * 4;
    const float4 v = *(const float4*)(src + i4);
    uint2 hw;
    hw.x = pk(v.x, v.y); hw.y = pk(v.z, v.w);
    *(uint2*)(hi + i4) = hw;
}

// ---------------------------------------------------------------------------
// bf16 MFMA GEMM, z/x block (2-phase dbuf global_load_lds)
// ---------------------------------------------------------------------------
__global__ __launch_bounds__(256) void mfma_gemm_zx(const u16* __restrict__ uA_,
                                                    const u16* __restrict__ uW,
                                                    float* __restrict__ zx) {
    __shared__ u16 Al[2][128 * 32];
    __shared__ u16 Bl[2][128 * 32];
    const int tid = threadIdx.x;
    const int m0 = blockIdx.y * 128, n0 = blockIdx.x * 128;
    const int lane = tid & 63, wave = tid >> 6;
    const int wr = wave >> 1, wc = wave & 1;
    const int lr = lane >> 4, lc = lane & 15;
    const int sr = tid >> 2;
    const int sc = (tid & 3) * 8;

    f32x4 acc[4][4] = {};

    const u16* pA = uA_ + (size_t)(m0 + sr) * DMODEL + sc;
    const u16* pB = uW  + (size_t)(n0 + sr) * DMODEL + sc;

#define STAGE_ZX(buf, k0) {                                              \
        gload16(pA + (k0), &Al[buf][tid * 8]);                           \
        gload16(pA + (k0) + (size_t)64 * DMODEL, &Al[buf][tid * 8 + 2048]); \
        gload16(pB + (k0), &Bl[buf][tid * 8]);                           \
        gload16(pB + (k0) + (size_t)64 * DMODEL, &Bl[buf][tid * 8 + 2048]); }

    STAGE_ZX(0, 0);
    __syncthreads();
    int cur = 0;
    for (int k0 = 0; k0 < DMODEL; k0 += 32) {
        if (k0 + 32 < DMODEL) STAGE_ZX(cur ^ 1, k0 + 32);
        s16x8 af[4], bf[4];
        #pragma unroll
        for (int f = 0; f < 4; ++f) {
            af[f] = *(const s16x8*)&Al[cur][(wr * 64 + f * 16 + lc) * 32 + lr * 8];
            bf[f] = *(const s16x8*)&Bl[cur][(wc * 64 + f * 16 + lc) * 32 + lr * 8];
        }
        #pragma unroll
        for (int fm = 0; fm < 4; ++fm)
            #pragma unroll
            for (int fn = 0; fn < 4; ++fn)
                acc[fm][fn] = __builtin_amdgcn_mfma_f32_16x16x32_bf16(
                    af[fm], bf[fn], acc[fm][fn], 0, 0, 0);
        __syncthreads();
        cur ^= 1;
    }
#undef STAGE_ZX

    #pragma unroll
    for (int fm = 0; fm < 4; ++fm)
        #pragma unroll
        for (int fn = 0; fn < 4; ++fn) {
            const size_t col = n0 + wc * 64 + fn * 16 + lc;
            #pragma unroll
            for (int j = 0; j < 4; ++j) {
                const size_t row = m0 + wr * 64 + fm * 16 + lr * 4 + j;
                zx[row * DTOT + col] = acc[fm][fn][j];
            }
        }
}

// ---------------------------------------------------------------------------
// bf16 MFMA GEMM, 128x64 tile, 2-phase dbuf: out = gn_bf @ wo_bf^T
// ---------------------------------------------------------------------------
__global__ __launch_bounds__(256) void mfma_gemm_out(const u16* __restrict__ A,
                                                     const u16* __restrict__ B,
                                                     float* __restrict__ C,
                                                     int K, int ldc) {
    __shared__ u16 Als[2][128 * 32];
    __shared__ u16 Bls[2][64 * 32];
    const int tid = threadIdx.x;
    const int m0 = blockIdx.y * 128, n0 = blockIdx.x * 64;
    const int lane = tid & 63, wave = tid >> 6;
    const int wr = wave >> 1, wc = wave & 1;
    const int lr = lane >> 4, lc = lane & 15;
    const int sr = tid >> 2;
    const int sc = (tid & 3) * 8;

    f32x4 acc[4][2] = {};

    const u16* pA = A + (size_t)(m0 + sr) * K + sc;
    const u16* pB = B + (size_t)(n0 + sr) * K + sc;

#define STAGE_OUT(buf, k0) {                                             \
        gload16(pA + (k0), &Als[buf][tid * 8]);                          \
        gload16(pA + (k0) + (size_t)64 * K, &Als[buf][tid * 8 + 2048]);  \
        gload16(pB + (k0), &Bls[buf][tid * 8]); }

    STAGE_OUT(0, 0);
    __syncthreads();
    int cur = 0;
    for (int k0 = 0; k0 < K; k0 += 32) {
        if (k0 + 32 < K) STAGE_OUT(cur ^ 1, k0 + 32);
        s16x8 af[4], bf[2];
        #pragma unroll
        for (int f = 0; f < 4; ++f)
            af[f] = *(const s16x8*)&Als[cur][(wr * 64 + f * 16 + lc) * 32 + lr * 8];
        #pragma unroll
        for (int f = 0; f < 2; ++f)
            bf[f] = *(const s16x8*)&Bls[cur][(wc * 32 + f * 16 + lc) * 32 + lr * 8];
        #pragma unroll
        for (int fm = 0; fm < 4; ++fm)
            #pragma unroll
            for (int fn = 0; fn < 2; ++fn)
                acc[fm][fn] = __builtin_amdgcn_mfma_f32_16x16x32_bf16(
                    af[fm], bf[fn], acc[fm][fn], 0, 0, 0);
        __syncthreads();
        cur ^= 1;
    }
#undef STAGE_OUT

    #pragma unroll
    for (int fm = 0; fm < 4; ++fm)
        #pragma unroll
        for (int fn = 0; fn < 2; ++fn) {
            const size_t col = n0 + wc * 32 + fn * 16 + lc;
            #pragma unroll
            for (int j = 0; j < 4; ++j) {
                const size_t row = m0 + wr * 64 + fm * 16 + lr * 4 + j;
                C[row * (size_t)ldc + col] = acc[fm][fn][j];
            }
        }
}

// ---------------------------------------------------------------------------
// split-bf16 3-pass MFMA GEMM, sensitive columns (2-phase dbuf)
// ---------------------------------------------------------------------------
__global__ __launch_bounds__(256) void mfma_gemm_rem3(const u16* __restrict__ uh,
        const u16* __restrict__ ul, const u16* __restrict__ wh,
        const u16* __restrict__ wl, float* __restrict__ zxr) {
    __shared__ u16 Ah[2][128 * 32], Alo[2][128 * 32];
    __shared__ u16 Bh[2][64 * 32],  Blo[2][64 * 32];
    const int tid = threadIdx.x;
    const int m0 = blockIdx.y * 128, n0 = blockIdx.x * 64;
    const int lane = tid & 63, wave = tid >> 6;
    const int wr = wave >> 1, wc = wave & 1;
    const int lr = lane >> 4, lc = lane & 15;
    const int sr = tid >> 2;
    const int sc = (tid & 3) * 8;

    f32x4 acc[4][2] = {};

    const u16* pAh = uh + (size_t)(m0 + sr) * DMODEL + sc;
    const u16* pAl = ul + (size_t)(m0 + sr) * DMODEL + sc;
    const u16* pBh = wh + (size_t)(n0 + sr) * DMODEL + sc;
    const u16* pBl = wl + (size_t)(n0 + sr) * DMODEL + sc;

#define STAGE_R3(buf, k0) {                                                  \
        gload16(pAh + (k0), &Ah[buf][tid * 8]);                              \
        gload16(pAh + (k0) + (size_t)64 * DMODEL, &Ah[buf][tid * 8 + 2048]); \
        gload16(pAl + (k0), &Alo[buf][tid * 8]);                             \
        gload16(pAl + (k0) + (size_t)64 * DMODEL, &Alo[buf][tid * 8 + 2048]);\
        gload16(pBh + (k0), &Bh[buf][tid * 8]);                              \
        gload16(pBl + (k0), &Blo[buf][tid * 8]); }

    STAGE_R3(0, 0);
    __syncthreads();
    int cur = 0;
    for (int k0 = 0; k0 < DMODEL; k0 += 32) {
        if (k0 + 32 < DMODEL) STAGE_R3(cur ^ 1, k0 + 32);
        s16x8 ahf[4], alf[4], bhf[2], blf[2];
        #pragma unroll
        for (int f = 0; f < 4; ++f) {
            ahf[f] = *(const s16x8*)&Ah[cur][(wr * 64 + f * 16 + lc) * 32 + lr * 8];
            alf[f] = *(const s16x8*)&Alo[cur][(wr * 64 + f * 16 + lc) * 32 + lr * 8];
        }
        #pragma unroll
        for (int f = 0; f < 2; ++f) {
            bhf[f] = *(const s16x8*)&Bh[cur][(wc * 32 + f * 16 + lc) * 32 + lr * 8];
            blf[f] = *(const s16x8*)&Blo[cur][(wc * 32 + f * 16 + lc) * 32 + lr * 8];
        }
        #pragma unroll
        for (int fm = 0; fm < 4; ++fm)
            #pragma unroll
            for (int fn = 0; fn < 2; ++fn) {
                acc[fm][fn] = __builtin_amdgcn_mfma_f32_16x16x32_bf16(
                    ahf[fm], bhf[fn], acc[fm][fn], 0, 0, 0);
                acc[fm][fn] = __builtin_amdgcn_mfma_f32_16x16x32_bf16(
                    ahf[fm], blf[fn], acc[fm][fn], 0, 0, 0);
                acc[fm][fn] = __builtin_amdgcn_mfma_f32_16x16x32_bf16(
                    alf[fm], bhf[fn], acc[fm][fn], 0, 0, 0);
            }
        __syncthreads();
        cur ^= 1;
    }
#undef STAGE_R3

    #pragma unroll
    for (int fm = 0; fm < 4; ++fm)
        #pragma unroll
        for (int fn = 0; fn < 2; ++fn) {
            const size_t col = n0 + wc * 32 + fn * 16 + lc;
            #pragma unroll
            for (int j = 0; j < 4; ++j) {
                const size_t row = m0 + wr * 64 + fm * 16 + lr * 4 + j;
                zxr[row * DTOT + col] = acc[fm][fn][j];
            }
        }
}

// ---------------------------------------------------------------------------
// prep: RMS-norm Br/Cr; abg4 = (alpha, beta, gamma, beta'=(1-lam)*dt) in (b,h,l).
// ---------------------------------------------------------------------------
__global__ __launch_bounds__(64) void prep_kernel(const float* __restrict__ zx,
        const float* __restrict__ dt_bias, const float* __restrict__ A_log,
        const float* __restrict__ B_norm_w, const float* __restrict__ C_norm_w,
        float* __restrict__ Bg, float* __restrict__ Cg,
        float4* __restrict__ abg4) {
    const int bl = blockIdx.x;
    const int b = bl >> 10, l = bl & (LSEQ - 1);
    const int t  = threadIdx.x;
    const float* row = zx + (size_t)bl * DTOT;
    const float br = row[OFF_BR + t];
    const float cr = row[OFF_CR + t];
    float ssb = br * br, ssc = cr * cr;
    #pragma unroll
    for (int k = 1; k < 64; k <<= 1) { ssb += __shfl_xor(ssb, k); ssc += __shfl_xor(ssc, k); }
    const float scB = rsqrtf(ssb * (1.f / 64.f) + 1e-5f);
    const float scC = rsqrtf(ssc * (1.f / 64.f) + 1e-5f);
    Bg[(size_t)bl * 64 + t] = br * scB * B_norm_w[t];
    Cg[(size_t)bl * 64 + t] = cr * scC * C_norm_w[t];
    if (t < NH) {
        const float dtr = row[OFF_DT + t] + dt_bias[t];
        const float dt  = (dtr > 20.f) ? dtr : log1pf(expf(dtr));
        const float lamr = row[OFF_LAM + t];
        const float lam  = 1.f / (1.f + expf(-lamr));
        const float Ah   = -expf(A_log[t]);
        const float al   = expf(dt * Ah);
        const float bp   = (1.f - lam) * dt;            // beta' = b/a
        const size_t o = ((size_t)b * NH + t) * LSEQ + l;
        abg4[o] = make_float4(al, bp * al, lam * dt, bp);
    }
}

// ---------------------------------------------------------------------------
// cumsum of thr over L, per (b,h): 32 dims.
// ---------------------------------------------------------------------------
__global__ __launch_bounds__(256) void cumsum_kernel(const float* __restrict__ zx,
                                                     float* __restrict__ th_cs) {
    const int bh = blockIdx.x;
    const int b = bh >> 5, h = bh & 31;
    const int d = threadIdx.x & 31, seg = threadIdx.x >> 5;
    const float* base = zx + (size_t)b * LSEQ * DTOT + OFF_TH + h * 32 + d;
    float* out = th_cs + (size_t)b * LSEQ * 1024 + h * 32 + d;
    __shared__ float sums[8][33];
    const int l0 = seg * 128;
    float s = 0.f;
    #pragma unroll 4
    for (int i = 0; i < 128; ++i) s += base[(size_t)(l0 + i) * DTOT];
    sums[seg][d] = s;
    __syncthreads();
    float acc = 0.f;
    for (int s2 = 0; s2 < seg; ++s2) acc += sums[s2][d];
    #pragma unroll 4
    for (int i = 0; i < 128; ++i) {
        acc += base[(size_t)(l0 + i) * DTOT];
        out[(size_t)(l0 + i) * 1024] = acc;
    }
}

// ---------------------------------------------------------------------------
// rot: Bh/Ch = rot(broadcast(Bg/Cg)+bias). Brot/Crot layout (B,NH,L,DS).
// ---------------------------------------------------------------------------
__global__ __launch_bounds__(256) void rot_kernel(const float* __restrict__ th_cs,
        const float* __restrict__ Bg, const float* __restrict__ Cg,
        const float* __restrict__ B_bias, const float* __restrict__ C_bias,
        float* __restrict__ Brot, float* __restrict__ Crot) {
    const size_t idx = (size_t)blockIdx.x * 256 + threadIdx.x;
    const int j = (int)(idx & 31);
    const int h = (int)((idx >> 5) & 31);
    const size_t bl = idx >> 10;
    const int l = (int)(bl & (LSEQ - 1));
    const int b = (int)(bl >> 10);
    const float th = th_cs[idx];
    float s, c;
    sincosf(th, &s, &c);
    float v1 = Bg[bl * 64 + j]      + B_bias[h * 64 + j];
    float v2 = Bg[bl * 64 + 32 + j] + B_bias[h * 64 + 32 + j];
    const size_t ob = ((size_t)(b * NH + h) * LSEQ + l) * DS + j;
    Brot[ob]      = v1 * c - v2 * s;
    Brot[ob + 32] = v1 * s + v2 * c;
    v1 = Cg[bl * 64 + j]      + C_bias[h * 64 + j];
    v2 = Cg[bl * 64 + 32 + j] + C_bias[h * 64 + 32 + j];
    Crot[ob]      = v1 * c - v2 * s;
    Crot[ob + 32] = v1 * s + v2 * c;
}

// ---------------------------------------------------------------------------
// wcalc: per (b,h,seg): within-seg log-cumsum of alpha; emits
//   wbuf[t] = exp(LE - L_t)*(gamma_t + beta'_{t+1}) (t<segend), gamma_t at end
//   Lbuf[t] = L_t (inclusive within-segment log-cumsum)
//   aprod[s] = exp(LE);  bscale[s] = exp(LE)*beta'_{t0}  (0 for seg 0)
// ---------------------------------------------------------------------------
__global__ __launch_bounds__(64) void wcalc_kernel(const float4* __restrict__ abg4,
        float* __restrict__ wbuf, float* __restrict__ aprod,
        float* __restrict__ bscale, float* __restrict__ Lbuf) {
    const int bh = blockIdx.x;
    const int lane = threadIdx.x;
    const int seg = lane >> 3, sub = lane & 7;
    const int t0 = seg * SEG;
    const int sbase = t0 + sub * 16;
    const float4* ab = abg4 + (size_t)bh * LSEQ;

    float part = 0.f;
    #pragma unroll
    for (int i = 0; i < 16; ++i) part += logf(ab[sbase + i].x);
    float incl = part;
    #pragma unroll
    for (int d = 1; d < 8; d <<= 1) {
        const float v = __shfl_up(incl, d, 8);
        if (sub >= d) incl += v;
    }
    const float LE = __shfl(incl, 7, 8);
    float Lrun = incl - part;                // exclusive prefix

    for (int i = 0; i < 16; ++i) {
        const int s = sbase + i;
        const float4 A = ab[s];
        Lrun += logf(A.x);
        Lbuf[(size_t)bh * LSEQ + s] = Lrun;
        float w;
        if ((s & (SEG - 1)) == (SEG - 1)) w = A.z;
        else w = __expf(LE - Lrun) * (A.z + ab[s + 1].w);
        wbuf[(size_t)bh * LSEQ + s] = w;
    }
    if (sub == 0) {
        aprod[bh * NSEG + seg] = __expf(LE);
        bscale[bh * NSEG + seg] = (seg > 0) ? __expf(LE) * ab[t0].w : 0.f;
    }
}

// ---------------------------------------------------------------------------
// hseg_gemm: h_local_end[p,n] = sum_s wbuf_s * x_s[p] * B_s[n] (split-bf16 3-pass)
// ---------------------------------------------------------------------------
#define WK 136
__global__ __launch_bounds__(256) void hseg_gemm(const float* __restrict__ zx,
        const float* __restrict__ Brot, const float* __restrict__ wbuf,
        float* __restrict__ hseg) {
    __shared__ u16 XH[64][WK], XL[64][WK], BHs[64][WK], BLs[64][WK];
    const int blk = blockIdx.x;
    const int seg = blk & (NSEG - 1), bh = blk >> 3;
    const int b = bh >> 5, h = bh & 31;
    const int tid = threadIdx.x;

    {
        const int sIdx = tid >> 1, half = tid & 1;
        const int t = seg * SEG + sIdx;
        const float wv = wbuf[(size_t)bh * LSEQ + t];
        const float* xsrc = zx + ((size_t)b * LSEQ + t) * DTOT + OFF_X + h * 64 + half * 32;
        const float* bsrc = Brot + ((size_t)bh * LSEQ + t) * DS + half * 32;
        #pragma unroll
        for (int i = 0; i < 32; i += 4) {
            const float4 xv = *(const float4*)(xsrc + i);
            const float4 bv = *(const float4*)(bsrc + i);
            const int p0 = half * 32 + i;
            u16 hi, lo;
            split1(xv.x * wv, hi, lo); XH[p0 + 0][sIdx] = hi; XL[p0 + 0][sIdx] = lo;
            split1(xv.y * wv, hi, lo); XH[p0 + 1][sIdx] = hi; XL[p0 + 1][sIdx] = lo;
            split1(xv.z * wv, hi, lo); XH[p0 + 2][sIdx] = hi; XL[p0 + 2][sIdx] = lo;
            split1(xv.w * wv, hi, lo); XH[p0 + 3][sIdx] = hi; XL[p0 + 3][sIdx] = lo;
            split1(bv.x, hi, lo); BHs[p0 + 0][sIdx] = hi; BLs[p0 + 0][sIdx] = lo;
            split1(bv.y, hi, lo); BHs[p0 + 1][sIdx] = hi; BLs[p0 + 1][sIdx] = lo;
            split1(bv.z, hi, lo); BHs[p0 + 2][sIdx] = hi; BLs[p0 + 2][sIdx] = lo;
            split1(bv.w, hi, lo); BHs[p0 + 3][sIdx] = hi; BLs[p0 + 3][sIdx] = lo;
        }
    }
    __syncthreads();

    const int lane = tid & 63, wave = tid >> 6;
    const int wR = wave >> 1, wC = wave & 1;
    const int lr = lane >> 4, lc = lane & 15;

    f32x4 acc[2][2] = {};
    #pragma unroll
    for (int ks = 0; ks < 4; ++ks) {
        const int k0 = ks * 32;
        s16x8 xh[2], xl[2], bhf[2], blf[2];
        #pragma unroll
        for (int f = 0; f < 2; ++f) {
            const int pr = wR * 32 + f * 16 + lc;
            xh[f] = *(const s16x8*)&XH[pr][k0 + lr * 8];
            xl[f] = *(const s16x8*)&XL[pr][k0 + lr * 8];
            const int nr = wC * 32 + f * 16 + lc;
            bhf[f] = *(const s16x8*)&BHs[nr][k0 + lr * 8];
            blf[f] = *(const s16x8*)&BLs[nr][k0 + lr * 8];
        }
        #pragma unroll
        for (int fm = 0; fm < 2; ++fm)
            #pragma unroll
            for (int fn = 0; fn < 2; ++fn) {
                acc[fm][fn] = __builtin_amdgcn_mfma_f32_16x16x32_bf16(
                    xh[fm], bhf[fn], acc[fm][fn], 0, 0, 0);
                acc[fm][fn] = __builtin_amdgcn_mfma_f32_16x16x32_bf16(
                    xh[fm], blf[fn], acc[fm][fn], 0, 0, 0);
                acc[fm][fn] = __builtin_amdgcn_mfma_f32_16x16x32_bf16(
                    xl[fm], bhf[fn], acc[fm][fn], 0, 0, 0);
            }
    }

    float* hp = hseg + ((size_t)(bh * NSEG + seg) * HD) * DS;
    #pragma unroll
    for (int fm = 0; fm < 2; ++fm)
        #pragma unroll
        for (int fn = 0; fn < 2; ++fn) {
            const int n = wC * 32 + fn * 16 + lc;
            #pragma unroll
            for (int j = 0; j < 4; ++j) {
                const int p = wR * 32 + fm * 16 + lr * 4 + j;
                hp[p * DS + n] = acc[fm][fn][j];
            }
        }
}

// ---------------------------------------------------------------------------
// scan_fix: sequential over segments. Produces hstar[s] = h_start[s] +
// beta'_{t0}*x_{t0-1}B_{t0-1}  (in place of h_start; used by ssd_y carry),
// and propagates h_end with the aprod-scaled boundary term.
// ---------------------------------------------------------------------------
__global__ __launch_bounds__(256) void scan_fix(float* __restrict__ hseg,
        const float* __restrict__ aprod, const float* __restrict__ bscale,
        const float* __restrict__ zx, const float* __restrict__ Brot,
        const float4* __restrict__ abg4) {
    const int blk = blockIdx.x;          // (b,h,ptile): 256
    const int ptile = blk & 3, h = (blk >> 2) & 31, b = blk >> 7;
    const int tid = threadIdx.x;
    const int pl = tid >> 4, ng = tid & 15;
    const int p = ptile * 16 + pl;
    const int n0 = ng * 4;
    const size_t bh = (size_t)b * NH + h;

    float4 cur = make_float4(0.f, 0.f, 0.f, 0.f);
    #pragma unroll
    for (int s = 0; s < NSEG; ++s) {
        float* hp = hseg + (((bh * NSEG + s) * HD + p) * DS + n0);
        float4 tmp = *(const float4*)hp;     // local h_end (no boundary)
        float4 hst = cur;                    // hstar = h_start (+ r1 below)
        if (s > 0) {
            const float bs = bscale[bh * NSEG + s];          // aprod*beta'
            const float bp0 = abg4[bh * LSEQ + s * SEG].w;   // beta'_{t0}
            const int tm1 = s * SEG - 1;
            const float4 Bm = *(const float4*)(Brot + ((size_t)bh * LSEQ + tm1) * DS + n0);
            const float xm = zx[((size_t)b * LSEQ + tm1) * DTOT + OFF_X + h * HD + p];
            const float fb = bs * xm;        // for h_end propagation
            const float f1 = bp0 * xm;       // for hstar
            tmp.x = fmaf(fb, Bm.x, tmp.x);
            tmp.y = fmaf(fb, Bm.y, tmp.y);
            tmp.z = fmaf(fb, Bm.z, tmp.z);
            tmp.w = fmaf(fb, Bm.w, tmp.w);
            hst.x = fmaf(f1, Bm.x, hst.x);
            hst.y = fmaf(f1, Bm.y, hst.y);
            hst.z = fmaf(f1, Bm.z, hst.z);
            hst.w = fmaf(f1, Bm.w, hst.w);
        }
        *(float4*)hp = hst;
        const float a = aprod[bh * NSEG + s];
        cur.x = fmaf(a, cur.x, tmp.x);
        cur.y = fmaf(a, cur.y, tmp.y);
        cur.z = fmaf(a, cur.z, tmp.z);
        cur.w = fmaf(a, cur.w, tmp.w);
    }
}

// ---------------------------------------------------------------------------
// ssd_y: per (b,h,seg) the full output block via MFMA:
//   y[i,p] = sum_j W[i,j]*(C_i.B_j)*x_j[p] + exp(L_i)*(C_i.hstar^T)[p] + D*x[i,p]
//   W[i,j] = exp(L_i-L_j)*(gamma_j + beta'_{j+1}) (j<i); gamma_i (j==i); 0 (j>i)
// LDS ~100KB: C/B split hi/lo (3-pass G), Gw hi/lo overlay, X/H single bf16.
// ---------------------------------------------------------------------------
#define GK   72    // C/B/H row stride (u16)
#define GWK2 136   // Gw/XT row stride (u16)
__global__ __launch_bounds__(256) void ssd_y(const float* __restrict__ zx,
        const float* __restrict__ Brot, const float* __restrict__ Crot,
        const float4* __restrict__ abg4, const float* __restrict__ hseg,
        const float* __restrict__ Lbuf, const float* __restrict__ Dp,
        float* __restrict__ yb) {
    __shared__ u16 sm[50176];
    __shared__ float Ls[128], gbs[128], gms[128], eLs[128];
    u16* CH = sm;                 // 128*72 = 9216
    u16* CL = sm + 9216;
    u16* BHl = sm + 18432;
    u16* BLl = sm + 27648;        // region ends 36864
    u16* GH = sm;                 // overlay: 128*136 = 17408
    u16* GL = sm + 17408;         // ends 34816 (< 36864)
    u16* XTH = sm + 36864;        // 64*136 = 8704
    u16* HH  = sm + 45568;        // 64*72  = 4608 -> 50176

    const int blk = blockIdx.x;
    const int seg = blk & (NSEG - 1), bh = blk >> 3;
    const int b = bh >> 5, h = bh & 31;
    const int tid = threadIdx.x;
    const int t0 = seg * SEG;
    const int lane = tid & 63, wave = tid >> 6;
    const int wr = wave >> 1, wc = wave & 1;
    const int lr = lane >> 4, lc = lane & 15;

    // ---- stage C,B (split), X^T and H (single bf16), per-step arrays ----
    {
        const int r = tid >> 1, half = tid & 1;
        const float* csrc = Crot + ((size_t)bh * LSEQ + t0 + r) * DS + half * 32;
        const float* bsrc = Brot + ((size_t)bh * LSEQ + t0 + r) * DS + half * 32;
        const float* xsrc = zx + ((size_t)b * LSEQ + t0 + r) * DTOT + OFF_X + h * 64 + half * 32;
        #pragma unroll
        for (int i = 0; i < 32; i += 4) {
            const float4 cv = *(const float4*)(csrc + i);
            const float4 bv = *(const float4*)(bsrc + i);
            const float4 xv = *(const float4*)(xsrc + i);
            const int c0 = half * 32 + i;
            u16 hi, lo;
            split1(cv.x, hi, lo); CH[r * GK + c0 + 0] = hi; CL[r * GK + c0 + 0] = lo;
            split1(cv.y, hi, lo); CH[r * GK + c0 + 1] = hi; CL[r * GK + c0 + 1] = lo;
            split1(cv.z, hi, lo); CH[r * GK + c0 + 2] = hi; CL[r * GK + c0 + 2] = lo;
            split1(cv.w, hi, lo); CH[r * GK + c0 + 3] = hi; CL[r * GK + c0 + 3] = lo;
            split1(bv.x, hi, lo); BHl[r * GK + c0 + 0] = hi; BLl[r * GK + c0 + 0] = lo;
            split1(bv.y, hi, lo); BHl[r * GK + c0 + 1] = hi; BLl[r * GK + c0 + 1] = lo;
            split1(bv.z, hi, lo); BHl[r * GK + c0 + 2] = hi; BLl[r * GK + c0 + 2] = lo;
            split1(bv.w, hi, lo); BHl[r * GK + c0 + 3] = hi; BLl[r * GK + c0 + 3] = lo;
            XTH[(c0 + 0) * GWK2 + r] = (u16)f2bf(xv.x);
            XTH[(c0 + 1) * GWK2 + r] = (u16)f2bf(xv.y);
            XTH[(c0 + 2) * GWK2 + r] = (u16)f2bf(xv.z);
            XTH[(c0 + 3) * GWK2 + r] = (u16)f2bf(xv.w);
        }
    }
    {
        const int p = tid >> 2, q = (tid & 3) * 16;
        const float* hsrc = hseg + (((size_t)(bh * NSEG + seg)) * HD + p) * DS + q;
        #pragma unroll
        for (int i = 0; i < 16; i += 4) {
            const float4 hv = *(const float4*)(hsrc + i);
            HH[p * GK + q + i + 0] = (u16)f2bf(hv.x);
            HH[p * GK + q + i + 1] = (u16)f2bf(hv.y);
            HH[p * GK + q + i + 2] = (u16)f2bf(hv.z);
            HH[p * GK + q + i + 3] = (u16)f2bf(hv.w);
        }
    }
    if (tid < 128) {
        const int t = t0 + tid;
        const float4 A = abg4[(size_t)bh * LSEQ + t];
        const float Lv = Lbuf[(size_t)bh * LSEQ + t];
        Ls[tid] = Lv;
        gms[tid] = A.z;
        gbs[tid] = (tid < 127) ? A.z + abg4[(size_t)bh * LSEQ + t + 1].w : 0.f;
        eLs[tid] = __expf(Lv);
    }
    __syncthreads();

    // ---- Y2 carry: P = C @ H^T (2-pass: Chi*H + Clo*H) ----
    f32x4 accP[4][2] = {};
    #pragma unroll
    for (int ks = 0; ks < 2; ++ks) {
        const int k0 = ks * 32;
        s16x8 ch[4], cl4[4], hh2[2];
        #pragma unroll
        for (int f = 0; f < 4; ++f) {
            const int row = wr * 64 + f * 16 + lc;
            ch[f]  = *(const s16x8*)&CH[row * GK + k0 + lr * 8];
            cl4[f] = *(const s16x8*)&CL[row * GK + k0 + lr * 8];
        }
        #pragma unroll
        for (int f = 0; f < 2; ++f) {
            const int row = wc * 32 + f * 16 + lc;
            hh2[f] = *(const s16x8*)&HH[row * GK + k0 + lr * 8];
        }
        #pragma unroll
        for (int fm = 0; fm < 4; ++fm)
            #pragma unroll
            for (int fn = 0; fn < 2; ++fn) {
                accP[fm][fn] = __builtin_amdgcn_mfma_f32_16x16x32_bf16(
                    ch[fm], hh2[fn], accP[fm][fn], 0, 0, 0);
                accP[fm][fn] = __builtin_amdgcn_mfma_f32_16x16x32_bf16(
                    cl4[fm], hh2[fn], accP[fm][fn], 0, 0, 0);
            }
    }
    f32x4 accY[4][2];
    #pragma unroll
    for (int fm = 0; fm < 4; ++fm)
        #pragma unroll
        for (int fn = 0; fn < 2; ++fn)
            #pragma unroll
            for (int jj = 0; jj < 4; ++jj) {
                const int i = wr * 64 + fm * 16 + lr * 4 + jj;
                accY[fm][fn][jj] = eLs[i] * accP[fm][fn][jj];
            }

    // ---- G = C @ B^T (3-pass split) ----
    f32x4 accG[4][4] = {};
    #pragma unroll
    for (int ks = 0; ks < 2; ++ks) {
        const int k0 = ks * 32;
        s16x8 ch[4], cl4[4], bh4[4], bl4[4];
        #pragma unroll
        for (int f = 0; f < 4; ++f) {
            const int rowc = wr * 64 + f * 16 + lc;
            ch[f]  = *(const s16x8*)&CH[rowc * GK + k0 + lr * 8];
            cl4[f] = *(const s16x8*)&CL[rowc * GK + k0 + lr * 8];
            const int rowb = wc * 64 + f * 16 + lc;
            bh4[f] = *(const s16x8*)&BHl[rowb * GK + k0 + lr * 8];
            bl4[f] = *(const s16x8*)&BLl[rowb * GK + k0 + lr * 8];
        }
        #pragma unroll
        for (int fm = 0; fm < 4; ++fm)
            #pragma unroll
            for (int fn = 0; fn < 4; ++fn) {
                accG[fm][fn] = __builtin_amdgcn_mfma_f32_16x16x32_bf16(
                    ch[fm], bh4[fn], accG[fm][fn], 0, 0, 0);
                accG[fm][fn] = __builtin_amdgcn_mfma_f32_16x16x32_bf16(
                    ch[fm], bl4[fn], accG[fm][fn], 0, 0, 0);
                accG[fm][fn] = __builtin_amdgcn_mfma_f32_16x16x32_bf16(
                    cl4[fm], bh4[fn], accG[fm][fn], 0, 0, 0);
            }
    }
    __syncthreads();   // all C/B reads done before Gw overlay

    // ---- mask & write Gw (bf16 hi/lo) ----
    #pragma unroll
    for (int fm = 0; fm < 4; ++fm)
        #pragma unroll
        for (int fn = 0; fn < 4; ++fn)
            #pragma unroll
            for (int jj = 0; jj < 4; ++jj) {
                const int i = wr * 64 + fm * 16 + lr * 4 + jj;
                const int j = wc * 64 + fn * 16 + lc;
                float w;
                if (j < i)      w = __expf(Ls[i] - Ls[j]) * gbs[j];
                else if (j == i) w = gms[i];
                else             w = 0.f;
                const float v = accG[fm][fn][jj] * w;
                u16 hi, lo; split1(v, hi, lo);
                GH[i * GWK2 + j] = hi;
                GL[i * GWK2 + j] = lo;
            }
    __syncthreads();

    // ---- Y1: accY += Gw @ X^T (2-pass) ----
    #pragma unroll
    for (int ks = 0; ks < 4; ++ks) {
        const int k0 = ks * 32;
        s16x8 gh4[4], gl4[4], xf[2];
        #pragma unroll
        for (int f = 0; f < 4; ++f) {
            const int row = wr * 64 + f * 16 + lc;
            gh4[f] = *(const s16x8*)&GH[row * GWK2 + k0 + lr * 8];
            gl4[f] = *(const s16x8*)&GL[row * GWK2 + k0 + lr * 8];
        }
        #pragma unroll
        for (int f = 0; f < 2; ++f) {
            const int row = wc * 32 + f * 16 + lc;
            xf[f] = *(const s16x8*)&XTH[row * GWK2 + k0 + lr * 8];
        }
        #pragma unroll
        for (int fm = 0; fm < 4; ++fm)
            #pragma unroll
            for (int fn = 0; fn < 2; ++fn) {
                accY[fm][fn] = __builtin_amdgcn_mfma_f32_16x16x32_bf16(
                    gh4[fm], xf[fn], accY[fm][fn], 0, 0, 0);
                accY[fm][fn] = __builtin_amdgcn_mfma_f32_16x16x32_bf16(
                    gl4[fm], xf[fn], accY[fm][fn], 0, 0, 0);
            }
    }

    // ---- store y = accY + D*x ----
    const float Dh = Dp[h];
    #pragma unroll
    for (int fm = 0; fm < 4; ++fm)
        #pragma unroll
        for (int fn = 0; fn < 2; ++fn) {
            const int p = wc * 32 + fn * 16 + lc;
            #pragma unroll
            for (int jj = 0; jj < 4; ++jj) {
                const int i = wr * 64 + fm * 16 + lr * 4 + jj;
                const float xv = __uint_as_float(((unsigned)XTH[p * GWK2 + i]) << 16);
                yb[((size_t)b * LSEQ + t0 + i) * DIN + h * 64 + p] =
                    accY[fm][fn][jj] + Dh * xv;
            }
        }
}

// ---------------------------------------------------------------------------
// gate + final RMS norm; emits bf16 directly for the out_proj GEMM.
// ---------------------------------------------------------------------------
__global__ __launch_bounds__(256) void gate_norm_kernel(const float* __restrict__ yb,
        const float* __restrict__ zx, const float* __restrict__ norm_w,
        u16* __restrict__ gnb) {
    const int bl = blockIdx.x;
    const int tid = threadIdx.x;
    const float* yrow = yb + (size_t)bl * DIN;
    const float* zrow = zx + (size_t)bl * DTOT + OFF_Z;
    float g[8];
    float ss = 0.f;
    #pragma unroll
    for (int i = 0; i < 8; ++i) {
        const int c = tid + i * 256;
        const float yv = yrow[c];
        const float zv = zrow[c];
        const float sg = 1.f / (1.f + expf(-zv));
        const float gv = yv * zv * sg;
        g[i] = gv;
        ss += gv * gv;
    }
    #pragma unroll
    for (int k = 1; k < 64; k <<= 1) ss += __shfl_xor(ss, k);
    __shared__ float wsum[4];
    if ((tid & 63) == 0) wsum[tid >> 6] = ss;
    __syncthreads();
    ss = wsum[0] + wsum[1] + wsum[2] + wsum[3];
    const float sc = rsqrtf(ss * (1.f / 2048.f) + 1e-5f);
    #pragma unroll
    for (int i = 0; i < 8; ++i) {
        const int c = tid + i * 256;
        gnb[(size_t)bl * DIN + c] = (u16)f2bf(g[i] * sc * norm_w[c]);
    }
}

// ---------------------------------------------------------------------------
extern "C" void kernel_launch(void* const* d_in, const int* in_sizes, int n_in,
                              void* d_out, int out_size, void* d_ws, size_t ws_size,
                              hipStream_t stream) {
    const float* u          = (const float*)d_in[0];
    const float* in_proj_w  = (const float*)d_in[1];
    const float* dt_bias    = (const float*)d_in[2];
    const float* A_log      = (const float*)d_in[3];
    const float* Dp         = (const float*)d_in[4];
    const float* B_norm_w   = (const float*)d_in[5];
    const float* C_norm_w   = (const float*)d_in[6];
    const float* B_bias     = (const float*)d_in[7];
    const float* C_bias     = (const float*)d_in[8];
    const float* norm_w     = (const float*)d_in[9];
    const float* out_proj_w = (const float*)d_in[10];
    float* out = (float*)d_out;

    float* p = (float*)d_ws;
    float* zx    = p; p += (size_t)ROWS * DTOT;
    float* th_cs = p; p += (size_t)ROWS * 1024;   // dead after rot -> hseg
    float* Brot  = p; p += (size_t)ROWS * 2048;   // doubles as bf16 scratch
    float* Crot  = p; p += (size_t)ROWS * 2048;
    float* Bg    = p; p += (size_t)ROWS * 64;     // dead after rot -> aprod/bscale/Lbuf
    float* Cg    = p; p += (size_t)ROWS * 64;     // dead after rot -> wbuf
    float4* abg4 = (float4*)p; p += (size_t)ROWS * NH * 4;
    float* yb    = p; p += (size_t)ROWS * 2048;
    float* hseg   = th_cs;                        // 2,097,152 floats
    float* aprod  = Bg;                           // 512
    float* bscale = Bg + 512;                     // 512
    float* Lbuf   = Bg + 2048;                    // 65,536 (Bg has 131,072)
    float* wbuf   = Cg;                           // 65,536

    // Phase-A bf16 scratch inside Brot+Crot (consumed before rot writes them):
    u16* u_bf = (u16*)Brot;
    u16* u_lo = u_bf + (size_t)ROWS * DMODEL;
    u16* w_bf = u_lo + (size_t)ROWS * DMODEL;
    u16* w_lo = w_bf + (size_t)DTOT * DMODEL;
    // Phase-B (after ssd_y, Brot/Crot dead again):
    u16* gn_bf = (u16*)Brot;
    u16* wo_bf = gn_bf + (size_t)ROWS * DIN;

    // 0. one-time fp32 -> bf16 (+residual) conversions
    conv_u<<<(ROWS * DMODEL / 4) / 256, 256, 0, stream>>>(u, u_bf, u_lo);
    conv_w<<<((size_t)DTOT * DMODEL / 4) / 256, 256, 0, stream>>>(in_proj_w, w_bf, w_lo);
    // 1a/1b. in_proj GEMMs
    mfma_gemm_zx<<<dim3(NZX / 128, ROWS / 128), 256, 0, stream>>>(u_bf, w_bf, zx);
    mfma_gemm_rem3<<<dim3(NREM / 64, ROWS / 128), 256, 0, stream>>>(
        u_bf, u_lo, w_bf + (size_t)NZX * DMODEL, w_lo, zx + NZX);
    // 2. per-row prep (abg4.w = beta')
    prep_kernel<<<ROWS, 64, 0, stream>>>(zx, dt_bias, A_log, B_norm_w, C_norm_w,
                                         Bg, Cg, abg4);
    // 3. cumsum of theta over L
    cumsum_kernel<<<BB * NH, 256, 0, stream>>>(zx, th_cs);
    // 4. rotary on B/C
    rot_kernel<<<(ROWS * 1024) / 256, 256, 0, stream>>>(th_cs, Bg, Cg, B_bias, C_bias,
                                                        Brot, Crot);
    // 5. segmented scan: weights -> h_end GEMM -> fixup -> SSD output blocks
    wcalc_kernel<<<BB * NH, 64, 0, stream>>>(abg4, wbuf, aprod, bscale, Lbuf);
    hseg_gemm<<<BB * NH * NSEG, 256, 0, stream>>>(zx, Brot, wbuf, hseg);
    scan_fix<<<BB * NH * 4, 256, 0, stream>>>(hseg, aprod, bscale, zx, Brot, abg4);
    ssd_y<<<BB * NH * NSEG, 256, 0, stream>>>(zx, Brot, Crot, abg4, hseg, Lbuf, Dp, yb);
    // 6-8. epilogue
    conv_wo<<<(DMODEL * DIN / 4) / 256, 256, 0, stream>>>(out_proj_w, wo_bf);
    gate_norm_kernel<<<ROWS, 256, 0, stream>>>(yb, zx, norm_w, gn_bf);
    mfma_gemm_out<<<dim3(DMODEL / 64, ROWS / 128), 256, 0, stream>>>(
        gn_bf, wo_bf, out, DIN, DMODEL);
}

// Round 17
// 198.961 us; speedup vs baseline: 1.7793x; 1.0525x over previous
//
#include <hip/hip_runtime.h>
#include <hip/hip_bf16.h>

// Problem constants
#define DMODEL 1024
#define DIN    2048
#define NH     32
#define HD     64
#define DS     64
#define LSEQ   1024
#define BB     2
#define DTOT   5312           // 2*DIN + 2*64 + 32 + 1024 + 32
#define ROWS   (BB*LSEQ)      // 2048
// column offsets inside zxbcdt
#define OFF_Z   0
#define OFF_X   2048
#define OFF_BR  4096
#define OFF_CR  4160
#define OFF_DT  4224
#define OFF_TH  4256
#define OFF_LAM 5280
#define NZX     4096          // z+x columns: single-pass bf16 MFMA
#define NREM    (DTOT - NZX)  // 1216 cols: 3-pass split-bf16 MFMA
// segmented scan
#define NSEG 8
#define SEG  (LSEQ / NSEG)    // 128

typedef short  s16x8 __attribute__((ext_vector_type(8)));
typedef float  f32x4 __attribute__((ext_vector_type(4)));
typedef unsigned short u16;

__device__ __forceinline__ unsigned int f2bf(float f) {   // RNE f32->bf16 (finite inputs)
    unsigned int u = __float_as_uint(f);
    u += 0x7fffu + ((u >> 16) & 1u);
    return u >> 16;
}
__device__ __forceinline__ unsigned int pk(float x, float y) {
    return f2bf(x) | (f2bf(y) << 16);
}
__device__ __forceinline__ void split1(float v, u16& hi, u16& lo) {
    const unsigned int h = f2bf(v);
    hi = (u16)h;
    lo = (u16)f2bf(v - __uint_as_float(h << 16));
}
// split 8 floats (two float4) into hi/lo bf16 fragments
__device__ __forceinline__ void split8(const float4 a, const float4 b,
                                       s16x8& hi, s16x8& lo) {
    u16 h_, l_;
    split1(a.x, h_, l_); hi[0] = (short)h_; lo[0] = (short)l_;
    split1(a.y, h_, l_); hi[1] = (short)h_; lo[1] = (short)l_;
    split1(a.z, h_, l_); hi[2] = (short)h_; lo[2] = (short)l_;
    split1(a.w, h_, l_); hi[3] = (short)h_; lo[3] = (short)l_;
    split1(b.x, h_, l_); hi[4] = (short)h_; lo[4] = (short)l_;
    split1(b.y, h_, l_); hi[5] = (short)h_; lo[5] = (short)l_;
    split1(b.z, h_, l_); hi[6] = (short)h_; lo[6] = (short)l_;
    split1(b.w, h_, l_); hi[7] = (short)h_; lo[7] = (short)l_;
}
__device__ __forceinline__ void cvt8(const float4 a, const float4 b, s16x8& hi) {
    hi[0] = (short)f2bf(a.x); hi[1] = (short)f2bf(a.y);
    hi[2] = (short)f2bf(a.z); hi[3] = (short)f2bf(a.w);
    hi[4] = (short)f2bf(b.x); hi[5] = (short)f2bf(b.y);
    hi[6] = (short)f2bf(b.z); hi[7] = (short)f2bf(b.w);
}

// HBM -> LDS direct 16B copy. Dest = wave-uniform base + lane*16 (m104).
typedef const __attribute__((address_space(1))) unsigned int glb_u32;
typedef __attribute__((address_space(3))) unsigned int lds_u32;
__device__ __forceinline__ void gload16(const void* g, void* l) {
    __builtin_amdgcn_global_load_lds((glb_u32*)g, (lds_u32*)l, 16, 0, 0);
}

// ---------------------------------------------------------------------------
// conversion kernels: fp32 -> bf16 (hi) and residual (lo).
// ---------------------------------------------------------------------------
__global__ __launch_bounds__(256) void conv_u(const float* __restrict__ src,
        u16* __restrict__ hi, u16* __restrict__ lo) {
    const size_t i4 = ((size_t)blockIdx.x * 256 + threadIdx.x) * 4;
    const float4 v = *(const float4*)(src + i4);
    const unsigned int h0 = f2bf(v.x), h1 = f2bf(v.y), h2 = f2bf(v.z), h3 = f2bf(v.w);
    uint2 hw, lw;
    hw.x = h0 | (h1 << 16); hw.y = h2 | (h3 << 16);
    lw.x = pk(v.x - __uint_as_float(h0 << 16), v.y - __uint_as_float(h1 << 16));
    lw.y = pk(v.z - __uint_as_float(h2 << 16), v.w - __uint_as_float(h3 << 16));
    *(uint2*)(hi + i4) = hw;
    *(uint2*)(lo + i4) = lw;
}

__global__ __launch_bounds__(256) void conv_w(const float* __restrict__ src,
        u16* __restrict__ hi, u16* __restrict__ lo) {
    const size_t i4 = ((size_t)blockIdx.x * 256 + threadIdx.x) * 4;
    const float4 v = *(const float4*)(src + i4);
    const unsigned int h0 = f2bf(v.x), h1 = f2bf(v.y), h2 = f2bf(v.z), h3 = f2bf(v.w);
    uint2 hw, lw;
    hw.x = h0 | (h1 << 16); hw.y = h2 | (h3 << 16);
    lw.x = pk(v.x - __uint_as_float(h0 << 16), v.y - __uint_as_float(h1 << 16));
    lw.y = pk(v.z - __uint_as_float(h2 << 16), v.w - __uint_as_float(h3 << 16));
    *(uint2*)(hi + i4) = hw;
    if ((i4 >> 10) >= NZX)
        *(uint2*)(lo + (i4 - (size_t)NZX * DMODEL)) = lw;
}

__global__ __launch_bounds__(256) void conv_wo(const float* __restrict__ src,
        u16* __restrict__ hi) {
    const size_t i4 = ((size_t)blockIdx.x * 256 + threadIdx.x) * 4;
    const float4 v = *(const float4*)(src + i4);
    uint2 hw;
    hw.x = pk(v.x, v.y); hw.y = pk(v.z, v.w);
    *(uint2*)(hi + i4) = hw;
}

// ---------------------------------------------------------------------------
// bf16 MFMA GEMM, z/x block (2-phase dbuf global_load_lds)
// ---------------------------------------------------------------------------
__global__ __launch_bounds__(256) void mfma_gemm_zx(const u16* __restrict__ uA_,
                                                    const u16* __restrict__ uW,
                                                    float* __restrict__ zx) {
    __shared__ u16 Al[2][128 * 32];
    __shared__ u16 Bl[2][128 * 32];
    const int tid = threadIdx.x;
    const int m0 = blockIdx.y * 128, n0 = blockIdx.x * 128;
    const int lane = tid & 63, wave = tid >> 6;
    const int wr = wave >> 1, wc = wave & 1;
    const int lr = lane >> 4, lc = lane & 15;
    const int sr = tid >> 2;
    const int sc = (tid & 3) * 8;

    f32x4 acc[4][4] = {};

    const u16* pA = uA_ + (size_t)(m0 + sr) * DMODEL + sc;
    const u16* pB = uW  + (size_t)(n0 + sr) * DMODEL + sc;

#define STAGE_ZX(buf, k0) {                                              \
        gload16(pA + (k0), &Al[buf][tid * 8]);                           \
        gload16(pA + (k0) + (size_t)64 * DMODEL, &Al[buf][tid * 8 + 2048]); \
        gload16(pB + (k0), &Bl[buf][tid * 8]);                           \
        gload16(pB + (k0) + (size_t)64 * DMODEL, &Bl[buf][tid * 8 + 2048]); }

    STAGE_ZX(0, 0);
    __syncthreads();
    int cur = 0;
    for (int k0 = 0; k0 < DMODEL; k0 += 32) {
        if (k0 + 32 < DMODEL) STAGE_ZX(cur ^ 1, k0 + 32);
        s16x8 af[4], bf[4];
        #pragma unroll
        for (int f = 0; f < 4; ++f) {
            af[f] = *(const s16x8*)&Al[cur][(wr * 64 + f * 16 + lc) * 32 + lr * 8];
            bf[f] = *(const s16x8*)&Bl[cur][(wc * 64 + f * 16 + lc) * 32 + lr * 8];
        }
        #pragma unroll
        for (int fm = 0; fm < 4; ++fm)
            #pragma unroll
            for (int fn = 0; fn < 4; ++fn)
                acc[fm][fn] = __builtin_amdgcn_mfma_f32_16x16x32_bf16(
                    af[fm], bf[fn], acc[fm][fn], 0, 0, 0);
        __syncthreads();
        cur ^= 1;
    }
#undef STAGE_ZX

    #pragma unroll
    for (int fm = 0; fm < 4; ++fm)
        #pragma unroll
        for (int fn = 0; fn < 4; ++fn) {
            const size_t col = n0 + wc * 64 + fn * 16 + lc;
            #pragma unroll
            for (int j = 0; j < 4; ++j) {
                const size_t row = m0 + wr * 64 + fm * 16 + lr * 4 + j;
                zx[row * DTOT + col] = acc[fm][fn][j];
            }
        }
}

// ---------------------------------------------------------------------------
// bf16 MFMA GEMM, 128x64 tile, 2-phase dbuf: out = gn_bf @ wo_bf^T
// ---------------------------------------------------------------------------
__global__ __launch_bounds__(256) void mfma_gemm_out(const u16* __restrict__ A,
                                                     const u16* __restrict__ B,
                                                     float* __restrict__ C,
                                                     int K, int ldc) {
    __shared__ u16 Als[2][128 * 32];
    __shared__ u16 Bls[2][64 * 32];
    const int tid = threadIdx.x;
    const int m0 = blockIdx.y * 128, n0 = blockIdx.x * 64;
    const int lane = tid & 63, wave = tid >> 6;
    const int wr = wave >> 1, wc = wave & 1;
    const int lr = lane >> 4, lc = lane & 15;
    const int sr = tid >> 2;
    const int sc = (tid & 3) * 8;

    f32x4 acc[4][2] = {};

    const u16* pA = A + (size_t)(m0 + sr) * K + sc;
    const u16* pB = B + (size_t)(n0 + sr) * K + sc;

#define STAGE_OUT(buf, k0) {                                             \
        gload16(pA + (k0), &Als[buf][tid * 8]);                          \
        gload16(pA + (k0) + (size_t)64 * K, &Als[buf][tid * 8 + 2048]);  \
        gload16(pB + (k0), &Bls[buf][tid * 8]); }

    STAGE_OUT(0, 0);
    __syncthreads();
    int cur = 0;
    for (int k0 = 0; k0 < K; k0 += 32) {
        if (k0 + 32 < K) STAGE_OUT(cur ^ 1, k0 + 32);
        s16x8 af[4], bf[2];
        #pragma unroll
        for (int f = 0; f < 4; ++f)
            af[f] = *(const s16x8*)&Als[cur][(wr * 64 + f * 16 + lc) * 32 + lr * 8];
        #pragma unroll
        for (int f = 0; f < 2; ++f)
            bf[f] = *(const s16x8*)&Bls[cur][(wc * 32 + f * 16 + lc) * 32 + lr * 8];
        #pragma unroll
        for (int fm = 0; fm < 4; ++fm)
            #pragma unroll
            for (int fn = 0; fn < 2; ++fn)
                acc[fm][fn] = __builtin_amdgcn_mfma_f32_16x16x32_bf16(
                    af[fm], bf[fn], acc[fm][fn], 0, 0, 0);
        __syncthreads();
        cur ^= 1;
    }
#undef STAGE_OUT

    #pragma unroll
    for (int fm = 0; fm < 4; ++fm)
        #pragma unroll
        for (int fn = 0; fn < 2; ++fn) {
            const size_t col = n0 + wc * 32 + fn * 16 + lc;
            #pragma unroll
            for (int j = 0; j < 4; ++j) {
                const size_t row = m0 + wr * 64 + fm * 16 + lr * 4 + j;
                C[row * (size_t)ldc + col] = acc[fm][fn][j];
            }
        }
}

// ---------------------------------------------------------------------------
// split-bf16 3-pass MFMA GEMM, sensitive columns (2-phase dbuf)
// ---------------------------------------------------------------------------
__global__ __launch_bounds__(256) void mfma_gemm_rem3(const u16* __restrict__ uh,
        const u16* __restrict__ ul, const u16* __restrict__ wh,
        const u16* __restrict__ wl, float* __restrict__ zxr) {
    __shared__ u16 Ah[2][128 * 32], Alo[2][128 * 32];
    __shared__ u16 Bh[2][64 * 32],  Blo[2][64 * 32];
    const int tid = threadIdx.x;
    const int m0 = blockIdx.y * 128, n0 = blockIdx.x * 64;
    const int lane = tid & 63, wave = tid >> 6;
    const int wr = wave >> 1, wc = wave & 1;
    const int lr = lane >> 4, lc = lane & 15;
    const int sr = tid >> 2;
    const int sc = (tid & 3) * 8;

    f32x4 acc[4][2] = {};

    const u16* pAh = uh + (size_t)(m0 + sr) * DMODEL + sc;
    const u16* pAl = ul + (size_t)(m0 + sr) * DMODEL + sc;
    const u16* pBh = wh + (size_t)(n0 + sr) * DMODEL + sc;
    const u16* pBl = wl + (size_t)(n0 + sr) * DMODEL + sc;

#define STAGE_R3(buf, k0) {                                                  \
        gload16(pAh + (k0), &Ah[buf][tid * 8]);                              \
        gload16(pAh + (k0) + (size_t)64 * DMODEL, &Ah[buf][tid * 8 + 2048]); \
        gload16(pAl + (k0), &Alo[buf][tid * 8]);                             \
        gload16(pAl + (k0) + (size_t)64 * DMODEL, &Alo[buf][tid * 8 + 2048]);\
        gload16(pBh + (k0), &Bh[buf][tid * 8]);                              \
        gload16(pBl + (k0), &Blo[buf][tid * 8]); }

    STAGE_R3(0, 0);
    __syncthreads();
    int cur = 0;
    for (int k0 = 0; k0 < DMODEL; k0 += 32) {
        if (k0 + 32 < DMODEL) STAGE_R3(cur ^ 1, k0 + 32);
        s16x8 ahf[4], alf[4], bhf[2], blf[2];
        #pragma unroll
        for (int f = 0; f < 4; ++f) {
            ahf[f] = *(const s16x8*)&Ah[cur][(wr * 64 + f * 16 + lc) * 32 + lr * 8];
            alf[f] = *(const s16x8*)&Alo[cur][(wr * 64 + f * 16 + lc) * 32 + lr * 8];
        }
        #pragma unroll
        for (int f = 0; f < 2; ++f) {
            bhf[f] = *(const s16x8*)&Bh[cur][(wc * 32 + f * 16 + lc) * 32 + lr * 8];
            blf[f] = *(const s16x8*)&Blo[cur][(wc * 32 + f * 16 + lc) * 32 + lr * 8];
        }
        #pragma unroll
        for (int fm = 0; fm < 4; ++fm)
            #pragma unroll
            for (int fn = 0; fn < 2; ++fn) {
                acc[fm][fn] = __builtin_amdgcn_mfma_f32_16x16x32_bf16(
                    ahf[fm], bhf[fn], acc[fm][fn], 0, 0, 0);
                acc[fm][fn] = __builtin_amdgcn_mfma_f32_16x16x32_bf16(
                    ahf[fm], blf[fn], acc[fm][fn], 0, 0, 0);
                acc[fm][fn] = __builtin_amdgcn_mfma_f32_16x16x32_bf16(
                    alf[fm], bhf[fn], acc[fm][fn], 0, 0, 0);
            }
        __syncthreads();
        cur ^= 1;
    }
#undef STAGE_R3

    #pragma unroll
    for (int fm = 0; fm < 4; ++fm)
        #pragma unroll
        for (int fn = 0; fn < 2; ++fn) {
            const size_t col = n0 + wc * 32 + fn * 16 + lc;
            #pragma unroll
            for (int j = 0; j < 4; ++j) {
                const size_t row = m0 + wr * 64 + fm * 16 + lr * 4 + j;
                zxr[row * DTOT + col] = acc[fm][fn][j];
            }
        }
}

// ---------------------------------------------------------------------------
// prep: RMS-norm Br/Cr; abg4 = (alpha, beta, gamma, beta'=(1-lam)*dt) in (b,h,l).
// ---------------------------------------------------------------------------
__global__ __launch_bounds__(64) void prep_kernel(const float* __restrict__ zx,
        const float* __restrict__ dt_bias, const float* __restrict__ A_log,
        const float* __restrict__ B_norm_w, const float* __restrict__ C_norm_w,
        float* __restrict__ Bg, float* __restrict__ Cg,
        float4* __restrict__ abg4) {
    const int bl = blockIdx.x;
    const int b = bl >> 10, l = bl & (LSEQ - 1);
    const int t  = threadIdx.x;
    const float* row = zx + (size_t)bl * DTOT;
    const float br = row[OFF_BR + t];
    const float cr = row[OFF_CR + t];
    float ssb = br * br, ssc = cr * cr;
    #pragma unroll
    for (int k = 1; k < 64; k <<= 1) { ssb += __shfl_xor(ssb, k); ssc += __shfl_xor(ssc, k); }
    const float scB = rsqrtf(ssb * (1.f / 64.f) + 1e-5f);
    const float scC = rsqrtf(ssc * (1.f / 64.f) + 1e-5f);
    Bg[(size_t)bl * 64 + t] = br * scB * B_norm_w[t];
    Cg[(size_t)bl * 64 + t] = cr * scC * C_norm_w[t];
    if (t < NH) {
        const float dtr = row[OFF_DT + t] + dt_bias[t];
        const float dt  = (dtr > 20.f) ? dtr : log1pf(expf(dtr));
        const float lamr = row[OFF_LAM + t];
        const float lam  = 1.f / (1.f + expf(-lamr));
        const float Ah   = -expf(A_log[t]);
        const float al   = expf(dt * Ah);
        const float bp   = (1.f - lam) * dt;            // beta' = b/a
        const size_t o = ((size_t)b * NH + t) * LSEQ + l;
        abg4[o] = make_float4(al, bp * al, lam * dt, bp);
    }
}

// ---------------------------------------------------------------------------
// cumsum of thr over L, per (b,h): 32 dims.
// ---------------------------------------------------------------------------
__global__ __launch_bounds__(256) void cumsum_kernel(const float* __restrict__ zx,
                                                     float* __restrict__ th_cs) {
    const int bh = blockIdx.x;
    const int b = bh >> 5, h = bh & 31;
    const int d = threadIdx.x & 31, seg = threadIdx.x >> 5;
    const float* base = zx + (size_t)b * LSEQ * DTOT + OFF_TH + h * 32 + d;
    float* out = th_cs + (size_t)b * LSEQ * 1024 + h * 32 + d;
    __shared__ float sums[8][33];
    const int l0 = seg * 128;
    float s = 0.f;
    #pragma unroll 4
    for (int i = 0; i < 128; ++i) s += base[(size_t)(l0 + i) * DTOT];
    sums[seg][d] = s;
    __syncthreads();
    float acc = 0.f;
    for (int s2 = 0; s2 < seg; ++s2) acc += sums[s2][d];
    #pragma unroll 4
    for (int i = 0; i < 128; ++i) {
        acc += base[(size_t)(l0 + i) * DTOT];
        out[(size_t)(l0 + i) * 1024] = acc;
    }
}

// ---------------------------------------------------------------------------
// rot: Bh/Ch = rot(broadcast(Bg/Cg)+bias). Brot/Crot layout (B,NH,L,DS).
// ---------------------------------------------------------------------------
__global__ __launch_bounds__(256) void rot_kernel(const float* __restrict__ th_cs,
        const float* __restrict__ Bg, const float* __restrict__ Cg,
        const float* __restrict__ B_bias, const float* __restrict__ C_bias,
        float* __restrict__ Brot, float* __restrict__ Crot) {
    const size_t idx = (size_t)blockIdx.x * 256 + threadIdx.x;
    const int j = (int)(idx & 31);
    const int h = (int)((idx >> 5) & 31);
    const size_t bl = idx >> 10;
    const int l = (int)(bl & (LSEQ - 1));
    const int b = (int)(bl >> 10);
    const float th = th_cs[idx];
    float s, c;
    sincosf(th, &s, &c);
    float v1 = Bg[bl * 64 + j]      + B_bias[h * 64 + j];
    float v2 = Bg[bl * 64 + 32 + j] + B_bias[h * 64 + 32 + j];
    const size_t ob = ((size_t)(b * NH + h) * LSEQ + l) * DS + j;
    Brot[ob]      = v1 * c - v2 * s;
    Brot[ob + 32] = v1 * s + v2 * c;
    v1 = Cg[bl * 64 + j]      + C_bias[h * 64 + j];
    v2 = Cg[bl * 64 + 32 + j] + C_bias[h * 64 + 32 + j];
    Crot[ob]      = v1 * c - v2 * s;
    Crot[ob + 32] = v1 * s + v2 * c;
}

// ---------------------------------------------------------------------------
// wcalc: per (b,h,seg): within-seg log-cumsum of alpha; emits
//   wbuf[t], Lbuf[t], aprod[s], bscale[s]  (see round 13/15 derivation)
// ---------------------------------------------------------------------------
__global__ __launch_bounds__(64) void wcalc_kernel(const float4* __restrict__ abg4,
        float* __restrict__ wbuf, float* __restrict__ aprod,
        float* __restrict__ bscale, float* __restrict__ Lbuf) {
    const int bh = blockIdx.x;
    const int lane = threadIdx.x;
    const int seg = lane >> 3, sub = lane & 7;
    const int t0 = seg * SEG;
    const int sbase = t0 + sub * 16;
    const float4* ab = abg4 + (size_t)bh * LSEQ;

    float part = 0.f;
    #pragma unroll
    for (int i = 0; i < 16; ++i) part += logf(ab[sbase + i].x);
    float incl = part;
    #pragma unroll
    for (int d = 1; d < 8; d <<= 1) {
        const float v = __shfl_up(incl, d, 8);
        if (sub >= d) incl += v;
    }
    const float LE = __shfl(incl, 7, 8);
    float Lrun = incl - part;                // exclusive prefix

    for (int i = 0; i < 16; ++i) {
        const int s = sbase + i;
        const float4 A = ab[s];
        Lrun += logf(A.x);
        Lbuf[(size_t)bh * LSEQ + s] = Lrun;
        float w;
        if ((s & (SEG - 1)) == (SEG - 1)) w = A.z;
        else w = __expf(LE - Lrun) * (A.z + ab[s + 1].w);
        wbuf[(size_t)bh * LSEQ + s] = w;
    }
    if (sub == 0) {
        aprod[bh * NSEG + seg] = __expf(LE);
        bscale[bh * NSEG + seg] = (seg > 0) ? __expf(LE) * ab[t0].w : 0.f;
    }
}

// ---------------------------------------------------------------------------
// hseg_gemm: h_local_end[p,n] = sum_s wbuf_s * x_s[p] * B_s[n] (split-bf16 3-pass)
// ---------------------------------------------------------------------------
#define WK 136
__global__ __launch_bounds__(256) void hseg_gemm(const float* __restrict__ zx,
        const float* __restrict__ Brot, const float* __restrict__ wbuf,
        float* __restrict__ hseg) {
    __shared__ u16 XH[64][WK], XL[64][WK], BHs[64][WK], BLs[64][WK];
    const int blk = blockIdx.x;
    const int seg = blk & (NSEG - 1), bh = blk >> 3;
    const int b = bh >> 5, h = bh & 31;
    const int tid = threadIdx.x;

    {
        const int sIdx = tid >> 1, half = tid & 1;
        const int t = seg * SEG + sIdx;
        const float wv = wbuf[(size_t)bh * LSEQ + t];
        const float* xsrc = zx + ((size_t)b * LSEQ + t) * DTOT + OFF_X + h * 64 + half * 32;
        const float* bsrc = Brot + ((size_t)bh * LSEQ + t) * DS + half * 32;
        #pragma unroll
        for (int i = 0; i < 32; i += 4) {
            const float4 xv = *(const float4*)(xsrc + i);
            const float4 bv = *(const float4*)(bsrc + i);
            const int p0 = half * 32 + i;
            u16 hi, lo;
            split1(xv.x * wv, hi, lo); XH[p0 + 0][sIdx] = hi; XL[p0 + 0][sIdx] = lo;
            split1(xv.y * wv, hi, lo); XH[p0 + 1][sIdx] = hi; XL[p0 + 1][sIdx] = lo;
            split1(xv.z * wv, hi, lo); XH[p0 + 2][sIdx] = hi; XL[p0 + 2][sIdx] = lo;
            split1(xv.w * wv, hi, lo); XH[p0 + 3][sIdx] = hi; XL[p0 + 3][sIdx] = lo;
            split1(bv.x, hi, lo); BHs[p0 + 0][sIdx] = hi; BLs[p0 + 0][sIdx] = lo;
            split1(bv.y, hi, lo); BHs[p0 + 1][sIdx] = hi; BLs[p0 + 1][sIdx] = lo;
            split1(bv.z, hi, lo); BHs[p0 + 2][sIdx] = hi; BLs[p0 + 2][sIdx] = lo;
            split1(bv.w, hi, lo); BHs[p0 + 3][sIdx] = hi; BLs[p0 + 3][sIdx] = lo;
        }
    }
    __syncthreads();

    const int lane = tid & 63, wave = tid >> 6;
    const int wR = wave >> 1, wC = wave & 1;
    const int lr = lane >> 4, lc = lane & 15;

    f32x4 acc[2][2] = {};
    #pragma unroll
    for (int ks = 0; ks < 4; ++ks) {
        const int k0 = ks * 32;
        s16x8 xh[2], xl[2], bhf[2], blf[2];
        #pragma unroll
        for (int f = 0; f < 2; ++f) {
            const int pr = wR * 32 + f * 16 + lc;
            xh[f] = *(const s16x8*)&XH[pr][k0 + lr * 8];
            xl[f] = *(const s16x8*)&XL[pr][k0 + lr * 8];
            const int nr = wC * 32 + f * 16 + lc;
            bhf[f] = *(const s16x8*)&BHs[nr][k0 + lr * 8];
            blf[f] = *(const s16x8*)&BLs[nr][k0 + lr * 8];
        }
        #pragma unroll
        for (int fm = 0; fm < 2; ++fm)
            #pragma unroll
            for (int fn = 0; fn < 2; ++fn) {
                acc[fm][fn] = __builtin_amdgcn_mfma_f32_16x16x32_bf16(
                    xh[fm], bhf[fn], acc[fm][fn], 0, 0, 0);
                acc[fm][fn] = __builtin_amdgcn_mfma_f32_16x16x32_bf16(
                    xh[fm], blf[fn], acc[fm][fn], 0, 0, 0);
                acc[fm][fn] = __builtin_amdgcn_mfma_f32_16x16x32_bf16(
                    xl[fm], bhf[fn], acc[fm][fn], 0, 0, 0);
            }
    }

    float* hp = hseg + ((size_t)(bh * NSEG + seg) * HD) * DS;
    #pragma unroll
    for (int fm = 0; fm < 2; ++fm)
        #pragma unroll
        for (int fn = 0; fn < 2; ++fn) {
            const int n = wC * 32 + fn * 16 + lc;
            #pragma unroll
            for (int j = 0; j < 4; ++j) {
                const int p = wR * 32 + fm * 16 + lr * 4 + j;
                hp[p * DS + n] = acc[fm][fn][j];
            }
        }
}

// ---------------------------------------------------------------------------
// scan_fix: sequential over segments -> hseg becomes hstar per segment.
// ---------------------------------------------------------------------------
__global__ __launch_bounds__(256) void scan_fix(float* __restrict__ hseg,
        const float* __restrict__ aprod, const float* __restrict__ bscale,
        const float* __restrict__ zx, const float* __restrict__ Brot,
        const float4* __restrict__ abg4) {
    const int blk = blockIdx.x;          // (b,h,ptile): 256
    const int ptile = blk & 3, h = (blk >> 2) & 31, b = blk >> 7;
    const int tid = threadIdx.x;
    const int pl = tid >> 4, ng = tid & 15;
    const int p = ptile * 16 + pl;
    const int n0 = ng * 4;
    const size_t bh = (size_t)b * NH + h;

    float4 cur = make_float4(0.f, 0.f, 0.f, 0.f);
    #pragma unroll
    for (int s = 0; s < NSEG; ++s) {
        float* hp = hseg + (((bh * NSEG + s) * HD + p) * DS + n0);
        float4 tmp = *(const float4*)hp;     // local h_end (no boundary)
        float4 hst = cur;                    // hstar = h_start (+ r1 below)
        if (s > 0) {
            const float bs = bscale[bh * NSEG + s];          // aprod*beta'
            const float bp0 = abg4[bh * LSEQ + s * SEG].w;   // beta'_{t0}
            const int tm1 = s * SEG - 1;
            const float4 Bm = *(const float4*)(Brot + ((size_t)bh * LSEQ + tm1) * DS + n0);
            const float xm = zx[((size_t)b * LSEQ + tm1) * DTOT + OFF_X + h * HD + p];
            const float fb = bs * xm;
            const float f1 = bp0 * xm;
            tmp.x = fmaf(fb, Bm.x, tmp.x);
            tmp.y = fmaf(fb, Bm.y, tmp.y);
            tmp.z = fmaf(fb, Bm.z, tmp.z);
            tmp.w = fmaf(fb, Bm.w, tmp.w);
            hst.x = fmaf(f1, Bm.x, hst.x);
            hst.y = fmaf(f1, Bm.y, hst.y);
            hst.z = fmaf(f1, Bm.z, hst.z);
            hst.w = fmaf(f1, Bm.w, hst.w);
        }
        *(float4*)hp = hst;
        const float a = aprod[bh * NSEG + s];
        cur.x = fmaf(a, cur.x, tmp.x);
        cur.y = fmaf(a, cur.y, tmp.y);
        cur.z = fmaf(a, cur.z, tmp.z);
        cur.w = fmaf(a, cur.w, tmp.w);
    }
}

// ---------------------------------------------------------------------------
// ssd_y v2: per (b,h,seg) output block via MFMA. C/B/H/X fragments loaded
// DIRECTLY from global (L2-resident) and split in-register — no C/B staging.
// Only Gw (fp32) lives in LDS -> 69.6KB -> 2 blocks/CU, single grid round.
//   y[i,p] = sum_j W[i,j]*(C_i.B_j)*x_j[p] + exp(L_i)*(C_i.hstar)[p] + D*x[i,p]
// ---------------------------------------------------------------------------
#define GWF 132   // f32 stride for Gw (132%32=4 -> 2-way banks on frag reads)
__global__ __launch_bounds__(256, 2) void ssd_y(const float* __restrict__ zx,
        const float* __restrict__ Brot, const float* __restrict__ Crot,
        const float4* __restrict__ abg4, const float* __restrict__ hseg,
        const float* __restrict__ Lbuf, const float* __restrict__ Dp,
        float* __restrict__ yb) {
    __shared__ float Gw[128 * GWF];          // 67,584 B
    __shared__ float Ls[128], gbs[128], gms[128], eLs[128];

    const int blk = blockIdx.x;
    const int seg = blk & (NSEG - 1), bh = blk >> 3;
    const int b = bh >> 5, h = bh & 31;
    const int tid = threadIdx.x;
    const int t0 = seg * SEG;
    const int lane = tid & 63, wave = tid >> 6;
    const int wr = wave >> 1, wc = wave & 1;
    const int lr = lane >> 4, lc = lane & 15;

    if (tid < 128) {
        const int t = t0 + tid;
        const float4 A = abg4[(size_t)bh * LSEQ + t];
        const float Lv = Lbuf[(size_t)bh * LSEQ + t];
        Ls[tid] = Lv;
        gms[tid] = A.z;
        gbs[tid] = (tid < 127) ? A.z + abg4[(size_t)bh * LSEQ + t + 1].w : 0.f;
        eLs[tid] = __expf(Lv);
    }
    __syncthreads();

    const float* Cbase = Crot + ((size_t)bh * LSEQ + t0) * DS;
    const float* Bbase = Brot + ((size_t)bh * LSEQ + t0) * DS;
    const float* Hbase = hseg + ((size_t)(bh * NSEG + seg) * HD) * DS;

    // ---- G = C.B^T (3-pass split) and P = C.hstar^T (2-pass), frags from global ----
    f32x4 accP[4][2] = {};
    f32x4 accG[4][4] = {};
    #pragma unroll
    for (int ks = 0; ks < 2; ++ks) {
        const int k0 = ks * 32 + lr * 8;
        s16x8 ch[4], cl4[4], bh4[4], bl4[4], hh2[2];
        #pragma unroll
        for (int f = 0; f < 4; ++f) {
            const int rowc = wr * 64 + f * 16 + lc;
            const float4 c0 = *(const float4*)(Cbase + (size_t)rowc * DS + k0);
            const float4 c1 = *(const float4*)(Cbase + (size_t)rowc * DS + k0 + 4);
            split8(c0, c1, ch[f], cl4[f]);
            const int rowb = wc * 64 + f * 16 + lc;
            const float4 b0 = *(const float4*)(Bbase + (size_t)rowb * DS + k0);
            const float4 b1 = *(const float4*)(Bbase + (size_t)rowb * DS + k0 + 4);
            split8(b0, b1, bh4[f], bl4[f]);
        }
        #pragma unroll
        for (int f = 0; f < 2; ++f) {
            const int rowp = wc * 32 + f * 16 + lc;
            const float4 h0 = *(const float4*)(Hbase + (size_t)rowp * DS + k0);
            const float4 h1 = *(const float4*)(Hbase + (size_t)rowp * DS + k0 + 4);
            cvt8(h0, h1, hh2[f]);
        }
        #pragma unroll
        for (int fm = 0; fm < 4; ++fm) {
            #pragma unroll
            for (int fn = 0; fn < 4; ++fn) {
                accG[fm][fn] = __builtin_amdgcn_mfma_f32_16x16x32_bf16(
                    ch[fm], bh4[fn], accG[fm][fn], 0, 0, 0);
                accG[fm][fn] = __builtin_amdgcn_mfma_f32_16x16x32_bf16(
                    ch[fm], bl4[fn], accG[fm][fn], 0, 0, 0);
                accG[fm][fn] = __builtin_amdgcn_mfma_f32_16x16x32_bf16(
                    cl4[fm], bh4[fn], accG[fm][fn], 0, 0, 0);
            }
            #pragma unroll
            for (int fn = 0; fn < 2; ++fn) {
                accP[fm][fn] = __builtin_amdgcn_mfma_f32_16x16x32_bf16(
                    ch[fm], hh2[fn], accP[fm][fn], 0, 0, 0);
                accP[fm][fn] = __builtin_amdgcn_mfma_f32_16x16x32_bf16(
                    cl4[fm], hh2[fn], accP[fm][fn], 0, 0, 0);
            }
        }
    }

    // ---- mask & write Gw (fp32) ----
    #pragma unroll
    for (int fm = 0; fm < 4; ++fm)
        #pragma unroll
        for (int fn = 0; fn < 4; ++fn)
            #pragma unroll
            for (int jj = 0; jj < 4; ++jj) {
                const int i = wr * 64 + fm * 16 + lr * 4 + jj;
                const int j = wc * 64 + fn * 16 + lc;
                float w;
                if (j < i)       w = __expf(Ls[i] - Ls[j]) * gbs[j];
                else if (j == i) w = gms[i];
                else             w = 0.f;
                Gw[i * GWF + j] = accG[fm][fn][jj] * w;
            }

    // carry term: accY = exp(L_i) * P
    f32x4 accY[4][2];
    #pragma unroll
    for (int fm = 0; fm < 4; ++fm)
        #pragma unroll
        for (int fn = 0; fn < 2; ++fn)
            #pragma unroll
            for (int jj = 0; jj < 4; ++jj) {
                const int i = wr * 64 + fm * 16 + lr * 4 + jj;
                accY[fm][fn][jj] = eLs[i] * accP[fm][fn][jj];
            }
    __syncthreads();

    // ---- Y1: accY += Gw @ X^T (Gw split at read; X single bf16 from global) ----
    const float* Xbase = zx + ((size_t)b * LSEQ + t0) * DTOT + OFF_X + h * 64;
    #pragma unroll
    for (int ks = 0; ks < 4; ++ks) {
        const int k0 = ks * 32 + lr * 8;
        s16x8 gh4[4], gl4[4], xf[2];
        #pragma unroll
        for (int f = 0; f < 4; ++f) {
            const int rowi = wr * 64 + f * 16 + lc;
            const float4 g0 = *(const float4*)&Gw[rowi * GWF + k0];
            const float4 g1 = *(const float4*)&Gw[rowi * GWF + k0 + 4];
            split8(g0, g1, gh4[f], gl4[f]);
        }
        #pragma unroll
        for (int f = 0; f < 2; ++f) {
            const int rowp = wc * 32 + f * 16 + lc;
            #pragma unroll
            for (int q = 0; q < 8; ++q)
                xf[f][q] = (short)f2bf(Xbase[(size_t)(k0 + q) * DTOT + rowp]);
        }
        #pragma unroll
        for (int fm = 0; fm < 4; ++fm)
            #pragma unroll
            for (int fn = 0; fn < 2; ++fn) {
                accY[fm][fn] = __builtin_amdgcn_mfma_f32_16x16x32_bf16(
                    gh4[fm], xf[fn], accY[fm][fn], 0, 0, 0);
                accY[fm][fn] = __builtin_amdgcn_mfma_f32_16x16x32_bf16(
                    gl4[fm], xf[fn], accY[fm][fn], 0, 0, 0);
            }
    }

    // ---- store y = accY + D*x ----
    const float Dh = Dp[h];
    #pragma unroll
    for (int fm = 0; fm < 4; ++fm)
        #pragma unroll
        for (int fn = 0; fn < 2; ++fn) {
            const int p = wc * 32 + fn * 16 + lc;
            #pragma unroll
            for (int jj = 0; jj < 4; ++jj) {
                const int i = wr * 64 + fm * 16 + lr * 4 + jj;
                const float xv = __uint_as_float(
                    f2bf(Xbase[(size_t)i * DTOT + p]) << 16);
                yb[((size_t)b * LSEQ + t0 + i) * DIN + h * 64 + p] =
                    accY[fm][fn][jj] + Dh * xv;
            }
        }
}

// ---------------------------------------------------------------------------
// gate + final RMS norm; emits bf16 directly for the out_proj GEMM.
// ---------------------------------------------------------------------------
__global__ __launch_bounds__(256) void gate_norm_kernel(const float* __restrict__ yb,
        const float* __restrict__ zx, const float* __restrict__ norm_w,
        u16* __restrict__ gnb) {
    const int bl = blockIdx.x;
    const int tid = threadIdx.x;
    const float* yrow = yb + (size_t)bl * DIN;
    const float* zrow = zx + (size_t)bl * DTOT + OFF_Z;
    float g[8];
    float ss = 0.f;
    #pragma unroll
    for (int i = 0; i < 8; ++i) {
        const int c = tid + i * 256;
        const float yv = yrow[c];
        const float zv = zrow[c];
        const float sg = 1.f / (1.f + expf(-zv));
        const float gv = yv * zv * sg;
        g[i] = gv;
        ss += gv * gv;
    }
    #pragma unroll
    for (int k = 1; k < 64; k <<= 1) ss += __shfl_xor(ss, k);
    __shared__ float wsum[4];
    if ((tid & 63) == 0) wsum[tid >> 6] = ss;
    __syncthreads();
    ss = wsum[0] + wsum[1] + wsum[2] + wsum[3];
    const float sc = rsqrtf(ss * (1.f / 2048.f) + 1e-5f);
    #pragma unroll
    for (int i = 0; i < 8; ++i) {
        const int c = tid + i * 256;
        gnb[(size_t)bl * DIN + c] = (u16)f2bf(g[i] * sc * norm_w[c]);
    }
}

// ---------------------------------------------------------------------------
extern "C" void kernel_launch(void* const* d_in, const int* in_sizes, int n_in,
                              void* d_out, int out_size, void* d_ws, size_t ws_size,
                              hipStream_t stream) {
    const float* u          = (const float*)d_in[0];
    const float* in_proj_w  = (const float*)d_in[1];
    const float* dt_bias    = (const float*)d_in[2];
    const float* A_log      = (const float*)d_in[3];
    const float* Dp         = (const float*)d_in[4];
    const float* B_norm_w   = (const float*)d_in[5];
    const float* C_norm_w   = (const float*)d_in[6];
    const float* B_bias     = (const float*)d_in[7];
    const float* C_bias     = (const float*)d_in[8];
    const float* norm_w     = (const float*)d_in[9];
    const float* out_proj_w = (const float*)d_in[10];
    float* out = (float*)d_out;

    float* p = (float*)d_ws;
    float* zx    = p; p += (size_t)ROWS * DTOT;
    float* th_cs = p; p += (size_t)ROWS * 1024;   // dead after rot -> hseg
    float* Brot  = p; p += (size_t)ROWS * 2048;   // doubles as bf16 scratch
    float* Crot  = p; p += (size_t)ROWS * 2048;
    float* Bg    = p; p += (size_t)ROWS * 64;     // dead after rot -> aprod/bscale/Lbuf
    float* Cg    = p; p += (size_t)ROWS * 64;     // dead after rot -> wbuf
    float4* abg4 = (float4*)p; p += (size_t)ROWS * NH * 4;
    float* yb    = p; p += (size_t)ROWS * 2048;
    float* hseg   = th_cs;                        // 2,097,152 floats
    float* aprod  = Bg;                           // 512
    float* bscale = Bg + 512;                     // 512
    float* Lbuf   = Bg + 2048;                    // 65,536 (Bg has 131,072)
    float* wbuf   = Cg;                           // 65,536

    // Phase-A bf16 scratch inside Brot+Crot (consumed before rot writes them):
    u16* u_bf = (u16*)Brot;
    u16* u_lo = u_bf + (size_t)ROWS * DMODEL;
    u16* w_bf = u_lo + (size_t)ROWS * DMODEL;
    u16* w_lo = w_bf + (size_t)DTOT * DMODEL;
    // Phase-B (after ssd_y, Brot/Crot dead again):
    u16* gn_bf = (u16*)Brot;
    u16* wo_bf = gn_bf + (size_t)ROWS * DIN;

    // 0. one-time fp32 -> bf16 (+residual) conversions
    conv_u<<<(ROWS * DMODEL / 4) / 256, 256, 0, stream>>>(u, u_bf, u_lo);
    conv_w<<<((size_t)DTOT * DMODEL / 4) / 256, 256, 0, stream>>>(in_proj_w, w_bf, w_lo);
    // 1a/1b. in_proj GEMMs
    mfma_gemm_zx<<<dim3(NZX / 128, ROWS / 128), 256, 0, stream>>>(u_bf, w_bf, zx);
    mfma_gemm_rem3<<<dim3(NREM / 64, ROWS / 128), 256, 0, stream>>>(
        u_bf, u_lo, w_bf + (size_t)NZX * DMODEL, w_lo, zx + NZX);
    // 2. per-row prep (abg4.w = beta')
    prep_kernel<<<ROWS, 64, 0, stream>>>(zx, dt_bias, A_log, B_norm_w, C_norm_w,
                                         Bg, Cg, abg4);
    // 3. cumsum of theta over L
    cumsum_kernel<<<BB * NH, 256, 0, stream>>>(zx, th_cs);
    // 4. rotary on B/C
    rot_kernel<<<(ROWS * 1024) / 256, 256, 0, stream>>>(th_cs, Bg, Cg, B_bias, C_bias,
                                                        Brot, Crot);
    // 5. segmented scan: weights -> h_end GEMM -> fixup -> SSD output blocks
    wcalc_kernel<<<BB * NH, 64, 0, stream>>>(abg4, wbuf, aprod, bscale, Lbuf);
    hseg_gemm<<<BB * NH * NSEG, 256, 0, stream>>>(zx, Brot, wbuf, hseg);
    scan_fix<<<BB * NH * 4, 256, 0, stream>>>(hseg, aprod, bscale, zx, Brot, abg4);
    ssd_y<<<BB * NH * NSEG, 256, 0, stream>>>(zx, Brot, Crot, abg4, hseg, Lbuf, Dp, yb);
    // 6-8. epilogue
    conv_wo<<<(DMODEL * DIN / 4) / 256, 256, 0, stream>>>(out_proj_w, wo_bf);
    gate_norm_kernel<<<ROWS, 256, 0, stream>>>(yb, zx, norm_w, gn_bf);
    mfma_gemm_out<<<dim3(DMODEL / 64, ROWS / 128), 256, 0, stream>>>(
        gn_bf, wo_bf, out, DIN, DMODEL);
}

// Round 18
// 198.580 us; speedup vs baseline: 1.7827x; 1.0019x over previous
//
#include <hip/hip_runtime.h>
#include <hip/hip_bf16.h>

// Problem constants
#define DMODEL 1024
#define DIN    2048
#define NH     32
#define HD     64
#define DS     64
#define LSEQ   1024
#define BB     2
#define DTOT   5312           // 2*DIN + 2*64 + 32 + 1024 + 32
#define ROWS   (BB*LSEQ)      // 2048
// column offsets inside zxbcdt
#define OFF_Z   0
#define OFF_X   2048
#define OFF_BR  4096
#define OFF_CR  4160
#define OFF_DT  4224
#define OFF_TH  4256
#define OFF_LAM 5280
#define NZX     4096          // z+x columns: single-pass bf16 MFMA
#define NREM    (DTOT - NZX)  // 1216 cols: 3-pass split-bf16 MFMA
// segmented scan
#define NSEG 8
#define SEG  (LSEQ / NSEG)    // 128

typedef short  s16x8 __attribute__((ext_vector_type(8)));
typedef float  f32x4 __attribute__((ext_vector_type(4)));
typedef unsigned short u16;

__device__ __forceinline__ unsigned int f2bf(float f) {   // RNE f32->bf16 (finite inputs)
    unsigned int u = __float_as_uint(f);
    u += 0x7fffu + ((u >> 16) & 1u);
    return u >> 16;
}
__device__ __forceinline__ unsigned int pk(float x, float y) {
    return f2bf(x) | (f2bf(y) << 16);
}
__device__ __forceinline__ void split1(float v, u16& hi, u16& lo) {
    const unsigned int h = f2bf(v);
    hi = (u16)h;
    lo = (u16)f2bf(v - __uint_as_float(h << 16));
}
// split 8 floats (two float4) into hi/lo bf16 fragments
__device__ __forceinline__ void split8(const float4 a, const float4 b,
                                       s16x8& hi, s16x8& lo) {
    u16 h_, l_;
    split1(a.x, h_, l_); hi[0] = (short)h_; lo[0] = (short)l_;
    split1(a.y, h_, l_); hi[1] = (short)h_; lo[1] = (short)l_;
    split1(a.z, h_, l_); hi[2] = (short)h_; lo[2] = (short)l_;
    split1(a.w, h_, l_); hi[3] = (short)h_; lo[3] = (short)l_;
    split1(b.x, h_, l_); hi[4] = (short)h_; lo[4] = (short)l_;
    split1(b.y, h_, l_); hi[5] = (short)h_; lo[5] = (short)l_;
    split1(b.z, h_, l_); hi[6] = (short)h_; lo[6] = (short)l_;
    split1(b.w, h_, l_); hi[7] = (short)h_; lo[7] = (short)l_;
}
__device__ __forceinline__ void cvt8(const float4 a, const float4 b, s16x8& hi) {
    hi[0] = (short)f2bf(a.x); hi[1] = (short)f2bf(a.y);
    hi[2] = (short)f2bf(a.z); hi[3] = (short)f2bf(a.w);
    hi[4] = (short)f2bf(b.x); hi[5] = (short)f2bf(b.y);
    hi[6] = (short)f2bf(b.z); hi[7] = (short)f2bf(b.w);
}

// HBM -> LDS direct 16B copy. Dest = wave-uniform base + lane*16 (m104).
typedef const __attribute__((address_space(1))) unsigned int glb_u32;
typedef __attribute__((address_space(3))) unsigned int lds_u32;
__device__ __forceinline__ void gload16(const void* g, void* l) {
    __builtin_amdgcn_global_load_lds((glb_u32*)g, (lds_u32*)l, 16, 0, 0);
}

// ---------------------------------------------------------------------------
// conversion kernels: fp32 -> bf16 (hi) and residual (lo).
// ---------------------------------------------------------------------------
__global__ __launch_bounds__(256) void conv_u(const float* __restrict__ src,
        u16* __restrict__ hi, u16* __restrict__ lo) {
    const size_t i4 = ((size_t)blockIdx.x * 256 + threadIdx.x) * 4;
    const float4 v = *(const float4*)(src + i4);
    const unsigned int h0 = f2bf(v.x), h1 = f2bf(v.y), h2 = f2bf(v.z), h3 = f2bf(v.w);
    uint2 hw, lw;
    hw.x = h0 | (h1 << 16); hw.y = h2 | (h3 << 16);
    lw.x = pk(v.x - __uint_as_float(h0 << 16), v.y - __uint_as_float(h1 << 16));
    lw.y = pk(v.z - __uint_as_float(h2 << 16), v.w - __uint_as_float(h3 << 16));
    *(uint2*)(hi + i4) = hw;
    *(uint2*)(lo + i4) = lw;
}

__global__ __launch_bounds__(256) void conv_w(const float* __restrict__ src,
        u16* __restrict__ hi, u16* __restrict__ lo) {
    const size_t i4 = ((size_t)blockIdx.x * 256 + threadIdx.x) * 4;
    const float4 v = *(const float4*)(src + i4);
    const unsigned int h0 = f2bf(v.x), h1 = f2bf(v.y), h2 = f2bf(v.z), h3 = f2bf(v.w);
    uint2 hw, lw;
    hw.x = h0 | (h1 << 16); hw.y = h2 | (h3 << 16);
    lw.x = pk(v.x - __uint_as_float(h0 << 16), v.y - __uint_as_float(h1 << 16));
    lw.y = pk(v.z - __uint_as_float(h2 << 16), v.w - __uint_as_float(h3 << 16));
    *(uint2*)(hi + i4) = hw;
    if ((i4 >> 10) >= NZX)
        *(uint2*)(lo + (i4 - (size_t)NZX * DMODEL)) = lw;
}

__global__ __launch_bounds__(256) void conv_wo(const float* __restrict__ src,
        u16* __restrict__ hi) {
    const size_t i4 = ((size_t)blockIdx.x * 256 + threadIdx.x) * 4;
    const float4 v = *(const float4*)(src + i4);
    uint2 hw;
    hw.x = pk(v.x, v.y); hw.y = pk(v.z, v.w);
    *(uint2*)(hi + i4) = hw;
}

// ---------------------------------------------------------------------------
// bf16 MFMA GEMM, z/x block (2-phase dbuf global_load_lds)
// ---------------------------------------------------------------------------
__global__ __launch_bounds__(256) void mfma_gemm_zx(const u16* __restrict__ uA_,
                                                    const u16* __restrict__ uW,
                                                    float* __restrict__ zx) {
    __shared__ u16 Al[2][128 * 32];
    __shared__ u16 Bl[2][128 * 32];
    const int tid = threadIdx.x;
    const int m0 = blockIdx.y * 128, n0 = blockIdx.x * 128;
    const int lane = tid & 63, wave = tid >> 6;
    const int wr = wave >> 1, wc = wave & 1;
    const int lr = lane >> 4, lc = lane & 15;
    const int sr = tid >> 2;
    const int sc = (tid & 3) * 8;

    f32x4 acc[4][4] = {};

    const u16* pA = uA_ + (size_t)(m0 + sr) * DMODEL + sc;
    const u16* pB = uW  + (size_t)(n0 + sr) * DMODEL + sc;

#define STAGE_ZX(buf, k0) {                                              \
        gload16(pA + (k0), &Al[buf][tid * 8]);                           \
        gload16(pA + (k0) + (size_t)64 * DMODEL, &Al[buf][tid * 8 + 2048]); \
        gload16(pB + (k0), &Bl[buf][tid * 8]);                           \
        gload16(pB + (k0) + (size_t)64 * DMODEL, &Bl[buf][tid * 8 + 2048]); }

    STAGE_ZX(0, 0);
    __syncthreads();
    int cur = 0;
    for (int k0 = 0; k0 < DMODEL; k0 += 32) {
        if (k0 + 32 < DMODEL) STAGE_ZX(cur ^ 1, k0 + 32);
        s16x8 af[4], bf[4];
        #pragma unroll
        for (int f = 0; f < 4; ++f) {
            af[f] = *(const s16x8*)&Al[cur][(wr * 64 + f * 16 + lc) * 32 + lr * 8];
            bf[f] = *(const s16x8*)&Bl[cur][(wc * 64 + f * 16 + lc) * 32 + lr * 8];
        }
        #pragma unroll
        for (int fm = 0; fm < 4; ++fm)
            #pragma unroll
            for (int fn = 0; fn < 4; ++fn)
                acc[fm][fn] = __builtin_amdgcn_mfma_f32_16x16x32_bf16(
                    af[fm], bf[fn], acc[fm][fn], 0, 0, 0);
        __syncthreads();
        cur ^= 1;
    }
#undef STAGE_ZX

    #pragma unroll
    for (int fm = 0; fm < 4; ++fm)
        #pragma unroll
        for (int fn = 0; fn < 4; ++fn) {
            const size_t col = n0 + wc * 64 + fn * 16 + lc;
            #pragma unroll
            for (int j = 0; j < 4; ++j) {
                const size_t row = m0 + wr * 64 + fm * 16 + lr * 4 + j;
                zx[row * DTOT + col] = acc[fm][fn][j];
            }
        }
}

// ---------------------------------------------------------------------------
// bf16 MFMA GEMM, 128x64 tile, 2-phase dbuf: out = gn_bf @ wo_bf^T
// ---------------------------------------------------------------------------
__global__ __launch_bounds__(256) void mfma_gemm_out(const u16* __restrict__ A,
                                                     const u16* __restrict__ B,
                                                     float* __restrict__ C,
                                                     int K, int ldc) {
    __shared__ u16 Als[2][128 * 32];
    __shared__ u16 Bls[2][64 * 32];
    const int tid = threadIdx.x;
    const int m0 = blockIdx.y * 128, n0 = blockIdx.x * 64;
    const int lane = tid & 63, wave = tid >> 6;
    const int wr = wave >> 1, wc = wave & 1;
    const int lr = lane >> 4, lc = lane & 15;
    const int sr = tid >> 2;
    const int sc = (tid & 3) * 8;

    f32x4 acc[4][2] = {};

    const u16* pA = A + (size_t)(m0 + sr) * K + sc;
    const u16* pB = B + (size_t)(n0 + sr) * K + sc;

#define STAGE_OUT(buf, k0) {                                             \
        gload16(pA + (k0), &Als[buf][tid * 8]);                          \
        gload16(pA + (k0) + (size_t)64 * K, &Als[buf][tid * 8 + 2048]);  \
        gload16(pB + (k0), &Bls[buf][tid * 8]); }

    STAGE_OUT(0, 0);
    __syncthreads();
    int cur = 0;
    for (int k0 = 0; k0 < K; k0 += 32) {
        if (k0 + 32 < K) STAGE_OUT(cur ^ 1, k0 + 32);
        s16x8 af[4], bf[2];
        #pragma unroll
        for (int f = 0; f < 4; ++f)
            af[f] = *(const s16x8*)&Als[cur][(wr * 64 + f * 16 + lc) * 32 + lr * 8];
        #pragma unroll
        for (int f = 0; f < 2; ++f)
            bf[f] = *(const s16x8*)&Bls[cur][(wc * 32 + f * 16 + lc) * 32 + lr * 8];
        #pragma unroll
        for (int fm = 0; fm < 4; ++fm)
            #pragma unroll
            for (int fn = 0; fn < 2; ++fn)
                acc[fm][fn] = __builtin_amdgcn_mfma_f32_16x16x32_bf16(
                    af[fm], bf[fn], acc[fm][fn], 0, 0, 0);
        __syncthreads();
        cur ^= 1;
    }
#undef STAGE_OUT

    #pragma unroll
    for (int fm = 0; fm < 4; ++fm)
        #pragma unroll
        for (int fn = 0; fn < 2; ++fn) {
            const size_t col = n0 + wc * 32 + fn * 16 + lc;
            #pragma unroll
            for (int j = 0; j < 4; ++j) {
                const size_t row = m0 + wr * 64 + fm * 16 + lr * 4 + j;
                C[row * (size_t)ldc + col] = acc[fm][fn][j];
            }
        }
}

// ---------------------------------------------------------------------------
// split-bf16 3-pass MFMA GEMM, sensitive columns (2-phase dbuf)
// ---------------------------------------------------------------------------
__global__ __launch_bounds__(256) void mfma_gemm_rem3(const u16* __restrict__ uh,
        const u16* __restrict__ ul, const u16* __restrict__ wh,
        const u16* __restrict__ wl, float* __restrict__ zxr) {
    __shared__ u16 Ah[2][128 * 32], Alo[2][128 * 32];
    __shared__ u16 Bh[2][64 * 32],  Blo[2][64 * 32];
    const int tid = threadIdx.x;
    const int m0 = blockIdx.y * 128, n0 = blockIdx.x * 64;
    const int lane = tid & 63, wave = tid >> 6;
    const int wr = wave >> 1, wc = wave & 1;
    const int lr = lane >> 4, lc = lane & 15;
    const int sr = tid >> 2;
    const int sc = (tid & 3) * 8;

    f32x4 acc[4][2] = {};

    const u16* pAh = uh + (size_t)(m0 + sr) * DMODEL + sc;
    const u16* pAl = ul + (size_t)(m0 + sr) * DMODEL + sc;
    const u16* pBh = wh + (size_t)(n0 + sr) * DMODEL + sc;
    const u16* pBl = wl + (size_t)(n0 + sr) * DMODEL + sc;

#define STAGE_R3(buf, k0) {                                                  \
        gload16(pAh + (k0), &Ah[buf][tid * 8]);                              \
        gload16(pAh + (k0) + (size_t)64 * DMODEL, &Ah[buf][tid * 8 + 2048]); \
        gload16(pAl + (k0), &Alo[buf][tid * 8]);                             \
        gload16(pAl + (k0) + (size_t)64 * DMODEL, &Alo[buf][tid * 8 + 2048]);\
        gload16(pBh + (k0), &Bh[buf][tid * 8]);                              \
        gload16(pBl + (k0), &Blo[buf][tid * 8]); }

    STAGE_R3(0, 0);
    __syncthreads();
    int cur = 0;
    for (int k0 = 0; k0 < DMODEL; k0 += 32) {
        if (k0 + 32 < DMODEL) STAGE_R3(cur ^ 1, k0 + 32);
        s16x8 ahf[4], alf[4], bhf[2], blf[2];
        #pragma unroll
        for (int f = 0; f < 4; ++f) {
            ahf[f] = *(const s16x8*)&Ah[cur][(wr * 64 + f * 16 + lc) * 32 + lr * 8];
            alf[f] = *(const s16x8*)&Alo[cur][(wr * 64 + f * 16 + lc) * 32 + lr * 8];
        }
        #pragma unroll
        for (int f = 0; f < 2; ++f) {
            bhf[f] = *(const s16x8*)&Bh[cur][(wc * 32 + f * 16 + lc) * 32 + lr * 8];
            blf[f] = *(const s16x8*)&Blo[cur][(wc * 32 + f * 16 + lc) * 32 + lr * 8];
        }
        #pragma unroll
        for (int fm = 0; fm < 4; ++fm)
            #pragma unroll
            for (int fn = 0; fn < 2; ++fn) {
                acc[fm][fn] = __builtin_amdgcn_mfma_f32_16x16x32_bf16(
                    ahf[fm], bhf[fn], acc[fm][fn], 0, 0, 0);
                acc[fm][fn] = __builtin_amdgcn_mfma_f32_16x16x32_bf16(
                    ahf[fm], blf[fn], acc[fm][fn], 0, 0, 0);
                acc[fm][fn] = __builtin_amdgcn_mfma_f32_16x16x32_bf16(
                    alf[fm], bhf[fn], acc[fm][fn], 0, 0, 0);
            }
        __syncthreads();
        cur ^= 1;
    }
#undef STAGE_R3

    #pragma unroll
    for (int fm = 0; fm < 4; ++fm)
        #pragma unroll
        for (int fn = 0; fn < 2; ++fn) {
            const size_t col = n0 + wc * 32 + fn * 16 + lc;
            #pragma unroll
            for (int j = 0; j < 4; ++j) {
                const size_t row = m0 + wr * 64 + fm * 16 + lr * 4 + j;
                zxr[row * DTOT + col] = acc[fm][fn][j];
            }
        }
}

// ---------------------------------------------------------------------------
// prep: RMS-norm Br/Cr; abg4 = (alpha, beta, gamma, beta'=(1-lam)*dt) in (b,h,l).
// ---------------------------------------------------------------------------
__global__ __launch_bounds__(64) void prep_kernel(const float* __restrict__ zx,
        const float* __restrict__ dt_bias, const float* __restrict__ A_log,
        const float* __restrict__ B_norm_w, const float* __restrict__ C_norm_w,
        float* __restrict__ Bg, float* __restrict__ Cg,
        float4* __restrict__ abg4) {
    const int bl = blockIdx.x;
    const int b = bl >> 10, l = bl & (LSEQ - 1);
    const int t  = threadIdx.x;
    const float* row = zx + (size_t)bl * DTOT;
    const float br = row[OFF_BR + t];
    const float cr = row[OFF_CR + t];
    float ssb = br * br, ssc = cr * cr;
    #pragma unroll
    for (int k = 1; k < 64; k <<= 1) { ssb += __shfl_xor(ssb, k); ssc += __shfl_xor(ssc, k); }
    const float scB = rsqrtf(ssb * (1.f / 64.f) + 1e-5f);
    const float scC = rsqrtf(ssc * (1.f / 64.f) + 1e-5f);
    Bg[(size_t)bl * 64 + t] = br * scB * B_norm_w[t];
    Cg[(size_t)bl * 64 + t] = cr * scC * C_norm_w[t];
    if (t < NH) {
        const float dtr = row[OFF_DT + t] + dt_bias[t];
        const float dt  = (dtr > 20.f) ? dtr : log1pf(expf(dtr));
        const float lamr = row[OFF_LAM + t];
        const float lam  = 1.f / (1.f + expf(-lamr));
        const float Ah   = -expf(A_log[t]);
        const float al   = expf(dt * Ah);
        const float bp   = (1.f - lam) * dt;            // beta' = b/a
        const size_t o = ((size_t)b * NH + t) * LSEQ + l;
        abg4[o] = make_float4(al, bp * al, lam * dt, bp);
    }
}

// ---------------------------------------------------------------------------
// cumsum of thr over L, per (b,h): 32 dims.
// ---------------------------------------------------------------------------
__global__ __launch_bounds__(256) void cumsum_kernel(const float* __restrict__ zx,
                                                     float* __restrict__ th_cs) {
    const int bh = blockIdx.x;
    const int b = bh >> 5, h = bh & 31;
    const int d = threadIdx.x & 31, seg = threadIdx.x >> 5;
    const float* base = zx + (size_t)b * LSEQ * DTOT + OFF_TH + h * 32 + d;
    float* out = th_cs + (size_t)b * LSEQ * 1024 + h * 32 + d;
    __shared__ float sums[8][33];
    const int l0 = seg * 128;
    float s = 0.f;
    #pragma unroll 4
    for (int i = 0; i < 128; ++i) s += base[(size_t)(l0 + i) * DTOT];
    sums[seg][d] = s;
    __syncthreads();
    float acc = 0.f;
    for (int s2 = 0; s2 < seg; ++s2) acc += sums[s2][d];
    #pragma unroll 4
    for (int i = 0; i < 128; ++i) {
        acc += base[(size_t)(l0 + i) * DTOT];
        out[(size_t)(l0 + i) * 1024] = acc;
    }
}

// ---------------------------------------------------------------------------
// rot: Bh/Ch = rot(broadcast(Bg/Cg)+bias). Brot/Crot layout (B,NH,L,DS).
// ---------------------------------------------------------------------------
__global__ __launch_bounds__(256) void rot_kernel(const float* __restrict__ th_cs,
        const float* __restrict__ Bg, const float* __restrict__ Cg,
        const float* __restrict__ B_bias, const float* __restrict__ C_bias,
        float* __restrict__ Brot, float* __restrict__ Crot) {
    const size_t idx = (size_t)blockIdx.x * 256 + threadIdx.x;
    const int j = (int)(idx & 31);
    const int h = (int)((idx >> 5) & 31);
    const size_t bl = idx >> 10;
    const int l = (int)(bl & (LSEQ - 1));
    const int b = (int)(bl >> 10);
    const float th = th_cs[idx];
    float s, c;
    sincosf(th, &s, &c);
    float v1 = Bg[bl * 64 + j]      + B_bias[h * 64 + j];
    float v2 = Bg[bl * 64 + 32 + j] + B_bias[h * 64 + 32 + j];
    const size_t ob = ((size_t)(b * NH + h) * LSEQ + l) * DS + j;
    Brot[ob]      = v1 * c - v2 * s;
    Brot[ob + 32] = v1 * s + v2 * c;
    v1 = Cg[bl * 64 + j]      + C_bias[h * 64 + j];
    v2 = Cg[bl * 64 + 32 + j] + C_bias[h * 64 + 32 + j];
    Crot[ob]      = v1 * c - v2 * s;
    Crot[ob + 32] = v1 * s + v2 * c;
}

// ---------------------------------------------------------------------------
// wcalc: per (b,h,seg): within-seg log-cumsum of alpha; emits
//   wbuf[t], Lbuf[t], aprod[s], bscale[s]  (see round 13/15 derivation)
// ---------------------------------------------------------------------------
__global__ __launch_bounds__(64) void wcalc_kernel(const float4* __restrict__ abg4,
        float* __restrict__ wbuf, float* __restrict__ aprod,
        float* __restrict__ bscale, float* __restrict__ Lbuf) {
    const int bh = blockIdx.x;
    const int lane = threadIdx.x;
    const int seg = lane >> 3, sub = lane & 7;
    const int t0 = seg * SEG;
    const int sbase = t0 + sub * 16;
    const float4* ab = abg4 + (size_t)bh * LSEQ;

    float part = 0.f;
    #pragma unroll
    for (int i = 0; i < 16; ++i) part += logf(ab[sbase + i].x);
    float incl = part;
    #pragma unroll
    for (int d = 1; d < 8; d <<= 1) {
        const float v = __shfl_up(incl, d, 8);
        if (sub >= d) incl += v;
    }
    const float LE = __shfl(incl, 7, 8);
    float Lrun = incl - part;                // exclusive prefix

    for (int i = 0; i < 16; ++i) {
        const int s = sbase + i;
        const float4 A = ab[s];
        Lrun += logf(A.x);
        Lbuf[(size_t)bh * LSEQ + s] = Lrun;
        float w;
        if ((s & (SEG - 1)) == (SEG - 1)) w = A.z;
        else w = __expf(LE - Lrun) * (A.z + ab[s + 1].w);
        wbuf[(size_t)bh * LSEQ + s] = w;
    }
    if (sub == 0) {
        aprod[bh * NSEG + seg] = __expf(LE);
        bscale[bh * NSEG + seg] = (seg > 0) ? __expf(LE) * ab[t0].w : 0.f;
    }
}

// ---------------------------------------------------------------------------
// hseg_gemm: h_local_end[p,n] = sum_s wbuf_s * x_s[p] * B_s[n] (split-bf16 3-pass)
// ---------------------------------------------------------------------------
#define WK 136
__global__ __launch_bounds__(256) void hseg_gemm(const float* __restrict__ zx,
        const float* __restrict__ Brot, const float* __restrict__ wbuf,
        float* __restrict__ hseg) {
    __shared__ u16 XH[64][WK], XL[64][WK], BHs[64][WK], BLs[64][WK];
    const int blk = blockIdx.x;
    const int seg = blk & (NSEG - 1), bh = blk >> 3;
    const int b = bh >> 5, h = bh & 31;
    const int tid = threadIdx.x;

    {
        const int sIdx = tid >> 1, half = tid & 1;
        const int t = seg * SEG + sIdx;
        const float wv = wbuf[(size_t)bh * LSEQ + t];
        const float* xsrc = zx + ((size_t)b * LSEQ + t) * DTOT + OFF_X + h * 64 + half * 32;
        const float* bsrc = Brot + ((size_t)bh * LSEQ + t) * DS + half * 32;
        #pragma unroll
        for (int i = 0; i < 32; i += 4) {
            const float4 xv = *(const float4*)(xsrc + i);
            const float4 bv = *(const float4*)(bsrc + i);
            const int p0 = half * 32 + i;
            u16 hi, lo;
            split1(xv.x * wv, hi, lo); XH[p0 + 0][sIdx] = hi; XL[p0 + 0][sIdx] = lo;
            split1(xv.y * wv, hi, lo); XH[p0 + 1][sIdx] = hi; XL[p0 + 1][sIdx] = lo;
            split1(xv.z * wv, hi, lo); XH[p0 + 2][sIdx] = hi; XL[p0 + 2][sIdx] = lo;
            split1(xv.w * wv, hi, lo); XH[p0 + 3][sIdx] = hi; XL[p0 + 3][sIdx] = lo;
            split1(bv.x, hi, lo); BHs[p0 + 0][sIdx] = hi; BLs[p0 + 0][sIdx] = lo;
            split1(bv.y, hi, lo); BHs[p0 + 1][sIdx] = hi; BLs[p0 + 1][sIdx] = lo;
            split1(bv.z, hi, lo); BHs[p0 + 2][sIdx] = hi; BLs[p0 + 2][sIdx] = lo;
            split1(bv.w, hi, lo); BHs[p0 + 3][sIdx] = hi; BLs[p0 + 3][sIdx] = lo;
        }
    }
    __syncthreads();

    const int lane = tid & 63, wave = tid >> 6;
    const int wR = wave >> 1, wC = wave & 1;
    const int lr = lane >> 4, lc = lane & 15;

    f32x4 acc[2][2] = {};
    #pragma unroll
    for (int ks = 0; ks < 4; ++ks) {
        const int k0 = ks * 32;
        s16x8 xh[2], xl[2], bhf[2], blf[2];
        #pragma unroll
        for (int f = 0; f < 2; ++f) {
            const int pr = wR * 32 + f * 16 + lc;
            xh[f] = *(const s16x8*)&XH[pr][k0 + lr * 8];
            xl[f] = *(const s16x8*)&XL[pr][k0 + lr * 8];
            const int nr = wC * 32 + f * 16 + lc;
            bhf[f] = *(const s16x8*)&BHs[nr][k0 + lr * 8];
            blf[f] = *(const s16x8*)&BLs[nr][k0 + lr * 8];
        }
        #pragma unroll
        for (int fm = 0; fm < 2; ++fm)
            #pragma unroll
            for (int fn = 0; fn < 2; ++fn) {
                acc[fm][fn] = __builtin_amdgcn_mfma_f32_16x16x32_bf16(
                    xh[fm], bhf[fn], acc[fm][fn], 0, 0, 0);
                acc[fm][fn] = __builtin_amdgcn_mfma_f32_16x16x32_bf16(
                    xh[fm], blf[fn], acc[fm][fn], 0, 0, 0);
                acc[fm][fn] = __builtin_amdgcn_mfma_f32_16x16x32_bf16(
                    xl[fm], bhf[fn], acc[fm][fn], 0, 0, 0);
            }
    }

    float* hp = hseg + ((size_t)(bh * NSEG + seg) * HD) * DS;
    #pragma unroll
    for (int fm = 0; fm < 2; ++fm)
        #pragma unroll
        for (int fn = 0; fn < 2; ++fn) {
            const int n = wC * 32 + fn * 16 + lc;
            #pragma unroll
            for (int j = 0; j < 4; ++j) {
                const int p = wR * 32 + fm * 16 + lr * 4 + j;
                hp[p * DS + n] = acc[fm][fn][j];
            }
        }
}

// ---------------------------------------------------------------------------
// scan_fix: sequential over segments -> hseg becomes hstar per segment.
// ---------------------------------------------------------------------------
__global__ __launch_bounds__(256) void scan_fix(float* __restrict__ hseg,
        const float* __restrict__ aprod, const float* __restrict__ bscale,
        const float* __restrict__ zx, const float* __restrict__ Brot,
        const float4* __restrict__ abg4) {
    const int blk = blockIdx.x;          // (b,h,ptile): 256
    const int ptile = blk & 3, h = (blk >> 2) & 31, b = blk >> 7;
    const int tid = threadIdx.x;
    const int pl = tid >> 4, ng = tid & 15;
    const int p = ptile * 16 + pl;
    const int n0 = ng * 4;
    const size_t bh = (size_t)b * NH + h;

    float4 cur = make_float4(0.f, 0.f, 0.f, 0.f);
    #pragma unroll
    for (int s = 0; s < NSEG; ++s) {
        float* hp = hseg + (((bh * NSEG + s) * HD + p) * DS + n0);
        float4 tmp = *(const float4*)hp;     // local h_end (no boundary)
        float4 hst = cur;                    // hstar = h_start (+ r1 below)
        if (s > 0) {
            const float bs = bscale[bh * NSEG + s];          // aprod*beta'
            const float bp0 = abg4[bh * LSEQ + s * SEG].w;   // beta'_{t0}
            const int tm1 = s * SEG - 1;
            const float4 Bm = *(const float4*)(Brot + ((size_t)bh * LSEQ + tm1) * DS + n0);
            const float xm = zx[((size_t)b * LSEQ + tm1) * DTOT + OFF_X + h * HD + p];
            const float fb = bs * xm;
            const float f1 = bp0 * xm;
            tmp.x = fmaf(fb, Bm.x, tmp.x);
            tmp.y = fmaf(fb, Bm.y, tmp.y);
            tmp.z = fmaf(fb, Bm.z, tmp.z);
            tmp.w = fmaf(fb, Bm.w, tmp.w);
            hst.x = fmaf(f1, Bm.x, hst.x);
            hst.y = fmaf(f1, Bm.y, hst.y);
            hst.z = fmaf(f1, Bm.z, hst.z);
            hst.w = fmaf(f1, Bm.w, hst.w);
        }
        *(float4*)hp = hst;
        const float a = aprod[bh * NSEG + s];
        cur.x = fmaf(a, cur.x, tmp.x);
        cur.y = fmaf(a, cur.y, tmp.y);
        cur.z = fmaf(a, cur.z, tmp.z);
        cur.w = fmaf(a, cur.w, tmp.w);
    }
}

// ---------------------------------------------------------------------------
// ssd_y v3: C/B/H fragments from global (L2); Gw fp32 in LDS with D folded
// into the diagonal (y = Gw@X^T + carry exactly); X^T staged in LDS in two
// 64-step halves (coalesced reads, b128 fragment reads). ~78.8KB -> 2 blk/CU.
// ---------------------------------------------------------------------------
#define GWF 132   // f32 stride for Gw
#define XTS 72    // u16 stride for XT half (64 l' + 8 pad)
__global__ __launch_bounds__(256, 2) void ssd_y(const float* __restrict__ zx,
        const float* __restrict__ Brot, const float* __restrict__ Crot,
        const float4* __restrict__ abg4, const float* __restrict__ hseg,
        const float* __restrict__ Lbuf, const float* __restrict__ Dp,
        float* __restrict__ yb) {
    __shared__ float Gw[128 * GWF];          // 67,584 B
    __shared__ u16 XTh[64 * XTS];            //  9,216 B
    __shared__ float Ls[128], gbs[128], gms[128], eLs[128];

    const int blk = blockIdx.x;
    const int seg = blk & (NSEG - 1), bh = blk >> 3;
    const int b = bh >> 5, h = bh & 31;
    const int tid = threadIdx.x;
    const int t0 = seg * SEG;
    const int lane = tid & 63, wave = tid >> 6;
    const int wr = wave >> 1, wc = wave & 1;
    const int lr = lane >> 4, lc = lane & 15;

    if (tid < 128) {
        const int t = t0 + tid;
        const float4 A = abg4[(size_t)bh * LSEQ + t];
        const float Lv = Lbuf[(size_t)bh * LSEQ + t];
        Ls[tid] = Lv;
        gms[tid] = A.z;
        gbs[tid] = (tid < 127) ? A.z + abg4[(size_t)bh * LSEQ + t + 1].w : 0.f;
        eLs[tid] = __expf(Lv);
    }
    __syncthreads();

    const float* Cbase = Crot + ((size_t)bh * LSEQ + t0) * DS;
    const float* Bbase = Brot + ((size_t)bh * LSEQ + t0) * DS;
    const float* Hbase = hseg + ((size_t)(bh * NSEG + seg) * HD) * DS;
    const float* Xbase = zx + ((size_t)b * LSEQ + t0) * DTOT + OFF_X + h * 64;

    // ---- G = C.B^T (3-pass split) and P = C.hstar^T (2-pass), frags from global ----
    f32x4 accP[4][2] = {};
    f32x4 accG[4][4] = {};
    #pragma unroll
    for (int ks = 0; ks < 2; ++ks) {
        const int k0 = ks * 32 + lr * 8;
        s16x8 ch[4], cl4[4], bh4[4], bl4[4], hh2[2];
        #pragma unroll
        for (int f = 0; f < 4; ++f) {
            const int rowc = wr * 64 + f * 16 + lc;
            const float4 c0 = *(const float4*)(Cbase + (size_t)rowc * DS + k0);
            const float4 c1 = *(const float4*)(Cbase + (size_t)rowc * DS + k0 + 4);
            split8(c0, c1, ch[f], cl4[f]);
            const int rowb = wc * 64 + f * 16 + lc;
            const float4 b0 = *(const float4*)(Bbase + (size_t)rowb * DS + k0);
            const float4 b1 = *(const float4*)(Bbase + (size_t)rowb * DS + k0 + 4);
            split8(b0, b1, bh4[f], bl4[f]);
        }
        #pragma unroll
        for (int f = 0; f < 2; ++f) {
            const int rowp = wc * 32 + f * 16 + lc;
            const float4 h0 = *(const float4*)(Hbase + (size_t)rowp * DS + k0);
            const float4 h1 = *(const float4*)(Hbase + (size_t)rowp * DS + k0 + 4);
            cvt8(h0, h1, hh2[f]);
        }
        #pragma unroll
        for (int fm = 0; fm < 4; ++fm) {
            #pragma unroll
            for (int fn = 0; fn < 4; ++fn) {
                accG[fm][fn] = __builtin_amdgcn_mfma_f32_16x16x32_bf16(
                    ch[fm], bh4[fn], accG[fm][fn], 0, 0, 0);
                accG[fm][fn] = __builtin_amdgcn_mfma_f32_16x16x32_bf16(
                    ch[fm], bl4[fn], accG[fm][fn], 0, 0, 0);
                accG[fm][fn] = __builtin_amdgcn_mfma_f32_16x16x32_bf16(
                    cl4[fm], bh4[fn], accG[fm][fn], 0, 0, 0);
            }
            #pragma unroll
            for (int fn = 0; fn < 2; ++fn) {
                accP[fm][fn] = __builtin_amdgcn_mfma_f32_16x16x32_bf16(
                    ch[fm], hh2[fn], accP[fm][fn], 0, 0, 0);
                accP[fm][fn] = __builtin_amdgcn_mfma_f32_16x16x32_bf16(
                    cl4[fm], hh2[fn], accP[fm][fn], 0, 0, 0);
            }
        }
    }

    // ---- mask & write Gw (fp32), D folded into the diagonal ----
    const float Dh = Dp[h];
    #pragma unroll
    for (int fm = 0; fm < 4; ++fm)
        #pragma unroll
        for (int fn = 0; fn < 4; ++fn)
            #pragma unroll
            for (int jj = 0; jj < 4; ++jj) {
                const int i = wr * 64 + fm * 16 + lr * 4 + jj;
                const int j = wc * 64 + fn * 16 + lc;
                float v;
                if (j < i)       v = accG[fm][fn][jj] * __expf(Ls[i] - Ls[j]) * gbs[j];
                else if (j == i) v = accG[fm][fn][jj] * gms[i] + Dh;
                else             v = 0.f;
                Gw[i * GWF + j] = v;
            }

    // carry term: accY = exp(L_i) * P
    f32x4 accY[4][2];
    #pragma unroll
    for (int fm = 0; fm < 4; ++fm)
        #pragma unroll
        for (int fn = 0; fn < 2; ++fn)
            #pragma unroll
            for (int jj = 0; jj < 4; ++jj) {
                const int i = wr * 64 + fm * 16 + lr * 4 + jj;
                accY[fm][fn][jj] = eLs[i] * accP[fm][fn][jj];
            }

    // ---- stage XT half 0 (l' = 0..63) ----
#define STAGE_XT(H) {                                                        \
        const int lp = tid >> 2, pq = (tid & 3) * 16;                        \
        const float* xs = Xbase + (size_t)((H) * 64 + lp) * DTOT + pq;       \
        _Pragma("unroll")                                                    \
        for (int i = 0; i < 16; i += 4) {                                    \
            const float4 xv = *(const float4*)(xs + i);                      \
            XTh[(pq + i + 0) * XTS + lp] = (u16)f2bf(xv.x);                  \
            XTh[(pq + i + 1) * XTS + lp] = (u16)f2bf(xv.y);                  \
            XTh[(pq + i + 2) * XTS + lp] = (u16)f2bf(xv.z);                  \
            XTh[(pq + i + 3) * XTS + lp] = (u16)f2bf(xv.w);                  \
        }                                                                    \
    }
    STAGE_XT(0);
    __syncthreads();   // Gw + XT0 visible

    // ---- Y1: accY += Gw @ X^T (Gw split at read; X from LDS halves) ----
    #pragma unroll
    for (int ks = 0; ks < 4; ++ks) {
        if (ks == 2) {
            __syncthreads();       // XT0 reads done
            STAGE_XT(1);
            __syncthreads();       // XT1 visible
        }
        const int k0 = ks * 32 + lr * 8;
        const int kl = (ks & 1) * 32 + lr * 8;    // offset within the XT half
        s16x8 gh4[4], gl4[4], xf[2];
        #pragma unroll
        for (int f = 0; f < 4; ++f) {
            const int rowi = wr * 64 + f * 16 + lc;
            const float4 g0 = *(const float4*)&Gw[rowi * GWF + k0];
            const float4 g1 = *(const float4*)&Gw[rowi * GWF + k0 + 4];
            split8(g0, g1, gh4[f], gl4[f]);
        }
        #pragma unroll
        for (int f = 0; f < 2; ++f) {
            const int rowp = wc * 32 + f * 16 + lc;
            xf[f] = *(const s16x8*)&XTh[rowp * XTS + kl];
        }
        #pragma unroll
        for (int fm = 0; fm < 4; ++fm)
            #pragma unroll
            for (int fn = 0; fn < 2; ++fn) {
                accY[fm][fn] = __builtin_amdgcn_mfma_f32_16x16x32_bf16(
                    gh4[fm], xf[fn], accY[fm][fn], 0, 0, 0);
                accY[fm][fn] = __builtin_amdgcn_mfma_f32_16x16x32_bf16(
                    gl4[fm], xf[fn], accY[fm][fn], 0, 0, 0);
            }
    }
#undef STAGE_XT

    // ---- store y (D*x already folded into Gw diagonal) ----
    #pragma unroll
    for (int fm = 0; fm < 4; ++fm)
        #pragma unroll
        for (int fn = 0; fn < 2; ++fn) {
            const int p = wc * 32 + fn * 16 + lc;
            #pragma unroll
            for (int jj = 0; jj < 4; ++jj) {
                const int i = wr * 64 + fm * 16 + lr * 4 + jj;
                yb[((size_t)b * LSEQ + t0 + i) * DIN + h * 64 + p] = accY[fm][fn][jj];
            }
        }
}

// ---------------------------------------------------------------------------
// gate + final RMS norm; emits bf16 directly for the out_proj GEMM.
// ---------------------------------------------------------------------------
__global__ __launch_bounds__(256) void gate_norm_kernel(const float* __restrict__ yb,
        const float* __restrict__ zx, const float* __restrict__ norm_w,
        u16* __restrict__ gnb) {
    const int bl = blockIdx.x;
    const int tid = threadIdx.x;
    const float* yrow = yb + (size_t)bl * DIN;
    const float* zrow = zx + (size_t)bl * DTOT + OFF_Z;
    float g[8];
    float ss = 0.f;
    #pragma unroll
    for (int i = 0; i < 8; ++i) {
        const int c = tid + i * 256;
        const float yv = yrow[c];
        const float zv = zrow[c];
        const float sg = 1.f / (1.f + expf(-zv));
        const float gv = yv * zv * sg;
        g[i] = gv;
        ss += gv * gv;
    }
    #pragma unroll
    for (int k = 1; k < 64; k <<= 1) ss += __shfl_xor(ss, k);
    __shared__ float wsum[4];
    if ((tid & 63) == 0) wsum[tid >> 6] = ss;
    __syncthreads();
    ss = wsum[0] + wsum[1] + wsum[2] + wsum[3];
    const float sc = rsqrtf(ss * (1.f / 2048.f) + 1e-5f);
    #pragma unroll
    for (int i = 0; i < 8; ++i) {
        const int c = tid + i * 256;
        gnb[(size_t)bl * DIN + c] = (u16)f2bf(g[i] * sc * norm_w[c]);
    }
}

// ---------------------------------------------------------------------------
extern "C" void kernel_launch(void* const* d_in, const int* in_sizes, int n_in,
                              void* d_out, int out_size, void* d_ws, size_t ws_size,
                              hipStream_t stream) {
    const float* u          = (const float*)d_in[0];
    const float* in_proj_w  = (const float*)d_in[1];
    const float* dt_bias    = (const float*)d_in[2];
    const float* A_log      = (const float*)d_in[3];
    const float* Dp         = (const float*)d_in[4];
    const float* B_norm_w   = (const float*)d_in[5];
    const float* C_norm_w   = (const float*)d_in[6];
    const float* B_bias     = (const float*)d_in[7];
    const float* C_bias     = (const float*)d_in[8];
    const float* norm_w     = (const float*)d_in[9];
    const float* out_proj_w = (const float*)d_in[10];
    float* out = (float*)d_out;

    float* p = (float*)d_ws;
    float* zx    = p; p += (size_t)ROWS * DTOT;
    float* th_cs = p; p += (size_t)ROWS * 1024;   // dead after rot -> hseg
    float* Brot  = p; p += (size_t)ROWS * 2048;   // doubles as bf16 scratch
    float* Crot  = p; p += (size_t)ROWS * 2048;
    float* Bg    = p; p += (size_t)ROWS * 64;     // dead after rot -> aprod/bscale/Lbuf
    float* Cg    = p; p += (size_t)ROWS * 64;     // dead after rot -> wbuf
    float4* abg4 = (float4*)p; p += (size_t)ROWS * NH * 4;
    float* yb    = p; p += (size_t)ROWS * 2048;
    float* hseg   = th_cs;                        // 2,097,152 floats
    float* aprod  = Bg;                           // 512
    float* bscale = Bg + 512;                     // 512
    float* Lbuf   = Bg + 2048;                    // 65,536 (Bg has 131,072)
    float* wbuf   = Cg;                           // 65,536

    // Phase-A bf16 scratch inside Brot+Crot (consumed before rot writes them):
    u16* u_bf = (u16*)Brot;
    u16* u_lo = u_bf + (size_t)ROWS * DMODEL;
    u16* w_bf = u_lo + (size_t)ROWS * DMODEL;
    u16* w_lo = w_bf + (size_t)DTOT * DMODEL;
    // Phase-B (after ssd_y, Brot/Crot dead again):
    u16* gn_bf = (u16*)Brot;
    u16* wo_bf = gn_bf + (size_t)ROWS * DIN;

    // 0. one-time fp32 -> bf16 (+residual) conversions
    conv_u<<<(ROWS * DMODEL / 4) / 256, 256, 0, stream>>>(u, u_bf, u_lo);
    conv_w<<<((size_t)DTOT * DMODEL / 4) / 256, 256, 0, stream>>>(in_proj_w, w_bf, w_lo);
    // 1a/1b. in_proj GEMMs
    mfma_gemm_zx<<<dim3(NZX / 128, ROWS / 128), 256, 0, stream>>>(u_bf, w_bf, zx);
    mfma_gemm_rem3<<<dim3(NREM / 64, ROWS / 128), 256, 0, stream>>>(
        u_bf, u_lo, w_bf + (size_t)NZX * DMODEL, w_lo, zx + NZX);
    // 2. per-row prep (abg4.w = beta')
    prep_kernel<<<ROWS, 64, 0, stream>>>(zx, dt_bias, A_log, B_norm_w, C_norm_w,
                                         Bg, Cg, abg4);
    // 3. cumsum of theta over L
    cumsum_kernel<<<BB * NH, 256, 0, stream>>>(zx, th_cs);
    // 4. rotary on B/C
    rot_kernel<<<(ROWS * 1024) / 256, 256, 0, stream>>>(th_cs, Bg, Cg, B_bias, C_bias,
                                                        Brot, Crot);
    // 5. segmented scan: weights -> h_end GEMM -> fixup -> SSD output blocks
    wcalc_kernel<<<BB * NH, 64, 0, stream>>>(abg4, wbuf, aprod, bscale, Lbuf);
    hseg_gemm<<<BB * NH * NSEG, 256, 0, stream>>>(zx, Brot, wbuf, hseg);
    scan_fix<<<BB * NH * 4, 256, 0, stream>>>(hseg, aprod, bscale, zx, Brot, abg4);
    ssd_y<<<BB * NH * NSEG, 256, 0, stream>>>(zx, Brot, Crot, abg4, hseg, Lbuf, Dp, yb);
    // 6-8. epilogue
    conv_wo<<<(DMODEL * DIN / 4) / 256, 256, 0, stream>>>(out_proj_w, wo_bf);
    gate_norm_kernel<<<ROWS, 256, 0, stream>>>(yb, zx, norm_w, gn_bf);
    mfma_gemm_out<<<dim3(DMODEL / 64, ROWS / 128), 256, 0, stream>>>(
        gn_bf, wo_bf, out, DIN, DMODEL);
}

// Round 19
// 197.145 us; speedup vs baseline: 1.7957x; 1.0073x over previous
//
#include <hip/hip_runtime.h>
#include <hip/hip_bf16.h>

// Problem constants
#define DMODEL 1024
#define DIN    2048
#define NH     32
#define HD     64
#define DS     64
#define LSEQ   1024
#define BB     2
#define DTOT   5312           // 2*DIN + 2*64 + 32 + 1024 + 32
#define ROWS   (BB*LSEQ)      // 2048
// column offsets inside zxbcdt
#define OFF_Z   0
#define OFF_X   2048
#define OFF_BR  4096
#define OFF_CR  4160
#define OFF_DT  4224
#define OFF_TH  4256
#define OFF_LAM 5280
#define NZX     4096          // z+x columns: single-pass bf16 MFMA
#define NREM    (DTOT - NZX)  // 1216 cols: 3-pass split-bf16 MFMA
// segmented scan
#define NSEG 8
#define SEG  (LSEQ / NSEG)    // 128

typedef short  s16x8 __attribute__((ext_vector_type(8)));
typedef float  f32x4 __attribute__((ext_vector_type(4)));
typedef unsigned short u16;

__device__ __forceinline__ unsigned int f2bf(float f) {   // RNE f32->bf16 (finite inputs)
    unsigned int u = __float_as_uint(f);
    u += 0x7fffu + ((u >> 16) & 1u);
    return u >> 16;
}
__device__ __forceinline__ unsigned int pk(float x, float y) {
    return f2bf(x) | (f2bf(y) << 16);
}
__device__ __forceinline__ void split1(float v, u16& hi, u16& lo) {
    const unsigned int h = f2bf(v);
    hi = (u16)h;
    lo = (u16)f2bf(v - __uint_as_float(h << 16));
}
__device__ __forceinline__ void split8(const float4 a, const float4 b,
                                       s16x8& hi, s16x8& lo) {
    u16 h_, l_;
    split1(a.x, h_, l_); hi[0] = (short)h_; lo[0] = (short)l_;
    split1(a.y, h_, l_); hi[1] = (short)h_; lo[1] = (short)l_;
    split1(a.z, h_, l_); hi[2] = (short)h_; lo[2] = (short)l_;
    split1(a.w, h_, l_); hi[3] = (short)h_; lo[3] = (short)l_;
    split1(b.x, h_, l_); hi[4] = (short)h_; lo[4] = (short)l_;
    split1(b.y, h_, l_); hi[5] = (short)h_; lo[5] = (short)l_;
    split1(b.z, h_, l_); hi[6] = (short)h_; lo[6] = (short)l_;
    split1(b.w, h_, l_); hi[7] = (short)h_; lo[7] = (short)l_;
}
__device__ __forceinline__ void cvt8(const float4 a, const float4 b, s16x8& hi) {
    hi[0] = (short)f2bf(a.x); hi[1] = (short)f2bf(a.y);
    hi[2] = (short)f2bf(a.z); hi[3] = (short)f2bf(a.w);
    hi[4] = (short)f2bf(b.x); hi[5] = (short)f2bf(b.y);
    hi[6] = (short)f2bf(b.z); hi[7] = (short)f2bf(b.w);
}

// HBM -> LDS direct 16B copy. Dest = wave-uniform base + lane*16 (m104).
typedef const __attribute__((address_space(1))) unsigned int glb_u32;
typedef __attribute__((address_space(3))) unsigned int lds_u32;
__device__ __forceinline__ void gload16(const void* g, void* l) {
    __builtin_amdgcn_global_load_lds((glb_u32*)g, (lds_u32*)l, 16, 0, 0);
}

// XOR swizzle for [row][32]-u16 GEMM tiles (64B rows): spread the 16-lane
// frag-read groups across all 8 16B slot positions (8-way -> 2-way banks).
// Involution; applied to the global SOURCE chunk at stage time and to the
// LDS read index (rule #21: linear gload_lds dest + inverse-swz source).
#define SWZ(row) (((row) >> 1) & 3)

// ---------------------------------------------------------------------------
// conversion kernels: fp32 -> bf16 (hi) and residual (lo).
// ---------------------------------------------------------------------------
__global__ __launch_bounds__(256) void conv_u(const float* __restrict__ src,
        u16* __restrict__ hi, u16* __restrict__ lo) {
    const size_t i4 = ((size_t)blockIdx.x * 256 + threadIdx.x) * 4;
    const float4 v = *(const float4*)(src + i4);
    const unsigned int h0 = f2bf(v.x), h1 = f2bf(v.y), h2 = f2bf(v.z), h3 = f2bf(v.w);
    uint2 hw, lw;
    hw.x = h0 | (h1 << 16); hw.y = h2 | (h3 << 16);
    lw.x = pk(v.x - __uint_as_float(h0 << 16), v.y - __uint_as_float(h1 << 16));
    lw.y = pk(v.z - __uint_as_float(h2 << 16), v.w - __uint_as_float(h3 << 16));
    *(uint2*)(hi + i4) = hw;
    *(uint2*)(lo + i4) = lw;
}

__global__ __launch_bounds__(256) void conv_w(const float* __restrict__ src,
        u16* __restrict__ hi, u16* __restrict__ lo) {
    const size_t i4 = ((size_t)blockIdx.x * 256 + threadIdx.x) * 4;
    const float4 v = *(const float4*)(src + i4);
    const unsigned int h0 = f2bf(v.x), h1 = f2bf(v.y), h2 = f2bf(v.z), h3 = f2bf(v.w);
    uint2 hw, lw;
    hw.x = h0 | (h1 << 16); hw.y = h2 | (h3 << 16);
    lw.x = pk(v.x - __uint_as_float(h0 << 16), v.y - __uint_as_float(h1 << 16));
    lw.y = pk(v.z - __uint_as_float(h2 << 16), v.w - __uint_as_float(h3 << 16));
    *(uint2*)(hi + i4) = hw;
    if ((i4 >> 10) >= NZX)
        *(uint2*)(lo + (i4 - (size_t)NZX * DMODEL)) = lw;
}

__global__ __launch_bounds__(256) void conv_wo(const float* __restrict__ src,
        u16* __restrict__ hi) {
    const size_t i4 = ((size_t)blockIdx.x * 256 + threadIdx.x) * 4;
    const float4 v = *(const float4*)(src + i4);
    uint2 hw;
    hw.x = pk(v.x, v.y); hw.y = pk(v.z, v.w);
    *(uint2*)(hi + i4) = hw;
}

// ---------------------------------------------------------------------------
// bf16 MFMA GEMM, z/x block (2-phase dbuf global_load_lds, XOR-swizzled tiles)
// ---------------------------------------------------------------------------
__global__ __launch_bounds__(256) void mfma_gemm_zx(const u16* __restrict__ uA_,
                                                    const u16* __restrict__ uW,
                                                    float* __restrict__ zx) {
    __shared__ u16 Al[2][128 * 32];
    __shared__ u16 Bl[2][128 * 32];
    const int tid = threadIdx.x;
    const int m0 = blockIdx.y * 128, n0 = blockIdx.x * 128;
    const int lane = tid & 63, wave = tid >> 6;
    const int wr = wave >> 1, wc = wave & 1;
    const int lr = lane >> 4, lc = lane & 15;
    const int sr = tid >> 2;                              // staging row 0..63
    const int sc = (((tid & 3) ^ SWZ(tid >> 2)) * 8);     // pre-swizzled chunk

    f32x4 acc[4][4] = {};

    const u16* pA = uA_ + (size_t)(m0 + sr) * DMODEL + sc;
    const u16* pB = uW  + (size_t)(n0 + sr) * DMODEL + sc;

#define STAGE_ZX(buf, k0) {                                              \
        gload16(pA + (k0), &Al[buf][tid * 8]);                           \
        gload16(pA + (k0) + (size_t)64 * DMODEL, &Al[buf][tid * 8 + 2048]); \
        gload16(pB + (k0), &Bl[buf][tid * 8]);                           \
        gload16(pB + (k0) + (size_t)64 * DMODEL, &Bl[buf][tid * 8 + 2048]); }

    STAGE_ZX(0, 0);
    __syncthreads();
    int cur = 0;
    for (int k0 = 0; k0 < DMODEL; k0 += 32) {
        if (k0 + 32 < DMODEL) STAGE_ZX(cur ^ 1, k0 + 32);
        s16x8 af[4], bf[4];
        #pragma unroll
        for (int f = 0; f < 4; ++f) {
            const int ra = wr * 64 + f * 16 + lc;
            af[f] = *(const s16x8*)&Al[cur][ra * 32 + ((lr ^ SWZ(ra)) * 8)];
            const int rb = wc * 64 + f * 16 + lc;
            bf[f] = *(const s16x8*)&Bl[cur][rb * 32 + ((lr ^ SWZ(rb)) * 8)];
        }
        #pragma unroll
        for (int fm = 0; fm < 4; ++fm)
            #pragma unroll
            for (int fn = 0; fn < 4; ++fn)
                acc[fm][fn] = __builtin_amdgcn_mfma_f32_16x16x32_bf16(
                    af[fm], bf[fn], acc[fm][fn], 0, 0, 0);
        __syncthreads();
        cur ^= 1;
    }
#undef STAGE_ZX

    #pragma unroll
    for (int fm = 0; fm < 4; ++fm)
        #pragma unroll
        for (int fn = 0; fn < 4; ++fn) {
            const size_t col = n0 + wc * 64 + fn * 16 + lc;
            #pragma unroll
            for (int j = 0; j < 4; ++j) {
                const size_t row = m0 + wr * 64 + fm * 16 + lr * 4 + j;
                zx[row * DTOT + col] = acc[fm][fn][j];
            }
        }
}

// ---------------------------------------------------------------------------
// bf16 MFMA GEMM, 128x64 tile, 2-phase dbuf (swizzled): out = gn_bf @ wo_bf^T
// ---------------------------------------------------------------------------
__global__ __launch_bounds__(256) void mfma_gemm_out(const u16* __restrict__ A,
                                                     const u16* __restrict__ B,
                                                     float* __restrict__ C,
                                                     int K, int ldc) {
    __shared__ u16 Als[2][128 * 32];
    __shared__ u16 Bls[2][64 * 32];
    const int tid = threadIdx.x;
    const int m0 = blockIdx.y * 128, n0 = blockIdx.x * 64;
    const int lane = tid & 63, wave = tid >> 6;
    const int wr = wave >> 1, wc = wave & 1;
    const int lr = lane >> 4, lc = lane & 15;
    const int sr = tid >> 2;
    const int sc = (((tid & 3) ^ SWZ(tid >> 2)) * 8);

    f32x4 acc[4][2] = {};

    const u16* pA = A + (size_t)(m0 + sr) * K + sc;
    const u16* pB = B + (size_t)(n0 + sr) * K + sc;

#define STAGE_OUT(buf, k0) {                                             \
        gload16(pA + (k0), &Als[buf][tid * 8]);                          \
        gload16(pA + (k0) + (size_t)64 * K, &Als[buf][tid * 8 + 2048]);  \
        gload16(pB + (k0), &Bls[buf][tid * 8]); }

    STAGE_OUT(0, 0);
    __syncthreads();
    int cur = 0;
    for (int k0 = 0; k0 < K; k0 += 32) {
        if (k0 + 32 < K) STAGE_OUT(cur ^ 1, k0 + 32);
        s16x8 af[4], bf[2];
        #pragma unroll
        for (int f = 0; f < 4; ++f) {
            const int ra = wr * 64 + f * 16 + lc;
            af[f] = *(const s16x8*)&Als[cur][ra * 32 + ((lr ^ SWZ(ra)) * 8)];
        }
        #pragma unroll
        for (int f = 0; f < 2; ++f) {
            const int rb = wc * 32 + f * 16 + lc;
            bf[f] = *(const s16x8*)&Bls[cur][rb * 32 + ((lr ^ SWZ(rb)) * 8)];
        }
        #pragma unroll
        for (int fm = 0; fm < 4; ++fm)
            #pragma unroll
            for (int fn = 0; fn < 2; ++fn)
                acc[fm][fn] = __builtin_amdgcn_mfma_f32_16x16x32_bf16(
                    af[fm], bf[fn], acc[fm][fn], 0, 0, 0);
        __syncthreads();
        cur ^= 1;
    }
#undef STAGE_OUT

    #pragma unroll
    for (int fm = 0; fm < 4; ++fm)
        #pragma unroll
        for (int fn = 0; fn < 2; ++fn) {
            const size_t col = n0 + wc * 32 + fn * 16 + lc;
            #pragma unroll
            for (int j = 0; j < 4; ++j) {
                const size_t row = m0 + wr * 64 + fm * 16 + lr * 4 + j;
                C[row * (size_t)ldc + col] = acc[fm][fn][j];
            }
        }
}

// ---------------------------------------------------------------------------
// split-bf16 3-pass MFMA GEMM, sensitive columns (2-phase dbuf, swizzled)
// ---------------------------------------------------------------------------
__global__ __launch_bounds__(256) void mfma_gemm_rem3(const u16* __restrict__ uh,
        const u16* __restrict__ ul, const u16* __restrict__ wh,
        const u16* __restrict__ wl, float* __restrict__ zxr) {
    __shared__ u16 Ah[2][128 * 32], Alo[2][128 * 32];
    __shared__ u16 Bh[2][64 * 32],  Blo[2][64 * 32];
    const int tid = threadIdx.x;
    const int m0 = blockIdx.y * 128, n0 = blockIdx.x * 64;
    const int lane = tid & 63, wave = tid >> 6;
    const int wr = wave >> 1, wc = wave & 1;
    const int lr = lane >> 4, lc = lane & 15;
    const int sr = tid >> 2;
    const int sc = (((tid & 3) ^ SWZ(tid >> 2)) * 8);

    f32x4 acc[4][2] = {};

    const u16* pAh = uh + (size_t)(m0 + sr) * DMODEL + sc;
    const u16* pAl = ul + (size_t)(m0 + sr) * DMODEL + sc;
    const u16* pBh = wh + (size_t)(n0 + sr) * DMODEL + sc;
    const u16* pBl = wl + (size_t)(n0 + sr) * DMODEL + sc;

#define STAGE_R3(buf, k0) {                                                  \
        gload16(pAh + (k0), &Ah[buf][tid * 8]);                              \
        gload16(pAh + (k0) + (size_t)64 * DMODEL, &Ah[buf][tid * 8 + 2048]); \
        gload16(pAl + (k0), &Alo[buf][tid * 8]);                             \
        gload16(pAl + (k0) + (size_t)64 * DMODEL, &Alo[buf][tid * 8 + 2048]);\
        gload16(pBh + (k0), &Bh[buf][tid * 8]);                              \
        gload16(pBl + (k0), &Blo[buf][tid * 8]); }

    STAGE_R3(0, 0);
    __syncthreads();
    int cur = 0;
    for (int k0 = 0; k0 < DMODEL; k0 += 32) {
        if (k0 + 32 < DMODEL) STAGE_R3(cur ^ 1, k0 + 32);
        s16x8 ahf[4], alf[4], bhf[2], blf[2];
        #pragma unroll
        for (int f = 0; f < 4; ++f) {
            const int ra = wr * 64 + f * 16 + lc;
            const int oa = ra * 32 + ((lr ^ SWZ(ra)) * 8);
            ahf[f] = *(const s16x8*)&Ah[cur][oa];
            alf[f] = *(const s16x8*)&Alo[cur][oa];
        }
        #pragma unroll
        for (int f = 0; f < 2; ++f) {
            const int rb = wc * 32 + f * 16 + lc;
            const int ob = rb * 32 + ((lr ^ SWZ(rb)) * 8);
            bhf[f] = *(const s16x8*)&Bh[cur][ob];
            blf[f] = *(const s16x8*)&Blo[cur][ob];
        }
        #pragma unroll
        for (int fm = 0; fm < 4; ++fm)
            #pragma unroll
            for (int fn = 0; fn < 2; ++fn) {
                acc[fm][fn] = __builtin_amdgcn_mfma_f32_16x16x32_bf16(
                    ahf[fm], bhf[fn], acc[fm][fn], 0, 0, 0);
                acc[fm][fn] = __builtin_amdgcn_mfma_f32_16x16x32_bf16(
                    ahf[fm], blf[fn], acc[fm][fn], 0, 0, 0);
                acc[fm][fn] = __builtin_amdgcn_mfma_f32_16x16x32_bf16(
                    alf[fm], bhf[fn], acc[fm][fn], 0, 0, 0);
            }
        __syncthreads();
        cur ^= 1;
    }
#undef STAGE_R3

    #pragma unroll
    for (int fm = 0; fm < 4; ++fm)
        #pragma unroll
        for (int fn = 0; fn < 2; ++fn) {
            const size_t col = n0 + wc * 32 + fn * 16 + lc;
            #pragma unroll
            for (int j = 0; j < 4; ++j) {
                const size_t row = m0 + wr * 64 + fm * 16 + lr * 4 + j;
                zxr[row * DTOT + col] = acc[fm][fn][j];
            }
        }
}

// ---------------------------------------------------------------------------
// prep: RMS-norm Br/Cr; abg4 = (alpha, beta, gamma, beta'=(1-lam)*dt) in (b,h,l).
// ---------------------------------------------------------------------------
__global__ __launch_bounds__(64) void prep_kernel(const float* __restrict__ zx,
        const float* __restrict__ dt_bias, const float* __restrict__ A_log,
        const float* __restrict__ B_norm_w, const float* __restrict__ C_norm_w,
        float* __restrict__ Bg, float* __restrict__ Cg,
        float4* __restrict__ abg4) {
    const int bl = blockIdx.x;
    const int b = bl >> 10, l = bl & (LSEQ - 1);
    const int t  = threadIdx.x;
    const float* row = zx + (size_t)bl * DTOT;
    const float br = row[OFF_BR + t];
    const float cr = row[OFF_CR + t];
    float ssb = br * br, ssc = cr * cr;
    #pragma unroll
    for (int k = 1; k < 64; k <<= 1) { ssb += __shfl_xor(ssb, k); ssc += __shfl_xor(ssc, k); }
    const float scB = rsqrtf(ssb * (1.f / 64.f) + 1e-5f);
    const float scC = rsqrtf(ssc * (1.f / 64.f) + 1e-5f);
    Bg[(size_t)bl * 64 + t] = br * scB * B_norm_w[t];
    Cg[(size_t)bl * 64 + t] = cr * scC * C_norm_w[t];
    if (t < NH) {
        const float dtr = row[OFF_DT + t] + dt_bias[t];
        const float dt  = (dtr > 20.f) ? dtr : log1pf(expf(dtr));
        const float lamr = row[OFF_LAM + t];
        const float lam  = 1.f / (1.f + expf(-lamr));
        const float Ah   = -expf(A_log[t]);
        const float al   = expf(dt * Ah);
        const float bp   = (1.f - lam) * dt;            // beta' = b/a
        const size_t o = ((size_t)b * NH + t) * LSEQ + l;
        abg4[o] = make_float4(al, bp * al, lam * dt, bp);
    }
}

// ---------------------------------------------------------------------------
// cumsum of thr over L, per (b,h): 32 dims.
// ---------------------------------------------------------------------------
__global__ __launch_bounds__(256) void cumsum_kernel(const float* __restrict__ zx,
                                                     float* __restrict__ th_cs) {
    const int bh = blockIdx.x;
    const int b = bh >> 5, h = bh & 31;
    const int d = threadIdx.x & 31, seg = threadIdx.x >> 5;
    const float* base = zx + (size_t)b * LSEQ * DTOT + OFF_TH + h * 32 + d;
    float* out = th_cs + (size_t)b * LSEQ * 1024 + h * 32 + d;
    __shared__ float sums[8][33];
    const int l0 = seg * 128;
    float s = 0.f;
    #pragma unroll 4
    for (int i = 0; i < 128; ++i) s += base[(size_t)(l0 + i) * DTOT];
    sums[seg][d] = s;
    __syncthreads();
    float acc = 0.f;
    for (int s2 = 0; s2 < seg; ++s2) acc += sums[s2][d];
    #pragma unroll 4
    for (int i = 0; i < 128; ++i) {
        acc += base[(size_t)(l0 + i) * DTOT];
        out[(size_t)(l0 + i) * 1024] = acc;
    }
}

// ---------------------------------------------------------------------------
// rot: Bh/Ch = rot(broadcast(Bg/Cg)+bias). Brot/Crot layout (B,NH,L,DS).
// ---------------------------------------------------------------------------
__global__ __launch_bounds__(256) void rot_kernel(const float* __restrict__ th_cs,
        const float* __restrict__ Bg, const float* __restrict__ Cg,
        const float* __restrict__ B_bias, const float* __restrict__ C_bias,
        float* __restrict__ Brot, float* __restrict__ Crot) {
    const size_t idx = (size_t)blockIdx.x * 256 + threadIdx.x;
    const int j = (int)(idx & 31);
    const int h = (int)((idx >> 5) & 31);
    const size_t bl = idx >> 10;
    const int l = (int)(bl & (LSEQ - 1));
    const int b = (int)(bl >> 10);
    const float th = th_cs[idx];
    float s, c;
    sincosf(th, &s, &c);
    float v1 = Bg[bl * 64 + j]      + B_bias[h * 64 + j];
    float v2 = Bg[bl * 64 + 32 + j] + B_bias[h * 64 + 32 + j];
    const size_t ob = ((size_t)(b * NH + h) * LSEQ + l) * DS + j;
    Brot[ob]      = v1 * c - v2 * s;
    Brot[ob + 32] = v1 * s + v2 * c;
    v1 = Cg[bl * 64 + j]      + C_bias[h * 64 + j];
    v2 = Cg[bl * 64 + 32 + j] + C_bias[h * 64 + 32 + j];
    Crot[ob]      = v1 * c - v2 * s;
    Crot[ob + 32] = v1 * s + v2 * c;
}

// ---------------------------------------------------------------------------
// wcalc: per (b,h,seg): within-seg log-cumsum of alpha; emits
//   wbuf[t], Lbuf[t], aprod[s], bscale[s]  (round 13/15 derivation)
// ---------------------------------------------------------------------------
__global__ __launch_bounds__(64) void wcalc_kernel(const float4* __restrict__ abg4,
        float* __restrict__ wbuf, float* __restrict__ aprod,
        float* __restrict__ bscale, float* __restrict__ Lbuf) {
    const int bh = blockIdx.x;
    const int lane = threadIdx.x;
    const int seg = lane >> 3, sub = lane & 7;
    const int t0 = seg * SEG;
    const int sbase = t0 + sub * 16;
    const float4* ab = abg4 + (size_t)bh * LSEQ;

    float part = 0.f;
    #pragma unroll
    for (int i = 0; i < 16; ++i) part += logf(ab[sbase + i].x);
    float incl = part;
    #pragma unroll
    for (int d = 1; d < 8; d <<= 1) {
        const float v = __shfl_up(incl, d, 8);
        if (sub >= d) incl += v;
    }
    const float LE = __shfl(incl, 7, 8);
    float Lrun = incl - part;                // exclusive prefix

    for (int i = 0; i < 16; ++i) {
        const int s = sbase + i;
        const float4 A = ab[s];
        Lrun += logf(A.x);
        Lbuf[(size_t)bh * LSEQ + s] = Lrun;
        float w;
        if ((s & (SEG - 1)) == (SEG - 1)) w = A.z;
        else w = __expf(LE - Lrun) * (A.z + ab[s + 1].w);
        wbuf[(size_t)bh * LSEQ + s] = w;
    }
    if (sub == 0) {
        aprod[bh * NSEG + seg] = __expf(LE);
        bscale[bh * NSEG + seg] = (seg > 0) ? __expf(LE) * ab[t0].w : 0.f;
    }
}

// ---------------------------------------------------------------------------
// hseg_gemm: h_local_end[p,n] = sum_s wbuf_s * x_s[p] * B_s[n] (split-bf16 3-pass)
// ---------------------------------------------------------------------------
#define WK 136
__global__ __launch_bounds__(256) void hseg_gemm(const float* __restrict__ zx,
        const float* __restrict__ Brot, const float* __restrict__ wbuf,
        float* __restrict__ hseg) {
    __shared__ u16 XH[64][WK], XL[64][WK], BHs[64][WK], BLs[64][WK];
    const int blk = blockIdx.x;
    const int seg = blk & (NSEG - 1), bh = blk >> 3;
    const int b = bh >> 5, h = bh & 31;
    const int tid = threadIdx.x;

    {
        const int sIdx = tid >> 1, half = tid & 1;
        const int t = seg * SEG + sIdx;
        const float wv = wbuf[(size_t)bh * LSEQ + t];
        const float* xsrc = zx + ((size_t)b * LSEQ + t) * DTOT + OFF_X + h * 64 + half * 32;
        const float* bsrc = Brot + ((size_t)bh * LSEQ + t) * DS + half * 32;
        #pragma unroll
        for (int i = 0; i < 32; i += 4) {
            const float4 xv = *(const float4*)(xsrc + i);
            const float4 bv = *(const float4*)(bsrc + i);
            const int p0 = half * 32 + i;
            u16 hi, lo;
            split1(xv.x * wv, hi, lo); XH[p0 + 0][sIdx] = hi; XL[p0 + 0][sIdx] = lo;
            split1(xv.y * wv, hi, lo); XH[p0 + 1][sIdx] = hi; XL[p0 + 1][sIdx] = lo;
            split1(xv.z * wv, hi, lo); XH[p0 + 2][sIdx] = hi; XL[p0 + 2][sIdx] = lo;
            split1(xv.w * wv, hi, lo); XH[p0 + 3][sIdx] = hi; XL[p0 + 3][sIdx] = lo;
            split1(bv.x, hi, lo); BHs[p0 + 0][sIdx] = hi; BLs[p0 + 0][sIdx] = lo;
            split1(bv.y, hi, lo); BHs[p0 + 1][sIdx] = hi; BLs[p0 + 1][sIdx] = lo;
            split1(bv.z, hi, lo); BHs[p0 + 2][sIdx] = hi; BLs[p0 + 2][sIdx] = lo;
            split1(bv.w, hi, lo); BHs[p0 + 3][sIdx] = hi; BLs[p0 + 3][sIdx] = lo;
        }
    }
    __syncthreads();

    const int lane = tid & 63, wave = tid >> 6;
    const int wR = wave >> 1, wC = wave & 1;
    const int lr = lane >> 4, lc = lane & 15;

    f32x4 acc[2][2] = {};
    #pragma unroll
    for (int ks = 0; ks < 4; ++ks) {
        const int k0 = ks * 32;
        s16x8 xh[2], xl[2], bhf[2], blf[2];
        #pragma unroll
        for (int f = 0; f < 2; ++f) {
            const int pr = wR * 32 + f * 16 + lc;
            xh[f] = *(const s16x8*)&XH[pr][k0 + lr * 8];
            xl[f] = *(const s16x8*)&XL[pr][k0 + lr * 8];
            const int nr = wC * 32 + f * 16 + lc;
            bhf[f] = *(const s16x8*)&BHs[nr][k0 + lr * 8];
            blf[f] = *(const s16x8*)&BLs[nr][k0 + lr * 8];
        }
        #pragma unroll
        for (int fm = 0; fm < 2; ++fm)
            #pragma unroll
            for (int fn = 0; fn < 2; ++fn) {
                acc[fm][fn] = __builtin_amdgcn_mfma_f32_16x16x32_bf16(
                    xh[fm], bhf[fn], acc[fm][fn], 0, 0, 0);
                acc[fm][fn] = __builtin_amdgcn_mfma_f32_16x16x32_bf16(
                    xh[fm], blf[fn], acc[fm][fn], 0, 0, 0);
                acc[fm][fn] = __builtin_amdgcn_mfma_f32_16x16x32_bf16(
                    xl[fm], bhf[fn], acc[fm][fn], 0, 0, 0);
            }
    }

    float* hp = hseg + ((size_t)(bh * NSEG + seg) * HD) * DS;
    #pragma unroll
    for (int fm = 0; fm < 2; ++fm)
        #pragma unroll
        for (int fn = 0; fn < 2; ++fn) {
            const int n = wC * 32 + fn * 16 + lc;
            #pragma unroll
            for (int j = 0; j < 4; ++j) {
                const int p = wR * 32 + fm * 16 + lr * 4 + j;
                hp[p * DS + n] = acc[fm][fn][j];
            }
        }
}

// ---------------------------------------------------------------------------
// scan_fix: sequential over segments -> hseg becomes hstar per segment.
// ---------------------------------------------------------------------------
__global__ __launch_bounds__(256) void scan_fix(float* __restrict__ hseg,
        const float* __restrict__ aprod, const float* __restrict__ bscale,
        const float* __restrict__ zx, const float* __restrict__ Brot,
        const float4* __restrict__ abg4) {
    const int blk = blockIdx.x;          // (b,h,ptile): 256
    const int ptile = blk & 3, h = (blk >> 2) & 31, b = blk >> 7;
    const int tid = threadIdx.x;
    const int pl = tid >> 4, ng = tid & 15;
    const int p = ptile * 16 + pl;
    const int n0 = ng * 4;
    const size_t bh = (size_t)b * NH + h;

    float4 cur = make_float4(0.f, 0.f, 0.f, 0.f);
    #pragma unroll
    for (int s = 0; s < NSEG; ++s) {
        float* hp = hseg + (((bh * NSEG + s) * HD + p) * DS + n0);
        float4 tmp = *(const float4*)hp;     // local h_end (no boundary)
        float4 hst = cur;                    // hstar = h_start (+ r1 below)
        if (s > 0) {
            const float bs = bscale[bh * NSEG + s];          // aprod*beta'
            const float bp0 = abg4[bh * LSEQ + s * SEG].w;   // beta'_{t0}
            const int tm1 = s * SEG - 1;
            const float4 Bm = *(const float4*)(Brot + ((size_t)bh * LSEQ + tm1) * DS + n0);
            const float xm = zx[((size_t)b * LSEQ + tm1) * DTOT + OFF_X + h * HD + p];
            const float fb = bs * xm;
            const float f1 = bp0 * xm;
            tmp.x = fmaf(fb, Bm.x, tmp.x);
            tmp.y = fmaf(fb, Bm.y, tmp.y);
            tmp.z = fmaf(fb, Bm.z, tmp.z);
            tmp.w = fmaf(fb, Bm.w, tmp.w);
            hst.x = fmaf(f1, Bm.x, hst.x);
            hst.y = fmaf(f1, Bm.y, hst.y);
            hst.z = fmaf(f1, Bm.z, hst.z);
            hst.w = fmaf(f1, Bm.w, hst.w);
        }
        *(float4*)hp = hst;
        const float a = aprod[bh * NSEG + s];
        cur.x = fmaf(a, cur.x, tmp.x);
        cur.y = fmaf(a, cur.y, tmp.y);
        cur.z = fmaf(a, cur.z, tmp.z);
        cur.w = fmaf(a, cur.w, tmp.w);
    }
}

// ---------------------------------------------------------------------------
// ssd_y v3: C/B/H fragments from global (L2); Gw fp32 in LDS with D folded
// into the diagonal; X^T staged in LDS in two 64-step halves. 2 blocks/CU.
// ---------------------------------------------------------------------------
#define GWF 132
#define XTS 72
__global__ __launch_bounds__(256, 2) void ssd_y(const float* __restrict__ zx,
        const float* __restrict__ Brot, const float* __restrict__ Crot,
        const float4* __restrict__ abg4, const float* __restrict__ hseg,
        const float* __restrict__ Lbuf, const float* __restrict__ Dp,
        float* __restrict__ yb) {
    __shared__ float Gw[128 * GWF];
    __shared__ u16 XTh[64 * XTS];
    __shared__ float Ls[128], gbs[128], gms[128], eLs[128];

    const int blk = blockIdx.x;
    const int seg = blk & (NSEG - 1), bh = blk >> 3;
    const int b = bh >> 5, h = bh & 31;
    const int tid = threadIdx.x;
    const int t0 = seg * SEG;
    const int lane = tid & 63, wave = tid >> 6;
    const int wr = wave >> 1, wc = wave & 1;
    const int lr = lane >> 4, lc = lane & 15;

    if (tid < 128) {
        const int t = t0 + tid;
        const float4 A = abg4[(size_t)bh * LSEQ + t];
        const float Lv = Lbuf[(size_t)bh * LSEQ + t];
        Ls[tid] = Lv;
        gms[tid] = A.z;
        gbs[tid] = (tid < 127) ? A.z + abg4[(size_t)bh * LSEQ + t + 1].w : 0.f;
        eLs[tid] = __expf(Lv);
    }
    __syncthreads();

    const float* Cbase = Crot + ((size_t)bh * LSEQ + t0) * DS;
    const float* Bbase = Brot + ((size_t)bh * LSEQ + t0) * DS;
    const float* Hbase = hseg + ((size_t)(bh * NSEG + seg) * HD) * DS;
    const float* Xbase = zx + ((size_t)b * LSEQ + t0) * DTOT + OFF_X + h * 64;

    f32x4 accP[4][2] = {};
    f32x4 accG[4][4] = {};
    #pragma unroll
    for (int ks = 0; ks < 2; ++ks) {
        const int k0 = ks * 32 + lr * 8;
        s16x8 ch[4], cl4[4], bh4[4], bl4[4], hh2[2];
        #pragma unroll
        for (int f = 0; f < 4; ++f) {
            const int rowc = wr * 64 + f * 16 + lc;
            const float4 c0 = *(const float4*)(Cbase + (size_t)rowc * DS + k0);
            const float4 c1 = *(const float4*)(Cbase + (size_t)rowc * DS + k0 + 4);
            split8(c0, c1, ch[f], cl4[f]);
            const int rowb = wc * 64 + f * 16 + lc;
            const float4 b0 = *(const float4*)(Bbase + (size_t)rowb * DS + k0);
            const float4 b1 = *(const float4*)(Bbase + (size_t)rowb * DS + k0 + 4);
            split8(b0, b1, bh4[f], bl4[f]);
        }
        #pragma unroll
        for (int f = 0; f < 2; ++f) {
            const int rowp = wc * 32 + f * 16 + lc;
            const float4 h0 = *(const float4*)(Hbase + (size_t)rowp * DS + k0);
            const float4 h1 = *(const float4*)(Hbase + (size_t)rowp * DS + k0 + 4);
            cvt8(h0, h1, hh2[f]);
        }
        #pragma unroll
        for (int fm = 0; fm < 4; ++fm) {
            #pragma unroll
            for (int fn = 0; fn < 4; ++fn) {
                accG[fm][fn] = __builtin_amdgcn_mfma_f32_16x16x32_bf16(
                    ch[fm], bh4[fn], accG[fm][fn], 0, 0, 0);
                accG[fm][fn] = __builtin_amdgcn_mfma_f32_16x16x32_bf16(
                    ch[fm], bl4[fn], accG[fm][fn], 0, 0, 0);
                accG[fm][fn] = __builtin_amdgcn_mfma_f32_16x16x32_bf16(
                    cl4[fm], bh4[fn], accG[fm][fn], 0, 0, 0);
            }
            #pragma unroll
            for (int fn = 0; fn < 2; ++fn) {
                accP[fm][fn] = __builtin_amdgcn_mfma_f32_16x16x32_bf16(
                    ch[fm], hh2[fn], accP[fm][fn], 0, 0, 0);
                accP[fm][fn] = __builtin_amdgcn_mfma_f32_16x16x32_bf16(
                    cl4[fm], hh2[fn], accP[fm][fn], 0, 0, 0);
            }
        }
    }

    const float Dh = Dp[h];
    #pragma unroll
    for (int fm = 0; fm < 4; ++fm)
        #pragma unroll
        for (int fn = 0; fn < 4; ++fn)
            #pragma unroll
            for (int jj = 0; jj < 4; ++jj) {
                const int i = wr * 64 + fm * 16 + lr * 4 + jj;
                const int j = wc * 64 + fn * 16 + lc;
                float v;
                if (j < i)       v = accG[fm][fn][jj] * __expf(Ls[i] - Ls[j]) * gbs[j];
                else if (j == i) v = accG[fm][fn][jj] * gms[i] + Dh;
                else             v = 0.f;
                Gw[i * GWF + j] = v;
            }

    f32x4 accY[4][2];
    #pragma unroll
    for (int fm = 0; fm < 4; ++fm)
        #pragma unroll
        for (int fn = 0; fn < 2; ++fn)
            #pragma unroll
            for (int jj = 0; jj < 4; ++jj) {
                const int i = wr * 64 + fm * 16 + lr * 4 + jj;
                accY[fm][fn][jj] = eLs[i] * accP[fm][fn][jj];
            }

#define STAGE_XT(H) {                                                        \
        const int lp = tid >> 2, pq = (tid & 3) * 16;                        \
        const float* xs = Xbase + (size_t)((H) * 64 + lp) * DTOT + pq;       \
        _Pragma("unroll")                                                    \
        for (int i = 0; i < 16; i += 4) {                                    \
            const float4 xv = *(const float4*)(xs + i);                      \
            XTh[(pq + i + 0) * XTS + lp] = (u16)f2bf(xv.x);                  \
            XTh[(pq + i + 1) * XTS + lp] = (u16)f2bf(xv.y);                  \
            XTh[(pq + i + 2) * XTS + lp] = (u16)f2bf(xv.z);                  \
            XTh[(pq + i + 3) * XTS + lp] = (u16)f2bf(xv.w);                  \
        }                                                                    \
    }
    STAGE_XT(0);
    __syncthreads();

    #pragma unroll
    for (int ks = 0; ks < 4; ++ks) {
        if (ks == 2) {
            __syncthreads();
            STAGE_XT(1);
            __syncthreads();
        }
        const int k0 = ks * 32 + lr * 8;
        const int kl = (ks & 1) * 32 + lr * 8;
        s16x8 gh4[4], gl4[4], xf[2];
        #pragma unroll
        for (int f = 0; f < 4; ++f) {
            const int rowi = wr * 64 + f * 16 + lc;
            const float4 g0 = *(const float4*)&Gw[rowi * GWF + k0];
            const float4 g1 = *(const float4*)&Gw[rowi * GWF + k0 + 4];
            split8(g0, g1, gh4[f], gl4[f]);
        }
        #pragma unroll
        for (int f = 0; f < 2; ++f) {
            const int rowp = wc * 32 + f * 16 + lc;
            xf[f] = *(const s16x8*)&XTh[rowp * XTS + kl];
        }
        #pragma unroll
        for (int fm = 0; fm < 4; ++fm)
            #pragma unroll
            for (int fn = 0; fn < 2; ++fn) {
                accY[fm][fn] = __builtin_amdgcn_mfma_f32_16x16x32_bf16(
                    gh4[fm], xf[fn], accY[fm][fn], 0, 0, 0);
                accY[fm][fn] = __builtin_amdgcn_mfma_f32_16x16x32_bf16(
                    gl4[fm], xf[fn], accY[fm][fn], 0, 0, 0);
            }
    }
#undef STAGE_XT

    #pragma unroll
    for (int fm = 0; fm < 4; ++fm)
        #pragma unroll
        for (int fn = 0; fn < 2; ++fn) {
            const int p = wc * 32 + fn * 16 + lc;
            #pragma unroll
            for (int jj = 0; jj < 4; ++jj) {
                const int i = wr * 64 + fm * 16 + lr * 4 + jj;
                yb[((size_t)b * LSEQ + t0 + i) * DIN + h * 64 + p] = accY[fm][fn][jj];
            }
        }
}

// ---------------------------------------------------------------------------
// gate + final RMS norm; emits bf16 directly for the out_proj GEMM.
// ---------------------------------------------------------------------------
__global__ __launch_bounds__(256) void gate_norm_kernel(const float* __restrict__ yb,
        const float* __restrict__ zx, const float* __restrict__ norm_w,
        u16* __restrict__ gnb) {
    const int bl = blockIdx.x;
    const int tid = threadIdx.x;
    const float* yrow = yb + (size_t)bl * DIN;
    const float* zrow = zx + (size_t)bl * DTOT + OFF_Z;
    float g[8];
    float ss = 0.f;
    #pragma unroll
    for (int i = 0; i < 8; ++i) {
        const int c = tid + i * 256;
        const float yv = yrow[c];
        const float zv = zrow[c];
        const float sg = 1.f / (1.f + expf(-zv));
        const float gv = yv * zv * sg;
        g[i] = gv;
        ss += gv * gv;
    }
    #pragma unroll
    for (int k = 1; k < 64; k <<= 1) ss += __shfl_xor(ss, k);
    __shared__ float wsum[4];
    if ((tid & 63) == 0) wsum[tid >> 6] = ss;
    __syncthreads();
    ss = wsum[0] + wsum[1] + wsum[2] + wsum[3];
    const float sc = rsqrtf(ss * (1.f / 2048.f) + 1e-5f);
    #pragma unroll
    for (int i = 0; i < 8; ++i) {
        const int c = tid + i * 256;
        gnb[(size_t)bl * DIN + c] = (u16)f2bf(g[i] * sc * norm_w[c]);
    }
}

// ---------------------------------------------------------------------------
extern "C" void kernel_launch(void* const* d_in, const int* in_sizes, int n_in,
                              void* d_out, int out_size, void* d_ws, size_t ws_size,
                              hipStream_t stream) {
    const float* u          = (const float*)d_in[0];
    const float* in_proj_w  = (const float*)d_in[1];
    const float* dt_bias    = (const float*)d_in[2];
    const float* A_log      = (const float*)d_in[3];
    const float* Dp         = (const float*)d_in[4];
    const float* B_norm_w   = (const float*)d_in[5];
    const float* C_norm_w   = (const float*)d_in[6];
    const float* B_bias     = (const float*)d_in[7];
    const float* C_bias     = (const float*)d_in[8];
    const float* norm_w     = (const float*)d_in[9];
    const float* out_proj_w = (const float*)d_in[10];
    float* out = (float*)d_out;

    float* p = (float*)d_ws;
    float* zx    = p; p += (size_t)ROWS * DTOT;
    float* th_cs = p; p += (size_t)ROWS * 1024;   // dead after rot -> hseg
    float* Brot  = p; p += (size_t)ROWS * 2048;   // doubles as bf16 scratch
    float* Crot  = p; p += (size_t)ROWS * 2048;
    float* Bg    = p; p += (size_t)ROWS * 64;     // dead after rot -> aprod/bscale/Lbuf
    float* Cg    = p; p += (size_t)ROWS * 64;     // dead after rot -> wbuf
    float4* abg4 = (float4*)p; p += (size_t)ROWS * NH * 4;
    float* yb    = p; p += (size_t)ROWS * 2048;
    float* hseg   = th_cs;
    float* aprod  = Bg;
    float* bscale = Bg + 512;
    float* Lbuf   = Bg + 2048;
    float* wbuf   = Cg;

    u16* u_bf = (u16*)Brot;
    u16* u_lo = u_bf + (size_t)ROWS * DMODEL;
    u16* w_bf = u_lo + (size_t)ROWS * DMODEL;
    u16* w_lo = w_bf + (size_t)DTOT * DMODEL;
    u16* gn_bf = (u16*)Brot;
    u16* wo_bf = gn_bf + (size_t)ROWS * DIN;

    conv_u<<<(ROWS * DMODEL / 4) / 256, 256, 0, stream>>>(u, u_bf, u_lo);
    conv_w<<<((size_t)DTOT * DMODEL / 4) / 256, 256, 0, stream>>>(in_proj_w, w_bf, w_lo);
    mfma_gemm_zx<<<dim3(NZX / 128, ROWS / 128), 256, 0, stream>>>(u_bf, w_bf, zx);
    mfma_gemm_rem3<<<dim3(NREM / 64, ROWS / 128), 256, 0, stream>>>(
        u_bf, u_lo, w_bf + (size_t)NZX * DMODEL, w_lo, zx + NZX);
    prep_kernel<<<ROWS, 64, 0, stream>>>(zx, dt_bias, A_log, B_norm_w, C_norm_w,
                                         Bg, Cg, abg4);
    cumsum_kernel<<<BB * NH, 256, 0, stream>>>(zx, th_cs);
    rot_kernel<<<(ROWS * 1024) / 256, 256, 0, stream>>>(th_cs, Bg, Cg, B_bias, C_bias,
                                                        Brot, Crot);
    wcalc_kernel<<<BB * NH, 64, 0, stream>>>(abg4, wbuf, aprod, bscale, Lbuf);
    hseg_gemm<<<BB * NH * NSEG, 256, 0, stream>>>(zx, Brot, wbuf, hseg);
    scan_fix<<<BB * NH * 4, 256, 0, stream>>>(hseg, aprod, bscale, zx, Brot, abg4);
    ssd_y<<<BB * NH * NSEG, 256, 0, stream>>>(zx, Brot, Crot, abg4, hseg, Lbuf, Dp, yb);
    conv_wo<<<(DMODEL * DIN / 4) / 256, 256, 0, stream>>>(out_proj_w, wo_bf);
    gate_norm_kernel<<<ROWS, 256, 0, stream>>>(yb, zx, norm_w, gn_bf);
    mfma_gemm_out<<<dim3(DMODEL / 64, ROWS / 128), 256, 0, stream>>>(
        gn_bf, wo_bf, out, DIN, DMODEL);
}

// Round 20
// 187.105 us; speedup vs baseline: 1.8920x; 1.0537x over previous
//
#include <hip/hip_runtime.h>
#include <hip/hip_bf16.h>

// Problem constants
#define DMODEL 1024
#define DIN    2048
#define NH     32
#define HD     64
#define DS     64
#define LSEQ   1024
#define BB     2
#define DTOT   5312           // 2*DIN + 2*64 + 32 + 1024 + 32
#define ROWS   (BB*LSEQ)      // 2048
// column offsets inside zxbcdt
#define OFF_Z   0
#define OFF_X   2048
#define OFF_BR  4096
#define OFF_CR  4160
#define OFF_DT  4224
#define OFF_TH  4256
#define OFF_LAM 5280
#define NZX     4096          // z+x columns: single-pass bf16 MFMA
#define NREM    (DTOT - NZX)  // 1216 cols: 3-pass split-bf16 MFMA
// segmented scan
#define NSEG 8
#define SEG  (LSEQ / NSEG)    // 128

typedef short  s16x8 __attribute__((ext_vector_type(8)));
typedef float  f32x4 __attribute__((ext_vector_type(4)));
typedef unsigned short u16;

__device__ __forceinline__ unsigned int f2bf(float f) {   // RNE f32->bf16 (finite inputs)
    unsigned int u = __float_as_uint(f);
    u += 0x7fffu + ((u >> 16) & 1u);
    return u >> 16;
}
__device__ __forceinline__ unsigned int pk(float x, float y) {
    return f2bf(x) | (f2bf(y) << 16);
}
__device__ __forceinline__ void split1(float v, u16& hi, u16& lo) {
    const unsigned int h = f2bf(v);
    hi = (u16)h;
    lo = (u16)f2bf(v - __uint_as_float(h << 16));
}
__device__ __forceinline__ void split8(const float4 a, const float4 b,
                                       s16x8& hi, s16x8& lo) {
    u16 h_, l_;
    split1(a.x, h_, l_); hi[0] = (short)h_; lo[0] = (short)l_;
    split1(a.y, h_, l_); hi[1] = (short)h_; lo[1] = (short)l_;
    split1(a.z, h_, l_); hi[2] = (short)h_; lo[2] = (short)l_;
    split1(a.w, h_, l_); hi[3] = (short)h_; lo[3] = (short)l_;
    split1(b.x, h_, l_); hi[4] = (short)h_; lo[4] = (short)l_;
    split1(b.y, h_, l_); hi[5] = (short)h_; lo[5] = (short)l_;
    split1(b.z, h_, l_); hi[6] = (short)h_; lo[6] = (short)l_;
    split1(b.w, h_, l_); hi[7] = (short)h_; lo[7] = (short)l_;
}
__device__ __forceinline__ void cvt8(const float4 a, const float4 b, s16x8& hi) {
    hi[0] = (short)f2bf(a.x); hi[1] = (short)f2bf(a.y);
    hi[2] = (short)f2bf(a.z); hi[3] = (short)f2bf(a.w);
    hi[4] = (short)f2bf(b.x); hi[5] = (short)f2bf(b.y);
    hi[6] = (short)f2bf(b.z); hi[7] = (short)f2bf(b.w);
}

// HBM -> LDS direct 16B copy. Dest = wave-uniform base + lane*16 (m104).
typedef const __attribute__((address_space(1))) unsigned int glb_u32;
typedef __attribute__((address_space(3))) unsigned int lds_u32;
__device__ __forceinline__ void gload16(const void* g, void* l) {
    __builtin_amdgcn_global_load_lds((glb_u32*)g, (lds_u32*)l, 16, 0, 0);
}

// XOR swizzles (involutions, applied to global SOURCE chunk + LDS read index;
// rule #21: gload_lds dest stays lane-linear).
#define SWZ(row)  (((row) >> 1) & 3)   // 4 chunks/row  (BK=32 tiles)
#define SWZ8(row) (((row) >> 1) & 7)   // 8 chunks/row  (BK=64 tiles)

// ---------------------------------------------------------------------------
// merged conversion kernel: u (blocks 0..2047) and in_proj_w (rest).
// fp32 -> bf16 hi (+ residual lo). Bit-identical to previous two kernels.
// ---------------------------------------------------------------------------
#define CONV_U_BLOCKS (ROWS * DMODEL / 4 / 256)           // 2048
#define CONV_W_BLOCKS ((DTOT * DMODEL / 4) / 256)         // 5312
__global__ __launch_bounds__(256) void conv_uw(const float* __restrict__ usrc,
        const float* __restrict__ wsrc, u16* __restrict__ u_hi,
        u16* __restrict__ u_lo, u16* __restrict__ w_hi, u16* __restrict__ w_lo) {
    const int bid = blockIdx.x;
    if (bid < CONV_U_BLOCKS) {
        const size_t i4 = ((size_t)bid * 256 + threadIdx.x) * 4;
        const float4 v = *(const float4*)(usrc + i4);
        const unsigned int h0 = f2bf(v.x), h1 = f2bf(v.y), h2 = f2bf(v.z), h3 = f2bf(v.w);
        uint2 hw, lw;
        hw.x = h0 | (h1 << 16); hw.y = h2 | (h3 << 16);
        lw.x = pk(v.x - __uint_as_float(h0 << 16), v.y - __uint_as_float(h1 << 16));
        lw.y = pk(v.z - __uint_as_float(h2 << 16), v.w - __uint_as_float(h3 << 16));
        *(uint2*)(u_hi + i4) = hw;
        *(uint2*)(u_lo + i4) = lw;
    } else {
        const size_t i4 = ((size_t)(bid - CONV_U_BLOCKS) * 256 + threadIdx.x) * 4;
        const float4 v = *(const float4*)(wsrc + i4);
        const unsigned int h0 = f2bf(v.x), h1 = f2bf(v.y), h2 = f2bf(v.z), h3 = f2bf(v.w);
        uint2 hw, lw;
        hw.x = h0 | (h1 << 16); hw.y = h2 | (h3 << 16);
        lw.x = pk(v.x - __uint_as_float(h0 << 16), v.y - __uint_as_float(h1 << 16));
        lw.y = pk(v.z - __uint_as_float(h2 << 16), v.w - __uint_as_float(h3 << 16));
        *(uint2*)(w_hi + i4) = hw;
        if ((i4 >> 10) >= NZX)
            *(uint2*)(w_lo + (i4 - (size_t)NZX * DMODEL)) = lw;
    }
}

// ---------------------------------------------------------------------------
// bf16 MFMA GEMM, z/x block. BK=64: 8 gloads + 32 MFMA + ONE barrier per
// K-tile (halves the barrier-drain count vs BK=32). LDS 64KB -> 2 blk/CU.
// ---------------------------------------------------------------------------
__global__ __launch_bounds__(256) void mfma_gemm_zx(const u16* __restrict__ uA_,
                                                    const u16* __restrict__ uW,
                                                    float* __restrict__ zx) {
    __shared__ u16 Al[2][128 * 64];
    __shared__ u16 Bl[2][128 * 64];
    const int tid = threadIdx.x;
    const int m0 = blockIdx.y * 128, n0 = blockIdx.x * 128;
    const int lane = tid & 63, wave = tid >> 6;
    const int wr = wave >> 1, wc = wave & 1;
    const int lr = lane >> 4, lc = lane & 15;
    const int sr = tid >> 3;                               // staging row 0..31
    const int sc = (((tid & 7) ^ ((tid >> 4) & 7)) * 8);   // pre-swizzled chunk

    f32x4 acc[4][4] = {};

    const u16* pA = uA_ + (size_t)(m0 + sr) * DMODEL + sc;
    const u16* pB = uW  + (size_t)(n0 + sr) * DMODEL + sc;

#define STAGE_ZX(buf, k0) {                                                   \
        gload16(pA + (k0),                        &Al[buf][tid * 8]);         \
        gload16(pA + (k0) + (size_t)32 * DMODEL,  &Al[buf][tid * 8 + 2048]);  \
        gload16(pA + (k0) + (size_t)64 * DMODEL,  &Al[buf][tid * 8 + 4096]);  \
        gload16(pA + (k0) + (size_t)96 * DMODEL,  &Al[buf][tid * 8 + 6144]);  \
        gload16(pB + (k0),                        &Bl[buf][tid * 8]);         \
        gload16(pB + (k0) + (size_t)32 * DMODEL,  &Bl[buf][tid * 8 + 2048]);  \
        gload16(pB + (k0) + (size_t)64 * DMODEL,  &Bl[buf][tid * 8 + 4096]);  \
        gload16(pB + (k0) + (size_t)96 * DMODEL,  &Bl[buf][tid * 8 + 6144]); }

    STAGE_ZX(0, 0);
    __syncthreads();
    int cur = 0;
    for (int k0 = 0; k0 < DMODEL; k0 += 64) {
        if (k0 + 64 < DMODEL) STAGE_ZX(cur ^ 1, k0 + 64);
        #pragma unroll
        for (int kk = 0; kk < 2; ++kk) {
            s16x8 af[4], bf[4];
            #pragma unroll
            for (int f = 0; f < 4; ++f) {
                const int ra = wr * 64 + f * 16 + lc;
                af[f] = *(const s16x8*)&Al[cur][ra * 64 + (((kk * 4 + lr) ^ SWZ8(ra)) * 8)];
                const int rb = wc * 64 + f * 16 + lc;
                bf[f] = *(const s16x8*)&Bl[cur][rb * 64 + (((kk * 4 + lr) ^ SWZ8(rb)) * 8)];
            }
            #pragma unroll
            for (int fm = 0; fm < 4; ++fm)
                #pragma unroll
                for (int fn = 0; fn < 4; ++fn)
                    acc[fm][fn] = __builtin_amdgcn_mfma_f32_16x16x32_bf16(
                        af[fm], bf[fn], acc[fm][fn], 0, 0, 0);
        }
        __syncthreads();
        cur ^= 1;
    }
#undef STAGE_ZX

    #pragma unroll
    for (int fm = 0; fm < 4; ++fm)
        #pragma unroll
        for (int fn = 0; fn < 4; ++fn) {
            const size_t col = n0 + wc * 64 + fn * 16 + lc;
            #pragma unroll
            for (int j = 0; j < 4; ++j) {
                const size_t row = m0 + wr * 64 + fm * 16 + lr * 4 + j;
                zx[row * DTOT + col] = acc[fm][fn][j];
            }
        }
}

// ---------------------------------------------------------------------------
// bf16 MFMA GEMM, 128x64 tile, BK=64: out = gn_bf @ wo_bf^T (LDS 48KB)
// ---------------------------------------------------------------------------
__global__ __launch_bounds__(256) void mfma_gemm_out(const u16* __restrict__ A,
                                                     const u16* __restrict__ B,
                                                     float* __restrict__ C,
                                                     int K, int ldc) {
    __shared__ u16 Als[2][128 * 64];
    __shared__ u16 Bls[2][64 * 64];
    const int tid = threadIdx.x;
    const int m0 = blockIdx.y * 128, n0 = blockIdx.x * 64;
    const int lane = tid & 63, wave = tid >> 6;
    const int wr = wave >> 1, wc = wave & 1;
    const int lr = lane >> 4, lc = lane & 15;
    const int sr = tid >> 3;
    const int sc = (((tid & 7) ^ ((tid >> 4) & 7)) * 8);

    f32x4 acc[4][2] = {};

    const u16* pA = A + (size_t)(m0 + sr) * K + sc;
    const u16* pB = B + (size_t)(n0 + sr) * K + sc;

#define STAGE_OUT(buf, k0) {                                                  \
        gload16(pA + (k0),                   &Als[buf][tid * 8]);             \
        gload16(pA + (k0) + (size_t)32 * K,  &Als[buf][tid * 8 + 2048]);      \
        gload16(pA + (k0) + (size_t)64 * K,  &Als[buf][tid * 8 + 4096]);      \
        gload16(pA + (k0) + (size_t)96 * K,  &Als[buf][tid * 8 + 6144]);      \
        gload16(pB + (k0),                   &Bls[buf][tid * 8]);             \
        gload16(pB + (k0) + (size_t)32 * K,  &Bls[buf][tid * 8 + 2048]); }

    STAGE_OUT(0, 0);
    __syncthreads();
    int cur = 0;
    for (int k0 = 0; k0 < K; k0 += 64) {
        if (k0 + 64 < K) STAGE_OUT(cur ^ 1, k0 + 64);
        #pragma unroll
        for (int kk = 0; kk < 2; ++kk) {
            s16x8 af[4], bf[2];
            #pragma unroll
            for (int f = 0; f < 4; ++f) {
                const int ra = wr * 64 + f * 16 + lc;
                af[f] = *(const s16x8*)&Als[cur][ra * 64 + (((kk * 4 + lr) ^ SWZ8(ra)) * 8)];
            }
            #pragma unroll
            for (int f = 0; f < 2; ++f) {
                const int rb = wc * 32 + f * 16 + lc;
                bf[f] = *(const s16x8*)&Bls[cur][rb * 64 + (((kk * 4 + lr) ^ SWZ8(rb)) * 8)];
            }
            #pragma unroll
            for (int fm = 0; fm < 4; ++fm)
                #pragma unroll
                for (int fn = 0; fn < 2; ++fn)
                    acc[fm][fn] = __builtin_amdgcn_mfma_f32_16x16x32_bf16(
                        af[fm], bf[fn], acc[fm][fn], 0, 0, 0);
        }
        __syncthreads();
        cur ^= 1;
    }
#undef STAGE_OUT

    #pragma unroll
    for (int fm = 0; fm < 4; ++fm)
        #pragma unroll
        for (int fn = 0; fn < 2; ++fn) {
            const size_t col = n0 + wc * 32 + fn * 16 + lc;
            #pragma unroll
            for (int j = 0; j < 4; ++j) {
                const size_t row = m0 + wr * 64 + fm * 16 + lr * 4 + j;
                C[row * (size_t)ldc + col] = acc[fm][fn][j];
            }
        }
}

// ---------------------------------------------------------------------------
// split-bf16 3-pass MFMA GEMM, sensitive columns (BK=32, 2-phase, swizzled)
// ---------------------------------------------------------------------------
__global__ __launch_bounds__(256) void mfma_gemm_rem3(const u16* __restrict__ uh,
        const u16* __restrict__ ul, const u16* __restrict__ wh,
        const u16* __restrict__ wl, float* __restrict__ zxr) {
    __shared__ u16 Ah[2][128 * 32], Alo[2][128 * 32];
    __shared__ u16 Bh[2][64 * 32],  Blo[2][64 * 32];
    const int tid = threadIdx.x;
    const int m0 = blockIdx.y * 128, n0 = blockIdx.x * 64;
    const int lane = tid & 63, wave = tid >> 6;
    const int wr = wave >> 1, wc = wave & 1;
    const int lr = lane >> 4, lc = lane & 15;
    const int sr = tid >> 2;
    const int sc = (((tid & 3) ^ SWZ(tid >> 2)) * 8);

    f32x4 acc[4][2] = {};

    const u16* pAh = uh + (size_t)(m0 + sr) * DMODEL + sc;
    const u16* pAl = ul + (size_t)(m0 + sr) * DMODEL + sc;
    const u16* pBh = wh + (size_t)(n0 + sr) * DMODEL + sc;
    const u16* pBl = wl + (size_t)(n0 + sr) * DMODEL + sc;

#define STAGE_R3(buf, k0) {                                                  \
        gload16(pAh + (k0), &Ah[buf][tid * 8]);                              \
        gload16(pAh + (k0) + (size_t)64 * DMODEL, &Ah[buf][tid * 8 + 2048]); \
        gload16(pAl + (k0), &Alo[buf][tid * 8]);                             \
        gload16(pAl + (k0) + (size_t)64 * DMODEL, &Alo[buf][tid * 8 + 2048]);\
        gload16(pBh + (k0), &Bh[buf][tid * 8]);                              \
        gload16(pBl + (k0), &Blo[buf][tid * 8]); }

    STAGE_R3(0, 0);
    __syncthreads();
    int cur = 0;
    for (int k0 = 0; k0 < DMODEL; k0 += 32) {
        if (k0 + 32 < DMODEL) STAGE_R3(cur ^ 1, k0 + 32);
        s16x8 ahf[4], alf[4], bhf[2], blf[2];
        #pragma unroll
        for (int f = 0; f < 4; ++f) {
            const int ra = wr * 64 + f * 16 + lc;
            const int oa = ra * 32 + ((lr ^ SWZ(ra)) * 8);
            ahf[f] = *(const s16x8*)&Ah[cur][oa];
            alf[f] = *(const s16x8*)&Alo[cur][oa];
        }
        #pragma unroll
        for (int f = 0; f < 2; ++f) {
            const int rb = wc * 32 + f * 16 + lc;
            const int ob = rb * 32 + ((lr ^ SWZ(rb)) * 8);
            bhf[f] = *(const s16x8*)&Bh[cur][ob];
            blf[f] = *(const s16x8*)&Blo[cur][ob];
        }
        #pragma unroll
        for (int fm = 0; fm < 4; ++fm)
            #pragma unroll
            for (int fn = 0; fn < 2; ++fn) {
                acc[fm][fn] = __builtin_amdgcn_mfma_f32_16x16x32_bf16(
                    ahf[fm], bhf[fn], acc[fm][fn], 0, 0, 0);
                acc[fm][fn] = __builtin_amdgcn_mfma_f32_16x16x32_bf16(
                    ahf[fm], blf[fn], acc[fm][fn], 0, 0, 0);
                acc[fm][fn] = __builtin_amdgcn_mfma_f32_16x16x32_bf16(
                    alf[fm], bhf[fn], acc[fm][fn], 0, 0, 0);
            }
        __syncthreads();
        cur ^= 1;
    }
#undef STAGE_R3

    #pragma unroll
    for (int fm = 0; fm < 4; ++fm)
        #pragma unroll
        for (int fn = 0; fn < 2; ++fn) {
            const size_t col = n0 + wc * 32 + fn * 16 + lc;
            #pragma unroll
            for (int j = 0; j < 4; ++j) {
                const size_t row = m0 + wr * 64 + fm * 16 + lr * 4 + j;
                zxr[row * DTOT + col] = acc[fm][fn][j];
            }
        }
}

// ---------------------------------------------------------------------------
// prep: RMS-norm Br/Cr; abg4 = (alpha, beta, gamma, beta'=(1-lam)*dt) in (b,h,l).
// ---------------------------------------------------------------------------
__global__ __launch_bounds__(64) void prep_kernel(const float* __restrict__ zx,
        const float* __restrict__ dt_bias, const float* __restrict__ A_log,
        const float* __restrict__ B_norm_w, const float* __restrict__ C_norm_w,
        float* __restrict__ Bg, float* __restrict__ Cg,
        float4* __restrict__ abg4) {
    const int bl = blockIdx.x;
    const int b = bl >> 10, l = bl & (LSEQ - 1);
    const int t  = threadIdx.x;
    const float* row = zx + (size_t)bl * DTOT;
    const float br = row[OFF_BR + t];
    const float cr = row[OFF_CR + t];
    float ssb = br * br, ssc = cr * cr;
    #pragma unroll
    for (int k = 1; k < 64; k <<= 1) { ssb += __shfl_xor(ssb, k); ssc += __shfl_xor(ssc, k); }
    const float scB = rsqrtf(ssb * (1.f / 64.f) + 1e-5f);
    const float scC = rsqrtf(ssc * (1.f / 64.f) + 1e-5f);
    Bg[(size_t)bl * 64 + t] = br * scB * B_norm_w[t];
    Cg[(size_t)bl * 64 + t] = cr * scC * C_norm_w[t];
    if (t < NH) {
        const float dtr = row[OFF_DT + t] + dt_bias[t];
        const float dt  = (dtr > 20.f) ? dtr : log1pf(expf(dtr));
        const float lamr = row[OFF_LAM + t];
        const float lam  = 1.f / (1.f + expf(-lamr));
        const float Ah   = -expf(A_log[t]);
        const float al   = expf(dt * Ah);
        const float bp   = (1.f - lam) * dt;            // beta' = b/a
        const size_t o = ((size_t)b * NH + t) * LSEQ + l;
        abg4[o] = make_float4(al, bp * al, lam * dt, bp);
    }
}

// ---------------------------------------------------------------------------
// cumsum of thr over L, per (b,h): 32 dims.
// ---------------------------------------------------------------------------
__global__ __launch_bounds__(256) void cumsum_kernel(const float* __restrict__ zx,
                                                     float* __restrict__ th_cs) {
    const int bh = blockIdx.x;
    const int b = bh >> 5, h = bh & 31;
    const int d = threadIdx.x & 31, seg = threadIdx.x >> 5;
    const float* base = zx + (size_t)b * LSEQ * DTOT + OFF_TH + h * 32 + d;
    float* out = th_cs + (size_t)b * LSEQ * 1024 + h * 32 + d;
    __shared__ float sums[8][33];
    const int l0 = seg * 128;
    float s = 0.f;
    #pragma unroll 4
    for (int i = 0; i < 128; ++i) s += base[(size_t)(l0 + i) * DTOT];
    sums[seg][d] = s;
    __syncthreads();
    float acc = 0.f;
    for (int s2 = 0; s2 < seg; ++s2) acc += sums[s2][d];
    #pragma unroll 4
    for (int i = 0; i < 128; ++i) {
        acc += base[(size_t)(l0 + i) * DTOT];
        out[(size_t)(l0 + i) * 1024] = acc;
    }
}

// ---------------------------------------------------------------------------
// rot: Bh/Ch = rot(broadcast(Bg/Cg)+bias). Brot/Crot layout (B,NH,L,DS).
// ---------------------------------------------------------------------------
__global__ __launch_bounds__(256) void rot_kernel(const float* __restrict__ th_cs,
        const float* __restrict__ Bg, const float* __restrict__ Cg,
        const float* __restrict__ B_bias, const float* __restrict__ C_bias,
        float* __restrict__ Brot, float* __restrict__ Crot) {
    const size_t idx = (size_t)blockIdx.x * 256 + threadIdx.x;
    const int j = (int)(idx & 31);
    const int h = (int)((idx >> 5) & 31);
    const size_t bl = idx >> 10;
    const int l = (int)(bl & (LSEQ - 1));
    const int b = (int)(bl >> 10);
    const float th = th_cs[idx];
    float s, c;
    sincosf(th, &s, &c);
    float v1 = Bg[bl * 64 + j]      + B_bias[h * 64 + j];
    float v2 = Bg[bl * 64 + 32 + j] + B_bias[h * 64 + 32 + j];
    const size_t ob = ((size_t)(b * NH + h) * LSEQ + l) * DS + j;
    Brot[ob]      = v1 * c - v2 * s;
    Brot[ob + 32] = v1 * s + v2 * c;
    v1 = Cg[bl * 64 + j]      + C_bias[h * 64 + j];
    v2 = Cg[bl * 64 + 32 + j] + C_bias[h * 64 + 32 + j];
    Crot[ob]      = v1 * c - v2 * s;
    Crot[ob + 32] = v1 * s + v2 * c;
}

// ---------------------------------------------------------------------------
// wcalc: per (b,h,seg): within-seg log-cumsum of alpha; emits
//   wbuf[t], Lbuf[t], aprod[s], bscale[s]  (round 13/15 derivation)
// ---------------------------------------------------------------------------
__global__ __launch_bounds__(64) void wcalc_kernel(const float4* __restrict__ abg4,
        float* __restrict__ wbuf, float* __restrict__ aprod,
        float* __restrict__ bscale, float* __restrict__ Lbuf) {
    const int bh = blockIdx.x;
    const int lane = threadIdx.x;
    const int seg = lane >> 3, sub = lane & 7;
    const int t0 = seg * SEG;
    const int sbase = t0 + sub * 16;
    const float4* ab = abg4 + (size_t)bh * LSEQ;

    float part = 0.f;
    #pragma unroll
    for (int i = 0; i < 16; ++i) part += logf(ab[sbase + i].x);
    float incl = part;
    #pragma unroll
    for (int d = 1; d < 8; d <<= 1) {
        const float v = __shfl_up(incl, d, 8);
        if (sub >= d) incl += v;
    }
    const float LE = __shfl(incl, 7, 8);
    float Lrun = incl - part;                // exclusive prefix

    for (int i = 0; i < 16; ++i) {
        const int s = sbase + i;
        const float4 A = ab[s];
        Lrun += logf(A.x);
        Lbuf[(size_t)bh * LSEQ + s] = Lrun;
        float w;
        if ((s & (SEG - 1)) == (SEG - 1)) w = A.z;
        else w = __expf(LE - Lrun) * (A.z + ab[s + 1].w);
        wbuf[(size_t)bh * LSEQ + s] = w;
    }
    if (sub == 0) {
        aprod[bh * NSEG + seg] = __expf(LE);
        bscale[bh * NSEG + seg] = (seg > 0) ? __expf(LE) * ab[t0].w : 0.f;
    }
}

// ---------------------------------------------------------------------------
// hseg_gemm: h_local_end[p,n] = sum_s wbuf_s * x_s[p] * B_s[n] (split-bf16 3-pass)
// ---------------------------------------------------------------------------
#define WK 136
__global__ __launch_bounds__(256) void hseg_gemm(const float* __restrict__ zx,
        const float* __restrict__ Brot, const float* __restrict__ wbuf,
        float* __restrict__ hseg) {
    __shared__ u16 XH[64][WK], XL[64][WK], BHs[64][WK], BLs[64][WK];
    const int blk = blockIdx.x;
    const int seg = blk & (NSEG - 1), bh = blk >> 3;
    const int b = bh >> 5, h = bh & 31;
    const int tid = threadIdx.x;

    {
        const int sIdx = tid >> 1, half = tid & 1;
        const int t = seg * SEG + sIdx;
        const float wv = wbuf[(size_t)bh * LSEQ + t];
        const float* xsrc = zx + ((size_t)b * LSEQ + t) * DTOT + OFF_X + h * 64 + half * 32;
        const float* bsrc = Brot + ((size_t)bh * LSEQ + t) * DS + half * 32;
        #pragma unroll
        for (int i = 0; i < 32; i += 4) {
            const float4 xv = *(const float4*)(xsrc + i);
            const float4 bv = *(const float4*)(bsrc + i);
            const int p0 = half * 32 + i;
            u16 hi, lo;
            split1(xv.x * wv, hi, lo); XH[p0 + 0][sIdx] = hi; XL[p0 + 0][sIdx] = lo;
            split1(xv.y * wv, hi, lo); XH[p0 + 1][sIdx] = hi; XL[p0 + 1][sIdx] = lo;
            split1(xv.z * wv, hi, lo); XH[p0 + 2][sIdx] = hi; XL[p0 + 2][sIdx] = lo;
            split1(xv.w * wv, hi, lo); XH[p0 + 3][sIdx] = hi; XL[p0 + 3][sIdx] = lo;
            split1(bv.x, hi, lo); BHs[p0 + 0][sIdx] = hi; BLs[p0 + 0][sIdx] = lo;
            split1(bv.y, hi, lo); BHs[p0 + 1][sIdx] = hi; BLs[p0 + 1][sIdx] = lo;
            split1(bv.z, hi, lo); BHs[p0 + 2][sIdx] = hi; BLs[p0 + 2][sIdx] = lo;
            split1(bv.w, hi, lo); BHs[p0 + 3][sIdx] = hi; BLs[p0 + 3][sIdx] = lo;
        }
    }
    __syncthreads();

    const int lane = tid & 63, wave = tid >> 6;
    const int wR = wave >> 1, wC = wave & 1;
    const int lr = lane >> 4, lc = lane & 15;

    f32x4 acc[2][2] = {};
    #pragma unroll
    for (int ks = 0; ks < 4; ++ks) {
        const int k0 = ks * 32;
        s16x8 xh[2], xl[2], bhf[2], blf[2];
        #pragma unroll
        for (int f = 0; f < 2; ++f) {
            const int pr = wR * 32 + f * 16 + lc;
            xh[f] = *(const s16x8*)&XH[pr][k0 + lr * 8];
            xl[f] = *(const s16x8*)&XL[pr][k0 + lr * 8];
            const int nr = wC * 32 + f * 16 + lc;
            bhf[f] = *(const s16x8*)&BHs[nr][k0 + lr * 8];
            blf[f] = *(const s16x8*)&BLs[nr][k0 + lr * 8];
        }
        #pragma unroll
        for (int fm = 0; fm < 2; ++fm)
            #pragma unroll
            for (int fn = 0; fn < 2; ++fn) {
                acc[fm][fn] = __builtin_amdgcn_mfma_f32_16x16x32_bf16(
                    xh[fm], bhf[fn], acc[fm][fn], 0, 0, 0);
                acc[fm][fn] = __builtin_amdgcn_mfma_f32_16x16x32_bf16(
                    xh[fm], blf[fn], acc[fm][fn], 0, 0, 0);
                acc[fm][fn] = __builtin_amdgcn_mfma_f32_16x16x32_bf16(
                    xl[fm], bhf[fn], acc[fm][fn], 0, 0, 0);
            }
    }

    float* hp = hseg + ((size_t)(bh * NSEG + seg) * HD) * DS;
    #pragma unroll
    for (int fm = 0; fm < 2; ++fm)
        #pragma unroll
        for (int fn = 0; fn < 2; ++fn) {
            const int n = wC * 32 + fn * 16 + lc;
            #pragma unroll
            for (int j = 0; j < 4; ++j) {
                const int p = wR * 32 + fm * 16 + lr * 4 + j;
                hp[p * DS + n] = acc[fm][fn][j];
            }
        }
}

// ---------------------------------------------------------------------------
// scan_fix: sequential over segments -> hseg becomes hstar per segment.
// ---------------------------------------------------------------------------
__global__ __launch_bounds__(256) void scan_fix(float* __restrict__ hseg,
        const float* __restrict__ aprod, const float* __restrict__ bscale,
        const float* __restrict__ zx, const float* __restrict__ Brot,
        const float4* __restrict__ abg4) {
    const int blk = blockIdx.x;          // (b,h,ptile): 256
    const int ptile = blk & 3, h = (blk >> 2) & 31, b = blk >> 7;
    const int tid = threadIdx.x;
    const int pl = tid >> 4, ng = tid & 15;
    const int p = ptile * 16 + pl;
    const int n0 = ng * 4;
    const size_t bh = (size_t)b * NH + h;

    float4 cur = make_float4(0.f, 0.f, 0.f, 0.f);
    #pragma unroll
    for (int s = 0; s < NSEG; ++s) {
        float* hp = hseg + (((bh * NSEG + s) * HD + p) * DS + n0);
        float4 tmp = *(const float4*)hp;     // local h_end (no boundary)
        float4 hst = cur;                    // hstar = h_start (+ r1 below)
        if (s > 0) {
            const float bs = bscale[bh * NSEG + s];          // aprod*beta'
            const float bp0 = abg4[bh * LSEQ + s * SEG].w;   // beta'_{t0}
            const int tm1 = s * SEG - 1;
            const float4 Bm = *(const float4*)(Brot + ((size_t)bh * LSEQ + tm1) * DS + n0);
            const float xm = zx[((size_t)b * LSEQ + tm1) * DTOT + OFF_X + h * HD + p];
            const float fb = bs * xm;
            const float f1 = bp0 * xm;
            tmp.x = fmaf(fb, Bm.x, tmp.x);
            tmp.y = fmaf(fb, Bm.y, tmp.y);
            tmp.z = fmaf(fb, Bm.z, tmp.z);
            tmp.w = fmaf(fb, Bm.w, tmp.w);
            hst.x = fmaf(f1, Bm.x, hst.x);
            hst.y = fmaf(f1, Bm.y, hst.y);
            hst.z = fmaf(f1, Bm.z, hst.z);
            hst.w = fmaf(f1, Bm.w, hst.w);
        }
        *(float4*)hp = hst;
        const float a = aprod[bh * NSEG + s];
        cur.x = fmaf(a, cur.x, tmp.x);
        cur.y = fmaf(a, cur.y, tmp.y);
        cur.z = fmaf(a, cur.z, tmp.z);
        cur.w = fmaf(a, cur.w, tmp.w);
    }
}

// ---------------------------------------------------------------------------
// ssd_y v3: C/B/H fragments from global (L2); Gw fp32 in LDS with D folded
// into the diagonal; X^T staged in LDS in two 64-step halves. 2 blocks/CU.
// ---------------------------------------------------------------------------
#define GWF 132
#define XTS 72
__global__ __launch_bounds__(256, 2) void ssd_y(const float* __restrict__ zx,
        const float* __restrict__ Brot, const float* __restrict__ Crot,
        const float4* __restrict__ abg4, const float* __restrict__ hseg,
        const float* __restrict__ Lbuf, const float* __restrict__ Dp,
        float* __restrict__ yb) {
    __shared__ float Gw[128 * GWF];
    __shared__ u16 XTh[64 * XTS];
    __shared__ float Ls[128], gbs[128], gms[128], eLs[128];

    const int blk = blockIdx.x;
    const int seg = blk & (NSEG - 1), bh = blk >> 3;
    const int b = bh >> 5, h = bh & 31;
    const int tid = threadIdx.x;
    const int t0 = seg * SEG;
    const int lane = tid & 63, wave = tid >> 6;
    const int wr = wave >> 1, wc = wave & 1;
    const int lr = lane >> 4, lc = lane & 15;

    if (tid < 128) {
        const int t = t0 + tid;
        const float4 A = abg4[(size_t)bh * LSEQ + t];
        const float Lv = Lbuf[(size_t)bh * LSEQ + t];
        Ls[tid] = Lv;
        gms[tid] = A.z;
        gbs[tid] = (tid < 127) ? A.z + abg4[(size_t)bh * LSEQ + t + 1].w : 0.f;
        eLs[tid] = __expf(Lv);
    }
    __syncthreads();

    const float* Cbase = Crot + ((size_t)bh * LSEQ + t0) * DS;
    const float* Bbase = Brot + ((size_t)bh * LSEQ + t0) * DS;
    const float* Hbase = hseg + ((size_t)(bh * NSEG + seg) * HD) * DS;
    const float* Xbase = zx + ((size_t)b * LSEQ + t0) * DTOT + OFF_X + h * 64;

    f32x4 accP[4][2] = {};
    f32x4 accG[4][4] = {};
    #pragma unroll
    for (int ks = 0; ks < 2; ++ks) {
        const int k0 = ks * 32 + lr * 8;
        s16x8 ch[4], cl4[4], bh4[4], bl4[4], hh2[2];
        #pragma unroll
        for (int f = 0; f < 4; ++f) {
            const int rowc = wr * 64 + f * 16 + lc;
            const float4 c0 = *(const float4*)(Cbase + (size_t)rowc * DS + k0);
            const float4 c1 = *(const float4*)(Cbase + (size_t)rowc * DS + k0 + 4);
            split8(c0, c1, ch[f], cl4[f]);
            const int rowb = wc * 64 + f * 16 + lc;
            const float4 b0 = *(const float4*)(Bbase + (size_t)rowb * DS + k0);
            const float4 b1 = *(const float4*)(Bbase + (size_t)rowb * DS + k0 + 4);
            split8(b0, b1, bh4[f], bl4[f]);
        }
        #pragma unroll
        for (int f = 0; f < 2; ++f) {
            const int rowp = wc * 32 + f * 16 + lc;
            const float4 h0 = *(const float4*)(Hbase + (size_t)rowp * DS + k0);
            const float4 h1 = *(const float4*)(Hbase + (size_t)rowp * DS + k0 + 4);
            cvt8(h0, h1, hh2[f]);
        }
        #pragma unroll
        for (int fm = 0; fm < 4; ++fm) {
            #pragma unroll
            for (int fn = 0; fn < 4; ++fn) {
                accG[fm][fn] = __builtin_amdgcn_mfma_f32_16x16x32_bf16(
                    ch[fm], bh4[fn], accG[fm][fn], 0, 0, 0);
                accG[fm][fn] = __builtin_amdgcn_mfma_f32_16x16x32_bf16(
                    ch[fm], bl4[fn], accG[fm][fn], 0, 0, 0);
                accG[fm][fn] = __builtin_amdgcn_mfma_f32_16x16x32_bf16(
                    cl4[fm], bh4[fn], accG[fm][fn], 0, 0, 0);
            }
            #pragma unroll
            for (int fn = 0; fn < 2; ++fn) {
                accP[fm][fn] = __builtin_amdgcn_mfma_f32_16x16x32_bf16(
                    ch[fm], hh2[fn], accP[fm][fn], 0, 0, 0);
                accP[fm][fn] = __builtin_amdgcn_mfma_f32_16x16x32_bf16(
                    cl4[fm], hh2[fn], accP[fm][fn], 0, 0, 0);
            }
        }
    }

    const float Dh = Dp[h];
    #pragma unroll
    for (int fm = 0; fm < 4; ++fm)
        #pragma unroll
        for (int fn = 0; fn < 4; ++fn)
            #pragma unroll
            for (int jj = 0; jj < 4; ++jj) {
                const int i = wr * 64 + fm * 16 + lr * 4 + jj;
                const int j = wc * 64 + fn * 16 + lc;
                float v;
                if (j < i)       v = accG[fm][fn][jj] * __expf(Ls[i] - Ls[j]) * gbs[j];
                else if (j == i) v = accG[fm][fn][jj] * gms[i] + Dh;
                else             v = 0.f;
                Gw[i * GWF + j] = v;
            }

    f32x4 accY[4][2];
    #pragma unroll
    for (int fm = 0; fm < 4; ++fm)
        #pragma unroll
        for (int fn = 0; fn < 2; ++fn)
            #pragma unroll
            for (int jj = 0; jj < 4; ++jj) {
                const int i = wr * 64 + fm * 16 + lr * 4 + jj;
                accY[fm][fn][jj] = eLs[i] * accP[fm][fn][jj];
            }

#define STAGE_XT(H) {                                                        \
        const int lp = tid >> 2, pq = (tid & 3) * 16;                        \
        const float* xs = Xbase + (size_t)((H) * 64 + lp) * DTOT + pq;       \
        _Pragma("unroll")                                                    \
        for (int i = 0; i < 16; i += 4) {                                    \
            const float4 xv = *(const float4*)(xs + i);                      \
            XTh[(pq + i + 0) * XTS + lp] = (u16)f2bf(xv.x);                  \
            XTh[(pq + i + 1) * XTS + lp] = (u16)f2bf(xv.y);                  \
            XTh[(pq + i + 2) * XTS + lp] = (u16)f2bf(xv.z);                  \
            XTh[(pq + i + 3) * XTS + lp] = (u16)f2bf(xv.w);                  \
        }                                                                    \
    }
    STAGE_XT(0);
    __syncthreads();

    #pragma unroll
    for (int ks = 0; ks < 4; ++ks) {
        if (ks == 2) {
            __syncthreads();
            STAGE_XT(1);
            __syncthreads();
        }
        const int k0 = ks * 32 + lr * 8;
        const int kl = (ks & 1) * 32 + lr * 8;
        s16x8 gh4[4], gl4[4], xf[2];
        #pragma unroll
        for (int f = 0; f < 4; ++f) {
            const int rowi = wr * 64 + f * 16 + lc;
            const float4 g0 = *(const float4*)&Gw[rowi * GWF + k0];
            const float4 g1 = *(const float4*)&Gw[rowi * GWF + k0 + 4];
            split8(g0, g1, gh4[f], gl4[f]);
        }
        #pragma unroll
        for (int f = 0; f < 2; ++f) {
            const int rowp = wc * 32 + f * 16 + lc;
            xf[f] = *(const s16x8*)&XTh[rowp * XTS + kl];
        }
        #pragma unroll
        for (int fm = 0; fm < 4; ++fm)
            #pragma unroll
            for (int fn = 0; fn < 2; ++fn) {
                accY[fm][fn] = __builtin_amdgcn_mfma_f32_16x16x32_bf16(
                    gh4[fm], xf[fn], accY[fm][fn], 0, 0, 0);
                accY[fm][fn] = __builtin_amdgcn_mfma_f32_16x16x32_bf16(
                    gl4[fm], xf[fn], accY[fm][fn], 0, 0, 0);
            }
    }
#undef STAGE_XT

    #pragma unroll
    for (int fm = 0; fm < 4; ++fm)
        #pragma unroll
        for (int fn = 0; fn < 2; ++fn) {
            const int p = wc * 32 + fn * 16 + lc;
            #pragma unroll
            for (int jj = 0; jj < 4; ++jj) {
                const int i = wr * 64 + fm * 16 + lr * 4 + jj;
                yb[((size_t)b * LSEQ + t0 + i) * DIN + h * 64 + p] = accY[fm][fn][jj];
            }
        }
}

// ---------------------------------------------------------------------------
// merged gate+RMS-norm (blocks 0..2047) and out_proj_w conversion (rest).
// ---------------------------------------------------------------------------
__global__ __launch_bounds__(256) void gate_convwo(const float* __restrict__ yb,
        const float* __restrict__ zx, const float* __restrict__ norm_w,
        u16* __restrict__ gnb, const float* __restrict__ wo_src,
        u16* __restrict__ wo_hi) {
    if (blockIdx.x < ROWS) {
        const int bl = blockIdx.x;
        const int tid = threadIdx.x;
        const float* yrow = yb + (size_t)bl * DIN;
        const float* zrow = zx + (size_t)bl * DTOT + OFF_Z;
        float g[8];
        float ss = 0.f;
        #pragma unroll
        for (int i = 0; i < 8; ++i) {
            const int c = tid + i * 256;
            const float yv = yrow[c];
            const float zv = zrow[c];
            const float sg = 1.f / (1.f + expf(-zv));
            const float gv = yv * zv * sg;
            g[i] = gv;
            ss += gv * gv;
        }
        #pragma unroll
        for (int k = 1; k < 64; k <<= 1) ss += __shfl_xor(ss, k);
        __shared__ float wsum[4];
        if ((tid & 63) == 0) wsum[tid >> 6] = ss;
        __syncthreads();
        ss = wsum[0] + wsum[1] + wsum[2] + wsum[3];
        const float sc = rsqrtf(ss * (1.f / 2048.f) + 1e-5f);
        #pragma unroll
        for (int i = 0; i < 8; ++i) {
            const int c = tid + i * 256;
            gnb[(size_t)bl * DIN + c] = (u16)f2bf(g[i] * sc * norm_w[c]);
        }
    } else {
        const size_t i4 = ((size_t)(blockIdx.x - ROWS) * 256 + threadIdx.x) * 4;
        const float4 v = *(const float4*)(wo_src + i4);
        uint2 hw;
        hw.x = pk(v.x, v.y); hw.y = pk(v.z, v.w);
        *(uint2*)(wo_hi + i4) = hw;
    }
}

// ---------------------------------------------------------------------------
extern "C" void kernel_launch(void* const* d_in, const int* in_sizes, int n_in,
                              void* d_out, int out_size, void* d_ws, size_t ws_size,
                              hipStream_t stream) {
    const float* u          = (const float*)d_in[0];
    const float* in_proj_w  = (const float*)d_in[1];
    const float* dt_bias    = (const float*)d_in[2];
    const float* A_log      = (const float*)d_in[3];
    const float* Dp         = (const float*)d_in[4];
    const float* B_norm_w   = (const float*)d_in[5];
    const float* C_norm_w   = (const float*)d_in[6];
    const float* B_bias     = (const float*)d_in[7];
    const float* C_bias     = (const float*)d_in[8];
    const float* norm_w     = (const float*)d_in[9];
    const float* out_proj_w = (const float*)d_in[10];
    float* out = (float*)d_out;

    float* p = (float*)d_ws;
    float* zx    = p; p += (size_t)ROWS * DTOT;
    float* th_cs = p; p += (size_t)ROWS * 1024;   // dead after rot -> hseg
    float* Brot  = p; p += (size_t)ROWS * 2048;   // doubles as bf16 scratch
    float* Crot  = p; p += (size_t)ROWS * 2048;
    float* Bg    = p; p += (size_t)ROWS * 64;     // dead after rot -> aprod/bscale/Lbuf
    float* Cg    = p; p += (size_t)ROWS * 64;     // dead after rot -> wbuf
    float4* abg4 = (float4*)p; p += (size_t)ROWS * NH * 4;
    float* yb    = p; p += (size_t)ROWS * 2048;
    float* hseg   = th_cs;
    float* aprod  = Bg;
    float* bscale = Bg + 512;
    float* Lbuf   = Bg + 2048;
    float* wbuf   = Cg;

    u16* u_bf = (u16*)Brot;
    u16* u_lo = u_bf + (size_t)ROWS * DMODEL;
    u16* w_bf = u_lo + (size_t)ROWS * DMODEL;
    u16* w_lo = w_bf + (size_t)DTOT * DMODEL;
    u16* gn_bf = (u16*)Brot;
    u16* wo_bf = gn_bf + (size_t)ROWS * DIN;

    conv_uw<<<CONV_U_BLOCKS + CONV_W_BLOCKS, 256, 0, stream>>>(
        u, in_proj_w, u_bf, u_lo, w_bf, w_lo);
    mfma_gemm_zx<<<dim3(NZX / 128, ROWS / 128), 256, 0, stream>>>(u_bf, w_bf, zx);
    mfma_gemm_rem3<<<dim3(NREM / 64, ROWS / 128), 256, 0, stream>>>(
        u_bf, u_lo, w_bf + (size_t)NZX * DMODEL, w_lo, zx + NZX);
    prep_kernel<<<ROWS, 64, 0, stream>>>(zx, dt_bias, A_log, B_norm_w, C_norm_w,
                                         Bg, Cg, abg4);
    cumsum_kernel<<<BB * NH, 256, 0, stream>>>(zx, th_cs);
    rot_kernel<<<(ROWS * 1024) / 256, 256, 0, stream>>>(th_cs, Bg, Cg, B_bias, C_bias,
                                                        Brot, Crot);
    wcalc_kernel<<<BB * NH, 64, 0, stream>>>(abg4, wbuf, aprod, bscale, Lbuf);
    hseg_gemm<<<BB * NH * NSEG, 256, 0, stream>>>(zx, Brot, wbuf, hseg);
    scan_fix<<<BB * NH * 4, 256, 0, stream>>>(hseg, aprod, bscale, zx, Brot, abg4);
    ssd_y<<<BB * NH * NSEG, 256, 0, stream>>>(zx, Brot, Crot, abg4, hseg, Lbuf, Dp, yb);
    gate_convwo<<<ROWS + (DMODEL * DIN / 4) / 256, 256, 0, stream>>>(
        yb, zx, norm_w, gn_bf, out_proj_w, wo_bf);
    mfma_gemm_out<<<dim3(DMODEL / 64, ROWS / 128), 256, 0, stream>>>(
        gn_bf, wo_bf, out, DIN, DMODEL);
}

// Round 21
// 183.184 us; speedup vs baseline: 1.9325x; 1.0214x over previous
//
#include <hip/hip_runtime.h>
#include <hip/hip_bf16.h>

// Problem constants
#define DMODEL 1024
#define DIN    2048
#define NH     32
#define HD     64
#define DS     64
#define LSEQ   1024
#define BB     2
#define DTOT   5312           // 2*DIN + 2*64 + 32 + 1024 + 32
#define ROWS   (BB*LSEQ)      // 2048
// column offsets inside zxbcdt
#define OFF_Z   0
#define OFF_X   2048
#define OFF_BR  4096
#define OFF_CR  4160
#define OFF_DT  4224
#define OFF_TH  4256
#define OFF_LAM 5280
#define NZX     4096          // z+x columns: single-pass bf16 MFMA
#define NREM    (DTOT - NZX)  // 1216 cols: 3-pass split-bf16 MFMA
// segmented scan
#define NSEG 8
#define SEG  (LSEQ / NSEG)    // 128

typedef short  s16x8 __attribute__((ext_vector_type(8)));
typedef float  f32x4 __attribute__((ext_vector_type(4)));
typedef unsigned short u16;

__device__ __forceinline__ unsigned int f2bf(float f) {   // RNE f32->bf16 (finite inputs)
    unsigned int u = __float_as_uint(f);
    u += 0x7fffu + ((u >> 16) & 1u);
    return u >> 16;
}
__device__ __forceinline__ unsigned int pk(float x, float y) {
    return f2bf(x) | (f2bf(y) << 16);
}
__device__ __forceinline__ void split1(float v, u16& hi, u16& lo) {
    const unsigned int h = f2bf(v);
    hi = (u16)h;
    lo = (u16)f2bf(v - __uint_as_float(h << 16));
}
__device__ __forceinline__ void split8(const float4 a, const float4 b,
                                       s16x8& hi, s16x8& lo) {
    u16 h_, l_;
    split1(a.x, h_, l_); hi[0] = (short)h_; lo[0] = (short)l_;
    split1(a.y, h_, l_); hi[1] = (short)h_; lo[1] = (short)l_;
    split1(a.z, h_, l_); hi[2] = (short)h_; lo[2] = (short)l_;
    split1(a.w, h_, l_); hi[3] = (short)h_; lo[3] = (short)l_;
    split1(b.x, h_, l_); hi[4] = (short)h_; lo[4] = (short)l_;
    split1(b.y, h_, l_); hi[5] = (short)h_; lo[5] = (short)l_;
    split1(b.z, h_, l_); hi[6] = (short)h_; lo[6] = (short)l_;
    split1(b.w, h_, l_); hi[7] = (short)h_; lo[7] = (short)l_;
}
__device__ __forceinline__ void cvt8(const float4 a, const float4 b, s16x8& hi) {
    hi[0] = (short)f2bf(a.x); hi[1] = (short)f2bf(a.y);
    hi[2] = (short)f2bf(a.z); hi[3] = (short)f2bf(a.w);
    hi[4] = (short)f2bf(b.x); hi[5] = (short)f2bf(b.y);
    hi[6] = (short)f2bf(b.z); hi[7] = (short)f2bf(b.w);
}

// HBM -> LDS direct 16B copy. Dest = wave-uniform base + lane*16 (m104).
typedef const __attribute__((address_space(1))) unsigned int glb_u32;
typedef __attribute__((address_space(3))) unsigned int lds_u32;
__device__ __forceinline__ void gload16(const void* g, void* l) {
    __builtin_amdgcn_global_load_lds((glb_u32*)g, (lds_u32*)l, 16, 0, 0);
}

// XOR swizzles (involutions; source chunk + LDS read index; rule #21).
#define SWZ(row)  (((row) >> 1) & 3)   // 4 chunks/row  (BK=32 tiles)
#define SWZ8(row) (((row) >> 1) & 7)   // 8 chunks/row  (BK=64 tiles)

// ---------------------------------------------------------------------------
// merged conversion kernel: u (blocks 0..2047) and in_proj_w (rest).
// ---------------------------------------------------------------------------
#define CONV_U_BLOCKS (ROWS * DMODEL / 4 / 256)           // 2048
#define CONV_W_BLOCKS ((DTOT * DMODEL / 4) / 256)         // 5312
__global__ __launch_bounds__(256) void conv_uw(const float* __restrict__ usrc,
        const float* __restrict__ wsrc, u16* __restrict__ u_hi,
        u16* __restrict__ u_lo, u16* __restrict__ w_hi, u16* __restrict__ w_lo) {
    const int bid = blockIdx.x;
    if (bid < CONV_U_BLOCKS) {
        const size_t i4 = ((size_t)bid * 256 + threadIdx.x) * 4;
        const float4 v = *(const float4*)(usrc + i4);
        const unsigned int h0 = f2bf(v.x), h1 = f2bf(v.y), h2 = f2bf(v.z), h3 = f2bf(v.w);
        uint2 hw, lw;
        hw.x = h0 | (h1 << 16); hw.y = h2 | (h3 << 16);
        lw.x = pk(v.x - __uint_as_float(h0 << 16), v.y - __uint_as_float(h1 << 16));
        lw.y = pk(v.z - __uint_as_float(h2 << 16), v.w - __uint_as_float(h3 << 16));
        *(uint2*)(u_hi + i4) = hw;
        *(uint2*)(u_lo + i4) = lw;
    } else {
        const size_t i4 = ((size_t)(bid - CONV_U_BLOCKS) * 256 + threadIdx.x) * 4;
        const float4 v = *(const float4*)(wsrc + i4);
        const unsigned int h0 = f2bf(v.x), h1 = f2bf(v.y), h2 = f2bf(v.z), h3 = f2bf(v.w);
        uint2 hw, lw;
        hw.x = h0 | (h1 << 16); hw.y = h2 | (h3 << 16);
        lw.x = pk(v.x - __uint_as_float(h0 << 16), v.y - __uint_as_float(h1 << 16));
        lw.y = pk(v.z - __uint_as_float(h2 << 16), v.w - __uint_as_float(h3 << 16));
        *(uint2*)(w_hi + i4) = hw;
        if ((i4 >> 10) >= NZX)
            *(uint2*)(w_lo + (i4 - (size_t)NZX * DMODEL)) = lw;
    }
}

// ---------------------------------------------------------------------------
// bf16 MFMA GEMM, z/x block. BK=64: one barrier per K-tile. LDS 64KB.
// ---------------------------------------------------------------------------
__global__ __launch_bounds__(256) void mfma_gemm_zx(const u16* __restrict__ uA_,
                                                    const u16* __restrict__ uW,
                                                    float* __restrict__ zx) {
    __shared__ u16 Al[2][128 * 64];
    __shared__ u16 Bl[2][128 * 64];
    const int tid = threadIdx.x;
    const int m0 = blockIdx.y * 128, n0 = blockIdx.x * 128;
    const int lane = tid & 63, wave = tid >> 6;
    const int wr = wave >> 1, wc = wave & 1;
    const int lr = lane >> 4, lc = lane & 15;
    const int sr = tid >> 3;                               // staging row 0..31
    const int sc = (((tid & 7) ^ ((tid >> 4) & 7)) * 8);   // pre-swizzled chunk

    f32x4 acc[4][4] = {};

    const u16* pA = uA_ + (size_t)(m0 + sr) * DMODEL + sc;
    const u16* pB = uW  + (size_t)(n0 + sr) * DMODEL + sc;

#define STAGE_ZX(buf, k0) {                                                   \
        gload16(pA + (k0),                        &Al[buf][tid * 8]);         \
        gload16(pA + (k0) + (size_t)32 * DMODEL,  &Al[buf][tid * 8 + 2048]);  \
        gload16(pA + (k0) + (size_t)64 * DMODEL,  &Al[buf][tid * 8 + 4096]);  \
        gload16(pA + (k0) + (size_t)96 * DMODEL,  &Al[buf][tid * 8 + 6144]);  \
        gload16(pB + (k0),                        &Bl[buf][tid * 8]);         \
        gload16(pB + (k0) + (size_t)32 * DMODEL,  &Bl[buf][tid * 8 + 2048]);  \
        gload16(pB + (k0) + (size_t)64 * DMODEL,  &Bl[buf][tid * 8 + 4096]);  \
        gload16(pB + (k0) + (size_t)96 * DMODEL,  &Bl[buf][tid * 8 + 6144]); }

    STAGE_ZX(0, 0);
    __syncthreads();
    int cur = 0;
    for (int k0 = 0; k0 < DMODEL; k0 += 64) {
        if (k0 + 64 < DMODEL) STAGE_ZX(cur ^ 1, k0 + 64);
        #pragma unroll
        for (int kk = 0; kk < 2; ++kk) {
            s16x8 af[4], bf[4];
            #pragma unroll
            for (int f = 0; f < 4; ++f) {
                const int ra = wr * 64 + f * 16 + lc;
                af[f] = *(const s16x8*)&Al[cur][ra * 64 + (((kk * 4 + lr) ^ SWZ8(ra)) * 8)];
                const int rb = wc * 64 + f * 16 + lc;
                bf[f] = *(const s16x8*)&Bl[cur][rb * 64 + (((kk * 4 + lr) ^ SWZ8(rb)) * 8)];
            }
            #pragma unroll
            for (int fm = 0; fm < 4; ++fm)
                #pragma unroll
                for (int fn = 0; fn < 4; ++fn)
                    acc[fm][fn] = __builtin_amdgcn_mfma_f32_16x16x32_bf16(
                        af[fm], bf[fn], acc[fm][fn], 0, 0, 0);
        }
        __syncthreads();
        cur ^= 1;
    }
#undef STAGE_ZX

    #pragma unroll
    for (int fm = 0; fm < 4; ++fm)
        #pragma unroll
        for (int fn = 0; fn < 4; ++fn) {
            const size_t col = n0 + wc * 64 + fn * 16 + lc;
            #pragma unroll
            for (int j = 0; j < 4; ++j) {
                const size_t row = m0 + wr * 64 + fm * 16 + lr * 4 + j;
                zx[row * DTOT + col] = acc[fm][fn][j];
            }
        }
}

// ---------------------------------------------------------------------------
// bf16 MFMA GEMM, 128x64 tile, BK=64: out = gn_bf @ wo_bf^T (LDS 48KB)
// ---------------------------------------------------------------------------
__global__ __launch_bounds__(256) void mfma_gemm_out(const u16* __restrict__ A,
                                                     const u16* __restrict__ B,
                                                     float* __restrict__ C,
                                                     int K, int ldc) {
    __shared__ u16 Als[2][128 * 64];
    __shared__ u16 Bls[2][64 * 64];
    const int tid = threadIdx.x;
    const int m0 = blockIdx.y * 128, n0 = blockIdx.x * 64;
    const int lane = tid & 63, wave = tid >> 6;
    const int wr = wave >> 1, wc = wave & 1;
    const int lr = lane >> 4, lc = lane & 15;
    const int sr = tid >> 3;
    const int sc = (((tid & 7) ^ ((tid >> 4) & 7)) * 8);

    f32x4 acc[4][2] = {};

    const u16* pA = A + (size_t)(m0 + sr) * K + sc;
    const u16* pB = B + (size_t)(n0 + sr) * K + sc;

#define STAGE_OUT(buf, k0) {                                                  \
        gload16(pA + (k0),                   &Als[buf][tid * 8]);             \
        gload16(pA + (k0) + (size_t)32 * K,  &Als[buf][tid * 8 + 2048]);      \
        gload16(pA + (k0) + (size_t)64 * K,  &Als[buf][tid * 8 + 4096]);      \
        gload16(pA + (k0) + (size_t)96 * K,  &Als[buf][tid * 8 + 6144]);      \
        gload16(pB + (k0),                   &Bls[buf][tid * 8]);             \
        gload16(pB + (k0) + (size_t)32 * K,  &Bls[buf][tid * 8 + 2048]); }

    STAGE_OUT(0, 0);
    __syncthreads();
    int cur = 0;
    for (int k0 = 0; k0 < K; k0 += 64) {
        if (k0 + 64 < K) STAGE_OUT(cur ^ 1, k0 + 64);
        #pragma unroll
        for (int kk = 0; kk < 2; ++kk) {
            s16x8 af[4], bf[2];
            #pragma unroll
            for (int f = 0; f < 4; ++f) {
                const int ra = wr * 64 + f * 16 + lc;
                af[f] = *(const s16x8*)&Als[cur][ra * 64 + (((kk * 4 + lr) ^ SWZ8(ra)) * 8)];
            }
            #pragma unroll
            for (int f = 0; f < 2; ++f) {
                const int rb = wc * 32 + f * 16 + lc;
                bf[f] = *(const s16x8*)&Bls[cur][rb * 64 + (((kk * 4 + lr) ^ SWZ8(rb)) * 8)];
            }
            #pragma unroll
            for (int fm = 0; fm < 4; ++fm)
                #pragma unroll
                for (int fn = 0; fn < 2; ++fn)
                    acc[fm][fn] = __builtin_amdgcn_mfma_f32_16x16x32_bf16(
                        af[fm], bf[fn], acc[fm][fn], 0, 0, 0);
        }
        __syncthreads();
        cur ^= 1;
    }
#undef STAGE_OUT

    #pragma unroll
    for (int fm = 0; fm < 4; ++fm)
        #pragma unroll
        for (int fn = 0; fn < 2; ++fn) {
            const size_t col = n0 + wc * 32 + fn * 16 + lc;
            #pragma unroll
            for (int j = 0; j < 4; ++j) {
                const size_t row = m0 + wr * 64 + fm * 16 + lr * 4 + j;
                C[row * (size_t)ldc + col] = acc[fm][fn][j];
            }
        }
}

// ---------------------------------------------------------------------------
// split-bf16 3-pass MFMA GEMM, sensitive columns (BK=32, 2-phase, swizzled)
// ---------------------------------------------------------------------------
__global__ __launch_bounds__(256) void mfma_gemm_rem3(const u16* __restrict__ uh,
        const u16* __restrict__ ul, const u16* __restrict__ wh,
        const u16* __restrict__ wl, float* __restrict__ zxr) {
    __shared__ u16 Ah[2][128 * 32], Alo[2][128 * 32];
    __shared__ u16 Bh[2][64 * 32],  Blo[2][64 * 32];
    const int tid = threadIdx.x;
    const int m0 = blockIdx.y * 128, n0 = blockIdx.x * 64;
    const int lane = tid & 63, wave = tid >> 6;
    const int wr = wave >> 1, wc = wave & 1;
    const int lr = lane >> 4, lc = lane & 15;
    const int sr = tid >> 2;
    const int sc = (((tid & 3) ^ SWZ(tid >> 2)) * 8);

    f32x4 acc[4][2] = {};

    const u16* pAh = uh + (size_t)(m0 + sr) * DMODEL + sc;
    const u16* pAl = ul + (size_t)(m0 + sr) * DMODEL + sc;
    const u16* pBh = wh + (size_t)(n0 + sr) * DMODEL + sc;
    const u16* pBl = wl + (size_t)(n0 + sr) * DMODEL + sc;

#define STAGE_R3(buf, k0) {                                                  \
        gload16(pAh + (k0), &Ah[buf][tid * 8]);                              \
        gload16(pAh + (k0) + (size_t)64 * DMODEL, &Ah[buf][tid * 8 + 2048]); \
        gload16(pAl + (k0), &Alo[buf][tid * 8]);                             \
        gload16(pAl + (k0) + (size_t)64 * DMODEL, &Alo[buf][tid * 8 + 2048]);\
        gload16(pBh + (k0), &Bh[buf][tid * 8]);                              \
        gload16(pBl + (k0), &Blo[buf][tid * 8]); }

    STAGE_R3(0, 0);
    __syncthreads();
    int cur = 0;
    for (int k0 = 0; k0 < DMODEL; k0 += 32) {
        if (k0 + 32 < DMODEL) STAGE_R3(cur ^ 1, k0 + 32);
        s16x8 ahf[4], alf[4], bhf[2], blf[2];
        #pragma unroll
        for (int f = 0; f < 4; ++f) {
            const int ra = wr * 64 + f * 16 + lc;
            const int oa = ra * 32 + ((lr ^ SWZ(ra)) * 8);
            ahf[f] = *(const s16x8*)&Ah[cur][oa];
            alf[f] = *(const s16x8*)&Alo[cur][oa];
        }
        #pragma unroll
        for (int f = 0; f < 2; ++f) {
            const int rb = wc * 32 + f * 16 + lc;
            const int ob = rb * 32 + ((lr ^ SWZ(rb)) * 8);
            bhf[f] = *(const s16x8*)&Bh[cur][ob];
            blf[f] = *(const s16x8*)&Blo[cur][ob];
        }
        #pragma unroll
        for (int fm = 0; fm < 4; ++fm)
            #pragma unroll
            for (int fn = 0; fn < 2; ++fn) {
                acc[fm][fn] = __builtin_amdgcn_mfma_f32_16x16x32_bf16(
                    ahf[fm], bhf[fn], acc[fm][fn], 0, 0, 0);
                acc[fm][fn] = __builtin_amdgcn_mfma_f32_16x16x32_bf16(
                    ahf[fm], blf[fn], acc[fm][fn], 0, 0, 0);
                acc[fm][fn] = __builtin_amdgcn_mfma_f32_16x16x32_bf16(
                    alf[fm], bhf[fn], acc[fm][fn], 0, 0, 0);
            }
        __syncthreads();
        cur ^= 1;
    }
#undef STAGE_R3

    #pragma unroll
    for (int fm = 0; fm < 4; ++fm)
        #pragma unroll
        for (int fn = 0; fn < 2; ++fn) {
            const size_t col = n0 + wc * 32 + fn * 16 + lc;
            #pragma unroll
            for (int j = 0; j < 4; ++j) {
                const size_t row = m0 + wr * 64 + fm * 16 + lr * 4 + j;
                zxr[row * DTOT + col] = acc[fm][fn][j];
            }
        }
}

// ---------------------------------------------------------------------------
// merged prep + cumsum (both only READ zx; outputs disjoint -> race-free).
// blocks 0..511: prep, 4 rows/block (one 64-lane wave per row).
// blocks 512..575: theta cumsum per (b,h).
// ---------------------------------------------------------------------------
__global__ __launch_bounds__(256) void prep_cumsum(const float* __restrict__ zx,
        const float* __restrict__ dt_bias, const float* __restrict__ A_log,
        const float* __restrict__ B_norm_w, const float* __restrict__ C_norm_w,
        float* __restrict__ Bg, float* __restrict__ Cg,
        float4* __restrict__ abg4, float* __restrict__ th_cs) {
    __shared__ float sums[8][33];
    const int bid = blockIdx.x;
    const int tid = threadIdx.x;
    if (bid < 512) {
        // ---- prep: row = bid*4 + wave; t = lane ----
        const int bl = bid * 4 + (tid >> 6);
        const int t  = tid & 63;
        const int b = bl >> 10, l = bl & (LSEQ - 1);
        const float* row = zx + (size_t)bl * DTOT;
        const float br = row[OFF_BR + t];
        const float cr = row[OFF_CR + t];
        float ssb = br * br, ssc = cr * cr;
        #pragma unroll
        for (int k = 1; k < 64; k <<= 1) { ssb += __shfl_xor(ssb, k); ssc += __shfl_xor(ssc, k); }
        const float scB = rsqrtf(ssb * (1.f / 64.f) + 1e-5f);
        const float scC = rsqrtf(ssc * (1.f / 64.f) + 1e-5f);
        Bg[(size_t)bl * 64 + t] = br * scB * B_norm_w[t];
        Cg[(size_t)bl * 64 + t] = cr * scC * C_norm_w[t];
        if (t < NH) {
            const float dtr = row[OFF_DT + t] + dt_bias[t];
            const float dt  = (dtr > 20.f) ? dtr : log1pf(expf(dtr));
            const float lamr = row[OFF_LAM + t];
            const float lam  = 1.f / (1.f + expf(-lamr));
            const float Ah   = -expf(A_log[t]);
            const float al   = expf(dt * Ah);
            const float bp   = (1.f - lam) * dt;        // beta' = b/a
            const size_t o = ((size_t)b * NH + t) * LSEQ + l;
            abg4[o] = make_float4(al, bp * al, lam * dt, bp);
        }
    } else {
        // ---- cumsum of theta over L for (b,h) = bid-512 ----
        const int bh = bid - 512;
        const int b = bh >> 5, h = bh & 31;
        const int d = tid & 31, seg = tid >> 5;
        const float* base = zx + (size_t)b * LSEQ * DTOT + OFF_TH + h * 32 + d;
        float* out = th_cs + (size_t)b * LSEQ * 1024 + h * 32 + d;
        const int l0 = seg * 128;
        float s = 0.f;
        #pragma unroll 4
        for (int i = 0; i < 128; ++i) s += base[(size_t)(l0 + i) * DTOT];
        sums[seg][d] = s;
        __syncthreads();
        float acc = 0.f;
        for (int s2 = 0; s2 < seg; ++s2) acc += sums[s2][d];
        #pragma unroll 4
        for (int i = 0; i < 128; ++i) {
            acc += base[(size_t)(l0 + i) * DTOT];
            out[(size_t)(l0 + i) * 1024] = acc;
        }
    }
}

// ---------------------------------------------------------------------------
// rot: Bh/Ch = rot(broadcast(Bg/Cg)+bias). Brot/Crot layout (B,NH,L,DS).
// ---------------------------------------------------------------------------
__global__ __launch_bounds__(256) void rot_kernel(const float* __restrict__ th_cs,
        const float* __restrict__ Bg, const float* __restrict__ Cg,
        const float* __restrict__ B_bias, const float* __restrict__ C_bias,
        float* __restrict__ Brot, float* __restrict__ Crot) {
    const size_t idx = (size_t)blockIdx.x * 256 + threadIdx.x;
    const int j = (int)(idx & 31);
    const int h = (int)((idx >> 5) & 31);
    const size_t bl = idx >> 10;
    const int l = (int)(bl & (LSEQ - 1));
    const int b = (int)(bl >> 10);
    const float th = th_cs[idx];
    float s, c;
    sincosf(th, &s, &c);
    float v1 = Bg[bl * 64 + j]      + B_bias[h * 64 + j];
    float v2 = Bg[bl * 64 + 32 + j] + B_bias[h * 64 + 32 + j];
    const size_t ob = ((size_t)(b * NH + h) * LSEQ + l) * DS + j;
    Brot[ob]      = v1 * c - v2 * s;
    Brot[ob + 32] = v1 * s + v2 * c;
    v1 = Cg[bl * 64 + j]      + C_bias[h * 64 + j];
    v2 = Cg[bl * 64 + 32 + j] + C_bias[h * 64 + 32 + j];
    Crot[ob]      = v1 * c - v2 * s;
    Crot[ob + 32] = v1 * s + v2 * c;
}

// ---------------------------------------------------------------------------
// wcalc: per (b,h,seg): within-seg log-cumsum of alpha; emits
//   wbuf[t], Lbuf[t], aprod[s], bscale[s]  (round 13/15 derivation)
// ---------------------------------------------------------------------------
__global__ __launch_bounds__(64) void wcalc_kernel(const float4* __restrict__ abg4,
        float* __restrict__ wbuf, float* __restrict__ aprod,
        float* __restrict__ bscale, float* __restrict__ Lbuf) {
    const int bh = blockIdx.x;
    const int lane = threadIdx.x;
    const int seg = lane >> 3, sub = lane & 7;
    const int t0 = seg * SEG;
    const int sbase = t0 + sub * 16;
    const float4* ab = abg4 + (size_t)bh * LSEQ;

    float part = 0.f;
    #pragma unroll
    for (int i = 0; i < 16; ++i) part += logf(ab[sbase + i].x);
    float incl = part;
    #pragma unroll
    for (int d = 1; d < 8; d <<= 1) {
        const float v = __shfl_up(incl, d, 8);
        if (sub >= d) incl += v;
    }
    const float LE = __shfl(incl, 7, 8);
    float Lrun = incl - part;                // exclusive prefix

    for (int i = 0; i < 16; ++i) {
        const int s = sbase + i;
        const float4 A = ab[s];
        Lrun += logf(A.x);
        Lbuf[(size_t)bh * LSEQ + s] = Lrun;
        float w;
        if ((s & (SEG - 1)) == (SEG - 1)) w = A.z;
        else w = __expf(LE - Lrun) * (A.z + ab[s + 1].w);
        wbuf[(size_t)bh * LSEQ + s] = w;
    }
    if (sub == 0) {
        aprod[bh * NSEG + seg] = __expf(LE);
        bscale[bh * NSEG + seg] = (seg > 0) ? __expf(LE) * ab[t0].w : 0.f;
    }
}

// ---------------------------------------------------------------------------
// hseg_gemm: h_local_end[p,n] = sum_s wbuf_s * x_s[p] * B_s[n] (split-bf16 3-pass)
// ---------------------------------------------------------------------------
#define WK 136
__global__ __launch_bounds__(256) void hseg_gemm(const float* __restrict__ zx,
        const float* __restrict__ Brot, const float* __restrict__ wbuf,
        float* __restrict__ hseg) {
    __shared__ u16 XH[64][WK], XL[64][WK], BHs[64][WK], BLs[64][WK];
    const int blk = blockIdx.x;
    const int seg = blk & (NSEG - 1), bh = blk >> 3;
    const int b = bh >> 5, h = bh & 31;
    const int tid = threadIdx.x;

    {
        const int sIdx = tid >> 1, half = tid & 1;
        const int t = seg * SEG + sIdx;
        const float wv = wbuf[(size_t)bh * LSEQ + t];
        const float* xsrc = zx + ((size_t)b * LSEQ + t) * DTOT + OFF_X + h * 64 + half * 32;
        const float* bsrc = Brot + ((size_t)bh * LSEQ + t) * DS + half * 32;
        #pragma unroll
        for (int i = 0; i < 32; i += 4) {
            const float4 xv = *(const float4*)(xsrc + i);
            const float4 bv = *(const float4*)(bsrc + i);
            const int p0 = half * 32 + i;
            u16 hi, lo;
            split1(xv.x * wv, hi, lo); XH[p0 + 0][sIdx] = hi; XL[p0 + 0][sIdx] = lo;
            split1(xv.y * wv, hi, lo); XH[p0 + 1][sIdx] = hi; XL[p0 + 1][sIdx] = lo;
            split1(xv.z * wv, hi, lo); XH[p0 + 2][sIdx] = hi; XL[p0 + 2][sIdx] = lo;
            split1(xv.w * wv, hi, lo); XH[p0 + 3][sIdx] = hi; XL[p0 + 3][sIdx] = lo;
            split1(bv.x, hi, lo); BHs[p0 + 0][sIdx] = hi; BLs[p0 + 0][sIdx] = lo;
            split1(bv.y, hi, lo); BHs[p0 + 1][sIdx] = hi; BLs[p0 + 1][sIdx] = lo;
            split1(bv.z, hi, lo); BHs[p0 + 2][sIdx] = hi; BLs[p0 + 2][sIdx] = lo;
            split1(bv.w, hi, lo); BHs[p0 + 3][sIdx] = hi; BLs[p0 + 3][sIdx] = lo;
        }
    }
    __syncthreads();

    const int lane = tid & 63, wave = tid >> 6;
    const int wR = wave >> 1, wC = wave & 1;
    const int lr = lane >> 4, lc = lane & 15;

    f32x4 acc[2][2] = {};
    #pragma unroll
    for (int ks = 0; ks < 4; ++ks) {
        const int k0 = ks * 32;
        s16x8 xh[2], xl[2], bhf[2], blf[2];
        #pragma unroll
        for (int f = 0; f < 2; ++f) {
            const int pr = wR * 32 + f * 16 + lc;
            xh[f] = *(const s16x8*)&XH[pr][k0 + lr * 8];
            xl[f] = *(const s16x8*)&XL[pr][k0 + lr * 8];
            const int nr = wC * 32 + f * 16 + lc;
            bhf[f] = *(const s16x8*)&BHs[nr][k0 + lr * 8];
            blf[f] = *(const s16x8*)&BLs[nr][k0 + lr * 8];
        }
        #pragma unroll
        for (int fm = 0; fm < 2; ++fm)
            #pragma unroll
            for (int fn = 0; fn < 2; ++fn) {
                acc[fm][fn] = __builtin_amdgcn_mfma_f32_16x16x32_bf16(
                    xh[fm], bhf[fn], acc[fm][fn], 0, 0, 0);
                acc[fm][fn] = __builtin_amdgcn_mfma_f32_16x16x32_bf16(
                    xh[fm], blf[fn], acc[fm][fn], 0, 0, 0);
                acc[fm][fn] = __builtin_amdgcn_mfma_f32_16x16x32_bf16(
                    xl[fm], bhf[fn], acc[fm][fn], 0, 0, 0);
            }
    }

    float* hp = hseg + ((size_t)(bh * NSEG + seg) * HD) * DS;
    #pragma unroll
    for (int fm = 0; fm < 2; ++fm)
        #pragma unroll
        for (int fn = 0; fn < 2; ++fn) {
            const int n = wC * 32 + fn * 16 + lc;
            #pragma unroll
            for (int j = 0; j < 4; ++j) {
                const int p = wR * 32 + fm * 16 + lr * 4 + j;
                hp[p * DS + n] = acc[fm][fn][j];
            }
        }
}

// ---------------------------------------------------------------------------
// scan_fix: sequential over segments -> hseg becomes hstar per segment.
// ---------------------------------------------------------------------------
__global__ __launch_bounds__(256) void scan_fix(float* __restrict__ hseg,
        const float* __restrict__ aprod, const float* __restrict__ bscale,
        const float* __restrict__ zx, const float* __restrict__ Brot,
        const float4* __restrict__ abg4) {
    const int blk = blockIdx.x;          // (b,h,ptile): 256
    const int ptile = blk & 3, h = (blk >> 2) & 31, b = blk >> 7;
    const int tid = threadIdx.x;
    const int pl = tid >> 4, ng = tid & 15;
    const int p = ptile * 16 + pl;
    const int n0 = ng * 4;
    const size_t bh = (size_t)b * NH + h;

    float4 cur = make_float4(0.f, 0.f, 0.f, 0.f);
    #pragma unroll
    for (int s = 0; s < NSEG; ++s) {
        float* hp = hseg + (((bh * NSEG + s) * HD + p) * DS + n0);
        float4 tmp = *(const float4*)hp;     // local h_end (no boundary)
        float4 hst = cur;                    // hstar = h_start (+ r1 below)
        if (s > 0) {
            const float bs = bscale[bh * NSEG + s];          // aprod*beta'
            const float bp0 = abg4[bh * LSEQ + s * SEG].w;   // beta'_{t0}
            const int tm1 = s * SEG - 1;
            const float4 Bm = *(const float4*)(Brot + ((size_t)bh * LSEQ + tm1) * DS + n0);
            const float xm = zx[((size_t)b * LSEQ + tm1) * DTOT + OFF_X + h * HD + p];
            const float fb = bs * xm;
            const float f1 = bp0 * xm;
            tmp.x = fmaf(fb, Bm.x, tmp.x);
            tmp.y = fmaf(fb, Bm.y, tmp.y);
            tmp.z = fmaf(fb, Bm.z, tmp.z);
            tmp.w = fmaf(fb, Bm.w, tmp.w);
            hst.x = fmaf(f1, Bm.x, hst.x);
            hst.y = fmaf(f1, Bm.y, hst.y);
            hst.z = fmaf(f1, Bm.z, hst.z);
            hst.w = fmaf(f1, Bm.w, hst.w);
        }
        *(float4*)hp = hst;
        const float a = aprod[bh * NSEG + s];
        cur.x = fmaf(a, cur.x, tmp.x);
        cur.y = fmaf(a, cur.y, tmp.y);
        cur.z = fmaf(a, cur.z, tmp.z);
        cur.w = fmaf(a, cur.w, tmp.w);
    }
}

// ---------------------------------------------------------------------------
// ssd_y v3: C/B/H fragments from global (L2); Gw fp32 in LDS with D folded
// into the diagonal; X^T staged in LDS in two 64-step halves. 2 blocks/CU.
// ---------------------------------------------------------------------------
#define GWF 132
#define XTS 72
__global__ __launch_bounds__(256, 2) void ssd_y(const float* __restrict__ zx,
        const float* __restrict__ Brot, const float* __restrict__ Crot,
        const float4* __restrict__ abg4, const float* __restrict__ hseg,
        const float* __restrict__ Lbuf, const float* __restrict__ Dp,
        float* __restrict__ yb) {
    __shared__ float Gw[128 * GWF];
    __shared__ u16 XTh[64 * XTS];
    __shared__ float Ls[128], gbs[128], gms[128], eLs[128];

    const int blk = blockIdx.x;
    const int seg = blk & (NSEG - 1), bh = blk >> 3;
    const int b = bh >> 5, h = bh & 31;
    const int tid = threadIdx.x;
    const int t0 = seg * SEG;
    const int lane = tid & 63, wave = tid >> 6;
    const int wr = wave >> 1, wc = wave & 1;
    const int lr = lane >> 4, lc = lane & 15;

    if (tid < 128) {
        const int t = t0 + tid;
        const float4 A = abg4[(size_t)bh * LSEQ + t];
        const float Lv = Lbuf[(size_t)bh * LSEQ + t];
        Ls[tid] = Lv;
        gms[tid] = A.z;
        gbs[tid] = (tid < 127) ? A.z + abg4[(size_t)bh * LSEQ + t + 1].w : 0.f;
        eLs[tid] = __expf(Lv);
    }
    __syncthreads();

    const float* Cbase = Crot + ((size_t)bh * LSEQ + t0) * DS;
    const float* Bbase = Brot + ((size_t)bh * LSEQ + t0) * DS;
    const float* Hbase = hseg + ((size_t)(bh * NSEG + seg) * HD) * DS;
    const float* Xbase = zx + ((size_t)b * LSEQ + t0) * DTOT + OFF_X + h * 64;

    f32x4 accP[4][2] = {};
    f32x4 accG[4][4] = {};
    #pragma unroll
    for (int ks = 0; ks < 2; ++ks) {
        const int k0 = ks * 32 + lr * 8;
        s16x8 ch[4], cl4[4], bh4[4], bl4[4], hh2[2];
        #pragma unroll
        for (int f = 0; f < 4; ++f) {
            const int rowc = wr * 64 + f * 16 + lc;
            const float4 c0 = *(const float4*)(Cbase + (size_t)rowc * DS + k0);
            const float4 c1 = *(const float4*)(Cbase + (size_t)rowc * DS + k0 + 4);
            split8(c0, c1, ch[f], cl4[f]);
            const int rowb = wc * 64 + f * 16 + lc;
            const float4 b0 = *(const float4*)(Bbase + (size_t)rowb * DS + k0);
            const float4 b1 = *(const float4*)(Bbase + (size_t)rowb * DS + k0 + 4);
            split8(b0, b1, bh4[f], bl4[f]);
        }
        #pragma unroll
        for (int f = 0; f < 2; ++f) {
            const int rowp = wc * 32 + f * 16 + lc;
            const float4 h0 = *(const float4*)(Hbase + (size_t)rowp * DS + k0);
            const float4 h1 = *(const float4*)(Hbase + (size_t)rowp * DS + k0 + 4);
            cvt8(h0, h1, hh2[f]);
        }
        #pragma unroll
        for (int fm = 0; fm < 4; ++fm) {
            #pragma unroll
            for (int fn = 0; fn < 4; ++fn) {
                accG[fm][fn] = __builtin_amdgcn_mfma_f32_16x16x32_bf16(
                    ch[fm], bh4[fn], accG[fm][fn], 0, 0, 0);
                accG[fm][fn] = __builtin_amdgcn_mfma_f32_16x16x32_bf16(
                    ch[fm], bl4[fn], accG[fm][fn], 0, 0, 0);
                accG[fm][fn] = __builtin_amdgcn_mfma_f32_16x16x32_bf16(
                    cl4[fm], bh4[fn], accG[fm][fn], 0, 0, 0);
            }
            #pragma unroll
            for (int fn = 0; fn < 2; ++fn) {
                accP[fm][fn] = __builtin_amdgcn_mfma_f32_16x16x32_bf16(
                    ch[fm], hh2[fn], accP[fm][fn], 0, 0, 0);
                accP[fm][fn] = __builtin_amdgcn_mfma_f32_16x16x32_bf16(
                    cl4[fm], hh2[fn], accP[fm][fn], 0, 0, 0);
            }
        }
    }

    const float Dh = Dp[h];
    #pragma unroll
    for (int fm = 0; fm < 4; ++fm)
        #pragma unroll
        for (int fn = 0; fn < 4; ++fn)
            #pragma unroll
            for (int jj = 0; jj < 4; ++jj) {
                const int i = wr * 64 + fm * 16 + lr * 4 + jj;
                const int j = wc * 64 + fn * 16 + lc;
                float v;
                if (j < i)       v = accG[fm][fn][jj] * __expf(Ls[i] - Ls[j]) * gbs[j];
                else if (j == i) v = accG[fm][fn][jj] * gms[i] + Dh;
                else             v = 0.f;
                Gw[i * GWF + j] = v;
            }

    f32x4 accY[4][2];
    #pragma unroll
    for (int fm = 0; fm < 4; ++fm)
        #pragma unroll
        for (int fn = 0; fn < 2; ++fn)
            #pragma unroll
            for (int jj = 0; jj < 4; ++jj) {
                const int i = wr * 64 + fm * 16 + lr * 4 + jj;
                accY[fm][fn][jj] = eLs[i] * accP[fm][fn][jj];
            }

#define STAGE_XT(H) {                                                        \
        const int lp = tid >> 2, pq = (tid & 3) * 16;                        \
        const float* xs = Xbase + (size_t)((H) * 64 + lp) * DTOT + pq;       \
        _Pragma("unroll")                                                    \
        for (int i = 0; i < 16; i += 4) {                                    \
            const float4 xv = *(const float4*)(xs + i);                      \
            XTh[(pq + i + 0) * XTS + lp] = (u16)f2bf(xv.x);                  \
            XTh[(pq + i + 1) * XTS + lp] = (u16)f2bf(xv.y);                  \
            XTh[(pq + i + 2) * XTS + lp] = (u16)f2bf(xv.z);                  \
            XTh[(pq + i + 3) * XTS + lp] = (u16)f2bf(xv.w);                  \
        }                                                                    \
    }
    STAGE_XT(0);
    __syncthreads();

    #pragma unroll
    for (int ks = 0; ks < 4; ++ks) {
        if (ks == 2) {
            __syncthreads();
            STAGE_XT(1);
            __syncthreads();
        }
        const int k0 = ks * 32 + lr * 8;
        const int kl = (ks & 1) * 32 + lr * 8;
        s16x8 gh4[4], gl4[4], xf[2];
        #pragma unroll
        for (int f = 0; f < 4; ++f) {
            const int rowi = wr * 64 + f * 16 + lc;
            const float4 g0 = *(const float4*)&Gw[rowi * GWF + k0];
            const float4 g1 = *(const float4*)&Gw[rowi * GWF + k0 + 4];
            split8(g0, g1, gh4[f], gl4[f]);
        }
        #pragma unroll
        for (int f = 0; f < 2; ++f) {
            const int rowp = wc * 32 + f * 16 + lc;
            xf[f] = *(const s16x8*)&XTh[rowp * XTS + kl];
        }
        #pragma unroll
        for (int fm = 0; fm < 4; ++fm)
            #pragma unroll
            for (int fn = 0; fn < 2; ++fn) {
                accY[fm][fn] = __builtin_amdgcn_mfma_f32_16x16x32_bf16(
                    gh4[fm], xf[fn], accY[fm][fn], 0, 0, 0);
                accY[fm][fn] = __builtin_amdgcn_mfma_f32_16x16x32_bf16(
                    gl4[fm], xf[fn], accY[fm][fn], 0, 0, 0);
            }
    }
#undef STAGE_XT

    #pragma unroll
    for (int fm = 0; fm < 4; ++fm)
        #pragma unroll
        for (int fn = 0; fn < 2; ++fn) {
            const int p = wc * 32 + fn * 16 + lc;
            #pragma unroll
            for (int jj = 0; jj < 4; ++jj) {
                const int i = wr * 64 + fm * 16 + lr * 4 + jj;
                yb[((size_t)b * LSEQ + t0 + i) * DIN + h * 64 + p] = accY[fm][fn][jj];
            }
        }
}

// ---------------------------------------------------------------------------
// merged gate+RMS-norm (blocks 0..2047) and out_proj_w conversion (rest).
// ---------------------------------------------------------------------------
__global__ __launch_bounds__(256) void gate_convwo(const float* __restrict__ yb,
        const float* __restrict__ zx, const float* __restrict__ norm_w,
        u16* __restrict__ gnb, const float* __restrict__ wo_src,
        u16* __restrict__ wo_hi) {
    if (blockIdx.x < ROWS) {
        const int bl = blockIdx.x;
        const int tid = threadIdx.x;
        const float* yrow = yb + (size_t)bl * DIN;
        const float* zrow = zx + (size_t)bl * DTOT + OFF_Z;
        float g[8];
        float ss = 0.f;
        #pragma unroll
        for (int i = 0; i < 8; ++i) {
            const int c = tid + i * 256;
            const float yv = yrow[c];
            const float zv = zrow[c];
            const float sg = 1.f / (1.f + expf(-zv));
            const float gv = yv * zv * sg;
            g[i] = gv;
            ss += gv * gv;
        }
        #pragma unroll
        for (int k = 1; k < 64; k <<= 1) ss += __shfl_xor(ss, k);
        __shared__ float wsum[4];
        if ((tid & 63) == 0) wsum[tid >> 6] = ss;
        __syncthreads();
        ss = wsum[0] + wsum[1] + wsum[2] + wsum[3];
        const float sc = rsqrtf(ss * (1.f / 2048.f) + 1e-5f);
        #pragma unroll
        for (int i = 0; i < 8; ++i) {
            const int c = tid + i * 256;
            gnb[(size_t)bl * DIN + c] = (u16)f2bf(g[i] * sc * norm_w[c]);
        }
    } else {
        const size_t i4 = ((size_t)(blockIdx.x - ROWS) * 256 + threadIdx.x) * 4;
        const float4 v = *(const float4*)(wo_src + i4);
        uint2 hw;
        hw.x = pk(v.x, v.y); hw.y = pk(v.z, v.w);
        *(uint2*)(wo_hi + i4) = hw;
    }
}

// ---------------------------------------------------------------------------
extern "C" void kernel_launch(void* const* d_in, const int* in_sizes, int n_in,
                              void* d_out, int out_size, void* d_ws, size_t ws_size,
                              hipStream_t stream) {
    const float* u          = (const float*)d_in[0];
    const float* in_proj_w  = (const float*)d_in[1];
    const float* dt_bias    = (const float*)d_in[2];
    const float* A_log      = (const float*)d_in[3];
    const float* Dp         = (const float*)d_in[4];
    const float* B_norm_w   = (const float*)d_in[5];
    const float* C_norm_w   = (const float*)d_in[6];
    const float* B_bias     = (const float*)d_in[7];
    const float* C_bias     = (const float*)d_in[8];
    const float* norm_w     = (const float*)d_in[9];
    const float* out_proj_w = (const float*)d_in[10];
    float* out = (float*)d_out;

    float* p = (float*)d_ws;
    float* zx    = p; p += (size_t)ROWS * DTOT;
    float* th_cs = p; p += (size_t)ROWS * 1024;   // dead after rot -> hseg
    float* Brot  = p; p += (size_t)ROWS * 2048;   // doubles as bf16 scratch
    float* Crot  = p; p += (size_t)ROWS * 2048;
    float* Bg    = p; p += (size_t)ROWS * 64;     // dead after rot -> aprod/bscale/Lbuf
    float* Cg    = p; p += (size_t)ROWS * 64;     // dead after rot -> wbuf
    float4* abg4 = (float4*)p; p += (size_t)ROWS * NH * 4;
    float* yb    = p; p += (size_t)ROWS * 2048;
    float* hseg   = th_cs;
    float* aprod  = Bg;
    float* bscale = Bg + 512;
    float* Lbuf   = Bg + 2048;
    float* wbuf   = Cg;

    u16* u_bf = (u16*)Brot;
    u16* u_lo = u_bf + (size_t)ROWS * DMODEL;
    u16* w_bf = u_lo + (size_t)ROWS * DMODEL;
    u16* w_lo = w_bf + (size_t)DTOT * DMODEL;
    u16* gn_bf = (u16*)Brot;
    u16* wo_bf = gn_bf + (size_t)ROWS * DIN;

    conv_uw<<<CONV_U_BLOCKS + CONV_W_BLOCKS, 256, 0, stream>>>(
        u, in_proj_w, u_bf, u_lo, w_bf, w_lo);
    mfma_gemm_zx<<<dim3(NZX / 128, ROWS / 128), 256, 0, stream>>>(u_bf, w_bf, zx);
    mfma_gemm_rem3<<<dim3(NREM / 64, ROWS / 128), 256, 0, stream>>>(
        u_bf, u_lo, w_bf + (size_t)NZX * DMODEL, w_lo, zx + NZX);
    prep_cumsum<<<512 + BB * NH, 256, 0, stream>>>(zx, dt_bias, A_log, B_norm_w,
                                                   C_norm_w, Bg, Cg, abg4, th_cs);
    rot_kernel<<<(ROWS * 1024) / 256, 256, 0, stream>>>(th_cs, Bg, Cg, B_bias, C_bias,
                                                        Brot, Crot);
    wcalc_kernel<<<BB * NH, 64, 0, stream>>>(abg4, wbuf, aprod, bscale, Lbuf);
    hseg_gemm<<<BB * NH * NSEG, 256, 0, stream>>>(zx, Brot, wbuf, hseg);
    scan_fix<<<BB * NH * 4, 256, 0, stream>>>(hseg, aprod, bscale, zx, Brot, abg4);
    ssd_y<<<BB * NH * NSEG, 256, 0, stream>>>(zx, Brot, Crot, abg4, hseg, Lbuf, Dp, yb);
    gate_convwo<<<ROWS + (DMODEL * DIN / 4) / 256, 256, 0, stream>>>(
        yb, zx, norm_w, gn_bf, out_proj_w, wo_bf);
    mfma_gemm_out<<<dim3(DMODEL / 64, ROWS / 128), 256, 0, stream>>>(
        gn_bf, wo_bf, out, DIN, DMODEL);
}